// Round 1
// baseline (803.919 us; speedup 1.0000x reference)
//
#include <hip/hip_runtime.h>
#include <cmath>

// ---------------------------------------------------------------------------
// TimestepVisionTransformer — Round 9: L2 transposed conv -> MFMA.
//   - k_ln1_apply now writes f16 NHWC padded XH2 [b][30][30][48]
//   - k_wcvt2 repacks Wd2 to f16 B-layout (dead L1 slice of Wr)
//   - k_conv2_mfma replaces k_convg<48,28,24,8> (77us, MfmaUtil=0)
//   - k_ln_pad_nhwc<56,24> bridges NHWC C2 -> planar padded XP3
// Everything else = r8 (verified).
// B=128, IMG=224, P=16, C_IN=1, E=96, H=4, d=24, NAX=14, N=196, M=B*N=25088
// ---------------------------------------------------------------------------

#define B_   128
#define NPATCH 196
#define M_ROWS (B_*NPATCH)     // 25088
#define E_   96
#define KS   4
#define SEG  49

typedef _Float16 half8 __attribute__((ext_vector_type(8)));
typedef _Float16 half4v __attribute__((ext_vector_type(4)));
typedef float f32x4 __attribute__((ext_vector_type(4)));

// ---------------------------------------------------------------------------
// time embedding
// ---------------------------------------------------------------------------
__global__ void k_time(const float* __restrict__ ts,
                       const float* __restrict__ Wt1, const float* __restrict__ bt1,
                       const float* __restrict__ Wt2, const float* __restrict__ bt2,
                       float* __restrict__ timev)
{
    __shared__ float h[128];
    float e = 0.69314718055994530942f * ts[0];
    float sv = sinf(e), cv = cosf(e);
    int t = threadIdx.x;
    float z = sv * Wt1[t] + cv * Wt1[128 + t] + bt1[t];
    h[t] = z / (1.f + expf(-z));
    __syncthreads();
    if (t < 96) {
        float acc = bt2[t];
        for (int j = 0; j < 128; ++j) acc += h[j] * Wt2[j * 96 + t];
        timev[t] = acc;
    }
}

// ---------------------------------------------------------------------------
// weight repack for convT layers 2..4 into per-parity float4 taps (fp32).
// (L1 slice [0,73728) is overwritten by k_wcvtc/k_wcvt2 — unused as fp32.)
// ---------------------------------------------------------------------------
__global__ void __launch_bounds__(256) k_repack(const float* __restrict__ w1,
                                                const float* __restrict__ w2,
                                                const float* __restrict__ w3,
                                                const float* __restrict__ w4f,
                                                float* __restrict__ wr)
{
    int i = blockIdx.x * 256 + threadIdx.x;
    const float* src; int CIN, COUT, e; float* dst;
    if      (i < 73728) { src = w1;  CIN = 96; COUT = 48; e = i;          dst = wr; }
    else if (i < 92160) { src = w2;  CIN = 48; COUT = 24; e = i - 73728;  dst = wr + 73728; }
    else if (i < 96768) { src = w3;  CIN = 24; COUT = 12; e = i - 92160;  dst = wr + 92160; }
    else if (i < 96960) { src = w4f; CIN = 12; COUT = 1;  e = i - 96768;  dst = wr + 96768; }
    else return;
    int per = CIN * COUT * 4;
    int par = e / per, rem = e % per;
    int ci = rem / (COUT * 4);
    int o  = (rem >> 2) % COUT;
    int j  = rem & 3;
    int ry = par >> 1, rx = par & 1;
    int wy = (j < 2)  ? (3 - ry) : (1 - ry);
    int wx = (j & 1)  ? (1 - rx) : (3 - rx);
    dst[e] = src[(ci * COUT + o) * 16 + wy * 4 + wx];
}

// ---------------------------------------------------------------------------
// conv1 weights -> f16 B-layout Wc[p][o][k=tap*96+ci]
// ---------------------------------------------------------------------------
__global__ void __launch_bounds__(256) k_wcvtc(const float* __restrict__ w1,
                                               _Float16* __restrict__ wc)
{
    int i = blockIdx.x * 256 + threadIdx.x;
    if (i >= 4 * 48 * 384) return;
    int p = i / 18432, rem = i % 18432;
    int o = rem / 384, k = rem % 384;
    int tap = k / 96, ci = k % 96;
    int ry = p >> 1, rx = p & 1;
    int wy = (tap < 2) ? (3 - ry) : (1 - ry);
    int wx = (tap & 1) ? (1 - rx) : (3 - rx);
    wc[i] = (_Float16)w1[(ci * 48 + o) * 16 + wy * 4 + wx];
}

// ---------------------------------------------------------------------------
// conv2 weights -> f16 B-layout Wc2[p][o(32, o>=24 zero)][k=tap*48+ci]
// ---------------------------------------------------------------------------
__global__ void __launch_bounds__(256) k_wcvt2(const float* __restrict__ w2,
                                               _Float16* __restrict__ wc2)
{
    int i = blockIdx.x * 256 + threadIdx.x;
    if (i >= 4 * 32 * 192) return;
    int p = i / 6144, rem = i % 6144;
    int o = rem / 192, k = rem % 192;
    int tap = k / 48, ci = k % 48;
    int ry = p >> 1, rx = p & 1;
    int wy = (tap < 2) ? (3 - ry) : (1 - ry);
    int wx = (tap & 1) ? (1 - rx) : (3 - rx);
    wc2[i] = (o < 24) ? (_Float16)w2[(ci * 24 + o) * 16 + wy * 4 + wx]
                      : (_Float16)0.f;
}

// ---------------------------------------------------------------------------
// transformer weight convert+transpose to half: Wt[n][k] = W[k][n]
// ---------------------------------------------------------------------------
__global__ void __launch_bounds__(256) k_wcvt(const float* __restrict__ qkv0,
                                              const float* __restrict__ qkv1,
                                              const float* __restrict__ wo0,
                                              const float* __restrict__ wo1,
                                              const float* __restrict__ wm0,
                                              const float* __restrict__ wm1,
                                              const float* __restrict__ wm2,
                                              _Float16* __restrict__ wh)
{
    int i = blockIdx.x * 256 + threadIdx.x;
    const float* src; int N; int e;
    if      (i < 27648)  { src = qkv0; N = 288; e = i; }
    else if (i < 55296)  { src = qkv1; N = 288; e = i - 27648; }
    else if (i < 64512)  { src = wo0;  N = 96;  e = i - 55296; }
    else if (i < 73728)  { src = wo1;  N = 96;  e = i - 64512; }
    else if (i < 82944)  { src = wm0;  N = 96;  e = i - 73728; }
    else if (i < 92160)  { src = wm1;  N = 96;  e = i - 82944; }
    else if (i < 101376) { src = wm2;  N = 96;  e = i - 92160; }
    else return;
    int n = e / 96, k = e % 96;
    wh[i] = (_Float16)src[k * N + n];
}

// ---------------------------------------------------------------------------
// zero the borders of xinh NHWC f16 [b][16][16][96]
// ---------------------------------------------------------------------------
__global__ void __launch_bounds__(256) k_zb_h(_Float16* __restrict__ xinh)
{
    int i = blockIdx.x * 256 + threadIdx.x;
    if (i >= 128 * 60 * 96) return;
    int b = i / 5760, r = i % 5760;
    int pos = r / 96, ch = r % 96;
    int py, px;
    if      (pos < 16) { py = 0;        px = pos; }
    else if (pos < 32) { py = 15;       px = pos - 16; }
    else if (pos < 46) { py = pos - 31; px = 0; }
    else               { py = pos - 45; px = 15; }
    xinh[((size_t)(b * 256) + py * 16 + px) * 96 + ch] = (_Float16)0.f;
}

// ---------------------------------------------------------------------------
// patch embed GEMM via f16 MFMA (r7, verified)
// ---------------------------------------------------------------------------
__global__ void __launch_bounds__(256) k_patch_mfma(const float* __restrict__ x,
                                                    const float* __restrict__ Wp,
                                                    const float* __restrict__ bp,
                                                    float* __restrict__ out)
{
    __shared__ __align__(16) _Float16 Ah[64 * 136];
    __shared__ __align__(16) _Float16 Wh[96 * 136];
    int t = threadIdx.x;
    int p0 = blockIdx.x * 64;
    int wave = t >> 6, lane = t & 63;
    int lm = lane & 15, quad = lane >> 4;
    f32x4 acc[6];
    #pragma unroll
    for (int nt = 0; nt < 6; ++nt) acc[nt] = (f32x4){0.f, 0.f, 0.f, 0.f};

    for (int kc = 0; kc < 2; ++kc) {
        __syncthreads();
        for (int i = t; i < 512; i += 256) {
            int lp = i >> 3, pyl = i & 7;
            int patch = p0 + lp;
            int b = patch / NPATCH, n = patch % NPATCH;
            int ny = n / 14, nx = n % 14;
            const float4* s4 = (const float4*)(x +
                ((size_t)(b * 224) + ny * 16 + kc * 8 + pyl) * 224 + nx * 16);
            float4 v0 = s4[0], v1 = s4[1], v2 = s4[2], v3 = s4[3];
            half8 h0, h1;
            h0[0]=(_Float16)v0.x; h0[1]=(_Float16)v0.y; h0[2]=(_Float16)v0.z; h0[3]=(_Float16)v0.w;
            h0[4]=(_Float16)v1.x; h0[5]=(_Float16)v1.y; h0[6]=(_Float16)v1.z; h0[7]=(_Float16)v1.w;
            h1[0]=(_Float16)v2.x; h1[1]=(_Float16)v2.y; h1[2]=(_Float16)v2.z; h1[3]=(_Float16)v2.w;
            h1[4]=(_Float16)v3.x; h1[5]=(_Float16)v3.y; h1[6]=(_Float16)v3.z; h1[7]=(_Float16)v3.w;
            *(half8*)&Ah[lp * 136 + pyl * 16]     = h0;
            *(half8*)&Ah[lp * 136 + pyl * 16 + 8] = h1;
        }
        for (int i = t; i < 1536; i += 256) {
            int e = i >> 4, s = i & 15;
            const float4* s4 = (const float4*)(Wp + e * 256 + kc * 128 + s * 8);
            float4 v0 = s4[0], v1 = s4[1];
            half8 h0;
            h0[0]=(_Float16)v0.x; h0[1]=(_Float16)v0.y; h0[2]=(_Float16)v0.z; h0[3]=(_Float16)v0.w;
            h0[4]=(_Float16)v1.x; h0[5]=(_Float16)v1.y; h0[6]=(_Float16)v1.z; h0[7]=(_Float16)v1.w;
            *(half8*)&Wh[e * 136 + s * 8] = h0;
        }
        __syncthreads();
        half8 af[4];
        #pragma unroll
        for (int ks = 0; ks < 4; ++ks)
            af[ks] = *(const half8*)&Ah[(wave * 16 + lm) * 136 + ks * 32 + quad * 8];
        #pragma unroll
        for (int ks = 0; ks < 4; ++ks) {
            #pragma unroll
            for (int nt = 0; nt < 6; ++nt) {
                half8 bf = *(const half8*)&Wh[(nt * 16 + lm) * 136 + ks * 32 + quad * 8];
                acc[nt] = __builtin_amdgcn_mfma_f32_16x16x32_f16(af[ks], bf, acc[nt], 0, 0, 0);
            }
        }
    }

    #pragma unroll
    for (int nt = 0; nt < 6; ++nt) {
        #pragma unroll
        for (int r = 0; r < 4; ++r) {
            int e = nt * 16 + lm;
            int lp = wave * 16 + quad * 4 + r;
            int patch = p0 + lp;
            int n = patch % NPATCH;
            int ny = n / 14, nx = n % 14;
            float yx = (float)(ny + nx);
            float v = acc[nt][r] + bp[e];
            float other = __shfl_xor(v, 1);
            float fi = (float)(e >> 1);
            float theta = expf(fi * (-2.f / 96.f) * 9.210340371976184f);
            float ang = theta * yx;
            float c = cosf(ang), s = sinf(ang);
            float outv = (lm & 1) ? (other * s + v * c) : (v * c - other * s);
            out[(size_t)patch * 96 + e] = outv;
        }
    }
}

// ---------------------------------------------------------------------------
// row LayerNorm over 96, wave per row
// ---------------------------------------------------------------------------
__global__ void __launch_bounds__(256) k_ln_row(const float* __restrict__ x,
                                                const float* __restrict__ g,
                                                const float* __restrict__ bv,
                                                float* __restrict__ out, int M)
{
    int lane = threadIdx.x & 63;
    int gw = (blockIdx.x * 256 + threadIdx.x) >> 6;
    int nw = (gridDim.x * 256) >> 6;
    float g0 = g[lane], b0 = bv[lane];
    float g1 = 0.f, b1 = 0.f;
    if (lane < 32) { g1 = g[64 + lane]; b1 = bv[64 + lane]; }
    for (int r = gw; r < M; r += nw) {
        const float* xr = x + (size_t)r * 96;
        float a = xr[lane];
        float c = (lane < 32) ? xr[64 + lane] : 0.f;
        float s = a + c, q = a * a + c * c;
        #pragma unroll
        for (int off = 32; off; off >>= 1) {
            s += __shfl_xor(s, off);
            q += __shfl_xor(q, off);
        }
        float mu = s * (1.f / 96.f);
        float rstd = rsqrtf(q * (1.f / 96.f) - mu * mu + 1e-5f);
        float* orow = out + (size_t)r * 96;
        orow[lane] = (a - mu) * rstd * g0 + b0;
        if (lane < 32) orow[64 + lane] = (c - mu) * rstd * g1 + b1;
    }
}

// ---------------------------------------------------------------------------
// MFMA row GEMM (r6, verified). OUTH: write f16 NHWC padded xinh instead.
// ---------------------------------------------------------------------------
template<int NCHUNKS, bool SILU, bool RES, bool ADDTIME, bool OUTH>
__global__ void __launch_bounds__(256) k_gemm_mfma(const float* __restrict__ A,
                                                   const _Float16* __restrict__ Wt,
                                                   const float* __restrict__ bias,
                                                   const float* __restrict__ res,
                                                   const float* __restrict__ timev,
                                                   float* __restrict__ out,
                                                   _Float16* __restrict__ outh)
{
    __shared__ __align__(16) _Float16 Ah[64 * 96];
    __shared__ __align__(16) _Float16 Wh[96 * 96];
    constexpr int NTOT = NCHUNKS * 96;
    int t = threadIdx.x;
    size_t row0 = (size_t)blockIdx.x * 64;

    const float4* a4 = (const float4*)(A + row0 * 96);
    for (int i = t; i < 1536; i += 256) {
        float4 v = a4[i];
        half4v hv;
        hv[0] = (_Float16)v.x; hv[1] = (_Float16)v.y;
        hv[2] = (_Float16)v.z; hv[3] = (_Float16)v.w;
        *(half4v*)&Ah[i * 4] = hv;
    }

    int wave = t >> 6, lane = t & 63;
    int lm = lane & 15, quad = lane >> 4;
    const f32x4 vzero = {0.f, 0.f, 0.f, 0.f};

    for (int ch = 0; ch < NCHUNKS; ++ch) {
        __syncthreads();
        {
            const uint4* src = (const uint4*)(Wt + (size_t)ch * 9216);
            uint4* dst = (uint4*)Wh;
            for (int i = t; i < 1152; i += 256) dst[i] = src[i];
        }
        __syncthreads();

        half8 af[3];
        #pragma unroll
        for (int ks = 0; ks < 3; ++ks)
            af[ks] = *(const half8*)&Ah[(wave * 16 + lm) * 96 + ks * 32 + quad * 8];

        f32x4 acc[6];
        #pragma unroll
        for (int ct = 0; ct < 6; ++ct) acc[ct] = vzero;

        #pragma unroll
        for (int ct = 0; ct < 6; ++ct) {
            #pragma unroll
            for (int ks = 0; ks < 3; ++ks) {
                half8 bf = *(const half8*)&Wh[(ct * 16 + lm) * 96 + ks * 32 + quad * 8];
                acc[ct] = __builtin_amdgcn_mfma_f32_16x16x32_f16(af[ks], bf, acc[ct], 0, 0, 0);
            }
        }

        #pragma unroll
        for (int ct = 0; ct < 6; ++ct) {
            #pragma unroll
            for (int r = 0; r < 4; ++r) {
                int lr = wave * 16 + quad * 4 + r;
                size_t row = row0 + lr;
                int lc = ct * 16 + lm;
                int col = ch * 96 + lc;
                float v = acc[ct][r] + bias[col];
                if constexpr (RES)     v += res[row * 96 + lc];
                if constexpr (ADDTIME) v += timev[lc];
                if constexpr (SILU)    v = v / (1.f + expf(-v));
                if constexpr (OUTH) {
                    size_t b = row / NPATCH; int n = (int)(row % NPATCH);
                    int ny = n / 14, nx = n % 14;
                    outh[((b * 256) + (1 + ny) * 16 + (1 + nx)) * 96 + col] = (_Float16)v;
                } else {
                    out[row * NTOT + col] = v;
                }
            }
        }
    }
}

// ---------------------------------------------------------------------------
// attention partials (r4, verified)
// ---------------------------------------------------------------------------
__global__ void __launch_bounds__(256) k_attn_part(const float* __restrict__ qkv,
                                                   float* __restrict__ part)
{
    int blk = blockIdx.x;
    int seg = blk % KS;
    int bh  = blk / KS;
    int b = bh >> 2, h = bh & 3;
    const float* base = qkv + (size_t)b * NPATCH * 288 + h * 24;
    __shared__ __align__(16) float KV[SEG * 48];
    int t = threadIdx.x;
    int k0 = seg * SEG;
    for (int i = t; i < SEG * 48; i += 256) {
        int k = i / 48, j = i % 48;
        KV[i] = base[(size_t)(k0 + k) * 288 + 96 + (j < 24 ? j : j + 72)];
    }
    __syncthreads();

    int q = (t < NPATCH) ? t : 0;
    float qv[24], acc[24];
    const float4* qrow = (const float4*)(base + (size_t)q * 288);
    #pragma unroll
    for (int j = 0; j < 6; ++j) {
        float4 v = qrow[j];
        qv[4 * j] = v.x; qv[4 * j + 1] = v.y; qv[4 * j + 2] = v.z; qv[4 * j + 3] = v.w;
    }
    #pragma unroll
    for (int d = 0; d < 24; ++d) acc[d] = 0.f;
    float sum = 0.f;
    const float scale = 0.2041241452319315f;

    #pragma unroll 2
    for (int k = 0; k < SEG; ++k) {
        const float4* kr = (const float4*)(&KV[k * 48]);
        float s0 = 0.f, s1 = 0.f, s2 = 0.f, s3 = 0.f;
        #pragma unroll
        for (int j = 0; j < 6; ++j) {
            float4 Kv = kr[j];
            s0 += qv[4 * j]     * Kv.x;
            s1 += qv[4 * j + 1] * Kv.y;
            s2 += qv[4 * j + 2] * Kv.z;
            s3 += qv[4 * j + 3] * Kv.w;
        }
        float s = (s0 + s1) + (s2 + s3);
        float p = __expf(fminf(s * scale, 60.f));
        sum += p;
        #pragma unroll
        for (int j = 0; j < 6; ++j) {
            float4 Vv = kr[6 + j];
            acc[4 * j]     += p * Vv.x;
            acc[4 * j + 1] += p * Vv.y;
            acc[4 * j + 2] += p * Vv.z;
            acc[4 * j + 3] += p * Vv.w;
        }
    }

    if (t < NPATCH) {
        float4* pp = (float4*)(part + ((size_t)blk * NPATCH + t) * 28);
        #pragma unroll
        for (int j = 0; j < 6; ++j) {
            float4 v;
            v.x = acc[4 * j]; v.y = acc[4 * j + 1];
            v.z = acc[4 * j + 2]; v.w = acc[4 * j + 3];
            pp[j] = v;
        }
        float4 sv; sv.x = sum; sv.y = 0.f; sv.z = 0.f; sv.w = 0.f;
        pp[6] = sv;
    }
}

// ---------------------------------------------------------------------------
// combine K-split partials
// ---------------------------------------------------------------------------
__global__ void __launch_bounds__(256) k_attn_comb(const float* __restrict__ part,
                                                   float* __restrict__ o)
{
    int idx = blockIdx.x * 256 + threadIdx.x;
    int bh = idx / NPATCH, q = idx % NPATCH;
    int b = bh >> 2, h = bh & 3;
    float acc[24];
    #pragma unroll
    for (int d = 0; d < 24; ++d) acc[d] = 0.f;
    float sum = 0.f;
    #pragma unroll
    for (int s = 0; s < KS; ++s) {
        const float4* pp = (const float4*)(part + ((size_t)(bh * KS + s) * NPATCH + q) * 28);
        #pragma unroll
        for (int j = 0; j < 6; ++j) {
            float4 v = pp[j];
            acc[4 * j]     += v.x;
            acc[4 * j + 1] += v.y;
            acc[4 * j + 2] += v.z;
            acc[4 * j + 3] += v.w;
        }
        sum += pp[6].x;
    }
    float inv = 1.f / sum;
    float4* orow = (float4*)(o + ((size_t)b * NPATCH + q) * 96 + h * 24);
    #pragma unroll
    for (int j = 0; j < 6; ++j) {
        float4 v;
        v.x = acc[4 * j] * inv; v.y = acc[4 * j + 1] * inv;
        v.z = acc[4 * j + 2] * inv; v.w = acc[4 * j + 3] * inv;
        orow[j] = v;
    }
}

// ---------------------------------------------------------------------------
// conv L1 via MFMA (r7, verified): xinh NHWC f16 padded -> C1 NHWC fp32
// ---------------------------------------------------------------------------
__global__ void __launch_bounds__(256) k_conv1(const _Float16* __restrict__ xinh,
                                               const _Float16* __restrict__ wc,
                                               const float* __restrict__ bias,
                                               float* __restrict__ c1)
{
    __shared__ __align__(16) _Float16 Ah[64 * 392];
    int t = threadIdx.x;
    int blk = blockIdx.x;
    int wave = t >> 6, lane = t & 63;
    int lm = lane & 15, quad = lane >> 4;

    for (int p = 0; p < 4; ++p) {
        int ry = p >> 1, rx = p & 1;
        __syncthreads();
        for (int i = t; i < 64 * 48; i += 256) {
            int lp = i / 48, rem = i % 48;
            int tap = rem / 12;
            int gp = blk * 64 + lp;
            int b = gp / NPATCH, pix = gp % NPATCH;
            int py = pix / 14, px = pix % 14;
            int row = py + ry + (tap >> 1), col = px + rx + (tap & 1);
            const uint4* src = (const uint4*)(xinh +
                ((size_t)(b * 256) + row * 16 + col) * 96 + (rem % 12) * 8);
            *(uint4*)&Ah[lp * 392 + rem * 8] = *src;
        }
        __syncthreads();

        half8 af[12];
        #pragma unroll
        for (int ks = 0; ks < 12; ++ks)
            af[ks] = *(const half8*)&Ah[(wave * 16 + lm) * 392 + ks * 32 + quad * 8];

        f32x4 acc[3];
        #pragma unroll
        for (int nt = 0; nt < 3; ++nt) acc[nt] = (f32x4){0.f, 0.f, 0.f, 0.f};

        #pragma unroll
        for (int ks = 0; ks < 12; ++ks) {
            #pragma unroll
            for (int nt = 0; nt < 3; ++nt) {
                half8 bf = *(const half8*)&wc[((size_t)(p * 48 + nt * 16 + lm)) * 384
                                              + ks * 32 + quad * 8];
                acc[nt] = __builtin_amdgcn_mfma_f32_16x16x32_f16(af[ks], bf, acc[nt], 0, 0, 0);
            }
        }

        #pragma unroll
        for (int nt = 0; nt < 3; ++nt) {
            #pragma unroll
            for (int r = 0; r < 4; ++r) {
                int o = nt * 16 + lm;
                int lp = wave * 16 + quad * 4 + r;
                int gp = blk * 64 + lp;
                int b = gp / NPATCH, pix = gp % NPATCH;
                int py = pix / 14, px = pix % 14;
                int oy = 2 * py + ry, ox = 2 * px + rx;
                c1[((size_t)(b * 28 + oy) * 28 + ox) * 48 + o] = acc[nt][r] + bias[o];
            }
        }
    }
}

// ---------------------------------------------------------------------------
// L1 LN stats: one wave per (b,ch) over NHWC C1 -> stat[b*48+ch] = {mu,rstd}
// grid 1536 x 256 (4 waves/block).
// ---------------------------------------------------------------------------
__global__ void __launch_bounds__(256) k_ln1_stats(const float* __restrict__ c1,
                                                   float* __restrict__ stat)
{
    int idx = blockIdx.x * 4 + (threadIdx.x >> 6);   // b*48+ch
    int lane = threadIdx.x & 63;
    int b = idx / 48, ch = idx % 48;
    const float* base = c1 + (size_t)b * 784 * 48 + ch;
    float s = 0.f, q = 0.f;
    for (int pix = lane; pix < 784; pix += 64) {
        float v = base[(size_t)pix * 48];
        s += v; q += v * v;
    }
    #pragma unroll
    for (int off = 32; off; off >>= 1) {
        s += __shfl_xor(s, off);
        q += __shfl_xor(q, off);
    }
    if (lane == 0) {
        float mu = s * (1.f / 784.f);
        float rstd = rsqrtf(q * (1.f / 784.f) - mu * mu + 1e-5f);
        stat[idx * 2]     = mu;
        stat[idx * 2 + 1] = rstd;
    }
}

// ---------------------------------------------------------------------------
// L1 LN apply: NHWC C1 + stat -> f16 NHWC padded XH2 [b][30][30][48], silu.
// one thread per padded element, ch-fastest; grid 21600. Borders -> 0.
// ---------------------------------------------------------------------------
__global__ void __launch_bounds__(256) k_ln1_apply(const float* __restrict__ c1,
                                                   const float* __restrict__ stat,
                                                   const float* __restrict__ g,
                                                   const float* __restrict__ bv,
                                                   _Float16* __restrict__ xh)
{
    int i = blockIdx.x * 256 + threadIdx.x;          // ((b*900)+pos)*48 + ch
    if (i >= 128 * 900 * 48) return;
    int ch = i % 48;
    int t2 = i / 48;
    int pos = t2 % 900;
    int b = t2 / 900;
    int py = pos / 30, px = pos % 30;
    float v = 0.f;
    if (py >= 1 && py <= 28 && px >= 1 && px <= 28) {
        int j = (py - 1) * 28 + (px - 1);
        int plane = b * 48 + ch;
        float mu = stat[plane * 2], rstd = stat[plane * 2 + 1];
        float u = (c1[((size_t)b * 784 + j) * 48 + ch] - mu) * rstd * g[j] + bv[j];
        v = u / (1.f + expf(-u));
    }
    xh[i] = (_Float16)v;
}

// ---------------------------------------------------------------------------
// conv L2 via MFMA: XH2 NHWC f16 padded [b][30][30][48] -> C2 NHWC fp32
// [b][56][56][24]. Per parity: A = 64 pixels x K=192 (4 taps x 48 ci),
// B = Wc2[p][o(32)][192], 6 k-slices x 2 col-tiles of 16x16x32 f16 MFMA.
// ---------------------------------------------------------------------------
__global__ void __launch_bounds__(256) k_conv2_mfma(const _Float16* __restrict__ xh,
                                                    const _Float16* __restrict__ wc,
                                                    const float* __restrict__ bias,
                                                    float* __restrict__ c2)
{
    __shared__ __align__(16) _Float16 Ah[64 * 200];   // 192 + 8 pad
    int t = threadIdx.x;
    int blk = blockIdx.x;
    int wave = t >> 6, lane = t & 63;
    int lm = lane & 15, quad = lane >> 4;

    for (int p = 0; p < 4; ++p) {
        int ry = p >> 1, rx = p & 1;
        __syncthreads();
        for (int i = t; i < 64 * 24; i += 256) {
            int lp = i / 24, c = i % 24;              // c = half8 chunk of K
            int tap = c / 6;
            int gp = blk * 64 + lp;
            int b = gp / 784, pix = gp % 784;
            int py = pix / 28, px = pix % 28;
            int row = py + ry + (tap >> 1), col = px + rx + (tap & 1);
            *(uint4*)&Ah[lp * 200 + c * 8] =
                *(const uint4*)(xh + ((size_t)(b * 900) + row * 30 + col) * 48
                                + (c % 6) * 8);
        }
        __syncthreads();

        half8 af[6];
        #pragma unroll
        for (int ks = 0; ks < 6; ++ks)
            af[ks] = *(const half8*)&Ah[(wave * 16 + lm) * 200 + ks * 32 + quad * 8];

        f32x4 acc[2];
        acc[0] = (f32x4){0.f, 0.f, 0.f, 0.f};
        acc[1] = (f32x4){0.f, 0.f, 0.f, 0.f};

        #pragma unroll
        for (int ks = 0; ks < 6; ++ks) {
            #pragma unroll
            for (int ct = 0; ct < 2; ++ct) {
                half8 bf = *(const half8*)&wc[((size_t)(p * 32 + ct * 16 + lm)) * 192
                                              + ks * 32 + quad * 8];
                acc[ct] = __builtin_amdgcn_mfma_f32_16x16x32_f16(af[ks], bf, acc[ct], 0, 0, 0);
            }
        }

        #pragma unroll
        for (int ct = 0; ct < 2; ++ct) {
            int o = ct * 16 + lm;
            if (o < 24) {
                #pragma unroll
                for (int r = 0; r < 4; ++r) {
                    int lp = wave * 16 + quad * 4 + r;
                    int gp = blk * 64 + lp;
                    int b = gp / 784, pix = gp % 784;
                    int py = pix / 28, px = pix % 28;
                    int oy = 2 * py + ry, ox = 2 * px + rx;
                    c2[((size_t)(b * 56 + oy) * 56 + ox) * 24 + o] = acc[ct][r] + bias[o];
                }
            }
        }
    }
}

// ---------------------------------------------------------------------------
// transposed conv (planar, r5-measured config) — L3
// ---------------------------------------------------------------------------
template<int CIN, int HIN, int COUT, int G>
__global__ void __launch_bounds__(256) k_convg(const float* __restrict__ xp,
                                               const float* __restrict__ wr,
                                               const float* __restrict__ bias,
                                               float* __restrict__ out)
{
    constexpr int HP = HIN + 2;
    constexpr int HO = 2 * HIN;
    constexpr int NPB = (B_ * HIN * HIN) / 256;
    int pb = blockIdx.x % NPB;
    int z  = blockIdx.x / NPB;
    int og = z % (COUT / G);
    int ry = z / (COUT / G);
    int o0 = og * G;
    int rem = pb * 256 + threadIdx.x;
    int b   = rem / (HIN * HIN);
    int pix = rem % (HIN * HIN);
    int py = pix / HIN, px = pix % HIN;
    const float* xb = xp + ((size_t)b * CIN) * (HP * HP) + (py + ry) * HP + px;
    const float4* w4 = (const float4*)wr;
    float acc0[G], acc1[G];
    #pragma unroll
    for (int o = 0; o < G; ++o) { acc0[o] = 0.f; acc1[o] = 0.f; }
    float f00 = xb[0], f01 = xb[1], f02 = xb[2];
    float f10 = xb[HP], f11 = xb[HP + 1], f12 = xb[HP + 2];
    for (int ci = 0; ci < CIN; ++ci) {
        int cn = (ci + 1 < CIN) ? (ci + 1) : (CIN - 1);
        const float* xn = xb + (size_t)cn * (HP * HP);
        float n00 = xn[0], n01 = xn[1], n02 = xn[2];
        float n10 = xn[HP], n11 = xn[HP + 1], n12 = xn[HP + 2];
        const float4* w0 = w4 + ((size_t)(2 * ry) * CIN + ci) * COUT + o0;
        const float4* w1 = w0 + (size_t)CIN * COUT;
        #pragma unroll
        for (int o = 0; o < G; ++o) {
            float4 W0 = w0[o], W1 = w1[o];
            acc0[o] += f00 * W0.x + f01 * W0.y + f10 * W0.z + f11 * W0.w;
            acc1[o] += f01 * W1.x + f02 * W1.y + f11 * W1.z + f12 * W1.w;
        }
        f00 = n00; f01 = n01; f02 = n02; f10 = n10; f11 = n11; f12 = n12;
    }
    int oy = 2 * py + ry;
    #pragma unroll
    for (int o = 0; o < G; ++o) {
        float bb = bias[o0 + o];
        float2 v; v.x = acc0[o] + bb; v.y = acc1[o] + bb;
        *(float2*)(out + ((size_t)(b * COUT + o0 + o) * HO + oy) * HO + 2 * px) = v;
    }
}

// ---------------------------------------------------------------------------
// spatial LN, NHWC source -> planar padded output (L2 bridge)
// one block per (b,ch) plane; src stride C.
// ---------------------------------------------------------------------------
template<int H, int C>
__global__ void __launch_bounds__(256) k_ln_pad_nhwc(const float* __restrict__ cin,
                                                     const float* __restrict__ g,
                                                     const float* __restrict__ bv,
                                                     float* __restrict__ xp)
{
    constexpr int HW = H * H;
    constexpr int HP = H + 2;
    constexpr int HWP = HP * HP;
    int plane = blockIdx.x;                 // b*C + ch
    int b = plane / C, ch = plane % C;
    const float* src = cin + (size_t)b * HW * C + ch;
    float* dst = xp + (size_t)plane * HWP;
    int t = threadIdx.x;
    float s = 0.f, q = 0.f;
    for (int i = t; i < HW; i += 256) {
        float v = src[(size_t)i * C];
        s += v; q += v * v;
    }
    #pragma unroll
    for (int off = 32; off; off >>= 1) {
        s += __shfl_xor(s, off);
        q += __shfl_xor(q, off);
    }
    __shared__ float rs[8];
    int wave = t >> 6, lane = t & 63;
    if (lane == 0) { rs[wave] = s; rs[4 + wave] = q; }
    __syncthreads();
    float st = rs[0] + rs[1] + rs[2] + rs[3];
    float qt = rs[4] + rs[5] + rs[6] + rs[7];
    float mu = st / (float)HW;
    float rstd = rsqrtf(qt / (float)HW - mu * mu + 1e-5f);
    for (int i = t; i < HWP; i += 256) {
        int py = i / HP, px = i % HP;
        float v = 0.f;
        if (py >= 1 && py <= H && px >= 1 && px <= H) {
            int j = (py - 1) * H + (px - 1);
            float u = (src[(size_t)j * C] - mu) * rstd * g[j] + bv[j];
            v = u / (1.f + expf(-u));
        }
        dst[i] = v;
    }
}

// ---------------------------------------------------------------------------
// in-place spatial LN + affine + silu (L3 output)
// ---------------------------------------------------------------------------
template<int HW>
__global__ void __launch_bounds__(256) k_ln_spatial(float* __restrict__ f,
                                                    const float* __restrict__ g,
                                                    const float* __restrict__ bv)
{
    size_t base = (size_t)blockIdx.x * HW;
    int t = threadIdx.x;
    float s = 0.f, q = 0.f;
    for (int i = t; i < HW; i += 256) {
        float v = f[base + i];
        s += v; q += v * v;
    }
    #pragma unroll
    for (int off = 32; off; off >>= 1) {
        s += __shfl_xor(s, off);
        q += __shfl_xor(q, off);
    }
    __shared__ float rs[8];
    int wave = t >> 6, lane = t & 63;
    if (lane == 0) { rs[wave] = s; rs[4 + wave] = q; }
    __syncthreads();
    float st = rs[0] + rs[1] + rs[2] + rs[3];
    float qt = rs[4] + rs[5] + rs[6] + rs[7];
    float mu = st / (float)HW;
    float rstd = rsqrtf(qt / (float)HW - mu * mu + 1e-5f);
    for (int i = t; i < HW; i += 256) {
        float v = (f[base + i] - mu) * rstd * g[i] + bv[i];
        f[base + i] = v / (1.f + expf(-v));
    }
}

// ---------------------------------------------------------------------------
// final convT 12->1 (r4-measured 2-parity version)
// ---------------------------------------------------------------------------
__global__ void __launch_bounds__(256) k_conv_final(const float* __restrict__ x,
                                                    const float* __restrict__ wr,
                                                    const float* __restrict__ bias,
                                                    float* __restrict__ out)
{
    constexpr int HIN = 112, CIN = 12, HP2 = 12544;
    constexpr int NPB = (B_ * HIN * HIN) / 256;
    int pb = blockIdx.x % NPB;
    int ry = blockIdx.x / NPB;
    int rem = pb * 256 + threadIdx.x;
    int b   = rem / (HIN * HIN);
    int pix = rem % (HIN * HIN);
    int py = pix / HIN, px = pix % HIN;
    int r0 = py + ry - 1, r1 = r0 + 1;
    bool my0 = r0 >= 0, my1 = r1 < HIN;
    bool mx0 = px >= 1, mx2 = px + 1 < HIN;
    const float* xb = x + (size_t)b * CIN * HP2;
    const float4* w4 = (const float4*)wr;
    float acc0 = 0.f, acc1 = 0.f;
    #pragma unroll
    for (int ci = 0; ci < CIN; ++ci) {
        const float* xc = xb + ci * HP2;
        const float* xr0 = xc + r0 * HIN + px;
        const float* xr1 = xc + r1 * HIN + px;
        float g00 = (my0 && mx0) ? xr0[-1] : 0.f;
        float g01 = my0 ? xr0[0] : 0.f;
        float g02 = (my0 && mx2) ? xr0[1] : 0.f;
        float g10 = (my1 && mx0) ? xr1[-1] : 0.f;
        float g11 = my1 ? xr1[0] : 0.f;
        float g12 = (my1 && mx2) ? xr1[1] : 0.f;
        float4 W0 = w4[(2 * ry) * CIN + ci];
        float4 W1 = w4[(2 * ry + 1) * CIN + ci];
        acc0 += g00 * W0.x + g01 * W0.y + g10 * W0.z + g11 * W0.w;
        acc1 += g01 * W1.x + g02 * W1.y + g11 * W1.z + g12 * W1.w;
    }
    float bb = bias[0];
    float u0 = acc0 + bb, u1 = acc1 + bb;
    u0 = u0 / (1.f + expf(-u0));
    u1 = u1 / (1.f + expf(-u1));
    float2 v;
    v.x = fminf(fmaxf(u0, 0.f), 1.f);
    v.y = fminf(fmaxf(u1, 0.f), 1.f);
    int oy = 2 * py + ry;
    *(float2*)(out + (size_t)b * 50176 + oy * 224 + 2 * px) = v;
}

// ---------------------------------------------------------------------------
// launch
// ---------------------------------------------------------------------------
extern "C" void kernel_launch(void* const* d_in, const int* in_sizes, int n_in,
                              void* d_out, int out_size, void* d_ws, size_t ws_size,
                              hipStream_t stream)
{
    const float* x       = (const float*)d_in[0];
    const float* ts      = (const float*)d_in[1];
    const float* Wp      = (const float*)d_in[2];
    const float* bp      = (const float*)d_in[3];
    const float* Wt1     = (const float*)d_in[4];
    const float* bt1     = (const float*)d_in[5];
    const float* Wt2     = (const float*)d_in[6];
    const float* bt2     = (const float*)d_in[7];
    const float* a0_g    = (const float*)d_in[8];
    const float* a0_b    = (const float*)d_in[9];
    const float* a0_Wqkv = (const float*)d_in[10];
    const float* a0_bqkv = (const float*)d_in[11];
    const float* a0_Wo   = (const float*)d_in[12];
    const float* a0_bo   = (const float*)d_in[13];
    const float* a1_g    = (const float*)d_in[14];
    const float* a1_b    = (const float*)d_in[15];
    const float* a1_Wqkv = (const float*)d_in[16];
    const float* a1_bqkv = (const float*)d_in[17];
    const float* a1_Wo   = (const float*)d_in[18];
    const float* a1_bo   = (const float*)d_in[19];
    const float* Wm0     = (const float*)d_in[20];
    const float* bm0     = (const float*)d_in[21];
    const float* Wm1     = (const float*)d_in[22];
    const float* bm1     = (const float*)d_in[23];
    const float* Wm2     = (const float*)d_in[24];
    const float* bm2     = (const float*)d_in[25];
    const float* Wd1     = (const float*)d_in[26];
    const float* bd1     = (const float*)d_in[27];
    const float* l1g     = (const float*)d_in[28];
    const float* l1b     = (const float*)d_in[29];
    const float* Wd2     = (const float*)d_in[30];
    const float* bd2     = (const float*)d_in[31];
    const float* l2g     = (const float*)d_in[32];
    const float* l2b     = (const float*)d_in[33];
    const float* Wd3     = (const float*)d_in[34];
    const float* bd3     = (const float*)d_in[35];
    const float* l3g     = (const float*)d_in[36];
    const float* l3b     = (const float*)d_in[37];
    const float* Wd4     = (const float*)d_in[38];
    const float* bd4     = (const float*)d_in[39];
    float* out = (float*)d_out;

    // arena (floats); R = 25088*96
    const size_t R = 2408448;
    float* ws   = (float*)d_ws;
    float* tvec = ws;                          // 96
    float* p0   = ws + 512;                    // R
    float* h    = ws + 512 + R;                // R
    float* qkvb = ws + 512 + 2 * R;            // 3R
    float* ob   = ws + 512 + 5 * R;            // R
    float* p1   = ws + 512 + 6 * R;            // R
    float* part = ws + 512 + 7 * R;            // attn partials (aliases XH2/XP3)
    // decoder aliases:
    _Float16* xinh = (_Float16*)(ws + 512 + 2 * R);   // f16 NHWC (qkv region)
    float* C1   = ws + 512 + 5 * R;            // NHWC fp32 [b][28][28][48] (ob+p1)
    _Float16* xh2 = (_Float16*)(ws + 512 + 7 * R);    // f16 NHWC padded [b][30][30][48]
    float* C2   = ws + 512;                    // NHWC fp32 [b][56][56][24] (p0..qkv)
    float* XP3  = ws + 512 + 7 * R + 5529600;  // planar padded [b*24][58][58]
    float* C3   = ws + 512;                    // planar [b*12][112][112]
    float* Wr   = ws + 512 + 7 * R + 5529600 + 10334208;  // 96,960 floats
    _Float16* WH = (_Float16*)(Wr + 96960);                // 101,376 halves = 50,688 floats
    _Float16* Wc = (_Float16*)Wr;              // conv1 f16 B-weights (dead L1 slice)
    _Float16* Wc2 = (_Float16*)(Wr + 36864);   // conv2 f16 B-weights (dead L1 slice)
    float* stat = Wr + 96960 + 50688;          // 12,288 floats (L1 LN stats)
    const size_t NEED = (512 + 7 * R + 5529600 + 10334208 + 96960 + 50688 + 12288 + 16)
                        * sizeof(float);
    if (ws_size < NEED) return;

    _Float16* WHqkv0 = WH;
    _Float16* WHqkv1 = WH + 27648;
    _Float16* WHwo0  = WH + 55296;
    _Float16* WHwo1  = WH + 64512;
    _Float16* WHwm0  = WH + 73728;
    _Float16* WHwm1  = WH + 82944;
    _Float16* WHwm2  = WH + 92160;

    k_time<<<1, 128, 0, stream>>>(ts, Wt1, bt1, Wt2, bt2, tvec);
    k_repack<<<379, 256, 0, stream>>>(Wd1, Wd2, Wd3, Wd4, Wr);
    k_wcvtc<<<288, 256, 0, stream>>>(Wd1, Wc);
    k_wcvt2<<<96, 256, 0, stream>>>(Wd2, Wc2);
    k_wcvt<<<396, 256, 0, stream>>>(a0_Wqkv, a1_Wqkv, a0_Wo, a1_Wo,
                                    Wm0, Wm1, Wm2, WH);
    k_patch_mfma<<<M_ROWS / 64, 256, 0, stream>>>(x, Wp, bp, p0);

    // MHSA block 0
    k_ln_row<<<1024, 256, 0, stream>>>(p0, a0_g, a0_b, h, M_ROWS);
    k_gemm_mfma<3, false, false, false, false><<<M_ROWS / 64, 256, 0, stream>>>(
        h, WHqkv0, a0_bqkv, nullptr, nullptr, qkvb, nullptr);
    k_attn_part<<<B_ * 4 * KS, 256, 0, stream>>>(qkvb, part);
    k_attn_comb<<<(B_ * 4 * NPATCH) / 256, 256, 0, stream>>>(part, ob);
    k_gemm_mfma<1, false, true, false, false><<<M_ROWS / 64, 256, 0, stream>>>(
        ob, WHwo0, a0_bo, p0, nullptr, p1, nullptr);

    // MHSA block 1 (+time)
    k_ln_row<<<1024, 256, 0, stream>>>(p1, a1_g, a1_b, h, M_ROWS);
    k_gemm_mfma<3, false, false, false, false><<<M_ROWS / 64, 256, 0, stream>>>(
        h, WHqkv1, a1_bqkv, nullptr, nullptr, qkvb, nullptr);
    k_attn_part<<<B_ * 4 * KS, 256, 0, stream>>>(qkvb, part);
    k_attn_comb<<<(B_ * 4 * NPATCH) / 256, 256, 0, stream>>>(part, ob);
    k_gemm_mfma<1, false, true, true, false><<<M_ROWS / 64, 256, 0, stream>>>(
        ob, WHwo1, a1_bo, p1, tvec, p0, nullptr);

    // qkv region free: zero xinh borders before MLP3 writes interior
    k_zb_h<<<2880, 256, 0, stream>>>(xinh);

    // MLP x3 (silu); last writes f16 NHWC padded xinh
    k_gemm_mfma<1, true, false, false, false><<<M_ROWS / 64, 256, 0, stream>>>(
        p0, WHwm0, bm0, nullptr, nullptr, p1, nullptr);
    k_gemm_mfma<1, true, false, false, false><<<M_ROWS / 64, 256, 0, stream>>>(
        p1, WHwm1, bm1, nullptr, nullptr, p0, nullptr);
    k_gemm_mfma<1, true, false, false, true><<<M_ROWS / 64, 256, 0, stream>>>(
        p0, WHwm2, bm2, nullptr, nullptr, nullptr, xinh);

    // decoder: L1 MFMA, parallel LN bridge (now f16 NHWC out), L2 MFMA
    k_conv1<<<M_ROWS / 64, 256, 0, stream>>>(xinh, Wc, bd1, C1);
    k_ln1_stats<<<1536, 256, 0, stream>>>(C1, stat);
    k_ln1_apply<<<21600, 256, 0, stream>>>(C1, stat, l1g, l1b, xh2);
    k_conv2_mfma<<<(B_ * 784) / 64, 256, 0, stream>>>(xh2, Wc2, bd2, C2);
    k_ln_pad_nhwc<56, 24><<<B_ * 24, 256, 0, stream>>>(C2, l2g, l2b, XP3);
    k_convg<24, 56, 12, 12><<<2 * 1 * 1568, 256, 0, stream>>>(XP3, Wr + 92160, bd3, C3);
    k_ln_spatial<12544><<<B_ * 12, 256, 0, stream>>>(C3, l3g, l3b);
    k_conv_final<<<2 * 6272, 256, 0, stream>>>(C3, Wr + 96768, bd4, out);
}

// Round 2
// 728.371 us; speedup vs baseline: 1.1037x; 1.1037x over previous
//
#include <hip/hip_runtime.h>
#include <cmath>

// ---------------------------------------------------------------------------
// TimestepVisionTransformer — Round 10: all-NHWC decoder, no transposes.
//   - k_ln2_stats/k_ln2_apply replace k_ln_pad_nhwc (387MB fetch, 115us):
//     coalesced NHWC stats (residue-slot binning) + coalesced apply -> f16
//     NHWC padded XH3 [b][58][58][24]
//   - k_conv3_mfma replaces k_convg<24,56,12,12> (VALU-bound, MfmaUtil=0)
//   - k_ln3_stats (4 slices/image) + k_ln3_apply (in-place NHWC)
//   - k_conv_final_nhwc reads C3 NHWC (12 contiguous ci floats per tap)
// Everything upstream = r9 (verified).
// B=128, IMG=224, P=16, C_IN=1, E=96, H=4, d=24, NAX=14, N=196, M=B*N=25088
// ---------------------------------------------------------------------------

#define B_   128
#define NPATCH 196
#define M_ROWS (B_*NPATCH)     // 25088
#define E_   96
#define KS   4
#define SEG  49

typedef _Float16 half8 __attribute__((ext_vector_type(8)));
typedef _Float16 half4v __attribute__((ext_vector_type(4)));
typedef float f32x4 __attribute__((ext_vector_type(4)));

// ---------------------------------------------------------------------------
// time embedding
// ---------------------------------------------------------------------------
__global__ void k_time(const float* __restrict__ ts,
                       const float* __restrict__ Wt1, const float* __restrict__ bt1,
                       const float* __restrict__ Wt2, const float* __restrict__ bt2,
                       float* __restrict__ timev)
{
    __shared__ float h[128];
    float e = 0.69314718055994530942f * ts[0];
    float sv = sinf(e), cv = cosf(e);
    int t = threadIdx.x;
    float z = sv * Wt1[t] + cv * Wt1[128 + t] + bt1[t];
    h[t] = z / (1.f + expf(-z));
    __syncthreads();
    if (t < 96) {
        float acc = bt2[t];
        for (int j = 0; j < 128; ++j) acc += h[j] * Wt2[j * 96 + t];
        timev[t] = acc;
    }
}

// ---------------------------------------------------------------------------
// weight repack (fp32 per-parity taps). Only the L4 slice [96768,96960) is
// still consumed as fp32 (conv_final); L1..L3 slices are overwritten by the
// f16 repacks below.
// ---------------------------------------------------------------------------
__global__ void __launch_bounds__(256) k_repack(const float* __restrict__ w1,
                                                const float* __restrict__ w2,
                                                const float* __restrict__ w3,
                                                const float* __restrict__ w4f,
                                                float* __restrict__ wr)
{
    int i = blockIdx.x * 256 + threadIdx.x;
    const float* src; int CIN, COUT, e; float* dst;
    if      (i < 73728) { src = w1;  CIN = 96; COUT = 48; e = i;          dst = wr; }
    else if (i < 92160) { src = w2;  CIN = 48; COUT = 24; e = i - 73728;  dst = wr + 73728; }
    else if (i < 96768) { src = w3;  CIN = 24; COUT = 12; e = i - 92160;  dst = wr + 92160; }
    else if (i < 96960) { src = w4f; CIN = 12; COUT = 1;  e = i - 96768;  dst = wr + 96768; }
    else return;
    int per = CIN * COUT * 4;
    int par = e / per, rem = e % per;
    int ci = rem / (COUT * 4);
    int o  = (rem >> 2) % COUT;
    int j  = rem & 3;
    int ry = par >> 1, rx = par & 1;
    int wy = (j < 2)  ? (3 - ry) : (1 - ry);
    int wx = (j & 1)  ? (1 - rx) : (3 - rx);
    dst[e] = src[(ci * COUT + o) * 16 + wy * 4 + wx];
}

// ---------------------------------------------------------------------------
// conv1 weights -> f16 B-layout Wc[p][o][k=tap*96+ci]
// ---------------------------------------------------------------------------
__global__ void __launch_bounds__(256) k_wcvtc(const float* __restrict__ w1,
                                               _Float16* __restrict__ wc)
{
    int i = blockIdx.x * 256 + threadIdx.x;
    if (i >= 4 * 48 * 384) return;
    int p = i / 18432, rem = i % 18432;
    int o = rem / 384, k = rem % 384;
    int tap = k / 96, ci = k % 96;
    int ry = p >> 1, rx = p & 1;
    int wy = (tap < 2) ? (3 - ry) : (1 - ry);
    int wx = (tap & 1) ? (1 - rx) : (3 - rx);
    wc[i] = (_Float16)w1[(ci * 48 + o) * 16 + wy * 4 + wx];
}

// ---------------------------------------------------------------------------
// conv2 weights -> f16 B-layout Wc2[p][o(32, o>=24 zero)][k=tap*48+ci]
// ---------------------------------------------------------------------------
__global__ void __launch_bounds__(256) k_wcvt2(const float* __restrict__ w2,
                                               _Float16* __restrict__ wc2)
{
    int i = blockIdx.x * 256 + threadIdx.x;
    if (i >= 4 * 32 * 192) return;
    int p = i / 6144, rem = i % 6144;
    int o = rem / 192, k = rem % 192;
    int tap = k / 48, ci = k % 48;
    int ry = p >> 1, rx = p & 1;
    int wy = (tap < 2) ? (3 - ry) : (1 - ry);
    int wx = (tap & 1) ? (1 - rx) : (3 - rx);
    wc2[i] = (o < 24) ? (_Float16)w2[(ci * 24 + o) * 16 + wy * 4 + wx]
                      : (_Float16)0.f;
}

// ---------------------------------------------------------------------------
// conv3 weights -> f16 B-layout Wc3[p][o(16, o>=12 zero)][k=tap*24+ci]
// ---------------------------------------------------------------------------
__global__ void __launch_bounds__(256) k_wcvt3(const float* __restrict__ w3,
                                               _Float16* __restrict__ wc3)
{
    int i = blockIdx.x * 256 + threadIdx.x;
    if (i >= 4 * 16 * 96) return;
    int p = i / 1536, rem = i % 1536;
    int o = rem / 96, k = rem % 96;
    int tap = k / 24, ci = k % 24;
    int ry = p >> 1, rx = p & 1;
    int wy = (tap < 2) ? (3 - ry) : (1 - ry);
    int wx = (tap & 1) ? (1 - rx) : (3 - rx);
    wc3[i] = (o < 12) ? (_Float16)w3[(ci * 12 + o) * 16 + wy * 4 + wx]
                      : (_Float16)0.f;
}

// ---------------------------------------------------------------------------
// transformer weight convert+transpose to half: Wt[n][k] = W[k][n]
// ---------------------------------------------------------------------------
__global__ void __launch_bounds__(256) k_wcvt(const float* __restrict__ qkv0,
                                              const float* __restrict__ qkv1,
                                              const float* __restrict__ wo0,
                                              const float* __restrict__ wo1,
                                              const float* __restrict__ wm0,
                                              const float* __restrict__ wm1,
                                              const float* __restrict__ wm2,
                                              _Float16* __restrict__ wh)
{
    int i = blockIdx.x * 256 + threadIdx.x;
    const float* src; int N; int e;
    if      (i < 27648)  { src = qkv0; N = 288; e = i; }
    else if (i < 55296)  { src = qkv1; N = 288; e = i - 27648; }
    else if (i < 64512)  { src = wo0;  N = 96;  e = i - 55296; }
    else if (i < 73728)  { src = wo1;  N = 96;  e = i - 64512; }
    else if (i < 82944)  { src = wm0;  N = 96;  e = i - 73728; }
    else if (i < 92160)  { src = wm1;  N = 96;  e = i - 82944; }
    else if (i < 101376) { src = wm2;  N = 96;  e = i - 92160; }
    else return;
    int n = e / 96, k = e % 96;
    wh[i] = (_Float16)src[k * N + n];
}

// ---------------------------------------------------------------------------
// zero the borders of xinh NHWC f16 [b][16][16][96]
// ---------------------------------------------------------------------------
__global__ void __launch_bounds__(256) k_zb_h(_Float16* __restrict__ xinh)
{
    int i = blockIdx.x * 256 + threadIdx.x;
    if (i >= 128 * 60 * 96) return;
    int b = i / 5760, r = i % 5760;
    int pos = r / 96, ch = r % 96;
    int py, px;
    if      (pos < 16) { py = 0;        px = pos; }
    else if (pos < 32) { py = 15;       px = pos - 16; }
    else if (pos < 46) { py = pos - 31; px = 0; }
    else               { py = pos - 45; px = 15; }
    xinh[((size_t)(b * 256) + py * 16 + px) * 96 + ch] = (_Float16)0.f;
}

// ---------------------------------------------------------------------------
// patch embed GEMM via f16 MFMA (r7, verified)
// ---------------------------------------------------------------------------
__global__ void __launch_bounds__(256) k_patch_mfma(const float* __restrict__ x,
                                                    const float* __restrict__ Wp,
                                                    const float* __restrict__ bp,
                                                    float* __restrict__ out)
{
    __shared__ __align__(16) _Float16 Ah[64 * 136];
    __shared__ __align__(16) _Float16 Wh[96 * 136];
    int t = threadIdx.x;
    int p0 = blockIdx.x * 64;
    int wave = t >> 6, lane = t & 63;
    int lm = lane & 15, quad = lane >> 4;
    f32x4 acc[6];
    #pragma unroll
    for (int nt = 0; nt < 6; ++nt) acc[nt] = (f32x4){0.f, 0.f, 0.f, 0.f};

    for (int kc = 0; kc < 2; ++kc) {
        __syncthreads();
        for (int i = t; i < 512; i += 256) {
            int lp = i >> 3, pyl = i & 7;
            int patch = p0 + lp;
            int b = patch / NPATCH, n = patch % NPATCH;
            int ny = n / 14, nx = n % 14;
            const float4* s4 = (const float4*)(x +
                ((size_t)(b * 224) + ny * 16 + kc * 8 + pyl) * 224 + nx * 16);
            float4 v0 = s4[0], v1 = s4[1], v2 = s4[2], v3 = s4[3];
            half8 h0, h1;
            h0[0]=(_Float16)v0.x; h0[1]=(_Float16)v0.y; h0[2]=(_Float16)v0.z; h0[3]=(_Float16)v0.w;
            h0[4]=(_Float16)v1.x; h0[5]=(_Float16)v1.y; h0[6]=(_Float16)v1.z; h0[7]=(_Float16)v1.w;
            h1[0]=(_Float16)v2.x; h1[1]=(_Float16)v2.y; h1[2]=(_Float16)v2.z; h1[3]=(_Float16)v2.w;
            h1[4]=(_Float16)v3.x; h1[5]=(_Float16)v3.y; h1[6]=(_Float16)v3.z; h1[7]=(_Float16)v3.w;
            *(half8*)&Ah[lp * 136 + pyl * 16]     = h0;
            *(half8*)&Ah[lp * 136 + pyl * 16 + 8] = h1;
        }
        for (int i = t; i < 1536; i += 256) {
            int e = i >> 4, s = i & 15;
            const float4* s4 = (const float4*)(Wp + e * 256 + kc * 128 + s * 8);
            float4 v0 = s4[0], v1 = s4[1];
            half8 h0;
            h0[0]=(_Float16)v0.x; h0[1]=(_Float16)v0.y; h0[2]=(_Float16)v0.z; h0[3]=(_Float16)v0.w;
            h0[4]=(_Float16)v1.x; h0[5]=(_Float16)v1.y; h0[6]=(_Float16)v1.z; h0[7]=(_Float16)v1.w;
            *(half8*)&Wh[e * 136 + s * 8] = h0;
        }
        __syncthreads();
        half8 af[4];
        #pragma unroll
        for (int ks = 0; ks < 4; ++ks)
            af[ks] = *(const half8*)&Ah[(wave * 16 + lm) * 136 + ks * 32 + quad * 8];
        #pragma unroll
        for (int ks = 0; ks < 4; ++ks) {
            #pragma unroll
            for (int nt = 0; nt < 6; ++nt) {
                half8 bf = *(const half8*)&Wh[(nt * 16 + lm) * 136 + ks * 32 + quad * 8];
                acc[nt] = __builtin_amdgcn_mfma_f32_16x16x32_f16(af[ks], bf, acc[nt], 0, 0, 0);
            }
        }
    }

    #pragma unroll
    for (int nt = 0; nt < 6; ++nt) {
        #pragma unroll
        for (int r = 0; r < 4; ++r) {
            int e = nt * 16 + lm;
            int lp = wave * 16 + quad * 4 + r;
            int patch = p0 + lp;
            int n = patch % NPATCH;
            int ny = n / 14, nx = n % 14;
            float yx = (float)(ny + nx);
            float v = acc[nt][r] + bp[e];
            float other = __shfl_xor(v, 1);
            float fi = (float)(e >> 1);
            float theta = expf(fi * (-2.f / 96.f) * 9.210340371976184f);
            float ang = theta * yx;
            float c = cosf(ang), s = sinf(ang);
            float outv = (lm & 1) ? (other * s + v * c) : (v * c - other * s);
            out[(size_t)patch * 96 + e] = outv;
        }
    }
}

// ---------------------------------------------------------------------------
// row LayerNorm over 96, wave per row
// ---------------------------------------------------------------------------
__global__ void __launch_bounds__(256) k_ln_row(const float* __restrict__ x,
                                                const float* __restrict__ g,
                                                const float* __restrict__ bv,
                                                float* __restrict__ out, int M)
{
    int lane = threadIdx.x & 63;
    int gw = (blockIdx.x * 256 + threadIdx.x) >> 6;
    int nw = (gridDim.x * 256) >> 6;
    float g0 = g[lane], b0 = bv[lane];
    float g1 = 0.f, b1 = 0.f;
    if (lane < 32) { g1 = g[64 + lane]; b1 = bv[64 + lane]; }
    for (int r = gw; r < M; r += nw) {
        const float* xr = x + (size_t)r * 96;
        float a = xr[lane];
        float c = (lane < 32) ? xr[64 + lane] : 0.f;
        float s = a + c, q = a * a + c * c;
        #pragma unroll
        for (int off = 32; off; off >>= 1) {
            s += __shfl_xor(s, off);
            q += __shfl_xor(q, off);
        }
        float mu = s * (1.f / 96.f);
        float rstd = rsqrtf(q * (1.f / 96.f) - mu * mu + 1e-5f);
        float* orow = out + (size_t)r * 96;
        orow[lane] = (a - mu) * rstd * g0 + b0;
        if (lane < 32) orow[64 + lane] = (c - mu) * rstd * g1 + b1;
    }
}

// ---------------------------------------------------------------------------
// MFMA row GEMM (r6, verified). OUTH: write f16 NHWC padded xinh instead.
// ---------------------------------------------------------------------------
template<int NCHUNKS, bool SILU, bool RES, bool ADDTIME, bool OUTH>
__global__ void __launch_bounds__(256) k_gemm_mfma(const float* __restrict__ A,
                                                   const _Float16* __restrict__ Wt,
                                                   const float* __restrict__ bias,
                                                   const float* __restrict__ res,
                                                   const float* __restrict__ timev,
                                                   float* __restrict__ out,
                                                   _Float16* __restrict__ outh)
{
    __shared__ __align__(16) _Float16 Ah[64 * 96];
    __shared__ __align__(16) _Float16 Wh[96 * 96];
    constexpr int NTOT = NCHUNKS * 96;
    int t = threadIdx.x;
    size_t row0 = (size_t)blockIdx.x * 64;

    const float4* a4 = (const float4*)(A + row0 * 96);
    for (int i = t; i < 1536; i += 256) {
        float4 v = a4[i];
        half4v hv;
        hv[0] = (_Float16)v.x; hv[1] = (_Float16)v.y;
        hv[2] = (_Float16)v.z; hv[3] = (_Float16)v.w;
        *(half4v*)&Ah[i * 4] = hv;
    }

    int wave = t >> 6, lane = t & 63;
    int lm = lane & 15, quad = lane >> 4;
    const f32x4 vzero = {0.f, 0.f, 0.f, 0.f};

    for (int ch = 0; ch < NCHUNKS; ++ch) {
        __syncthreads();
        {
            const uint4* src = (const uint4*)(Wt + (size_t)ch * 9216);
            uint4* dst = (uint4*)Wh;
            for (int i = t; i < 1152; i += 256) dst[i] = src[i];
        }
        __syncthreads();

        half8 af[3];
        #pragma unroll
        for (int ks = 0; ks < 3; ++ks)
            af[ks] = *(const half8*)&Ah[(wave * 16 + lm) * 96 + ks * 32 + quad * 8];

        f32x4 acc[6];
        #pragma unroll
        for (int ct = 0; ct < 6; ++ct) acc[ct] = vzero;

        #pragma unroll
        for (int ct = 0; ct < 6; ++ct) {
            #pragma unroll
            for (int ks = 0; ks < 3; ++ks) {
                half8 bf = *(const half8*)&Wh[(ct * 16 + lm) * 96 + ks * 32 + quad * 8];
                acc[ct] = __builtin_amdgcn_mfma_f32_16x16x32_f16(af[ks], bf, acc[ct], 0, 0, 0);
            }
        }

        #pragma unroll
        for (int ct = 0; ct < 6; ++ct) {
            #pragma unroll
            for (int r = 0; r < 4; ++r) {
                int lr = wave * 16 + quad * 4 + r;
                size_t row = row0 + lr;
                int lc = ct * 16 + lm;
                int col = ch * 96 + lc;
                float v = acc[ct][r] + bias[col];
                if constexpr (RES)     v += res[row * 96 + lc];
                if constexpr (ADDTIME) v += timev[lc];
                if constexpr (SILU)    v = v / (1.f + expf(-v));
                if constexpr (OUTH) {
                    size_t b = row / NPATCH; int n = (int)(row % NPATCH);
                    int ny = n / 14, nx = n % 14;
                    outh[((b * 256) + (1 + ny) * 16 + (1 + nx)) * 96 + col] = (_Float16)v;
                } else {
                    out[row * NTOT + col] = v;
                }
            }
        }
    }
}

// ---------------------------------------------------------------------------
// attention partials (r4, verified)
// ---------------------------------------------------------------------------
__global__ void __launch_bounds__(256) k_attn_part(const float* __restrict__ qkv,
                                                   float* __restrict__ part)
{
    int blk = blockIdx.x;
    int seg = blk % KS;
    int bh  = blk / KS;
    int b = bh >> 2, h = bh & 3;
    const float* base = qkv + (size_t)b * NPATCH * 288 + h * 24;
    __shared__ __align__(16) float KV[SEG * 48];
    int t = threadIdx.x;
    int k0 = seg * SEG;
    for (int i = t; i < SEG * 48; i += 256) {
        int k = i / 48, j = i % 48;
        KV[i] = base[(size_t)(k0 + k) * 288 + 96 + (j < 24 ? j : j + 72)];
    }
    __syncthreads();

    int q = (t < NPATCH) ? t : 0;
    float qv[24], acc[24];
    const float4* qrow = (const float4*)(base + (size_t)q * 288);
    #pragma unroll
    for (int j = 0; j < 6; ++j) {
        float4 v = qrow[j];
        qv[4 * j] = v.x; qv[4 * j + 1] = v.y; qv[4 * j + 2] = v.z; qv[4 * j + 3] = v.w;
    }
    #pragma unroll
    for (int d = 0; d < 24; ++d) acc[d] = 0.f;
    float sum = 0.f;
    const float scale = 0.2041241452319315f;

    #pragma unroll 2
    for (int k = 0; k < SEG; ++k) {
        const float4* kr = (const float4*)(&KV[k * 48]);
        float s0 = 0.f, s1 = 0.f, s2 = 0.f, s3 = 0.f;
        #pragma unroll
        for (int j = 0; j < 6; ++j) {
            float4 Kv = kr[j];
            s0 += qv[4 * j]     * Kv.x;
            s1 += qv[4 * j + 1] * Kv.y;
            s2 += qv[4 * j + 2] * Kv.z;
            s3 += qv[4 * j + 3] * Kv.w;
        }
        float s = (s0 + s1) + (s2 + s3);
        float p = __expf(fminf(s * scale, 60.f));
        sum += p;
        #pragma unroll
        for (int j = 0; j < 6; ++j) {
            float4 Vv = kr[6 + j];
            acc[4 * j]     += p * Vv.x;
            acc[4 * j + 1] += p * Vv.y;
            acc[4 * j + 2] += p * Vv.z;
            acc[4 * j + 3] += p * Vv.w;
        }
    }

    if (t < NPATCH) {
        float4* pp = (float4*)(part + ((size_t)blk * NPATCH + t) * 28);
        #pragma unroll
        for (int j = 0; j < 6; ++j) {
            float4 v;
            v.x = acc[4 * j]; v.y = acc[4 * j + 1];
            v.z = acc[4 * j + 2]; v.w = acc[4 * j + 3];
            pp[j] = v;
        }
        float4 sv; sv.x = sum; sv.y = 0.f; sv.z = 0.f; sv.w = 0.f;
        pp[6] = sv;
    }
}

// ---------------------------------------------------------------------------
// combine K-split partials
// ---------------------------------------------------------------------------
__global__ void __launch_bounds__(256) k_attn_comb(const float* __restrict__ part,
                                                   float* __restrict__ o)
{
    int idx = blockIdx.x * 256 + threadIdx.x;
    int bh = idx / NPATCH, q = idx % NPATCH;
    int b = bh >> 2, h = bh & 3;
    float acc[24];
    #pragma unroll
    for (int d = 0; d < 24; ++d) acc[d] = 0.f;
    float sum = 0.f;
    #pragma unroll
    for (int s = 0; s < KS; ++s) {
        const float4* pp = (const float4*)(part + ((size_t)(bh * KS + s) * NPATCH + q) * 28);
        #pragma unroll
        for (int j = 0; j < 6; ++j) {
            float4 v = pp[j];
            acc[4 * j]     += v.x;
            acc[4 * j + 1] += v.y;
            acc[4 * j + 2] += v.z;
            acc[4 * j + 3] += v.w;
        }
        sum += pp[6].x;
    }
    float inv = 1.f / sum;
    float4* orow = (float4*)(o + ((size_t)b * NPATCH + q) * 96 + h * 24);
    #pragma unroll
    for (int j = 0; j < 6; ++j) {
        float4 v;
        v.x = acc[4 * j] * inv; v.y = acc[4 * j + 1] * inv;
        v.z = acc[4 * j + 2] * inv; v.w = acc[4 * j + 3] * inv;
        orow[j] = v;
    }
}

// ---------------------------------------------------------------------------
// conv L1 via MFMA (r7, verified): xinh NHWC f16 padded -> C1 NHWC fp32
// ---------------------------------------------------------------------------
__global__ void __launch_bounds__(256) k_conv1(const _Float16* __restrict__ xinh,
                                               const _Float16* __restrict__ wc,
                                               const float* __restrict__ bias,
                                               float* __restrict__ c1)
{
    __shared__ __align__(16) _Float16 Ah[64 * 392];
    int t = threadIdx.x;
    int blk = blockIdx.x;
    int wave = t >> 6, lane = t & 63;
    int lm = lane & 15, quad = lane >> 4;

    for (int p = 0; p < 4; ++p) {
        int ry = p >> 1, rx = p & 1;
        __syncthreads();
        for (int i = t; i < 64 * 48; i += 256) {
            int lp = i / 48, rem = i % 48;
            int tap = rem / 12;
            int gp = blk * 64 + lp;
            int b = gp / NPATCH, pix = gp % NPATCH;
            int py = pix / 14, px = pix % 14;
            int row = py + ry + (tap >> 1), col = px + rx + (tap & 1);
            const uint4* src = (const uint4*)(xinh +
                ((size_t)(b * 256) + row * 16 + col) * 96 + (rem % 12) * 8);
            *(uint4*)&Ah[lp * 392 + rem * 8] = *src;
        }
        __syncthreads();

        half8 af[12];
        #pragma unroll
        for (int ks = 0; ks < 12; ++ks)
            af[ks] = *(const half8*)&Ah[(wave * 16 + lm) * 392 + ks * 32 + quad * 8];

        f32x4 acc[3];
        #pragma unroll
        for (int nt = 0; nt < 3; ++nt) acc[nt] = (f32x4){0.f, 0.f, 0.f, 0.f};

        #pragma unroll
        for (int ks = 0; ks < 12; ++ks) {
            #pragma unroll
            for (int nt = 0; nt < 3; ++nt) {
                half8 bf = *(const half8*)&wc[((size_t)(p * 48 + nt * 16 + lm)) * 384
                                              + ks * 32 + quad * 8];
                acc[nt] = __builtin_amdgcn_mfma_f32_16x16x32_f16(af[ks], bf, acc[nt], 0, 0, 0);
            }
        }

        #pragma unroll
        for (int nt = 0; nt < 3; ++nt) {
            #pragma unroll
            for (int r = 0; r < 4; ++r) {
                int o = nt * 16 + lm;
                int lp = wave * 16 + quad * 4 + r;
                int gp = blk * 64 + lp;
                int b = gp / NPATCH, pix = gp % NPATCH;
                int py = pix / 14, px = pix % 14;
                int oy = 2 * py + ry, ox = 2 * px + rx;
                c1[((size_t)(b * 28 + oy) * 28 + ox) * 48 + o] = acc[nt][r] + bias[o];
            }
        }
    }
}

// ---------------------------------------------------------------------------
// L1 LN stats: one wave per (b,ch) over NHWC C1 -> stat[b*48+ch] = {mu,rstd}
// grid 1536 x 256 (4 waves/block).
// ---------------------------------------------------------------------------
__global__ void __launch_bounds__(256) k_ln1_stats(const float* __restrict__ c1,
                                                   float* __restrict__ stat)
{
    int idx = blockIdx.x * 4 + (threadIdx.x >> 6);   // b*48+ch
    int lane = threadIdx.x & 63;
    int b = idx / 48, ch = idx % 48;
    const float* base = c1 + (size_t)b * 784 * 48 + ch;
    float s = 0.f, q = 0.f;
    for (int pix = lane; pix < 784; pix += 64) {
        float v = base[(size_t)pix * 48];
        s += v; q += v * v;
    }
    #pragma unroll
    for (int off = 32; off; off >>= 1) {
        s += __shfl_xor(s, off);
        q += __shfl_xor(q, off);
    }
    if (lane == 0) {
        float mu = s * (1.f / 784.f);
        float rstd = rsqrtf(q * (1.f / 784.f) - mu * mu + 1e-5f);
        stat[idx * 2]     = mu;
        stat[idx * 2 + 1] = rstd;
    }
}

// ---------------------------------------------------------------------------
// L1 LN apply: NHWC C1 + stat -> f16 NHWC padded XH2 [b][30][30][48], silu.
// ---------------------------------------------------------------------------
__global__ void __launch_bounds__(256) k_ln1_apply(const float* __restrict__ c1,
                                                   const float* __restrict__ stat,
                                                   const float* __restrict__ g,
                                                   const float* __restrict__ bv,
                                                   _Float16* __restrict__ xh)
{
    int i = blockIdx.x * 256 + threadIdx.x;          // ((b*900)+pos)*48 + ch
    if (i >= 128 * 900 * 48) return;
    int ch = i % 48;
    int t2 = i / 48;
    int pos = t2 % 900;
    int b = t2 / 900;
    int py = pos / 30, px = pos % 30;
    float v = 0.f;
    if (py >= 1 && py <= 28 && px >= 1 && px <= 28) {
        int j = (py - 1) * 28 + (px - 1);
        int plane = b * 48 + ch;
        float mu = stat[plane * 2], rstd = stat[plane * 2 + 1];
        float u = (c1[((size_t)b * 784 + j) * 48 + ch] - mu) * rstd * g[j] + bv[j];
        v = u / (1.f + expf(-u));
    }
    xh[i] = (_Float16)v;
}

// ---------------------------------------------------------------------------
// conv L2 via MFMA (r9, verified): XH2 NHWC f16 padded -> C2 NHWC fp32
// [b][56][56][24].
// ---------------------------------------------------------------------------
__global__ void __launch_bounds__(256) k_conv2_mfma(const _Float16* __restrict__ xh,
                                                    const _Float16* __restrict__ wc,
                                                    const float* __restrict__ bias,
                                                    float* __restrict__ c2)
{
    __shared__ __align__(16) _Float16 Ah[64 * 200];   // 192 + 8 pad
    int t = threadIdx.x;
    int blk = blockIdx.x;
    int wave = t >> 6, lane = t & 63;
    int lm = lane & 15, quad = lane >> 4;

    for (int p = 0; p < 4; ++p) {
        int ry = p >> 1, rx = p & 1;
        __syncthreads();
        for (int i = t; i < 64 * 24; i += 256) {
            int lp = i / 24, c = i % 24;              // c = half8 chunk of K
            int tap = c / 6;
            int gp = blk * 64 + lp;
            int b = gp / 784, pix = gp % 784;
            int py = pix / 28, px = pix % 28;
            int row = py + ry + (tap >> 1), col = px + rx + (tap & 1);
            *(uint4*)&Ah[lp * 200 + c * 8] =
                *(const uint4*)(xh + ((size_t)(b * 900) + row * 30 + col) * 48
                                + (c % 6) * 8);
        }
        __syncthreads();

        half8 af[6];
        #pragma unroll
        for (int ks = 0; ks < 6; ++ks)
            af[ks] = *(const half8*)&Ah[(wave * 16 + lm) * 200 + ks * 32 + quad * 8];

        f32x4 acc[2];
        acc[0] = (f32x4){0.f, 0.f, 0.f, 0.f};
        acc[1] = (f32x4){0.f, 0.f, 0.f, 0.f};

        #pragma unroll
        for (int ks = 0; ks < 6; ++ks) {
            #pragma unroll
            for (int ct = 0; ct < 2; ++ct) {
                half8 bf = *(const half8*)&wc[((size_t)(p * 32 + ct * 16 + lm)) * 192
                                              + ks * 32 + quad * 8];
                acc[ct] = __builtin_amdgcn_mfma_f32_16x16x32_f16(af[ks], bf, acc[ct], 0, 0, 0);
            }
        }

        #pragma unroll
        for (int ct = 0; ct < 2; ++ct) {
            int o = ct * 16 + lm;
            if (o < 24) {
                #pragma unroll
                for (int r = 0; r < 4; ++r) {
                    int lp = wave * 16 + quad * 4 + r;
                    int gp = blk * 64 + lp;
                    int b = gp / 784, pix = gp % 784;
                    int py = pix / 28, px = pix % 28;
                    int oy = 2 * py + ry, ox = 2 * px + rx;
                    c2[((size_t)(b * 56 + oy) * 56 + ox) * 24 + o] = acc[ct][r] + bias[o];
                }
            }
        }
    }
}

// ---------------------------------------------------------------------------
// L2 LN stats, coalesced: block per (image b, half h). Reads C2 NHWC
// linearly; element channel = (t + 16k) % 24 -> 3 residue slots per thread.
// pstat[(b*2+h)*48 + ch*2 + {0:sum,1:sumsq}]
// ---------------------------------------------------------------------------
__global__ void __launch_bounds__(256) k_ln2_stats(const float* __restrict__ c2,
                                                   float* __restrict__ pstat)
{
    __shared__ float bins[48];
    int t = threadIdx.x;
    int b = blockIdx.x >> 1, h = blockIdx.x & 1;
    if (t < 48) bins[t] = 0.f;
    __syncthreads();
    const float* base = c2 + (size_t)b * 75264 + h * 37632;
    float s0 = 0.f, s1 = 0.f, s2 = 0.f, q0 = 0.f, q1 = 0.f, q2 = 0.f;
    for (int k = 0; k < 147; k += 3) {
        float v0 = base[t + 256 * k];
        float v1 = base[t + 256 * (k + 1)];
        float v2 = base[t + 256 * (k + 2)];
        s0 += v0; q0 += v0 * v0;
        s1 += v1; q1 += v1 * v1;
        s2 += v2; q2 += v2 * v2;
    }
    int c0 = t % 24;
    int c1 = (c0 + 16) % 24;
    int c2i = (c0 + 8) % 24;
    atomicAdd(&bins[c0 * 2],      s0); atomicAdd(&bins[c0 * 2 + 1],  q0);
    atomicAdd(&bins[c1 * 2],      s1); atomicAdd(&bins[c1 * 2 + 1],  q1);
    atomicAdd(&bins[c2i * 2],     s2); atomicAdd(&bins[c2i * 2 + 1], q2);
    __syncthreads();
    if (t < 48) pstat[(size_t)blockIdx.x * 48 + t] = bins[t];
}

// ---------------------------------------------------------------------------
// L2 LN apply: C2 NHWC + pstat -> f16 NHWC padded XH3 [b][58][58][24], silu.
// All reads/writes coalesced. Borders -> 0.
// ---------------------------------------------------------------------------
__global__ void __launch_bounds__(256) k_ln2_apply(const float* __restrict__ c2,
                                                   const float* __restrict__ pstat,
                                                   const float* __restrict__ g,
                                                   const float* __restrict__ bv,
                                                   _Float16* __restrict__ xh)
{
    int i = blockIdx.x * 256 + threadIdx.x;          // ((b*3364)+pos)*24 + ch
    int ch = i % 24;
    int t2 = i / 24;
    int pos = t2 % 3364;
    int b = t2 / 3364;
    int py = pos / 58, px = pos % 58;
    float v = 0.f;
    if (py >= 1 && py <= 56 && px >= 1 && px <= 56) {
        int j = (py - 1) * 56 + (px - 1);
        const float* ps = pstat + (size_t)b * 96 + ch * 2;
        float s = ps[0] + ps[48];
        float q = ps[1] + ps[49];
        float mu = s * (1.f / 3136.f);
        float rstd = rsqrtf(q * (1.f / 3136.f) - mu * mu + 1e-5f);
        float u = (c2[((size_t)b * 3136 + j) * 24 + ch] - mu) * rstd * g[j] + bv[j];
        v = u / (1.f + expf(-u));
    }
    xh[i] = (_Float16)v;
}

// ---------------------------------------------------------------------------
// conv L3 via MFMA: XH3 NHWC f16 padded [b][58][58][24] -> C3 NHWC fp32
// [b][112][112][12]. Per parity: A = 64 pixels x K=96 (4 taps x 24 ci),
// B = Wc3[p][o(16)][96], 3 k-slices x 1 col-tile of 16x16x32 f16 MFMA.
// ---------------------------------------------------------------------------
__global__ void __launch_bounds__(256) k_conv3_mfma(const _Float16* __restrict__ xh,
                                                    const _Float16* __restrict__ wc,
                                                    const float* __restrict__ bias,
                                                    float* __restrict__ c3)
{
    __shared__ __align__(16) _Float16 Ah[64 * 104];   // 96 + 8 pad
    int t = threadIdx.x;
    int blk = blockIdx.x;
    int wave = t >> 6, lane = t & 63;
    int lm = lane & 15, quad = lane >> 4;

    for (int p = 0; p < 4; ++p) {
        int ry = p >> 1, rx = p & 1;
        __syncthreads();
        for (int i = t; i < 64 * 12; i += 256) {
            int lp = i / 12, c = i % 12;              // c = half8 chunk of K
            int tap = c / 3;
            int gp = blk * 64 + lp;
            int b = gp / 3136, pix = gp % 3136;
            int py = pix / 56, px = pix % 56;
            int row = py + ry + (tap >> 1), col = px + rx + (tap & 1);
            *(uint4*)&Ah[lp * 104 + c * 8] =
                *(const uint4*)(xh + ((size_t)(b * 3364) + row * 58 + col) * 24
                                + (c % 3) * 8);
        }
        __syncthreads();

        half8 af[3];
        #pragma unroll
        for (int ks = 0; ks < 3; ++ks)
            af[ks] = *(const half8*)&Ah[(wave * 16 + lm) * 104 + ks * 32 + quad * 8];

        f32x4 acc = (f32x4){0.f, 0.f, 0.f, 0.f};
        #pragma unroll
        for (int ks = 0; ks < 3; ++ks) {
            half8 bf = *(const half8*)&wc[((size_t)(p * 16 + lm)) * 96
                                          + ks * 32 + quad * 8];
            acc = __builtin_amdgcn_mfma_f32_16x16x32_f16(af[ks], bf, acc, 0, 0, 0);
        }

        if (lm < 12) {
            #pragma unroll
            for (int r = 0; r < 4; ++r) {
                int lp = wave * 16 + quad * 4 + r;
                int gp = blk * 64 + lp;
                int b = gp / 3136, pix = gp % 3136;
                int py = pix / 56, px = pix % 56;
                int oy = 2 * py + ry, ox = 2 * px + rx;
                c3[((size_t)(b * 112 + oy) * 112 + ox) * 12 + lm] = acc[r] + bias[lm];
            }
        }
    }
}

// ---------------------------------------------------------------------------
// L3 LN stats, coalesced: block per (image b, quarter h). channel =
// (t + 4k) % 12 -> 3 residue slots. pstat[(b*4+h)*24 + ch*2 + {0,1}]
// ---------------------------------------------------------------------------
__global__ void __launch_bounds__(256) k_ln3_stats(const float* __restrict__ c3,
                                                   float* __restrict__ pstat)
{
    __shared__ float bins[24];
    int t = threadIdx.x;
    int b = blockIdx.x >> 2, h = blockIdx.x & 3;
    if (t < 24) bins[t] = 0.f;
    __syncthreads();
    const float* base = c3 + (size_t)b * 150528 + h * 37632;
    float s0 = 0.f, s1 = 0.f, s2 = 0.f, q0 = 0.f, q1 = 0.f, q2 = 0.f;
    for (int k = 0; k < 147; k += 3) {
        float v0 = base[t + 256 * k];
        float v1 = base[t + 256 * (k + 1)];
        float v2 = base[t + 256 * (k + 2)];
        s0 += v0; q0 += v0 * v0;
        s1 += v1; q1 += v1 * v1;
        s2 += v2; q2 += v2 * v2;
    }
    int c0 = t % 12;
    int c1 = (c0 + 4) % 12;
    int c2i = (c0 + 8) % 12;
    atomicAdd(&bins[c0 * 2],      s0); atomicAdd(&bins[c0 * 2 + 1],  q0);
    atomicAdd(&bins[c1 * 2],      s1); atomicAdd(&bins[c1 * 2 + 1],  q1);
    atomicAdd(&bins[c2i * 2],     s2); atomicAdd(&bins[c2i * 2 + 1], q2);
    __syncthreads();
    if (t < 24) pstat[(size_t)blockIdx.x * 24 + t] = bins[t];
}

// ---------------------------------------------------------------------------
// L3 LN apply, in-place on C3 NHWC: combine 4 slice partials, LN + silu.
// ---------------------------------------------------------------------------
__global__ void __launch_bounds__(256) k_ln3_apply(float* __restrict__ c3,
                                                   const float* __restrict__ pstat,
                                                   const float* __restrict__ g,
                                                   const float* __restrict__ bv)
{
    int i = blockIdx.x * 256 + threadIdx.x;
    int ch = i % 12;
    int t2 = i / 12;
    int pix = t2 % 12544;
    int b = t2 / 12544;
    const float* ps = pstat + (size_t)b * 96 + ch * 2;
    float s = ps[0] + ps[24] + ps[48] + ps[72];
    float q = ps[1] + ps[25] + ps[49] + ps[73];
    float mu = s * (1.f / 12544.f);
    float rstd = rsqrtf(q * (1.f / 12544.f) - mu * mu + 1e-5f);
    float v = (c3[i] - mu) * rstd * g[pix] + bv[pix];
    c3[i] = v / (1.f + expf(-v));
}

// ---------------------------------------------------------------------------
// final convT 12->1, NHWC input: per tap position read 12 contiguous ci
// floats (wave reads 64x48B contiguous). Weight taps are wave-uniform
// scalar loads.
// ---------------------------------------------------------------------------
__global__ void __launch_bounds__(256) k_conv_final_nhwc(const float* __restrict__ x,
                                                         const float* __restrict__ wr,
                                                         const float* __restrict__ bias,
                                                         float* __restrict__ out)
{
    constexpr int HIN = 112, CIN = 12;
    constexpr int NPB = (B_ * HIN * HIN) / 256;   // 6272
    int pb = blockIdx.x % NPB;
    int ry = blockIdx.x / NPB;
    int rem = pb * 256 + threadIdx.x;
    int b   = rem / (HIN * HIN);
    int pix = rem % (HIN * HIN);
    int py = pix / HIN, px = pix % HIN;
    int r0 = py + ry - 1, r1 = r0 + 1;
    const float* xb = x + (size_t)b * (HIN * HIN * CIN);

    int   rows[2] = { r0, r1 };
    bool  rm[2]   = { r0 >= 0, r1 < HIN };
    int   cols[3] = { px - 1, px, px + 1 };
    bool  cm[3]   = { px >= 1, true, px + 1 < HIN };

    float gv[6][12];
    #pragma unroll
    for (int a = 0; a < 2; ++a) {
        #pragma unroll
        for (int cc = 0; cc < 3; ++cc) {
            int gi = a * 3 + cc;
            if (rm[a] && cm[cc]) {
                const float4* p4 = (const float4*)(xb +
                    ((size_t)(rows[a] * HIN + cols[cc])) * CIN);
                float4 v0 = p4[0], v1 = p4[1], v2 = p4[2];
                gv[gi][0] = v0.x; gv[gi][1]  = v0.y; gv[gi][2]  = v0.z; gv[gi][3]  = v0.w;
                gv[gi][4] = v1.x; gv[gi][5]  = v1.y; gv[gi][6]  = v1.z; gv[gi][7]  = v1.w;
                gv[gi][8] = v2.x; gv[gi][9]  = v2.y; gv[gi][10] = v2.z; gv[gi][11] = v2.w;
            } else {
                #pragma unroll
                for (int j = 0; j < 12; ++j) gv[gi][j] = 0.f;
            }
        }
    }

    const float4* w4 = (const float4*)wr;
    float acc0 = 0.f, acc1 = 0.f;
    #pragma unroll
    for (int ci = 0; ci < CIN; ++ci) {
        float4 W0 = w4[(2 * ry) * CIN + ci];
        float4 W1 = w4[(2 * ry + 1) * CIN + ci];
        acc0 += gv[0][ci] * W0.x + gv[1][ci] * W0.y + gv[3][ci] * W0.z + gv[4][ci] * W0.w;
        acc1 += gv[1][ci] * W1.x + gv[2][ci] * W1.y + gv[4][ci] * W1.z + gv[5][ci] * W1.w;
    }

    float bb = bias[0];
    float u0 = acc0 + bb, u1 = acc1 + bb;
    u0 = u0 / (1.f + expf(-u0));
    u1 = u1 / (1.f + expf(-u1));
    float2 v;
    v.x = fminf(fmaxf(u0, 0.f), 1.f);
    v.y = fminf(fmaxf(u1, 0.f), 1.f);
    int oy = 2 * py + ry;
    *(float2*)(out + (size_t)b * 50176 + oy * 224 + 2 * px) = v;
}

// ---------------------------------------------------------------------------
// launch
// ---------------------------------------------------------------------------
extern "C" void kernel_launch(void* const* d_in, const int* in_sizes, int n_in,
                              void* d_out, int out_size, void* d_ws, size_t ws_size,
                              hipStream_t stream)
{
    const float* x       = (const float*)d_in[0];
    const float* ts      = (const float*)d_in[1];
    const float* Wp      = (const float*)d_in[2];
    const float* bp      = (const float*)d_in[3];
    const float* Wt1     = (const float*)d_in[4];
    const float* bt1     = (const float*)d_in[5];
    const float* Wt2     = (const float*)d_in[6];
    const float* bt2     = (const float*)d_in[7];
    const float* a0_g    = (const float*)d_in[8];
    const float* a0_b    = (const float*)d_in[9];
    const float* a0_Wqkv = (const float*)d_in[10];
    const float* a0_bqkv = (const float*)d_in[11];
    const float* a0_Wo   = (const float*)d_in[12];
    const float* a0_bo   = (const float*)d_in[13];
    const float* a1_g    = (const float*)d_in[14];
    const float* a1_b    = (const float*)d_in[15];
    const float* a1_Wqkv = (const float*)d_in[16];
    const float* a1_bqkv = (const float*)d_in[17];
    const float* a1_Wo   = (const float*)d_in[18];
    const float* a1_bo   = (const float*)d_in[19];
    const float* Wm0     = (const float*)d_in[20];
    const float* bm0     = (const float*)d_in[21];
    const float* Wm1     = (const float*)d_in[22];
    const float* bm1     = (const float*)d_in[23];
    const float* Wm2     = (const float*)d_in[24];
    const float* bm2     = (const float*)d_in[25];
    const float* Wd1     = (const float*)d_in[26];
    const float* bd1     = (const float*)d_in[27];
    const float* l1g     = (const float*)d_in[28];
    const float* l1b     = (const float*)d_in[29];
    const float* Wd2     = (const float*)d_in[30];
    const float* bd2     = (const float*)d_in[31];
    const float* l2g     = (const float*)d_in[32];
    const float* l2b     = (const float*)d_in[33];
    const float* Wd3     = (const float*)d_in[34];
    const float* bd3     = (const float*)d_in[35];
    const float* l3g     = (const float*)d_in[36];
    const float* l3b     = (const float*)d_in[37];
    const float* Wd4     = (const float*)d_in[38];
    const float* bd4     = (const float*)d_in[39];
    float* out = (float*)d_out;

    // arena (floats); R = 25088*96
    const size_t R = 2408448;
    float* ws   = (float*)d_ws;
    float* tvec = ws;                          // 96
    float* p0   = ws + 512;                    // R
    float* h    = ws + 512 + R;                // R
    float* qkvb = ws + 512 + 2 * R;            // 3R
    float* ob   = ws + 512 + 5 * R;            // R
    float* p1   = ws + 512 + 6 * R;            // R
    float* part = ws + 512 + 7 * R;            // attn partials (aliases xh2/XH3)
    // decoder aliases:
    _Float16* xinh = (_Float16*)(ws + 512 + 2 * R);   // f16 NHWC (qkv region)
    float* C1   = ws + 512 + 5 * R;            // NHWC fp32 [b][28][28][48] (ob+p1)
    _Float16* xh2 = (_Float16*)(ws + 512 + 7 * R);    // f16 NHWC padded [b][30][30][48]
    float* C2   = ws + 512;                    // NHWC fp32 [b][56][56][24] (p0..qkv)
    _Float16* xh3 = (_Float16*)(ws + 512 + 7 * R + 5529600); // f16 NHWC padded [b][58][58][24]
    float* C3   = ws + 512;                    // NHWC fp32 [b][112][112][12]
    float* Wr   = ws + 512 + 7 * R + 5529600 + 10334208;  // 96,960 floats
    _Float16* WH = (_Float16*)(Wr + 96960);                // 101,376 halves
    _Float16* Wc  = (_Float16*)Wr;              // conv1 f16 B-weights (dead L1 slice)
    _Float16* Wc2 = (_Float16*)(Wr + 36864);    // conv2 f16 B-weights
    _Float16* Wc3 = (_Float16*)(Wr + 49152);    // conv3 f16 B-weights
    float* stat = Wr + 96960 + 50688;          // 12,288 floats (LN stats, reused)
    const size_t NEED = (512 + 7 * R + 5529600 + 10334208 + 96960 + 50688 + 12288 + 16)
                        * sizeof(float);
    if (ws_size < NEED) return;

    _Float16* WHqkv0 = WH;
    _Float16* WHqkv1 = WH + 27648;
    _Float16* WHwo0  = WH + 55296;
    _Float16* WHwo1  = WH + 64512;
    _Float16* WHwm0  = WH + 73728;
    _Float16* WHwm1  = WH + 82944;
    _Float16* WHwm2  = WH + 92160;

    k_time<<<1, 128, 0, stream>>>(ts, Wt1, bt1, Wt2, bt2, tvec);
    k_repack<<<379, 256, 0, stream>>>(Wd1, Wd2, Wd3, Wd4, Wr);
    k_wcvtc<<<288, 256, 0, stream>>>(Wd1, Wc);
    k_wcvt2<<<96, 256, 0, stream>>>(Wd2, Wc2);
    k_wcvt3<<<24, 256, 0, stream>>>(Wd3, Wc3);
    k_wcvt<<<396, 256, 0, stream>>>(a0_Wqkv, a1_Wqkv, a0_Wo, a1_Wo,
                                    Wm0, Wm1, Wm2, WH);
    k_patch_mfma<<<M_ROWS / 64, 256, 0, stream>>>(x, Wp, bp, p0);

    // MHSA block 0
    k_ln_row<<<1024, 256, 0, stream>>>(p0, a0_g, a0_b, h, M_ROWS);
    k_gemm_mfma<3, false, false, false, false><<<M_ROWS / 64, 256, 0, stream>>>(
        h, WHqkv0, a0_bqkv, nullptr, nullptr, qkvb, nullptr);
    k_attn_part<<<B_ * 4 * KS, 256, 0, stream>>>(qkvb, part);
    k_attn_comb<<<(B_ * 4 * NPATCH) / 256, 256, 0, stream>>>(part, ob);
    k_gemm_mfma<1, false, true, false, false><<<M_ROWS / 64, 256, 0, stream>>>(
        ob, WHwo0, a0_bo, p0, nullptr, p1, nullptr);

    // MHSA block 1 (+time)
    k_ln_row<<<1024, 256, 0, stream>>>(p1, a1_g, a1_b, h, M_ROWS);
    k_gemm_mfma<3, false, false, false, false><<<M_ROWS / 64, 256, 0, stream>>>(
        h, WHqkv1, a1_bqkv, nullptr, nullptr, qkvb, nullptr);
    k_attn_part<<<B_ * 4 * KS, 256, 0, stream>>>(qkvb, part);
    k_attn_comb<<<(B_ * 4 * NPATCH) / 256, 256, 0, stream>>>(part, ob);
    k_gemm_mfma<1, false, true, true, false><<<M_ROWS / 64, 256, 0, stream>>>(
        ob, WHwo1, a1_bo, p1, tvec, p0, nullptr);

    // qkv region free: zero xinh borders before MLP3 writes interior
    k_zb_h<<<2880, 256, 0, stream>>>(xinh);

    // MLP x3 (silu); last writes f16 NHWC padded xinh
    k_gemm_mfma<1, true, false, false, false><<<M_ROWS / 64, 256, 0, stream>>>(
        p0, WHwm0, bm0, nullptr, nullptr, p1, nullptr);
    k_gemm_mfma<1, true, false, false, false><<<M_ROWS / 64, 256, 0, stream>>>(
        p1, WHwm1, bm1, nullptr, nullptr, p0, nullptr);
    k_gemm_mfma<1, true, false, false, true><<<M_ROWS / 64, 256, 0, stream>>>(
        p0, WHwm2, bm2, nullptr, nullptr, nullptr, xinh);

    // decoder: all-NHWC chain
    k_conv1<<<M_ROWS / 64, 256, 0, stream>>>(xinh, Wc, bd1, C1);
    k_ln1_stats<<<1536, 256, 0, stream>>>(C1, stat);
    k_ln1_apply<<<21600, 256, 0, stream>>>(C1, stat, l1g, l1b, xh2);
    k_conv2_mfma<<<(B_ * 784) / 64, 256, 0, stream>>>(xh2, Wc2, bd2, C2);
    k_ln2_stats<<<256, 256, 0, stream>>>(C2, stat);
    k_ln2_apply<<<40368, 256, 0, stream>>>(C2, stat, l2g, l2b, xh3);
    k_conv3_mfma<<<(B_ * 3136) / 64, 256, 0, stream>>>(xh3, Wc3, bd3, C3);
    k_ln3_stats<<<512, 256, 0, stream>>>(C3, stat);
    k_ln3_apply<<<75264, 256, 0, stream>>>(C3, stat, l3g, l3b);
    k_conv_final_nhwc<<<2 * 6272, 256, 0, stream>>>(C3, Wr + 96768, bd4, out);
}

// Round 3
// 618.882 us; speedup vs baseline: 1.2990x; 1.1769x over previous
//
#include <hip/hip_runtime.h>
#include <cmath>

// ---------------------------------------------------------------------------
// TimestepVisionTransformer — Round 11: MFMA attention.
//   - k_attn_mfma (one block per (b,h), 4 waves, flash-style, f16 MFMA)
//     replaces k_attn_part + k_attn_comb (134+20us, MfmaUtil=0, VALU-bound).
//   - Q/K staged f16 [208][40], V transposed Vt[32][232], wave-private P
//     strips [16][232]; unnormalized P in f16, fp32 rowsum + final scale.
// Everything else = r10 (verified, 728us).
// B=128, IMG=224, P=16, C_IN=1, E=96, H=4, d=24, NAX=14, N=196, M=B*N=25088
// ---------------------------------------------------------------------------

#define B_   128
#define NPATCH 196
#define M_ROWS (B_*NPATCH)     // 25088
#define E_   96

typedef _Float16 half8 __attribute__((ext_vector_type(8)));
typedef _Float16 half4v __attribute__((ext_vector_type(4)));
typedef float f32x4 __attribute__((ext_vector_type(4)));

// ---------------------------------------------------------------------------
// time embedding
// ---------------------------------------------------------------------------
__global__ void k_time(const float* __restrict__ ts,
                       const float* __restrict__ Wt1, const float* __restrict__ bt1,
                       const float* __restrict__ Wt2, const float* __restrict__ bt2,
                       float* __restrict__ timev)
{
    __shared__ float h[128];
    float e = 0.69314718055994530942f * ts[0];
    float sv = sinf(e), cv = cosf(e);
    int t = threadIdx.x;
    float z = sv * Wt1[t] + cv * Wt1[128 + t] + bt1[t];
    h[t] = z / (1.f + expf(-z));
    __syncthreads();
    if (t < 96) {
        float acc = bt2[t];
        for (int j = 0; j < 128; ++j) acc += h[j] * Wt2[j * 96 + t];
        timev[t] = acc;
    }
}

// ---------------------------------------------------------------------------
// weight repack (fp32 per-parity taps). Only the L4 slice [96768,96960) is
// still consumed as fp32 (conv_final); other slices overwritten by f16 packs.
// ---------------------------------------------------------------------------
__global__ void __launch_bounds__(256) k_repack(const float* __restrict__ w1,
                                                const float* __restrict__ w2,
                                                const float* __restrict__ w3,
                                                const float* __restrict__ w4f,
                                                float* __restrict__ wr)
{
    int i = blockIdx.x * 256 + threadIdx.x;
    const float* src; int CIN, COUT, e; float* dst;
    if      (i < 73728) { src = w1;  CIN = 96; COUT = 48; e = i;          dst = wr; }
    else if (i < 92160) { src = w2;  CIN = 48; COUT = 24; e = i - 73728;  dst = wr + 73728; }
    else if (i < 96768) { src = w3;  CIN = 24; COUT = 12; e = i - 92160;  dst = wr + 92160; }
    else if (i < 96960) { src = w4f; CIN = 12; COUT = 1;  e = i - 96768;  dst = wr + 96768; }
    else return;
    int per = CIN * COUT * 4;
    int par = e / per, rem = e % per;
    int ci = rem / (COUT * 4);
    int o  = (rem >> 2) % COUT;
    int j  = rem & 3;
    int ry = par >> 1, rx = par & 1;
    int wy = (j < 2)  ? (3 - ry) : (1 - ry);
    int wx = (j & 1)  ? (1 - rx) : (3 - rx);
    dst[e] = src[(ci * COUT + o) * 16 + wy * 4 + wx];
}

// ---------------------------------------------------------------------------
// conv1 weights -> f16 B-layout Wc[p][o][k=tap*96+ci]
// ---------------------------------------------------------------------------
__global__ void __launch_bounds__(256) k_wcvtc(const float* __restrict__ w1,
                                               _Float16* __restrict__ wc)
{
    int i = blockIdx.x * 256 + threadIdx.x;
    if (i >= 4 * 48 * 384) return;
    int p = i / 18432, rem = i % 18432;
    int o = rem / 384, k = rem % 384;
    int tap = k / 96, ci = k % 96;
    int ry = p >> 1, rx = p & 1;
    int wy = (tap < 2) ? (3 - ry) : (1 - ry);
    int wx = (tap & 1) ? (1 - rx) : (3 - rx);
    wc[i] = (_Float16)w1[(ci * 48 + o) * 16 + wy * 4 + wx];
}

// ---------------------------------------------------------------------------
// conv2 weights -> f16 B-layout Wc2[p][o(32, o>=24 zero)][k=tap*48+ci]
// ---------------------------------------------------------------------------
__global__ void __launch_bounds__(256) k_wcvt2(const float* __restrict__ w2,
                                               _Float16* __restrict__ wc2)
{
    int i = blockIdx.x * 256 + threadIdx.x;
    if (i >= 4 * 32 * 192) return;
    int p = i / 6144, rem = i % 6144;
    int o = rem / 192, k = rem % 192;
    int tap = k / 48, ci = k % 48;
    int ry = p >> 1, rx = p & 1;
    int wy = (tap < 2) ? (3 - ry) : (1 - ry);
    int wx = (tap & 1) ? (1 - rx) : (3 - rx);
    wc2[i] = (o < 24) ? (_Float16)w2[(ci * 24 + o) * 16 + wy * 4 + wx]
                      : (_Float16)0.f;
}

// ---------------------------------------------------------------------------
// conv3 weights -> f16 B-layout Wc3[p][o(16, o>=12 zero)][k=tap*24+ci]
// ---------------------------------------------------------------------------
__global__ void __launch_bounds__(256) k_wcvt3(const float* __restrict__ w3,
                                               _Float16* __restrict__ wc3)
{
    int i = blockIdx.x * 256 + threadIdx.x;
    if (i >= 4 * 16 * 96) return;
    int p = i / 1536, rem = i % 1536;
    int o = rem / 96, k = rem % 96;
    int tap = k / 24, ci = k % 24;
    int ry = p >> 1, rx = p & 1;
    int wy = (tap < 2) ? (3 - ry) : (1 - ry);
    int wx = (tap & 1) ? (1 - rx) : (3 - rx);
    wc3[i] = (o < 12) ? (_Float16)w3[(ci * 12 + o) * 16 + wy * 4 + wx]
                      : (_Float16)0.f;
}

// ---------------------------------------------------------------------------
// transformer weight convert+transpose to half: Wt[n][k] = W[k][n]
// ---------------------------------------------------------------------------
__global__ void __launch_bounds__(256) k_wcvt(const float* __restrict__ qkv0,
                                              const float* __restrict__ qkv1,
                                              const float* __restrict__ wo0,
                                              const float* __restrict__ wo1,
                                              const float* __restrict__ wm0,
                                              const float* __restrict__ wm1,
                                              const float* __restrict__ wm2,
                                              _Float16* __restrict__ wh)
{
    int i = blockIdx.x * 256 + threadIdx.x;
    const float* src; int N; int e;
    if      (i < 27648)  { src = qkv0; N = 288; e = i; }
    else if (i < 55296)  { src = qkv1; N = 288; e = i - 27648; }
    else if (i < 64512)  { src = wo0;  N = 96;  e = i - 55296; }
    else if (i < 73728)  { src = wo1;  N = 96;  e = i - 64512; }
    else if (i < 82944)  { src = wm0;  N = 96;  e = i - 73728; }
    else if (i < 92160)  { src = wm1;  N = 96;  e = i - 82944; }
    else if (i < 101376) { src = wm2;  N = 96;  e = i - 92160; }
    else return;
    int n = e / 96, k = e % 96;
    wh[i] = (_Float16)src[k * N + n];
}

// ---------------------------------------------------------------------------
// zero the borders of xinh NHWC f16 [b][16][16][96]
// ---------------------------------------------------------------------------
__global__ void __launch_bounds__(256) k_zb_h(_Float16* __restrict__ xinh)
{
    int i = blockIdx.x * 256 + threadIdx.x;
    if (i >= 128 * 60 * 96) return;
    int b = i / 5760, r = i % 5760;
    int pos = r / 96, ch = r % 96;
    int py, px;
    if      (pos < 16) { py = 0;        px = pos; }
    else if (pos < 32) { py = 15;       px = pos - 16; }
    else if (pos < 46) { py = pos - 31; px = 0; }
    else               { py = pos - 45; px = 15; }
    xinh[((size_t)(b * 256) + py * 16 + px) * 96 + ch] = (_Float16)0.f;
}

// ---------------------------------------------------------------------------
// patch embed GEMM via f16 MFMA (r7, verified)
// ---------------------------------------------------------------------------
__global__ void __launch_bounds__(256) k_patch_mfma(const float* __restrict__ x,
                                                    const float* __restrict__ Wp,
                                                    const float* __restrict__ bp,
                                                    float* __restrict__ out)
{
    __shared__ __align__(16) _Float16 Ah[64 * 136];
    __shared__ __align__(16) _Float16 Wh[96 * 136];
    int t = threadIdx.x;
    int p0 = blockIdx.x * 64;
    int wave = t >> 6, lane = t & 63;
    int lm = lane & 15, quad = lane >> 4;
    f32x4 acc[6];
    #pragma unroll
    for (int nt = 0; nt < 6; ++nt) acc[nt] = (f32x4){0.f, 0.f, 0.f, 0.f};

    for (int kc = 0; kc < 2; ++kc) {
        __syncthreads();
        for (int i = t; i < 512; i += 256) {
            int lp = i >> 3, pyl = i & 7;
            int patch = p0 + lp;
            int b = patch / NPATCH, n = patch % NPATCH;
            int ny = n / 14, nx = n % 14;
            const float4* s4 = (const float4*)(x +
                ((size_t)(b * 224) + ny * 16 + kc * 8 + pyl) * 224 + nx * 16);
            float4 v0 = s4[0], v1 = s4[1], v2 = s4[2], v3 = s4[3];
            half8 h0, h1;
            h0[0]=(_Float16)v0.x; h0[1]=(_Float16)v0.y; h0[2]=(_Float16)v0.z; h0[3]=(_Float16)v0.w;
            h0[4]=(_Float16)v1.x; h0[5]=(_Float16)v1.y; h0[6]=(_Float16)v1.z; h0[7]=(_Float16)v1.w;
            h1[0]=(_Float16)v2.x; h1[1]=(_Float16)v2.y; h1[2]=(_Float16)v2.z; h1[3]=(_Float16)v2.w;
            h1[4]=(_Float16)v3.x; h1[5]=(_Float16)v3.y; h1[6]=(_Float16)v3.z; h1[7]=(_Float16)v3.w;
            *(half8*)&Ah[lp * 136 + pyl * 16]     = h0;
            *(half8*)&Ah[lp * 136 + pyl * 16 + 8] = h1;
        }
        for (int i = t; i < 1536; i += 256) {
            int e = i >> 4, s = i & 15;
            const float4* s4 = (const float4*)(Wp + e * 256 + kc * 128 + s * 8);
            float4 v0 = s4[0], v1 = s4[1];
            half8 h0;
            h0[0]=(_Float16)v0.x; h0[1]=(_Float16)v0.y; h0[2]=(_Float16)v0.z; h0[3]=(_Float16)v0.w;
            h0[4]=(_Float16)v1.x; h0[5]=(_Float16)v1.y; h0[6]=(_Float16)v1.z; h0[7]=(_Float16)v1.w;
            *(half8*)&Wh[e * 136 + s * 8] = h0;
        }
        __syncthreads();
        half8 af[4];
        #pragma unroll
        for (int ks = 0; ks < 4; ++ks)
            af[ks] = *(const half8*)&Ah[(wave * 16 + lm) * 136 + ks * 32 + quad * 8];
        #pragma unroll
        for (int ks = 0; ks < 4; ++ks) {
            #pragma unroll
            for (int nt = 0; nt < 6; ++nt) {
                half8 bf = *(const half8*)&Wh[(nt * 16 + lm) * 136 + ks * 32 + quad * 8];
                acc[nt] = __builtin_amdgcn_mfma_f32_16x16x32_f16(af[ks], bf, acc[nt], 0, 0, 0);
            }
        }
    }

    #pragma unroll
    for (int nt = 0; nt < 6; ++nt) {
        #pragma unroll
        for (int r = 0; r < 4; ++r) {
            int e = nt * 16 + lm;
            int lp = wave * 16 + quad * 4 + r;
            int patch = p0 + lp;
            int n = patch % NPATCH;
            int ny = n / 14, nx = n % 14;
            float yx = (float)(ny + nx);
            float v = acc[nt][r] + bp[e];
            float other = __shfl_xor(v, 1);
            float fi = (float)(e >> 1);
            float theta = expf(fi * (-2.f / 96.f) * 9.210340371976184f);
            float ang = theta * yx;
            float c = cosf(ang), s = sinf(ang);
            float outv = (lm & 1) ? (other * s + v * c) : (v * c - other * s);
            out[(size_t)patch * 96 + e] = outv;
        }
    }
}

// ---------------------------------------------------------------------------
// row LayerNorm over 96, wave per row
// ---------------------------------------------------------------------------
__global__ void __launch_bounds__(256) k_ln_row(const float* __restrict__ x,
                                                const float* __restrict__ g,
                                                const float* __restrict__ bv,
                                                float* __restrict__ out, int M)
{
    int lane = threadIdx.x & 63;
    int gw = (blockIdx.x * 256 + threadIdx.x) >> 6;
    int nw = (gridDim.x * 256) >> 6;
    float g0 = g[lane], b0 = bv[lane];
    float g1 = 0.f, b1 = 0.f;
    if (lane < 32) { g1 = g[64 + lane]; b1 = bv[64 + lane]; }
    for (int r = gw; r < M; r += nw) {
        const float* xr = x + (size_t)r * 96;
        float a = xr[lane];
        float c = (lane < 32) ? xr[64 + lane] : 0.f;
        float s = a + c, q = a * a + c * c;
        #pragma unroll
        for (int off = 32; off; off >>= 1) {
            s += __shfl_xor(s, off);
            q += __shfl_xor(q, off);
        }
        float mu = s * (1.f / 96.f);
        float rstd = rsqrtf(q * (1.f / 96.f) - mu * mu + 1e-5f);
        float* orow = out + (size_t)r * 96;
        orow[lane] = (a - mu) * rstd * g0 + b0;
        if (lane < 32) orow[64 + lane] = (c - mu) * rstd * g1 + b1;
    }
}

// ---------------------------------------------------------------------------
// MFMA row GEMM (r6, verified). OUTH: write f16 NHWC padded xinh instead.
// ---------------------------------------------------------------------------
template<int NCHUNKS, bool SILU, bool RES, bool ADDTIME, bool OUTH>
__global__ void __launch_bounds__(256) k_gemm_mfma(const float* __restrict__ A,
                                                   const _Float16* __restrict__ Wt,
                                                   const float* __restrict__ bias,
                                                   const float* __restrict__ res,
                                                   const float* __restrict__ timev,
                                                   float* __restrict__ out,
                                                   _Float16* __restrict__ outh)
{
    __shared__ __align__(16) _Float16 Ah[64 * 96];
    __shared__ __align__(16) _Float16 Wh[96 * 96];
    constexpr int NTOT = NCHUNKS * 96;
    int t = threadIdx.x;
    size_t row0 = (size_t)blockIdx.x * 64;

    const float4* a4 = (const float4*)(A + row0 * 96);
    for (int i = t; i < 1536; i += 256) {
        float4 v = a4[i];
        half4v hv;
        hv[0] = (_Float16)v.x; hv[1] = (_Float16)v.y;
        hv[2] = (_Float16)v.z; hv[3] = (_Float16)v.w;
        *(half4v*)&Ah[i * 4] = hv;
    }

    int wave = t >> 6, lane = t & 63;
    int lm = lane & 15, quad = lane >> 4;
    const f32x4 vzero = {0.f, 0.f, 0.f, 0.f};

    for (int ch = 0; ch < NCHUNKS; ++ch) {
        __syncthreads();
        {
            const uint4* src = (const uint4*)(Wt + (size_t)ch * 9216);
            uint4* dst = (uint4*)Wh;
            for (int i = t; i < 1152; i += 256) dst[i] = src[i];
        }
        __syncthreads();

        half8 af[3];
        #pragma unroll
        for (int ks = 0; ks < 3; ++ks)
            af[ks] = *(const half8*)&Ah[(wave * 16 + lm) * 96 + ks * 32 + quad * 8];

        f32x4 acc[6];
        #pragma unroll
        for (int ct = 0; ct < 6; ++ct) acc[ct] = vzero;

        #pragma unroll
        for (int ct = 0; ct < 6; ++ct) {
            #pragma unroll
            for (int ks = 0; ks < 3; ++ks) {
                half8 bf = *(const half8*)&Wh[(ct * 16 + lm) * 96 + ks * 32 + quad * 8];
                acc[ct] = __builtin_amdgcn_mfma_f32_16x16x32_f16(af[ks], bf, acc[ct], 0, 0, 0);
            }
        }

        #pragma unroll
        for (int ct = 0; ct < 6; ++ct) {
            #pragma unroll
            for (int r = 0; r < 4; ++r) {
                int lr = wave * 16 + quad * 4 + r;
                size_t row = row0 + lr;
                int lc = ct * 16 + lm;
                int col = ch * 96 + lc;
                float v = acc[ct][r] + bias[col];
                if constexpr (RES)     v += res[row * 96 + lc];
                if constexpr (ADDTIME) v += timev[lc];
                if constexpr (SILU)    v = v / (1.f + expf(-v));
                if constexpr (OUTH) {
                    size_t b = row / NPATCH; int n = (int)(row % NPATCH);
                    int ny = n / 14, nx = n % 14;
                    outh[((b * 256) + (1 + ny) * 16 + (1 + nx)) * 96 + col] = (_Float16)v;
                } else {
                    out[row * NTOT + col] = v;
                }
            }
        }
    }
}

// ---------------------------------------------------------------------------
// MFMA attention: one block per (b,h), 4 waves. Q/K f16 LDS [208][40],
// V transposed Vt[32][232], wave-private P strip [16][232] f16.
// QK^T: 13 MFMA per row-tile; exp+mask in regs; fp32 rowsum via shfl_xor;
// PV: 7 ksteps x 2 col-tiles; final scale by 1/rowsum; write ob fp32.
// ---------------------------------------------------------------------------
__global__ void __launch_bounds__(256) k_attn_mfma(const float* __restrict__ qkv,
                                                   float* __restrict__ o)
{
    __shared__ __align__(16) _Float16 Qs[208 * 40];
    __shared__ __align__(16) _Float16 Ks[208 * 40];
    __shared__ __align__(16) _Float16 Vt[32 * 232];
    __shared__ __align__(16) _Float16 Pw[4][16 * 232];

    int t = threadIdx.x;
    int bh = blockIdx.x;
    int b = bh >> 2, h = bh & 3;
    const float* base = qkv + (size_t)b * NPATCH * 288 + h * 24;

    // zero all LDS (pads must be 0)
    {
        const int4 z = {0, 0, 0, 0};
        int4* q4 = (int4*)Qs; int4* k4 = (int4*)Ks;
        for (int i = t; i < 1040; i += 256) { q4[i] = z; k4[i] = z; }
        int4* v4 = (int4*)Vt;
        for (int i = t; i < 928; i += 256) v4[i] = z;
        int4* p4 = (int4*)&Pw[0][0];
        for (int i = t; i < 1856; i += 256) p4[i] = z;
    }
    __syncthreads();

    // stage Q,K (row-major, stride 40) and V transposed (Vt[d][key], stride 232)
    for (int i = t; i < NPATCH * 24; i += 256) {
        int r = i / 24, d = i % 24;
        const float* row = base + (size_t)r * 288;
        Qs[r * 40 + d]   = (_Float16)row[d];
        Ks[r * 40 + d]   = (_Float16)row[96 + d];
        Vt[d * 232 + r]  = (_Float16)row[192 + d];
    }
    __syncthreads();

    int wave = t >> 6, lane = t & 63;
    int lm = lane & 15, quad = lane >> 4;
    const float scale = 0.2041241452319315f;

    // hoist K B-fragments (shared across this wave's row-tiles)
    half8 bk[13];
    #pragma unroll
    for (int ct = 0; ct < 13; ++ct)
        bk[ct] = *(const half8*)&Ks[(ct * 16 + lm) * 40 + quad * 8];

    _Float16* pw = &Pw[wave][0];

    for (int rt = wave; rt < 13; rt += 4) {
        half8 aq = *(const half8*)&Qs[(rt * 16 + lm) * 40 + quad * 8];
        float rsum[4] = {0.f, 0.f, 0.f, 0.f};

        #pragma unroll
        for (int ct = 0; ct < 13; ++ct) {
            f32x4 s = (f32x4){0.f, 0.f, 0.f, 0.f};
            s = __builtin_amdgcn_mfma_f32_16x16x32_f16(aq, bk[ct], s, 0, 0, 0);
            #pragma unroll
            for (int r = 0; r < 4; ++r) {
                float p = __expf(fminf(s[r] * scale, 60.f));
                if (ct == 12 && lm >= 4) p = 0.f;   // keys 196..207 invalid
                rsum[r] += p;
                pw[(quad * 4 + r) * 232 + ct * 16 + lm] = (_Float16)p;
            }
        }

        // reduce row sums across the 16 lm-lanes
        #pragma unroll
        for (int r = 0; r < 4; ++r) {
            float s = rsum[r];
            s += __shfl_xor(s, 1);
            s += __shfl_xor(s, 2);
            s += __shfl_xor(s, 4);
            s += __shfl_xor(s, 8);
            rsum[r] = 1.f / s;
        }

        // PV: P[16][208(+pad0)] @ Vt -> O[16][32]
        f32x4 ov0 = (f32x4){0.f, 0.f, 0.f, 0.f};
        f32x4 ov1 = (f32x4){0.f, 0.f, 0.f, 0.f};
        #pragma unroll
        for (int ks = 0; ks < 7; ++ks) {
            half8 ap = *(const half8*)&pw[lm * 232 + ks * 32 + quad * 8];
            half8 bv0 = *(const half8*)&Vt[(lm) * 232 + ks * 32 + quad * 8];
            half8 bv1 = *(const half8*)&Vt[(16 + lm) * 232 + ks * 32 + quad * 8];
            ov0 = __builtin_amdgcn_mfma_f32_16x16x32_f16(ap, bv0, ov0, 0, 0, 0);
            ov1 = __builtin_amdgcn_mfma_f32_16x16x32_f16(ap, bv1, ov1, 0, 0, 0);
        }

        // write O (d = lm for ov0, 16+lm for ov1; valid d < 24)
        #pragma unroll
        for (int r = 0; r < 4; ++r) {
            int row = rt * 16 + quad * 4 + r;
            if (row < NPATCH) {
                float* orow = o + ((size_t)b * NPATCH + row) * 96 + h * 24;
                orow[lm] = ov0[r] * rsum[r];
                if (lm < 8) orow[16 + lm] = ov1[r] * rsum[r];
            }
        }
    }
}

// ---------------------------------------------------------------------------
// conv L1 via MFMA (r7, verified): xinh NHWC f16 padded -> C1 NHWC fp32
// ---------------------------------------------------------------------------
__global__ void __launch_bounds__(256) k_conv1(const _Float16* __restrict__ xinh,
                                               const _Float16* __restrict__ wc,
                                               const float* __restrict__ bias,
                                               float* __restrict__ c1)
{
    __shared__ __align__(16) _Float16 Ah[64 * 392];
    int t = threadIdx.x;
    int blk = blockIdx.x;
    int wave = t >> 6, lane = t & 63;
    int lm = lane & 15, quad = lane >> 4;

    for (int p = 0; p < 4; ++p) {
        int ry = p >> 1, rx = p & 1;
        __syncthreads();
        for (int i = t; i < 64 * 48; i += 256) {
            int lp = i / 48, rem = i % 48;
            int tap = rem / 12;
            int gp = blk * 64 + lp;
            int b = gp / NPATCH, pix = gp % NPATCH;
            int py = pix / 14, px = pix % 14;
            int row = py + ry + (tap >> 1), col = px + rx + (tap & 1);
            const uint4* src = (const uint4*)(xinh +
                ((size_t)(b * 256) + row * 16 + col) * 96 + (rem % 12) * 8);
            *(uint4*)&Ah[lp * 392 + rem * 8] = *src;
        }
        __syncthreads();

        half8 af[12];
        #pragma unroll
        for (int ks = 0; ks < 12; ++ks)
            af[ks] = *(const half8*)&Ah[(wave * 16 + lm) * 392 + ks * 32 + quad * 8];

        f32x4 acc[3];
        #pragma unroll
        for (int nt = 0; nt < 3; ++nt) acc[nt] = (f32x4){0.f, 0.f, 0.f, 0.f};

        #pragma unroll
        for (int ks = 0; ks < 12; ++ks) {
            #pragma unroll
            for (int nt = 0; nt < 3; ++nt) {
                half8 bf = *(const half8*)&wc[((size_t)(p * 48 + nt * 16 + lm)) * 384
                                              + ks * 32 + quad * 8];
                acc[nt] = __builtin_amdgcn_mfma_f32_16x16x32_f16(af[ks], bf, acc[nt], 0, 0, 0);
            }
        }

        #pragma unroll
        for (int nt = 0; nt < 3; ++nt) {
            #pragma unroll
            for (int r = 0; r < 4; ++r) {
                int o = nt * 16 + lm;
                int lp = wave * 16 + quad * 4 + r;
                int gp = blk * 64 + lp;
                int b = gp / NPATCH, pix = gp % NPATCH;
                int py = pix / 14, px = pix % 14;
                int oy = 2 * py + ry, ox = 2 * px + rx;
                c1[((size_t)(b * 28 + oy) * 28 + ox) * 48 + o] = acc[nt][r] + bias[o];
            }
        }
    }
}

// ---------------------------------------------------------------------------
// L1 LN stats: one wave per (b,ch) over NHWC C1 -> stat[b*48+ch] = {mu,rstd}
// ---------------------------------------------------------------------------
__global__ void __launch_bounds__(256) k_ln1_stats(const float* __restrict__ c1,
                                                   float* __restrict__ stat)
{
    int idx = blockIdx.x * 4 + (threadIdx.x >> 6);   // b*48+ch
    int lane = threadIdx.x & 63;
    int b = idx / 48, ch = idx % 48;
    const float* base = c1 + (size_t)b * 784 * 48 + ch;
    float s = 0.f, q = 0.f;
    for (int pix = lane; pix < 784; pix += 64) {
        float v = base[(size_t)pix * 48];
        s += v; q += v * v;
    }
    #pragma unroll
    for (int off = 32; off; off >>= 1) {
        s += __shfl_xor(s, off);
        q += __shfl_xor(q, off);
    }
    if (lane == 0) {
        float mu = s * (1.f / 784.f);
        float rstd = rsqrtf(q * (1.f / 784.f) - mu * mu + 1e-5f);
        stat[idx * 2]     = mu;
        stat[idx * 2 + 1] = rstd;
    }
}

// ---------------------------------------------------------------------------
// L1 LN apply: NHWC C1 + stat -> f16 NHWC padded XH2 [b][30][30][48], silu.
// ---------------------------------------------------------------------------
__global__ void __launch_bounds__(256) k_ln1_apply(const float* __restrict__ c1,
                                                   const float* __restrict__ stat,
                                                   const float* __restrict__ g,
                                                   const float* __restrict__ bv,
                                                   _Float16* __restrict__ xh)
{
    int i = blockIdx.x * 256 + threadIdx.x;          // ((b*900)+pos)*48 + ch
    if (i >= 128 * 900 * 48) return;
    int ch = i % 48;
    int t2 = i / 48;
    int pos = t2 % 900;
    int b = t2 / 900;
    int py = pos / 30, px = pos % 30;
    float v = 0.f;
    if (py >= 1 && py <= 28 && px >= 1 && px <= 28) {
        int j = (py - 1) * 28 + (px - 1);
        int plane = b * 48 + ch;
        float mu = stat[plane * 2], rstd = stat[plane * 2 + 1];
        float u = (c1[((size_t)b * 784 + j) * 48 + ch] - mu) * rstd * g[j] + bv[j];
        v = u / (1.f + expf(-u));
    }
    xh[i] = (_Float16)v;
}

// ---------------------------------------------------------------------------
// conv L2 via MFMA (r9, verified): XH2 NHWC f16 padded -> C2 NHWC fp32
// ---------------------------------------------------------------------------
__global__ void __launch_bounds__(256) k_conv2_mfma(const _Float16* __restrict__ xh,
                                                    const _Float16* __restrict__ wc,
                                                    const float* __restrict__ bias,
                                                    float* __restrict__ c2)
{
    __shared__ __align__(16) _Float16 Ah[64 * 200];   // 192 + 8 pad
    int t = threadIdx.x;
    int blk = blockIdx.x;
    int wave = t >> 6, lane = t & 63;
    int lm = lane & 15, quad = lane >> 4;

    for (int p = 0; p < 4; ++p) {
        int ry = p >> 1, rx = p & 1;
        __syncthreads();
        for (int i = t; i < 64 * 24; i += 256) {
            int lp = i / 24, c = i % 24;              // c = half8 chunk of K
            int tap = c / 6;
            int gp = blk * 64 + lp;
            int b = gp / 784, pix = gp % 784;
            int py = pix / 28, px = pix % 28;
            int row = py + ry + (tap >> 1), col = px + rx + (tap & 1);
            *(uint4*)&Ah[lp * 200 + c * 8] =
                *(const uint4*)(xh + ((size_t)(b * 900) + row * 30 + col) * 48
                                + (c % 6) * 8);
        }
        __syncthreads();

        half8 af[6];
        #pragma unroll
        for (int ks = 0; ks < 6; ++ks)
            af[ks] = *(const half8*)&Ah[(wave * 16 + lm) * 200 + ks * 32 + quad * 8];

        f32x4 acc[2];
        acc[0] = (f32x4){0.f, 0.f, 0.f, 0.f};
        acc[1] = (f32x4){0.f, 0.f, 0.f, 0.f};

        #pragma unroll
        for (int ks = 0; ks < 6; ++ks) {
            #pragma unroll
            for (int ct = 0; ct < 2; ++ct) {
                half8 bf = *(const half8*)&wc[((size_t)(p * 32 + ct * 16 + lm)) * 192
                                              + ks * 32 + quad * 8];
                acc[ct] = __builtin_amdgcn_mfma_f32_16x16x32_f16(af[ks], bf, acc[ct], 0, 0, 0);
            }
        }

        #pragma unroll
        for (int ct = 0; ct < 2; ++ct) {
            int o = ct * 16 + lm;
            if (o < 24) {
                #pragma unroll
                for (int r = 0; r < 4; ++r) {
                    int lp = wave * 16 + quad * 4 + r;
                    int gp = blk * 64 + lp;
                    int b = gp / 784, pix = gp % 784;
                    int py = pix / 28, px = pix % 28;
                    int oy = 2 * py + ry, ox = 2 * px + rx;
                    c2[((size_t)(b * 56 + oy) * 56 + ox) * 24 + o] = acc[ct][r] + bias[o];
                }
            }
        }
    }
}

// ---------------------------------------------------------------------------
// L2 LN stats, coalesced: block per (image b, half h).
// ---------------------------------------------------------------------------
__global__ void __launch_bounds__(256) k_ln2_stats(const float* __restrict__ c2,
                                                   float* __restrict__ pstat)
{
    __shared__ float bins[48];
    int t = threadIdx.x;
    int b = blockIdx.x >> 1, h = blockIdx.x & 1;
    if (t < 48) bins[t] = 0.f;
    __syncthreads();
    const float* base = c2 + (size_t)b * 75264 + h * 37632;
    float s0 = 0.f, s1 = 0.f, s2 = 0.f, q0 = 0.f, q1 = 0.f, q2 = 0.f;
    for (int k = 0; k < 147; k += 3) {
        float v0 = base[t + 256 * k];
        float v1 = base[t + 256 * (k + 1)];
        float v2 = base[t + 256 * (k + 2)];
        s0 += v0; q0 += v0 * v0;
        s1 += v1; q1 += v1 * v1;
        s2 += v2; q2 += v2 * v2;
    }
    int c0 = t % 24;
    int c1 = (c0 + 16) % 24;
    int c2i = (c0 + 8) % 24;
    atomicAdd(&bins[c0 * 2],      s0); atomicAdd(&bins[c0 * 2 + 1],  q0);
    atomicAdd(&bins[c1 * 2],      s1); atomicAdd(&bins[c1 * 2 + 1],  q1);
    atomicAdd(&bins[c2i * 2],     s2); atomicAdd(&bins[c2i * 2 + 1], q2);
    __syncthreads();
    if (t < 48) pstat[(size_t)blockIdx.x * 48 + t] = bins[t];
}

// ---------------------------------------------------------------------------
// L2 LN apply: C2 NHWC + pstat -> f16 NHWC padded XH3 [b][58][58][24], silu.
// ---------------------------------------------------------------------------
__global__ void __launch_bounds__(256) k_ln2_apply(const float* __restrict__ c2,
                                                   const float* __restrict__ pstat,
                                                   const float* __restrict__ g,
                                                   const float* __restrict__ bv,
                                                   _Float16* __restrict__ xh)
{
    int i = blockIdx.x * 256 + threadIdx.x;          // ((b*3364)+pos)*24 + ch
    int ch = i % 24;
    int t2 = i / 24;
    int pos = t2 % 3364;
    int b = t2 / 3364;
    int py = pos / 58, px = pos % 58;
    float v = 0.f;
    if (py >= 1 && py <= 56 && px >= 1 && px <= 56) {
        int j = (py - 1) * 56 + (px - 1);
        const float* ps = pstat + (size_t)b * 96 + ch * 2;
        float s = ps[0] + ps[48];
        float q = ps[1] + ps[49];
        float mu = s * (1.f / 3136.f);
        float rstd = rsqrtf(q * (1.f / 3136.f) - mu * mu + 1e-5f);
        float u = (c2[((size_t)b * 3136 + j) * 24 + ch] - mu) * rstd * g[j] + bv[j];
        v = u / (1.f + expf(-u));
    }
    xh[i] = (_Float16)v;
}

// ---------------------------------------------------------------------------
// conv L3 via MFMA (r10, verified): XH3 NHWC f16 padded -> C3 NHWC fp32
// ---------------------------------------------------------------------------
__global__ void __launch_bounds__(256) k_conv3_mfma(const _Float16* __restrict__ xh,
                                                    const _Float16* __restrict__ wc,
                                                    const float* __restrict__ bias,
                                                    float* __restrict__ c3)
{
    __shared__ __align__(16) _Float16 Ah[64 * 104];   // 96 + 8 pad
    int t = threadIdx.x;
    int blk = blockIdx.x;
    int wave = t >> 6, lane = t & 63;
    int lm = lane & 15, quad = lane >> 4;

    for (int p = 0; p < 4; ++p) {
        int ry = p >> 1, rx = p & 1;
        __syncthreads();
        for (int i = t; i < 64 * 12; i += 256) {
            int lp = i / 12, c = i % 12;              // c = half8 chunk of K
            int tap = c / 3;
            int gp = blk * 64 + lp;
            int b = gp / 3136, pix = gp % 3136;
            int py = pix / 56, px = pix % 56;
            int row = py + ry + (tap >> 1), col = px + rx + (tap & 1);
            *(uint4*)&Ah[lp * 104 + c * 8] =
                *(const uint4*)(xh + ((size_t)(b * 3364) + row * 58 + col) * 24
                                + (c % 3) * 8);
        }
        __syncthreads();

        half8 af[3];
        #pragma unroll
        for (int ks = 0; ks < 3; ++ks)
            af[ks] = *(const half8*)&Ah[(wave * 16 + lm) * 104 + ks * 32 + quad * 8];

        f32x4 acc = (f32x4){0.f, 0.f, 0.f, 0.f};
        #pragma unroll
        for (int ks = 0; ks < 3; ++ks) {
            half8 bf = *(const half8*)&wc[((size_t)(p * 16 + lm)) * 96
                                          + ks * 32 + quad * 8];
            acc = __builtin_amdgcn_mfma_f32_16x16x32_f16(af[ks], bf, acc, 0, 0, 0);
        }

        if (lm < 12) {
            #pragma unroll
            for (int r = 0; r < 4; ++r) {
                int lp = wave * 16 + quad * 4 + r;
                int gp = blk * 64 + lp;
                int b = gp / 3136, pix = gp % 3136;
                int py = pix / 56, px = pix % 56;
                int oy = 2 * py + ry, ox = 2 * px + rx;
                c3[((size_t)(b * 112 + oy) * 112 + ox) * 12 + lm] = acc[r] + bias[lm];
            }
        }
    }
}

// ---------------------------------------------------------------------------
// L3 LN stats, coalesced: block per (image b, quarter h).
// ---------------------------------------------------------------------------
__global__ void __launch_bounds__(256) k_ln3_stats(const float* __restrict__ c3,
                                                   float* __restrict__ pstat)
{
    __shared__ float bins[24];
    int t = threadIdx.x;
    int b = blockIdx.x >> 2, h = blockIdx.x & 3;
    if (t < 24) bins[t] = 0.f;
    __syncthreads();
    const float* base = c3 + (size_t)b * 150528 + h * 37632;
    float s0 = 0.f, s1 = 0.f, s2 = 0.f, q0 = 0.f, q1 = 0.f, q2 = 0.f;
    for (int k = 0; k < 147; k += 3) {
        float v0 = base[t + 256 * k];
        float v1 = base[t + 256 * (k + 1)];
        float v2 = base[t + 256 * (k + 2)];
        s0 += v0; q0 += v0 * v0;
        s1 += v1; q1 += v1 * v1;
        s2 += v2; q2 += v2 * v2;
    }
    int c0 = t % 12;
    int c1 = (c0 + 4) % 12;
    int c2i = (c0 + 8) % 12;
    atomicAdd(&bins[c0 * 2],      s0); atomicAdd(&bins[c0 * 2 + 1],  q0);
    atomicAdd(&bins[c1 * 2],      s1); atomicAdd(&bins[c1 * 2 + 1],  q1);
    atomicAdd(&bins[c2i * 2],     s2); atomicAdd(&bins[c2i * 2 + 1], q2);
    __syncthreads();
    if (t < 24) pstat[(size_t)blockIdx.x * 24 + t] = bins[t];
}

// ---------------------------------------------------------------------------
// L3 LN apply, in-place on C3 NHWC.
// ---------------------------------------------------------------------------
__global__ void __launch_bounds__(256) k_ln3_apply(float* __restrict__ c3,
                                                   const float* __restrict__ pstat,
                                                   const float* __restrict__ g,
                                                   const float* __restrict__ bv)
{
    int i = blockIdx.x * 256 + threadIdx.x;
    int ch = i % 12;
    int t2 = i / 12;
    int pix = t2 % 12544;
    int b = t2 / 12544;
    const float* ps = pstat + (size_t)b * 96 + ch * 2;
    float s = ps[0] + ps[24] + ps[48] + ps[72];
    float q = ps[1] + ps[25] + ps[49] + ps[73];
    float mu = s * (1.f / 12544.f);
    float rstd = rsqrtf(q * (1.f / 12544.f) - mu * mu + 1e-5f);
    float v = (c3[i] - mu) * rstd * g[pix] + bv[pix];
    c3[i] = v / (1.f + expf(-v));
}

// ---------------------------------------------------------------------------
// final convT 12->1, NHWC input.
// ---------------------------------------------------------------------------
__global__ void __launch_bounds__(256) k_conv_final_nhwc(const float* __restrict__ x,
                                                         const float* __restrict__ wr,
                                                         const float* __restrict__ bias,
                                                         float* __restrict__ out)
{
    constexpr int HIN = 112, CIN = 12;
    constexpr int NPB = (B_ * HIN * HIN) / 256;   // 6272
    int pb = blockIdx.x % NPB;
    int ry = blockIdx.x / NPB;
    int rem = pb * 256 + threadIdx.x;
    int b   = rem / (HIN * HIN);
    int pix = rem % (HIN * HIN);
    int py = pix / HIN, px = pix % HIN;
    int r0 = py + ry - 1, r1 = r0 + 1;
    const float* xb = x + (size_t)b * (HIN * HIN * CIN);

    int   rows[2] = { r0, r1 };
    bool  rm[2]   = { r0 >= 0, r1 < HIN };
    int   cols[3] = { px - 1, px, px + 1 };
    bool  cm[3]   = { px >= 1, true, px + 1 < HIN };

    float gv[6][12];
    #pragma unroll
    for (int a = 0; a < 2; ++a) {
        #pragma unroll
        for (int cc = 0; cc < 3; ++cc) {
            int gi = a * 3 + cc;
            if (rm[a] && cm[cc]) {
                const float4* p4 = (const float4*)(xb +
                    ((size_t)(rows[a] * HIN + cols[cc])) * CIN);
                float4 v0 = p4[0], v1 = p4[1], v2 = p4[2];
                gv[gi][0] = v0.x; gv[gi][1]  = v0.y; gv[gi][2]  = v0.z; gv[gi][3]  = v0.w;
                gv[gi][4] = v1.x; gv[gi][5]  = v1.y; gv[gi][6]  = v1.z; gv[gi][7]  = v1.w;
                gv[gi][8] = v2.x; gv[gi][9]  = v2.y; gv[gi][10] = v2.z; gv[gi][11] = v2.w;
            } else {
                #pragma unroll
                for (int j = 0; j < 12; ++j) gv[gi][j] = 0.f;
            }
        }
    }

    const float4* w4 = (const float4*)wr;
    float acc0 = 0.f, acc1 = 0.f;
    #pragma unroll
    for (int ci = 0; ci < CIN; ++ci) {
        float4 W0 = w4[(2 * ry) * CIN + ci];
        float4 W1 = w4[(2 * ry + 1) * CIN + ci];
        acc0 += gv[0][ci] * W0.x + gv[1][ci] * W0.y + gv[3][ci] * W0.z + gv[4][ci] * W0.w;
        acc1 += gv[1][ci] * W1.x + gv[2][ci] * W1.y + gv[4][ci] * W1.z + gv[5][ci] * W1.w;
    }

    float bb = bias[0];
    float u0 = acc0 + bb, u1 = acc1 + bb;
    u0 = u0 / (1.f + expf(-u0));
    u1 = u1 / (1.f + expf(-u1));
    float2 v;
    v.x = fminf(fmaxf(u0, 0.f), 1.f);
    v.y = fminf(fmaxf(u1, 0.f), 1.f);
    int oy = 2 * py + ry;
    *(float2*)(out + (size_t)b * 50176 + oy * 224 + 2 * px) = v;
}

// ---------------------------------------------------------------------------
// launch
// ---------------------------------------------------------------------------
extern "C" void kernel_launch(void* const* d_in, const int* in_sizes, int n_in,
                              void* d_out, int out_size, void* d_ws, size_t ws_size,
                              hipStream_t stream)
{
    const float* x       = (const float*)d_in[0];
    const float* ts      = (const float*)d_in[1];
    const float* Wp      = (const float*)d_in[2];
    const float* bp      = (const float*)d_in[3];
    const float* Wt1     = (const float*)d_in[4];
    const float* bt1     = (const float*)d_in[5];
    const float* Wt2     = (const float*)d_in[6];
    const float* bt2     = (const float*)d_in[7];
    const float* a0_g    = (const float*)d_in[8];
    const float* a0_b    = (const float*)d_in[9];
    const float* a0_Wqkv = (const float*)d_in[10];
    const float* a0_bqkv = (const float*)d_in[11];
    const float* a0_Wo   = (const float*)d_in[12];
    const float* a0_bo   = (const float*)d_in[13];
    const float* a1_g    = (const float*)d_in[14];
    const float* a1_b    = (const float*)d_in[15];
    const float* a1_Wqkv = (const float*)d_in[16];
    const float* a1_bqkv = (const float*)d_in[17];
    const float* a1_Wo   = (const float*)d_in[18];
    const float* a1_bo   = (const float*)d_in[19];
    const float* Wm0     = (const float*)d_in[20];
    const float* bm0     = (const float*)d_in[21];
    const float* Wm1     = (const float*)d_in[22];
    const float* bm1     = (const float*)d_in[23];
    const float* Wm2     = (const float*)d_in[24];
    const float* bm2     = (const float*)d_in[25];
    const float* Wd1     = (const float*)d_in[26];
    const float* bd1     = (const float*)d_in[27];
    const float* l1g     = (const float*)d_in[28];
    const float* l1b     = (const float*)d_in[29];
    const float* Wd2     = (const float*)d_in[30];
    const float* bd2     = (const float*)d_in[31];
    const float* l2g     = (const float*)d_in[32];
    const float* l2b     = (const float*)d_in[33];
    const float* Wd3     = (const float*)d_in[34];
    const float* bd3     = (const float*)d_in[35];
    const float* l3g     = (const float*)d_in[36];
    const float* l3b     = (const float*)d_in[37];
    const float* Wd4     = (const float*)d_in[38];
    const float* bd4     = (const float*)d_in[39];
    float* out = (float*)d_out;

    // arena (floats); R = 25088*96
    const size_t R = 2408448;
    float* ws   = (float*)d_ws;
    float* tvec = ws;                          // 96
    float* p0   = ws + 512;                    // R
    float* h    = ws + 512 + R;                // R
    float* qkvb = ws + 512 + 2 * R;            // 3R
    float* ob   = ws + 512 + 5 * R;            // R
    float* p1   = ws + 512 + 6 * R;            // R
    // decoder aliases:
    _Float16* xinh = (_Float16*)(ws + 512 + 2 * R);   // f16 NHWC (qkv region)
    float* C1   = ws + 512 + 5 * R;            // NHWC fp32 [b][28][28][48] (ob+p1)
    _Float16* xh2 = (_Float16*)(ws + 512 + 7 * R);    // f16 NHWC padded [b][30][30][48]
    float* C2   = ws + 512;                    // NHWC fp32 [b][56][56][24] (p0..qkv)
    _Float16* xh3 = (_Float16*)(ws + 512 + 7 * R + 5529600); // f16 NHWC padded [b][58][58][24]
    float* C3   = ws + 512;                    // NHWC fp32 [b][112][112][12]
    float* Wr   = ws + 512 + 7 * R + 5529600 + 10334208;  // 96,960 floats
    _Float16* WH = (_Float16*)(Wr + 96960);                // 101,376 halves
    _Float16* Wc  = (_Float16*)Wr;              // conv1 f16 B-weights (dead L1 slice)
    _Float16* Wc2 = (_Float16*)(Wr + 36864);    // conv2 f16 B-weights
    _Float16* Wc3 = (_Float16*)(Wr + 49152);    // conv3 f16 B-weights
    float* stat = Wr + 96960 + 50688;          // 12,288 floats (LN stats, reused)
    const size_t NEED = (512 + 7 * R + 5529600 + 10334208 + 96960 + 50688 + 12288 + 16)
                        * sizeof(float);
    if (ws_size < NEED) return;

    _Float16* WHqkv0 = WH;
    _Float16* WHqkv1 = WH + 27648;
    _Float16* WHwo0  = WH + 55296;
    _Float16* WHwo1  = WH + 64512;
    _Float16* WHwm0  = WH + 73728;
    _Float16* WHwm1  = WH + 82944;
    _Float16* WHwm2  = WH + 92160;

    k_time<<<1, 128, 0, stream>>>(ts, Wt1, bt1, Wt2, bt2, tvec);
    k_repack<<<379, 256, 0, stream>>>(Wd1, Wd2, Wd3, Wd4, Wr);
    k_wcvtc<<<288, 256, 0, stream>>>(Wd1, Wc);
    k_wcvt2<<<96, 256, 0, stream>>>(Wd2, Wc2);
    k_wcvt3<<<24, 256, 0, stream>>>(Wd3, Wc3);
    k_wcvt<<<396, 256, 0, stream>>>(a0_Wqkv, a1_Wqkv, a0_Wo, a1_Wo,
                                    Wm0, Wm1, Wm2, WH);
    k_patch_mfma<<<M_ROWS / 64, 256, 0, stream>>>(x, Wp, bp, p0);

    // MHSA block 0
    k_ln_row<<<1024, 256, 0, stream>>>(p0, a0_g, a0_b, h, M_ROWS);
    k_gemm_mfma<3, false, false, false, false><<<M_ROWS / 64, 256, 0, stream>>>(
        h, WHqkv0, a0_bqkv, nullptr, nullptr, qkvb, nullptr);
    k_attn_mfma<<<B_ * 4, 256, 0, stream>>>(qkvb, ob);
    k_gemm_mfma<1, false, true, false, false><<<M_ROWS / 64, 256, 0, stream>>>(
        ob, WHwo0, a0_bo, p0, nullptr, p1, nullptr);

    // MHSA block 1 (+time)
    k_ln_row<<<1024, 256, 0, stream>>>(p1, a1_g, a1_b, h, M_ROWS);
    k_gemm_mfma<3, false, false, false, false><<<M_ROWS / 64, 256, 0, stream>>>(
        h, WHqkv1, a1_bqkv, nullptr, nullptr, qkvb, nullptr);
    k_attn_mfma<<<B_ * 4, 256, 0, stream>>>(qkvb, ob);
    k_gemm_mfma<1, false, true, true, false><<<M_ROWS / 64, 256, 0, stream>>>(
        ob, WHwo1, a1_bo, p1, tvec, p0, nullptr);

    // qkv region free: zero xinh borders before MLP3 writes interior
    k_zb_h<<<2880, 256, 0, stream>>>(xinh);

    // MLP x3 (silu); last writes f16 NHWC padded xinh
    k_gemm_mfma<1, true, false, false, false><<<M_ROWS / 64, 256, 0, stream>>>(
        p0, WHwm0, bm0, nullptr, nullptr, p1, nullptr);
    k_gemm_mfma<1, true, false, false, false><<<M_ROWS / 64, 256, 0, stream>>>(
        p1, WHwm1, bm1, nullptr, nullptr, p0, nullptr);
    k_gemm_mfma<1, true, false, false, true><<<M_ROWS / 64, 256, 0, stream>>>(
        p0, WHwm2, bm2, nullptr, nullptr, nullptr, xinh);

    // decoder: all-NHWC chain
    k_conv1<<<M_ROWS / 64, 256, 0, stream>>>(xinh, Wc, bd1, C1);
    k_ln1_stats<<<1536, 256, 0, stream>>>(C1, stat);
    k_ln1_apply<<<21600, 256, 0, stream>>>(C1, stat, l1g, l1b, xh2);
    k_conv2_mfma<<<(B_ * 784) / 64, 256, 0, stream>>>(xh2, Wc2, bd2, C2);
    k_ln2_stats<<<256, 256, 0, stream>>>(C2, stat);
    k_ln2_apply<<<40368, 256, 0, stream>>>(C2, stat, l2g, l2b, xh3);
    k_conv3_mfma<<<(B_ * 3136) / 64, 256, 0, stream>>>(xh3, Wc3, bd3, C3);
    k_ln3_stats<<<512, 256, 0, stream>>>(C3, stat);
    k_ln3_apply<<<75264, 256, 0, stream>>>(C3, stat, l3g, l3b);
    k_conv_final_nhwc<<<2 * 6272, 256, 0, stream>>>(C3, Wr + 96768, bd4, out);
}

// Round 4
// 567.547 us; speedup vs baseline: 1.4165x; 1.0905x over previous
//
#include <hip/hip_runtime.h>
#include <cmath>

// ---------------------------------------------------------------------------
// TimestepVisionTransformer — Round 12: tile-resident convT for L2/L3.
//   - k_conv2_tile / k_conv3_tile replace the 4-phase-serial conv2/conv3
//     (59us latency-bound, MfmaUtil 3%): stage input strip ONCE, one
//     barrier, parity-per-wave, B-fragments hoisted to registers,
//     stride-2 writes of both parities merged within the block.
// Everything else = r11 (verified, 619us).
// B=128, IMG=224, P=16, C_IN=1, E=96, H=4, d=24, NAX=14, N=196, M=B*N=25088
// ---------------------------------------------------------------------------

#define B_   128
#define NPATCH 196
#define M_ROWS (B_*NPATCH)     // 25088
#define E_   96

typedef _Float16 half8 __attribute__((ext_vector_type(8)));
typedef _Float16 half4v __attribute__((ext_vector_type(4)));
typedef float f32x4 __attribute__((ext_vector_type(4)));

// ---------------------------------------------------------------------------
// time embedding
// ---------------------------------------------------------------------------
__global__ void k_time(const float* __restrict__ ts,
                       const float* __restrict__ Wt1, const float* __restrict__ bt1,
                       const float* __restrict__ Wt2, const float* __restrict__ bt2,
                       float* __restrict__ timev)
{
    __shared__ float h[128];
    float e = 0.69314718055994530942f * ts[0];
    float sv = sinf(e), cv = cosf(e);
    int t = threadIdx.x;
    float z = sv * Wt1[t] + cv * Wt1[128 + t] + bt1[t];
    h[t] = z / (1.f + expf(-z));
    __syncthreads();
    if (t < 96) {
        float acc = bt2[t];
        for (int j = 0; j < 128; ++j) acc += h[j] * Wt2[j * 96 + t];
        timev[t] = acc;
    }
}

// ---------------------------------------------------------------------------
// weight repack (fp32 per-parity taps). Only the L4 slice [96768,96960) is
// still consumed as fp32 (conv_final); other slices overwritten by f16 packs.
// ---------------------------------------------------------------------------
__global__ void __launch_bounds__(256) k_repack(const float* __restrict__ w1,
                                                const float* __restrict__ w2,
                                                const float* __restrict__ w3,
                                                const float* __restrict__ w4f,
                                                float* __restrict__ wr)
{
    int i = blockIdx.x * 256 + threadIdx.x;
    const float* src; int CIN, COUT, e; float* dst;
    if      (i < 73728) { src = w1;  CIN = 96; COUT = 48; e = i;          dst = wr; }
    else if (i < 92160) { src = w2;  CIN = 48; COUT = 24; e = i - 73728;  dst = wr + 73728; }
    else if (i < 96768) { src = w3;  CIN = 24; COUT = 12; e = i - 92160;  dst = wr + 92160; }
    else if (i < 96960) { src = w4f; CIN = 12; COUT = 1;  e = i - 96768;  dst = wr + 96768; }
    else return;
    int per = CIN * COUT * 4;
    int par = e / per, rem = e % per;
    int ci = rem / (COUT * 4);
    int o  = (rem >> 2) % COUT;
    int j  = rem & 3;
    int ry = par >> 1, rx = par & 1;
    int wy = (j < 2)  ? (3 - ry) : (1 - ry);
    int wx = (j & 1)  ? (1 - rx) : (3 - rx);
    dst[e] = src[(ci * COUT + o) * 16 + wy * 4 + wx];
}

// ---------------------------------------------------------------------------
// conv1 weights -> f16 B-layout Wc[p][o][k=tap*96+ci]
// ---------------------------------------------------------------------------
__global__ void __launch_bounds__(256) k_wcvtc(const float* __restrict__ w1,
                                               _Float16* __restrict__ wc)
{
    int i = blockIdx.x * 256 + threadIdx.x;
    if (i >= 4 * 48 * 384) return;
    int p = i / 18432, rem = i % 18432;
    int o = rem / 384, k = rem % 384;
    int tap = k / 96, ci = k % 96;
    int ry = p >> 1, rx = p & 1;
    int wy = (tap < 2) ? (3 - ry) : (1 - ry);
    int wx = (tap & 1) ? (1 - rx) : (3 - rx);
    wc[i] = (_Float16)w1[(ci * 48 + o) * 16 + wy * 4 + wx];
}

// ---------------------------------------------------------------------------
// conv2 weights -> f16 B-layout Wc2[p][o(32, o>=24 zero)][k=tap*48+ci]
// ---------------------------------------------------------------------------
__global__ void __launch_bounds__(256) k_wcvt2(const float* __restrict__ w2,
                                               _Float16* __restrict__ wc2)
{
    int i = blockIdx.x * 256 + threadIdx.x;
    if (i >= 4 * 32 * 192) return;
    int p = i / 6144, rem = i % 6144;
    int o = rem / 192, k = rem % 192;
    int tap = k / 48, ci = k % 48;
    int ry = p >> 1, rx = p & 1;
    int wy = (tap < 2) ? (3 - ry) : (1 - ry);
    int wx = (tap & 1) ? (1 - rx) : (3 - rx);
    wc2[i] = (o < 24) ? (_Float16)w2[(ci * 24 + o) * 16 + wy * 4 + wx]
                      : (_Float16)0.f;
}

// ---------------------------------------------------------------------------
// conv3 weights -> f16 B-layout Wc3[p][o(16, o>=12 zero)][k=tap*24+ci]
// ---------------------------------------------------------------------------
__global__ void __launch_bounds__(256) k_wcvt3(const float* __restrict__ w3,
                                               _Float16* __restrict__ wc3)
{
    int i = blockIdx.x * 256 + threadIdx.x;
    if (i >= 4 * 16 * 96) return;
    int p = i / 1536, rem = i % 1536;
    int o = rem / 96, k = rem % 96;
    int tap = k / 24, ci = k % 24;
    int ry = p >> 1, rx = p & 1;
    int wy = (tap < 2) ? (3 - ry) : (1 - ry);
    int wx = (tap & 1) ? (1 - rx) : (3 - rx);
    wc3[i] = (o < 12) ? (_Float16)w3[(ci * 12 + o) * 16 + wy * 4 + wx]
                      : (_Float16)0.f;
}

// ---------------------------------------------------------------------------
// transformer weight convert+transpose to half: Wt[n][k] = W[k][n]
// ---------------------------------------------------------------------------
__global__ void __launch_bounds__(256) k_wcvt(const float* __restrict__ qkv0,
                                              const float* __restrict__ qkv1,
                                              const float* __restrict__ wo0,
                                              const float* __restrict__ wo1,
                                              const float* __restrict__ wm0,
                                              const float* __restrict__ wm1,
                                              const float* __restrict__ wm2,
                                              _Float16* __restrict__ wh)
{
    int i = blockIdx.x * 256 + threadIdx.x;
    const float* src; int N; int e;
    if      (i < 27648)  { src = qkv0; N = 288; e = i; }
    else if (i < 55296)  { src = qkv1; N = 288; e = i - 27648; }
    else if (i < 64512)  { src = wo0;  N = 96;  e = i - 55296; }
    else if (i < 73728)  { src = wo1;  N = 96;  e = i - 64512; }
    else if (i < 82944)  { src = wm0;  N = 96;  e = i - 73728; }
    else if (i < 92160)  { src = wm1;  N = 96;  e = i - 82944; }
    else if (i < 101376) { src = wm2;  N = 96;  e = i - 92160; }
    else return;
    int n = e / 96, k = e % 96;
    wh[i] = (_Float16)src[k * N + n];
}

// ---------------------------------------------------------------------------
// zero the borders of xinh NHWC f16 [b][16][16][96]
// ---------------------------------------------------------------------------
__global__ void __launch_bounds__(256) k_zb_h(_Float16* __restrict__ xinh)
{
    int i = blockIdx.x * 256 + threadIdx.x;
    if (i >= 128 * 60 * 96) return;
    int b = i / 5760, r = i % 5760;
    int pos = r / 96, ch = r % 96;
    int py, px;
    if      (pos < 16) { py = 0;        px = pos; }
    else if (pos < 32) { py = 15;       px = pos - 16; }
    else if (pos < 46) { py = pos - 31; px = 0; }
    else               { py = pos - 45; px = 15; }
    xinh[((size_t)(b * 256) + py * 16 + px) * 96 + ch] = (_Float16)0.f;
}

// ---------------------------------------------------------------------------
// patch embed GEMM via f16 MFMA (r7, verified)
// ---------------------------------------------------------------------------
__global__ void __launch_bounds__(256) k_patch_mfma(const float* __restrict__ x,
                                                    const float* __restrict__ Wp,
                                                    const float* __restrict__ bp,
                                                    float* __restrict__ out)
{
    __shared__ __align__(16) _Float16 Ah[64 * 136];
    __shared__ __align__(16) _Float16 Wh[96 * 136];
    int t = threadIdx.x;
    int p0 = blockIdx.x * 64;
    int wave = t >> 6, lane = t & 63;
    int lm = lane & 15, quad = lane >> 4;
    f32x4 acc[6];
    #pragma unroll
    for (int nt = 0; nt < 6; ++nt) acc[nt] = (f32x4){0.f, 0.f, 0.f, 0.f};

    for (int kc = 0; kc < 2; ++kc) {
        __syncthreads();
        for (int i = t; i < 512; i += 256) {
            int lp = i >> 3, pyl = i & 7;
            int patch = p0 + lp;
            int b = patch / NPATCH, n = patch % NPATCH;
            int ny = n / 14, nx = n % 14;
            const float4* s4 = (const float4*)(x +
                ((size_t)(b * 224) + ny * 16 + kc * 8 + pyl) * 224 + nx * 16);
            float4 v0 = s4[0], v1 = s4[1], v2 = s4[2], v3 = s4[3];
            half8 h0, h1;
            h0[0]=(_Float16)v0.x; h0[1]=(_Float16)v0.y; h0[2]=(_Float16)v0.z; h0[3]=(_Float16)v0.w;
            h0[4]=(_Float16)v1.x; h0[5]=(_Float16)v1.y; h0[6]=(_Float16)v1.z; h0[7]=(_Float16)v1.w;
            h1[0]=(_Float16)v2.x; h1[1]=(_Float16)v2.y; h1[2]=(_Float16)v2.z; h1[3]=(_Float16)v2.w;
            h1[4]=(_Float16)v3.x; h1[5]=(_Float16)v3.y; h1[6]=(_Float16)v3.z; h1[7]=(_Float16)v3.w;
            *(half8*)&Ah[lp * 136 + pyl * 16]     = h0;
            *(half8*)&Ah[lp * 136 + pyl * 16 + 8] = h1;
        }
        for (int i = t; i < 1536; i += 256) {
            int e = i >> 4, s = i & 15;
            const float4* s4 = (const float4*)(Wp + e * 256 + kc * 128 + s * 8);
            float4 v0 = s4[0], v1 = s4[1];
            half8 h0;
            h0[0]=(_Float16)v0.x; h0[1]=(_Float16)v0.y; h0[2]=(_Float16)v0.z; h0[3]=(_Float16)v0.w;
            h0[4]=(_Float16)v1.x; h0[5]=(_Float16)v1.y; h0[6]=(_Float16)v1.z; h0[7]=(_Float16)v1.w;
            *(half8*)&Wh[e * 136 + s * 8] = h0;
        }
        __syncthreads();
        half8 af[4];
        #pragma unroll
        for (int ks = 0; ks < 4; ++ks)
            af[ks] = *(const half8*)&Ah[(wave * 16 + lm) * 136 + ks * 32 + quad * 8];
        #pragma unroll
        for (int ks = 0; ks < 4; ++ks) {
            #pragma unroll
            for (int nt = 0; nt < 6; ++nt) {
                half8 bf = *(const half8*)&Wh[(nt * 16 + lm) * 136 + ks * 32 + quad * 8];
                acc[nt] = __builtin_amdgcn_mfma_f32_16x16x32_f16(af[ks], bf, acc[nt], 0, 0, 0);
            }
        }
    }

    #pragma unroll
    for (int nt = 0; nt < 6; ++nt) {
        #pragma unroll
        for (int r = 0; r < 4; ++r) {
            int e = nt * 16 + lm;
            int lp = wave * 16 + quad * 4 + r;
            int patch = p0 + lp;
            int n = patch % NPATCH;
            int ny = n / 14, nx = n % 14;
            float yx = (float)(ny + nx);
            float v = acc[nt][r] + bp[e];
            float other = __shfl_xor(v, 1);
            float fi = (float)(e >> 1);
            float theta = expf(fi * (-2.f / 96.f) * 9.210340371976184f);
            float ang = theta * yx;
            float c = cosf(ang), s = sinf(ang);
            float outv = (lm & 1) ? (other * s + v * c) : (v * c - other * s);
            out[(size_t)patch * 96 + e] = outv;
        }
    }
}

// ---------------------------------------------------------------------------
// row LayerNorm over 96, wave per row
// ---------------------------------------------------------------------------
__global__ void __launch_bounds__(256) k_ln_row(const float* __restrict__ x,
                                                const float* __restrict__ g,
                                                const float* __restrict__ bv,
                                                float* __restrict__ out, int M)
{
    int lane = threadIdx.x & 63;
    int gw = (blockIdx.x * 256 + threadIdx.x) >> 6;
    int nw = (gridDim.x * 256) >> 6;
    float g0 = g[lane], b0 = bv[lane];
    float g1 = 0.f, b1 = 0.f;
    if (lane < 32) { g1 = g[64 + lane]; b1 = bv[64 + lane]; }
    for (int r = gw; r < M; r += nw) {
        const float* xr = x + (size_t)r * 96;
        float a = xr[lane];
        float c = (lane < 32) ? xr[64 + lane] : 0.f;
        float s = a + c, q = a * a + c * c;
        #pragma unroll
        for (int off = 32; off; off >>= 1) {
            s += __shfl_xor(s, off);
            q += __shfl_xor(q, off);
        }
        float mu = s * (1.f / 96.f);
        float rstd = rsqrtf(q * (1.f / 96.f) - mu * mu + 1e-5f);
        float* orow = out + (size_t)r * 96;
        orow[lane] = (a - mu) * rstd * g0 + b0;
        if (lane < 32) orow[64 + lane] = (c - mu) * rstd * g1 + b1;
    }
}

// ---------------------------------------------------------------------------
// MFMA row GEMM (r6, verified). OUTH: write f16 NHWC padded xinh instead.
// ---------------------------------------------------------------------------
template<int NCHUNKS, bool SILU, bool RES, bool ADDTIME, bool OUTH>
__global__ void __launch_bounds__(256) k_gemm_mfma(const float* __restrict__ A,
                                                   const _Float16* __restrict__ Wt,
                                                   const float* __restrict__ bias,
                                                   const float* __restrict__ res,
                                                   const float* __restrict__ timev,
                                                   float* __restrict__ out,
                                                   _Float16* __restrict__ outh)
{
    __shared__ __align__(16) _Float16 Ah[64 * 96];
    __shared__ __align__(16) _Float16 Wh[96 * 96];
    constexpr int NTOT = NCHUNKS * 96;
    int t = threadIdx.x;
    size_t row0 = (size_t)blockIdx.x * 64;

    const float4* a4 = (const float4*)(A + row0 * 96);
    for (int i = t; i < 1536; i += 256) {
        float4 v = a4[i];
        half4v hv;
        hv[0] = (_Float16)v.x; hv[1] = (_Float16)v.y;
        hv[2] = (_Float16)v.z; hv[3] = (_Float16)v.w;
        *(half4v*)&Ah[i * 4] = hv;
    }

    int wave = t >> 6, lane = t & 63;
    int lm = lane & 15, quad = lane >> 4;
    const f32x4 vzero = {0.f, 0.f, 0.f, 0.f};

    for (int ch = 0; ch < NCHUNKS; ++ch) {
        __syncthreads();
        {
            const uint4* src = (const uint4*)(Wt + (size_t)ch * 9216);
            uint4* dst = (uint4*)Wh;
            for (int i = t; i < 1152; i += 256) dst[i] = src[i];
        }
        __syncthreads();

        half8 af[3];
        #pragma unroll
        for (int ks = 0; ks < 3; ++ks)
            af[ks] = *(const half8*)&Ah[(wave * 16 + lm) * 96 + ks * 32 + quad * 8];

        f32x4 acc[6];
        #pragma unroll
        for (int ct = 0; ct < 6; ++ct) acc[ct] = vzero;

        #pragma unroll
        for (int ct = 0; ct < 6; ++ct) {
            #pragma unroll
            for (int ks = 0; ks < 3; ++ks) {
                half8 bf = *(const half8*)&Wh[(ct * 16 + lm) * 96 + ks * 32 + quad * 8];
                acc[ct] = __builtin_amdgcn_mfma_f32_16x16x32_f16(af[ks], bf, acc[ct], 0, 0, 0);
            }
        }

        #pragma unroll
        for (int ct = 0; ct < 6; ++ct) {
            #pragma unroll
            for (int r = 0; r < 4; ++r) {
                int lr = wave * 16 + quad * 4 + r;
                size_t row = row0 + lr;
                int lc = ct * 16 + lm;
                int col = ch * 96 + lc;
                float v = acc[ct][r] + bias[col];
                if constexpr (RES)     v += res[row * 96 + lc];
                if constexpr (ADDTIME) v += timev[lc];
                if constexpr (SILU)    v = v / (1.f + expf(-v));
                if constexpr (OUTH) {
                    size_t b = row / NPATCH; int n = (int)(row % NPATCH);
                    int ny = n / 14, nx = n % 14;
                    outh[((b * 256) + (1 + ny) * 16 + (1 + nx)) * 96 + col] = (_Float16)v;
                } else {
                    out[row * NTOT + col] = v;
                }
            }
        }
    }
}

// ---------------------------------------------------------------------------
// MFMA attention (r11, verified): one block per (b,h), 4 waves.
// ---------------------------------------------------------------------------
__global__ void __launch_bounds__(256) k_attn_mfma(const float* __restrict__ qkv,
                                                   float* __restrict__ o)
{
    __shared__ __align__(16) _Float16 Qs[208 * 40];
    __shared__ __align__(16) _Float16 Ks[208 * 40];
    __shared__ __align__(16) _Float16 Vt[32 * 232];
    __shared__ __align__(16) _Float16 Pw[4][16 * 232];

    int t = threadIdx.x;
    int bh = blockIdx.x;
    int b = bh >> 2, h = bh & 3;
    const float* base = qkv + (size_t)b * NPATCH * 288 + h * 24;

    // zero all LDS (pads must be 0)
    {
        const int4 z = {0, 0, 0, 0};
        int4* q4 = (int4*)Qs; int4* k4 = (int4*)Ks;
        for (int i = t; i < 1040; i += 256) { q4[i] = z; k4[i] = z; }
        int4* v4 = (int4*)Vt;
        for (int i = t; i < 928; i += 256) v4[i] = z;
        int4* p4 = (int4*)&Pw[0][0];
        for (int i = t; i < 1856; i += 256) p4[i] = z;
    }
    __syncthreads();

    // stage Q,K (row-major, stride 40) and V transposed (Vt[d][key], stride 232)
    for (int i = t; i < NPATCH * 24; i += 256) {
        int r = i / 24, d = i % 24;
        const float* row = base + (size_t)r * 288;
        Qs[r * 40 + d]   = (_Float16)row[d];
        Ks[r * 40 + d]   = (_Float16)row[96 + d];
        Vt[d * 232 + r]  = (_Float16)row[192 + d];
    }
    __syncthreads();

    int wave = t >> 6, lane = t & 63;
    int lm = lane & 15, quad = lane >> 4;
    const float scale = 0.2041241452319315f;

    // hoist K B-fragments (shared across this wave's row-tiles)
    half8 bk[13];
    #pragma unroll
    for (int ct = 0; ct < 13; ++ct)
        bk[ct] = *(const half8*)&Ks[(ct * 16 + lm) * 40 + quad * 8];

    _Float16* pw = &Pw[wave][0];

    for (int rt = wave; rt < 13; rt += 4) {
        half8 aq = *(const half8*)&Qs[(rt * 16 + lm) * 40 + quad * 8];
        float rsum[4] = {0.f, 0.f, 0.f, 0.f};

        #pragma unroll
        for (int ct = 0; ct < 13; ++ct) {
            f32x4 s = (f32x4){0.f, 0.f, 0.f, 0.f};
            s = __builtin_amdgcn_mfma_f32_16x16x32_f16(aq, bk[ct], s, 0, 0, 0);
            #pragma unroll
            for (int r = 0; r < 4; ++r) {
                float p = __expf(fminf(s[r] * scale, 60.f));
                if (ct == 12 && lm >= 4) p = 0.f;   // keys 196..207 invalid
                rsum[r] += p;
                pw[(quad * 4 + r) * 232 + ct * 16 + lm] = (_Float16)p;
            }
        }

        // reduce row sums across the 16 lm-lanes
        #pragma unroll
        for (int r = 0; r < 4; ++r) {
            float s = rsum[r];
            s += __shfl_xor(s, 1);
            s += __shfl_xor(s, 2);
            s += __shfl_xor(s, 4);
            s += __shfl_xor(s, 8);
            rsum[r] = 1.f / s;
        }

        // PV: P[16][208(+pad0)] @ Vt -> O[16][32]
        f32x4 ov0 = (f32x4){0.f, 0.f, 0.f, 0.f};
        f32x4 ov1 = (f32x4){0.f, 0.f, 0.f, 0.f};
        #pragma unroll
        for (int ks = 0; ks < 7; ++ks) {
            half8 ap = *(const half8*)&pw[lm * 232 + ks * 32 + quad * 8];
            half8 bv0 = *(const half8*)&Vt[(lm) * 232 + ks * 32 + quad * 8];
            half8 bv1 = *(const half8*)&Vt[(16 + lm) * 232 + ks * 32 + quad * 8];
            ov0 = __builtin_amdgcn_mfma_f32_16x16x32_f16(ap, bv0, ov0, 0, 0, 0);
            ov1 = __builtin_amdgcn_mfma_f32_16x16x32_f16(ap, bv1, ov1, 0, 0, 0);
        }

        // write O (d = lm for ov0, 16+lm for ov1; valid d < 24)
        #pragma unroll
        for (int r = 0; r < 4; ++r) {
            int row = rt * 16 + quad * 4 + r;
            if (row < NPATCH) {
                float* orow = o + ((size_t)b * NPATCH + row) * 96 + h * 24;
                orow[lm] = ov0[r] * rsum[r];
                if (lm < 8) orow[16 + lm] = ov1[r] * rsum[r];
            }
        }
    }
}

// ---------------------------------------------------------------------------
// conv L1 via MFMA (r7, verified): xinh NHWC f16 padded -> C1 NHWC fp32
// ---------------------------------------------------------------------------
__global__ void __launch_bounds__(256) k_conv1(const _Float16* __restrict__ xinh,
                                               const _Float16* __restrict__ wc,
                                               const float* __restrict__ bias,
                                               float* __restrict__ c1)
{
    __shared__ __align__(16) _Float16 Ah[64 * 392];
    int t = threadIdx.x;
    int blk = blockIdx.x;
    int wave = t >> 6, lane = t & 63;
    int lm = lane & 15, quad = lane >> 4;

    for (int p = 0; p < 4; ++p) {
        int ry = p >> 1, rx = p & 1;
        __syncthreads();
        for (int i = t; i < 64 * 48; i += 256) {
            int lp = i / 48, rem = i % 48;
            int tap = rem / 12;
            int gp = blk * 64 + lp;
            int b = gp / NPATCH, pix = gp % NPATCH;
            int py = pix / 14, px = pix % 14;
            int row = py + ry + (tap >> 1), col = px + rx + (tap & 1);
            const uint4* src = (const uint4*)(xinh +
                ((size_t)(b * 256) + row * 16 + col) * 96 + (rem % 12) * 8);
            *(uint4*)&Ah[lp * 392 + rem * 8] = *src;
        }
        __syncthreads();

        half8 af[12];
        #pragma unroll
        for (int ks = 0; ks < 12; ++ks)
            af[ks] = *(const half8*)&Ah[(wave * 16 + lm) * 392 + ks * 32 + quad * 8];

        f32x4 acc[3];
        #pragma unroll
        for (int nt = 0; nt < 3; ++nt) acc[nt] = (f32x4){0.f, 0.f, 0.f, 0.f};

        #pragma unroll
        for (int ks = 0; ks < 12; ++ks) {
            #pragma unroll
            for (int nt = 0; nt < 3; ++nt) {
                half8 bf = *(const half8*)&wc[((size_t)(p * 48 + nt * 16 + lm)) * 384
                                              + ks * 32 + quad * 8];
                acc[nt] = __builtin_amdgcn_mfma_f32_16x16x32_f16(af[ks], bf, acc[nt], 0, 0, 0);
            }
        }

        #pragma unroll
        for (int nt = 0; nt < 3; ++nt) {
            #pragma unroll
            for (int r = 0; r < 4; ++r) {
                int o = nt * 16 + lm;
                int lp = wave * 16 + quad * 4 + r;
                int gp = blk * 64 + lp;
                int b = gp / NPATCH, pix = gp % NPATCH;
                int py = pix / 14, px = pix % 14;
                int oy = 2 * py + ry, ox = 2 * px + rx;
                c1[((size_t)(b * 28 + oy) * 28 + ox) * 48 + o] = acc[nt][r] + bias[o];
            }
        }
    }
}

// ---------------------------------------------------------------------------
// L1 LN stats: one wave per (b,ch) over NHWC C1 -> stat[b*48+ch] = {mu,rstd}
// ---------------------------------------------------------------------------
__global__ void __launch_bounds__(256) k_ln1_stats(const float* __restrict__ c1,
                                                   float* __restrict__ stat)
{
    int idx = blockIdx.x * 4 + (threadIdx.x >> 6);   // b*48+ch
    int lane = threadIdx.x & 63;
    int b = idx / 48, ch = idx % 48;
    const float* base = c1 + (size_t)b * 784 * 48 + ch;
    float s = 0.f, q = 0.f;
    for (int pix = lane; pix < 784; pix += 64) {
        float v = base[(size_t)pix * 48];
        s += v; q += v * v;
    }
    #pragma unroll
    for (int off = 32; off; off >>= 1) {
        s += __shfl_xor(s, off);
        q += __shfl_xor(q, off);
    }
    if (lane == 0) {
        float mu = s * (1.f / 784.f);
        float rstd = rsqrtf(q * (1.f / 784.f) - mu * mu + 1e-5f);
        stat[idx * 2]     = mu;
        stat[idx * 2 + 1] = rstd;
    }
}

// ---------------------------------------------------------------------------
// L1 LN apply: NHWC C1 + stat -> f16 NHWC padded XH2 [b][30][30][48], silu.
// ---------------------------------------------------------------------------
__global__ void __launch_bounds__(256) k_ln1_apply(const float* __restrict__ c1,
                                                   const float* __restrict__ stat,
                                                   const float* __restrict__ g,
                                                   const float* __restrict__ bv,
                                                   _Float16* __restrict__ xh)
{
    int i = blockIdx.x * 256 + threadIdx.x;          // ((b*900)+pos)*48 + ch
    if (i >= 128 * 900 * 48) return;
    int ch = i % 48;
    int t2 = i / 48;
    int pos = t2 % 900;
    int b = t2 / 900;
    int py = pos / 30, px = pos % 30;
    float v = 0.f;
    if (py >= 1 && py <= 28 && px >= 1 && px <= 28) {
        int j = (py - 1) * 28 + (px - 1);
        int plane = b * 48 + ch;
        float mu = stat[plane * 2], rstd = stat[plane * 2 + 1];
        float u = (c1[((size_t)b * 784 + j) * 48 + ch] - mu) * rstd * g[j] + bv[j];
        v = u / (1.f + expf(-u));
    }
    xh[i] = (_Float16)v;
}

// ---------------------------------------------------------------------------
// conv L2, tile-resident: XH2 NHWC f16 padded [b][30][30][48] -> C2 NHWC
// fp32 [b][56][56][24]. Block = 2-pixel-row strip (56 px) of one image:
// stage input window [4][30][48] once (pixel stride 56 in LDS), one
// barrier, parity-per-wave, B-fragments in registers.
// ---------------------------------------------------------------------------
__global__ void __launch_bounds__(256) k_conv2_tile(const _Float16* __restrict__ xh,
                                                    const _Float16* __restrict__ wc,
                                                    const float* __restrict__ bias,
                                                    float* __restrict__ c2)
{
    __shared__ __align__(16) _Float16 Xs[4 * 30 * 56];   // 13.1 KB
    int t = threadIdx.x;
    int blk = blockIdx.x;
    int b = blk / 14, s = blk % 14;      // strip covers pixel rows 2s, 2s+1

    // stage xh2 rows 2s..2s+3, 30 cols, 48 ch (6 chunks of 8 halves each)
    for (int i = t; i < 720; i += 256) {
        int r = i / 180, rem = i % 180;
        int c = rem / 6, ch = (rem % 6) * 8;
        *(uint4*)&Xs[(r * 30 + c) * 56 + ch] =
            *(const uint4*)(xh + ((size_t)(b * 900) + (2 * s + r) * 30 + c) * 48 + ch);
    }

    int wave = t >> 6, lane = t & 63;
    int lm = lane & 15, quad = lane >> 4;
    int ry = wave >> 1, rx = wave & 1;   // parity per wave

    // hoist B fragments: 2 col-tiles x 6 k-slices (once per kernel)
    half8 bf0[6], bf1[6];
    #pragma unroll
    for (int ks = 0; ks < 6; ++ks) {
        bf0[ks] = *(const half8*)&wc[((size_t)(wave * 32 + lm)) * 192 + ks * 32 + quad * 8];
        bf1[ks] = *(const half8*)&wc[((size_t)(wave * 32 + 16 + lm)) * 192 + ks * 32 + quad * 8];
    }

    __syncthreads();

    #pragma unroll
    for (int rt = 0; rt < 4; ++rt) {
        int pp = rt * 16 + lm;
        int ppc = pp < 56 ? pp : 55;
        int pyl = ppc / 28, px = ppc % 28;

        half8 af[6];
        #pragma unroll
        for (int ks = 0; ks < 6; ++ks) {
            int k0 = ks * 32 + quad * 8;
            int tap = k0 / 48, off = k0 % 48;
            int dy = tap >> 1, dx = tap & 1;
            af[ks] = *(const half8*)&Xs[((pyl + ry + dy) * 30 + (px + rx + dx)) * 56 + off];
        }

        f32x4 acc0 = (f32x4){0.f, 0.f, 0.f, 0.f};
        f32x4 acc1 = (f32x4){0.f, 0.f, 0.f, 0.f};
        #pragma unroll
        for (int ks = 0; ks < 6; ++ks) {
            acc0 = __builtin_amdgcn_mfma_f32_16x16x32_f16(af[ks], bf0[ks], acc0, 0, 0, 0);
            acc1 = __builtin_amdgcn_mfma_f32_16x16x32_f16(af[ks], bf1[ks], acc1, 0, 0, 0);
        }

        // write: output pixel for D row = rt*16 + quad*4 + r
        #pragma unroll
        for (int r = 0; r < 4; ++r) {
            int pw = rt * 16 + quad * 4 + r;
            if (pw < 56) {
                int pylw = pw / 28, pxw = pw % 28;
                int oy = 2 * (2 * s + pylw) + ry, ox = 2 * pxw + rx;
                float* orow = c2 + ((size_t)(b * 56 + oy) * 56 + ox) * 24;
                orow[lm] = acc0[r] + bias[lm];
                if (lm < 8) orow[16 + lm] = acc1[r] + bias[16 + lm];
            }
        }
    }
}

// ---------------------------------------------------------------------------
// L2 LN stats, coalesced: block per (image b, half h).
// ---------------------------------------------------------------------------
__global__ void __launch_bounds__(256) k_ln2_stats(const float* __restrict__ c2,
                                                   float* __restrict__ pstat)
{
    __shared__ float bins[48];
    int t = threadIdx.x;
    int b = blockIdx.x >> 1, h = blockIdx.x & 1;
    if (t < 48) bins[t] = 0.f;
    __syncthreads();
    const float* base = c2 + (size_t)b * 75264 + h * 37632;
    float s0 = 0.f, s1 = 0.f, s2 = 0.f, q0 = 0.f, q1 = 0.f, q2 = 0.f;
    for (int k = 0; k < 147; k += 3) {
        float v0 = base[t + 256 * k];
        float v1 = base[t + 256 * (k + 1)];
        float v2 = base[t + 256 * (k + 2)];
        s0 += v0; q0 += v0 * v0;
        s1 += v1; q1 += v1 * v1;
        s2 += v2; q2 += v2 * v2;
    }
    int c0 = t % 24;
    int c1 = (c0 + 16) % 24;
    int c2i = (c0 + 8) % 24;
    atomicAdd(&bins[c0 * 2],      s0); atomicAdd(&bins[c0 * 2 + 1],  q0);
    atomicAdd(&bins[c1 * 2],      s1); atomicAdd(&bins[c1 * 2 + 1],  q1);
    atomicAdd(&bins[c2i * 2],     s2); atomicAdd(&bins[c2i * 2 + 1], q2);
    __syncthreads();
    if (t < 48) pstat[(size_t)blockIdx.x * 48 + t] = bins[t];
}

// ---------------------------------------------------------------------------
// L2 LN apply: C2 NHWC + pstat -> f16 NHWC padded XH3 [b][58][58][24], silu.
// ---------------------------------------------------------------------------
__global__ void __launch_bounds__(256) k_ln2_apply(const float* __restrict__ c2,
                                                   const float* __restrict__ pstat,
                                                   const float* __restrict__ g,
                                                   const float* __restrict__ bv,
                                                   _Float16* __restrict__ xh)
{
    int i = blockIdx.x * 256 + threadIdx.x;          // ((b*3364)+pos)*24 + ch
    int ch = i % 24;
    int t2 = i / 24;
    int pos = t2 % 3364;
    int b = t2 / 3364;
    int py = pos / 58, px = pos % 58;
    float v = 0.f;
    if (py >= 1 && py <= 56 && px >= 1 && px <= 56) {
        int j = (py - 1) * 56 + (px - 1);
        const float* ps = pstat + (size_t)b * 96 + ch * 2;
        float s = ps[0] + ps[48];
        float q = ps[1] + ps[49];
        float mu = s * (1.f / 3136.f);
        float rstd = rsqrtf(q * (1.f / 3136.f) - mu * mu + 1e-5f);
        float u = (c2[((size_t)b * 3136 + j) * 24 + ch] - mu) * rstd * g[j] + bv[j];
        v = u / (1.f + expf(-u));
    }
    xh[i] = (_Float16)v;
}

// ---------------------------------------------------------------------------
// conv L3, tile-resident: XH3 NHWC f16 padded [b][58][58][24] -> C3 NHWC
// fp32 [b][112][112][12]. Block = 1-pixel-row strip (56 px): stage
// [3][58][24] once (pixel stride 40 in LDS), parity-per-wave.
// ---------------------------------------------------------------------------
__global__ void __launch_bounds__(256) k_conv3_tile(const _Float16* __restrict__ xh,
                                                    const _Float16* __restrict__ wc,
                                                    const float* __restrict__ bias,
                                                    float* __restrict__ c3)
{
    __shared__ __align__(16) _Float16 Xs[3 * 58 * 40];   // 13.6 KB
    int t = threadIdx.x;
    int blk = blockIdx.x;
    int b = blk / 56, s = blk % 56;     // strip covers pixel row s

    // stage xh3 rows s..s+2, 58 cols, 24 ch (3 chunks of 8 halves)
    for (int i = t; i < 522; i += 256) {
        int r = i / 174, rem = i % 174;
        int c = rem / 3, ch = (rem % 3) * 8;
        *(uint4*)&Xs[(r * 58 + c) * 40 + ch] =
            *(const uint4*)(xh + ((size_t)(b * 3364) + (s + r) * 58 + c) * 24 + ch);
    }

    int wave = t >> 6, lane = t & 63;
    int lm = lane & 15, quad = lane >> 4;
    int ry = wave >> 1, rx = wave & 1;

    half8 bf[3];
    #pragma unroll
    for (int ks = 0; ks < 3; ++ks)
        bf[ks] = *(const half8*)&wc[((size_t)(wave * 16 + lm)) * 96 + ks * 32 + quad * 8];

    __syncthreads();

    #pragma unroll
    for (int rt = 0; rt < 4; ++rt) {
        int px = rt * 16 + lm;
        int pxc = px < 56 ? px : 55;

        half8 af[3];
        #pragma unroll
        for (int ks = 0; ks < 3; ++ks) {
            int k0 = ks * 32 + quad * 8;
            int tap = k0 / 24, off = k0 % 24;
            int dy = tap >> 1, dx = tap & 1;
            af[ks] = *(const half8*)&Xs[((ry + dy) * 58 + (pxc + rx + dx)) * 40 + off];
        }

        f32x4 acc = (f32x4){0.f, 0.f, 0.f, 0.f};
        #pragma unroll
        for (int ks = 0; ks < 3; ++ks)
            acc = __builtin_amdgcn_mfma_f32_16x16x32_f16(af[ks], bf[ks], acc, 0, 0, 0);

        if (lm < 12) {
            #pragma unroll
            for (int r = 0; r < 4; ++r) {
                int pw = rt * 16 + quad * 4 + r;
                if (pw < 56) {
                    int oy = 2 * s + ry, ox = 2 * pw + rx;
                    c3[((size_t)(b * 112 + oy) * 112 + ox) * 12 + lm] = acc[r] + bias[lm];
                }
            }
        }
    }
}

// ---------------------------------------------------------------------------
// L3 LN stats, coalesced: block per (image b, quarter h).
// ---------------------------------------------------------------------------
__global__ void __launch_bounds__(256) k_ln3_stats(const float* __restrict__ c3,
                                                   float* __restrict__ pstat)
{
    __shared__ float bins[24];
    int t = threadIdx.x;
    int b = blockIdx.x >> 2, h = blockIdx.x & 3;
    if (t < 24) bins[t] = 0.f;
    __syncthreads();
    const float* base = c3 + (size_t)b * 150528 + h * 37632;
    float s0 = 0.f, s1 = 0.f, s2 = 0.f, q0 = 0.f, q1 = 0.f, q2 = 0.f;
    for (int k = 0; k < 147; k += 3) {
        float v0 = base[t + 256 * k];
        float v1 = base[t + 256 * (k + 1)];
        float v2 = base[t + 256 * (k + 2)];
        s0 += v0; q0 += v0 * v0;
        s1 += v1; q1 += v1 * v1;
        s2 += v2; q2 += v2 * v2;
    }
    int c0 = t % 12;
    int c1 = (c0 + 4) % 12;
    int c2i = (c0 + 8) % 12;
    atomicAdd(&bins[c0 * 2],      s0); atomicAdd(&bins[c0 * 2 + 1],  q0);
    atomicAdd(&bins[c1 * 2],      s1); atomicAdd(&bins[c1 * 2 + 1],  q1);
    atomicAdd(&bins[c2i * 2],     s2); atomicAdd(&bins[c2i * 2 + 1], q2);
    __syncthreads();
    if (t < 24) pstat[(size_t)blockIdx.x * 24 + t] = bins[t];
}

// ---------------------------------------------------------------------------
// L3 LN apply, in-place on C3 NHWC.
// ---------------------------------------------------------------------------
__global__ void __launch_bounds__(256) k_ln3_apply(float* __restrict__ c3,
                                                   const float* __restrict__ pstat,
                                                   const float* __restrict__ g,
                                                   const float* __restrict__ bv)
{
    int i = blockIdx.x * 256 + threadIdx.x;
    int ch = i % 12;
    int t2 = i / 12;
    int pix = t2 % 12544;
    int b = t2 / 12544;
    const float* ps = pstat + (size_t)b * 96 + ch * 2;
    float s = ps[0] + ps[24] + ps[48] + ps[72];
    float q = ps[1] + ps[25] + ps[49] + ps[73];
    float mu = s * (1.f / 12544.f);
    float rstd = rsqrtf(q * (1.f / 12544.f) - mu * mu + 1e-5f);
    float v = (c3[i] - mu) * rstd * g[pix] + bv[pix];
    c3[i] = v / (1.f + expf(-v));
}

// ---------------------------------------------------------------------------
// final convT 12->1, NHWC input.
// ---------------------------------------------------------------------------
__global__ void __launch_bounds__(256) k_conv_final_nhwc(const float* __restrict__ x,
                                                         const float* __restrict__ wr,
                                                         const float* __restrict__ bias,
                                                         float* __restrict__ out)
{
    constexpr int HIN = 112, CIN = 12;
    constexpr int NPB = (B_ * HIN * HIN) / 256;   // 6272
    int pb = blockIdx.x % NPB;
    int ry = blockIdx.x / NPB;
    int rem = pb * 256 + threadIdx.x;
    int b   = rem / (HIN * HIN);
    int pix = rem % (HIN * HIN);
    int py = pix / HIN, px = pix % HIN;
    int r0 = py + ry - 1, r1 = r0 + 1;
    const float* xb = x + (size_t)b * (HIN * HIN * CIN);

    int   rows[2] = { r0, r1 };
    bool  rm[2]   = { r0 >= 0, r1 < HIN };
    int   cols[3] = { px - 1, px, px + 1 };
    bool  cm[3]   = { px >= 1, true, px + 1 < HIN };

    float gv[6][12];
    #pragma unroll
    for (int a = 0; a < 2; ++a) {
        #pragma unroll
        for (int cc = 0; cc < 3; ++cc) {
            int gi = a * 3 + cc;
            if (rm[a] && cm[cc]) {
                const float4* p4 = (const float4*)(xb +
                    ((size_t)(rows[a] * HIN + cols[cc])) * CIN);
                float4 v0 = p4[0], v1 = p4[1], v2 = p4[2];
                gv[gi][0] = v0.x; gv[gi][1]  = v0.y; gv[gi][2]  = v0.z; gv[gi][3]  = v0.w;
                gv[gi][4] = v1.x; gv[gi][5]  = v1.y; gv[gi][6]  = v1.z; gv[gi][7]  = v1.w;
                gv[gi][8] = v2.x; gv[gi][9]  = v2.y; gv[gi][10] = v2.z; gv[gi][11] = v2.w;
            } else {
                #pragma unroll
                for (int j = 0; j < 12; ++j) gv[gi][j] = 0.f;
            }
        }
    }

    const float4* w4 = (const float4*)wr;
    float acc0 = 0.f, acc1 = 0.f;
    #pragma unroll
    for (int ci = 0; ci < CIN; ++ci) {
        float4 W0 = w4[(2 * ry) * CIN + ci];
        float4 W1 = w4[(2 * ry + 1) * CIN + ci];
        acc0 += gv[0][ci] * W0.x + gv[1][ci] * W0.y + gv[3][ci] * W0.z + gv[4][ci] * W0.w;
        acc1 += gv[1][ci] * W1.x + gv[2][ci] * W1.y + gv[4][ci] * W1.z + gv[5][ci] * W1.w;
    }

    float bb = bias[0];
    float u0 = acc0 + bb, u1 = acc1 + bb;
    u0 = u0 / (1.f + expf(-u0));
    u1 = u1 / (1.f + expf(-u1));
    float2 v;
    v.x = fminf(fmaxf(u0, 0.f), 1.f);
    v.y = fminf(fmaxf(u1, 0.f), 1.f);
    int oy = 2 * py + ry;
    *(float2*)(out + (size_t)b * 50176 + oy * 224 + 2 * px) = v;
}

// ---------------------------------------------------------------------------
// launch
// ---------------------------------------------------------------------------
extern "C" void kernel_launch(void* const* d_in, const int* in_sizes, int n_in,
                              void* d_out, int out_size, void* d_ws, size_t ws_size,
                              hipStream_t stream)
{
    const float* x       = (const float*)d_in[0];
    const float* ts      = (const float*)d_in[1];
    const float* Wp      = (const float*)d_in[2];
    const float* bp      = (const float*)d_in[3];
    const float* Wt1     = (const float*)d_in[4];
    const float* bt1     = (const float*)d_in[5];
    const float* Wt2     = (const float*)d_in[6];
    const float* bt2     = (const float*)d_in[7];
    const float* a0_g    = (const float*)d_in[8];
    const float* a0_b    = (const float*)d_in[9];
    const float* a0_Wqkv = (const float*)d_in[10];
    const float* a0_bqkv = (const float*)d_in[11];
    const float* a0_Wo   = (const float*)d_in[12];
    const float* a0_bo   = (const float*)d_in[13];
    const float* a1_g    = (const float*)d_in[14];
    const float* a1_b    = (const float*)d_in[15];
    const float* a1_Wqkv = (const float*)d_in[16];
    const float* a1_bqkv = (const float*)d_in[17];
    const float* a1_Wo   = (const float*)d_in[18];
    const float* a1_bo   = (const float*)d_in[19];
    const float* Wm0     = (const float*)d_in[20];
    const float* bm0     = (const float*)d_in[21];
    const float* Wm1     = (const float*)d_in[22];
    const float* bm1     = (const float*)d_in[23];
    const float* Wm2     = (const float*)d_in[24];
    const float* bm2     = (const float*)d_in[25];
    const float* Wd1     = (const float*)d_in[26];
    const float* bd1     = (const float*)d_in[27];
    const float* l1g     = (const float*)d_in[28];
    const float* l1b     = (const float*)d_in[29];
    const float* Wd2     = (const float*)d_in[30];
    const float* bd2     = (const float*)d_in[31];
    const float* l2g     = (const float*)d_in[32];
    const float* l2b     = (const float*)d_in[33];
    const float* Wd3     = (const float*)d_in[34];
    const float* bd3     = (const float*)d_in[35];
    const float* l3g     = (const float*)d_in[36];
    const float* l3b     = (const float*)d_in[37];
    const float* Wd4     = (const float*)d_in[38];
    const float* bd4     = (const float*)d_in[39];
    float* out = (float*)d_out;

    // arena (floats); R = 25088*96
    const size_t R = 2408448;
    float* ws   = (float*)d_ws;
    float* tvec = ws;                          // 96
    float* p0   = ws + 512;                    // R
    float* h    = ws + 512 + R;                // R
    float* qkvb = ws + 512 + 2 * R;            // 3R
    float* ob   = ws + 512 + 5 * R;            // R
    float* p1   = ws + 512 + 6 * R;            // R
    // decoder aliases:
    _Float16* xinh = (_Float16*)(ws + 512 + 2 * R);   // f16 NHWC (qkv region)
    float* C1   = ws + 512 + 5 * R;            // NHWC fp32 [b][28][28][48] (ob+p1)
    _Float16* xh2 = (_Float16*)(ws + 512 + 7 * R);    // f16 NHWC padded [b][30][30][48]
    float* C2   = ws + 512;                    // NHWC fp32 [b][56][56][24] (p0..qkv)
    _Float16* xh3 = (_Float16*)(ws + 512 + 7 * R + 5529600); // f16 NHWC padded [b][58][58][24]
    float* C3   = ws + 512;                    // NHWC fp32 [b][112][112][12]
    float* Wr   = ws + 512 + 7 * R + 5529600 + 10334208;  // 96,960 floats
    _Float16* WH = (_Float16*)(Wr + 96960);                // 101,376 halves
    _Float16* Wc  = (_Float16*)Wr;              // conv1 f16 B-weights (dead L1 slice)
    _Float16* Wc2 = (_Float16*)(Wr + 36864);    // conv2 f16 B-weights
    _Float16* Wc3 = (_Float16*)(Wr + 49152);    // conv3 f16 B-weights
    float* stat = Wr + 96960 + 50688;          // 12,288 floats (LN stats, reused)
    const size_t NEED = (512 + 7 * R + 5529600 + 10334208 + 96960 + 50688 + 12288 + 16)
                        * sizeof(float);
    if (ws_size < NEED) return;

    _Float16* WHqkv0 = WH;
    _Float16* WHqkv1 = WH + 27648;
    _Float16* WHwo0  = WH + 55296;
    _Float16* WHwo1  = WH + 64512;
    _Float16* WHwm0  = WH + 73728;
    _Float16* WHwm1  = WH + 82944;
    _Float16* WHwm2  = WH + 92160;

    k_time<<<1, 128, 0, stream>>>(ts, Wt1, bt1, Wt2, bt2, tvec);
    k_repack<<<379, 256, 0, stream>>>(Wd1, Wd2, Wd3, Wd4, Wr);
    k_wcvtc<<<288, 256, 0, stream>>>(Wd1, Wc);
    k_wcvt2<<<96, 256, 0, stream>>>(Wd2, Wc2);
    k_wcvt3<<<24, 256, 0, stream>>>(Wd3, Wc3);
    k_wcvt<<<396, 256, 0, stream>>>(a0_Wqkv, a1_Wqkv, a0_Wo, a1_Wo,
                                    Wm0, Wm1, Wm2, WH);
    k_patch_mfma<<<M_ROWS / 64, 256, 0, stream>>>(x, Wp, bp, p0);

    // MHSA block 0
    k_ln_row<<<1024, 256, 0, stream>>>(p0, a0_g, a0_b, h, M_ROWS);
    k_gemm_mfma<3, false, false, false, false><<<M_ROWS / 64, 256, 0, stream>>>(
        h, WHqkv0, a0_bqkv, nullptr, nullptr, qkvb, nullptr);
    k_attn_mfma<<<B_ * 4, 256, 0, stream>>>(qkvb, ob);
    k_gemm_mfma<1, false, true, false, false><<<M_ROWS / 64, 256, 0, stream>>>(
        ob, WHwo0, a0_bo, p0, nullptr, p1, nullptr);

    // MHSA block 1 (+time)
    k_ln_row<<<1024, 256, 0, stream>>>(p1, a1_g, a1_b, h, M_ROWS);
    k_gemm_mfma<3, false, false, false, false><<<M_ROWS / 64, 256, 0, stream>>>(
        h, WHqkv1, a1_bqkv, nullptr, nullptr, qkvb, nullptr);
    k_attn_mfma<<<B_ * 4, 256, 0, stream>>>(qkvb, ob);
    k_gemm_mfma<1, false, true, true, false><<<M_ROWS / 64, 256, 0, stream>>>(
        ob, WHwo1, a1_bo, p1, tvec, p0, nullptr);

    // qkv region free: zero xinh borders before MLP3 writes interior
    k_zb_h<<<2880, 256, 0, stream>>>(xinh);

    // MLP x3 (silu); last writes f16 NHWC padded xinh
    k_gemm_mfma<1, true, false, false, false><<<M_ROWS / 64, 256, 0, stream>>>(
        p0, WHwm0, bm0, nullptr, nullptr, p1, nullptr);
    k_gemm_mfma<1, true, false, false, false><<<M_ROWS / 64, 256, 0, stream>>>(
        p1, WHwm1, bm1, nullptr, nullptr, p0, nullptr);
    k_gemm_mfma<1, true, false, false, true><<<M_ROWS / 64, 256, 0, stream>>>(
        p0, WHwm2, bm2, nullptr, nullptr, nullptr, xinh);

    // decoder: all-NHWC chain, tile-resident convs
    k_conv1<<<M_ROWS / 64, 256, 0, stream>>>(xinh, Wc, bd1, C1);
    k_ln1_stats<<<1536, 256, 0, stream>>>(C1, stat);
    k_ln1_apply<<<21600, 256, 0, stream>>>(C1, stat, l1g, l1b, xh2);
    k_conv2_tile<<<B_ * 14, 256, 0, stream>>>(xh2, Wc2, bd2, C2);
    k_ln2_stats<<<256, 256, 0, stream>>>(C2, stat);
    k_ln2_apply<<<40368, 256, 0, stream>>>(C2, stat, l2g, l2b, xh3);
    k_conv3_tile<<<B_ * 56, 256, 0, stream>>>(xh3, Wc3, bd3, C3);
    k_ln3_stats<<<512, 256, 0, stream>>>(C3, stat);
    k_ln3_apply<<<75264, 256, 0, stream>>>(C3, stat, l3g, l3b);
    k_conv_final_nhwc<<<2 * 6272, 256, 0, stream>>>(C3, Wr + 96768, bd4, out);
}

// Round 5
// 533.290 us; speedup vs baseline: 1.5075x; 1.0642x over previous
//
#include <hip/hip_runtime.h>
#include <cmath>

// ---------------------------------------------------------------------------
// TimestepVisionTransformer — Round 13: cheap LN-apply bridges.
//   - k_ln3_apply: float4-vectorized, __expf, writes f16 NHWC xh4 (37.6MB
//     instead of 75MB fp32); k_conv_final_nhwc reads f16.
//   - k_ln1_apply / k_ln2_apply: float4-vectorized + __expf.
//   - MLP silu epilogue -> __expf.
// Everything else = r12 (verified, 567us).
// B=128, IMG=224, P=16, C_IN=1, E=96, H=4, d=24, NAX=14, N=196, M=B*N=25088
// ---------------------------------------------------------------------------

#define B_   128
#define NPATCH 196
#define M_ROWS (B_*NPATCH)     // 25088
#define E_   96

typedef _Float16 half8 __attribute__((ext_vector_type(8)));
typedef _Float16 half4v __attribute__((ext_vector_type(4)));
typedef float f32x4 __attribute__((ext_vector_type(4)));

// ---------------------------------------------------------------------------
// time embedding
// ---------------------------------------------------------------------------
__global__ void k_time(const float* __restrict__ ts,
                       const float* __restrict__ Wt1, const float* __restrict__ bt1,
                       const float* __restrict__ Wt2, const float* __restrict__ bt2,
                       float* __restrict__ timev)
{
    __shared__ float h[128];
    float e = 0.69314718055994530942f * ts[0];
    float sv = sinf(e), cv = cosf(e);
    int t = threadIdx.x;
    float z = sv * Wt1[t] + cv * Wt1[128 + t] + bt1[t];
    h[t] = z / (1.f + expf(-z));
    __syncthreads();
    if (t < 96) {
        float acc = bt2[t];
        for (int j = 0; j < 128; ++j) acc += h[j] * Wt2[j * 96 + t];
        timev[t] = acc;
    }
}

// ---------------------------------------------------------------------------
// weight repack (fp32 per-parity taps). Only the L4 slice [96768,96960) is
// still consumed as fp32 (conv_final); other slices overwritten by f16 packs.
// ---------------------------------------------------------------------------
__global__ void __launch_bounds__(256) k_repack(const float* __restrict__ w1,
                                                const float* __restrict__ w2,
                                                const float* __restrict__ w3,
                                                const float* __restrict__ w4f,
                                                float* __restrict__ wr)
{
    int i = blockIdx.x * 256 + threadIdx.x;
    const float* src; int CIN, COUT, e; float* dst;
    if      (i < 73728) { src = w1;  CIN = 96; COUT = 48; e = i;          dst = wr; }
    else if (i < 92160) { src = w2;  CIN = 48; COUT = 24; e = i - 73728;  dst = wr + 73728; }
    else if (i < 96768) { src = w3;  CIN = 24; COUT = 12; e = i - 92160;  dst = wr + 92160; }
    else if (i < 96960) { src = w4f; CIN = 12; COUT = 1;  e = i - 96768;  dst = wr + 96768; }
    else return;
    int per = CIN * COUT * 4;
    int par = e / per, rem = e % per;
    int ci = rem / (COUT * 4);
    int o  = (rem >> 2) % COUT;
    int j  = rem & 3;
    int ry = par >> 1, rx = par & 1;
    int wy = (j < 2)  ? (3 - ry) : (1 - ry);
    int wx = (j & 1)  ? (1 - rx) : (3 - rx);
    dst[e] = src[(ci * COUT + o) * 16 + wy * 4 + wx];
}

// ---------------------------------------------------------------------------
// conv1 weights -> f16 B-layout Wc[p][o][k=tap*96+ci]
// ---------------------------------------------------------------------------
__global__ void __launch_bounds__(256) k_wcvtc(const float* __restrict__ w1,
                                               _Float16* __restrict__ wc)
{
    int i = blockIdx.x * 256 + threadIdx.x;
    if (i >= 4 * 48 * 384) return;
    int p = i / 18432, rem = i % 18432;
    int o = rem / 384, k = rem % 384;
    int tap = k / 96, ci = k % 96;
    int ry = p >> 1, rx = p & 1;
    int wy = (tap < 2) ? (3 - ry) : (1 - ry);
    int wx = (tap & 1) ? (1 - rx) : (3 - rx);
    wc[i] = (_Float16)w1[(ci * 48 + o) * 16 + wy * 4 + wx];
}

// ---------------------------------------------------------------------------
// conv2 weights -> f16 B-layout Wc2[p][o(32, o>=24 zero)][k=tap*48+ci]
// ---------------------------------------------------------------------------
__global__ void __launch_bounds__(256) k_wcvt2(const float* __restrict__ w2,
                                               _Float16* __restrict__ wc2)
{
    int i = blockIdx.x * 256 + threadIdx.x;
    if (i >= 4 * 32 * 192) return;
    int p = i / 6144, rem = i % 6144;
    int o = rem / 192, k = rem % 192;
    int tap = k / 48, ci = k % 48;
    int ry = p >> 1, rx = p & 1;
    int wy = (tap < 2) ? (3 - ry) : (1 - ry);
    int wx = (tap & 1) ? (1 - rx) : (3 - rx);
    wc2[i] = (o < 24) ? (_Float16)w2[(ci * 24 + o) * 16 + wy * 4 + wx]
                      : (_Float16)0.f;
}

// ---------------------------------------------------------------------------
// conv3 weights -> f16 B-layout Wc3[p][o(16, o>=12 zero)][k=tap*24+ci]
// ---------------------------------------------------------------------------
__global__ void __launch_bounds__(256) k_wcvt3(const float* __restrict__ w3,
                                               _Float16* __restrict__ wc3)
{
    int i = blockIdx.x * 256 + threadIdx.x;
    if (i >= 4 * 16 * 96) return;
    int p = i / 1536, rem = i % 1536;
    int o = rem / 96, k = rem % 96;
    int tap = k / 24, ci = k % 24;
    int ry = p >> 1, rx = p & 1;
    int wy = (tap < 2) ? (3 - ry) : (1 - ry);
    int wx = (tap & 1) ? (1 - rx) : (3 - rx);
    wc3[i] = (o < 12) ? (_Float16)w3[(ci * 12 + o) * 16 + wy * 4 + wx]
                      : (_Float16)0.f;
}

// ---------------------------------------------------------------------------
// transformer weight convert+transpose to half: Wt[n][k] = W[k][n]
// ---------------------------------------------------------------------------
__global__ void __launch_bounds__(256) k_wcvt(const float* __restrict__ qkv0,
                                              const float* __restrict__ qkv1,
                                              const float* __restrict__ wo0,
                                              const float* __restrict__ wo1,
                                              const float* __restrict__ wm0,
                                              const float* __restrict__ wm1,
                                              const float* __restrict__ wm2,
                                              _Float16* __restrict__ wh)
{
    int i = blockIdx.x * 256 + threadIdx.x;
    const float* src; int N; int e;
    if      (i < 27648)  { src = qkv0; N = 288; e = i; }
    else if (i < 55296)  { src = qkv1; N = 288; e = i - 27648; }
    else if (i < 64512)  { src = wo0;  N = 96;  e = i - 55296; }
    else if (i < 73728)  { src = wo1;  N = 96;  e = i - 64512; }
    else if (i < 82944)  { src = wm0;  N = 96;  e = i - 73728; }
    else if (i < 92160)  { src = wm1;  N = 96;  e = i - 82944; }
    else if (i < 101376) { src = wm2;  N = 96;  e = i - 92160; }
    else return;
    int n = e / 96, k = e % 96;
    wh[i] = (_Float16)src[k * N + n];
}

// ---------------------------------------------------------------------------
// zero the borders of xinh NHWC f16 [b][16][16][96]
// ---------------------------------------------------------------------------
__global__ void __launch_bounds__(256) k_zb_h(_Float16* __restrict__ xinh)
{
    int i = blockIdx.x * 256 + threadIdx.x;
    if (i >= 128 * 60 * 96) return;
    int b = i / 5760, r = i % 5760;
    int pos = r / 96, ch = r % 96;
    int py, px;
    if      (pos < 16) { py = 0;        px = pos; }
    else if (pos < 32) { py = 15;       px = pos - 16; }
    else if (pos < 46) { py = pos - 31; px = 0; }
    else               { py = pos - 45; px = 15; }
    xinh[((size_t)(b * 256) + py * 16 + px) * 96 + ch] = (_Float16)0.f;
}

// ---------------------------------------------------------------------------
// patch embed GEMM via f16 MFMA (r7, verified)
// ---------------------------------------------------------------------------
__global__ void __launch_bounds__(256) k_patch_mfma(const float* __restrict__ x,
                                                    const float* __restrict__ Wp,
                                                    const float* __restrict__ bp,
                                                    float* __restrict__ out)
{
    __shared__ __align__(16) _Float16 Ah[64 * 136];
    __shared__ __align__(16) _Float16 Wh[96 * 136];
    int t = threadIdx.x;
    int p0 = blockIdx.x * 64;
    int wave = t >> 6, lane = t & 63;
    int lm = lane & 15, quad = lane >> 4;
    f32x4 acc[6];
    #pragma unroll
    for (int nt = 0; nt < 6; ++nt) acc[nt] = (f32x4){0.f, 0.f, 0.f, 0.f};

    for (int kc = 0; kc < 2; ++kc) {
        __syncthreads();
        for (int i = t; i < 512; i += 256) {
            int lp = i >> 3, pyl = i & 7;
            int patch = p0 + lp;
            int b = patch / NPATCH, n = patch % NPATCH;
            int ny = n / 14, nx = n % 14;
            const float4* s4 = (const float4*)(x +
                ((size_t)(b * 224) + ny * 16 + kc * 8 + pyl) * 224 + nx * 16);
            float4 v0 = s4[0], v1 = s4[1], v2 = s4[2], v3 = s4[3];
            half8 h0, h1;
            h0[0]=(_Float16)v0.x; h0[1]=(_Float16)v0.y; h0[2]=(_Float16)v0.z; h0[3]=(_Float16)v0.w;
            h0[4]=(_Float16)v1.x; h0[5]=(_Float16)v1.y; h0[6]=(_Float16)v1.z; h0[7]=(_Float16)v1.w;
            h1[0]=(_Float16)v2.x; h1[1]=(_Float16)v2.y; h1[2]=(_Float16)v2.z; h1[3]=(_Float16)v2.w;
            h1[4]=(_Float16)v3.x; h1[5]=(_Float16)v3.y; h1[6]=(_Float16)v3.z; h1[7]=(_Float16)v3.w;
            *(half8*)&Ah[lp * 136 + pyl * 16]     = h0;
            *(half8*)&Ah[lp * 136 + pyl * 16 + 8] = h1;
        }
        for (int i = t; i < 1536; i += 256) {
            int e = i >> 4, s = i & 15;
            const float4* s4 = (const float4*)(Wp + e * 256 + kc * 128 + s * 8);
            float4 v0 = s4[0], v1 = s4[1];
            half8 h0;
            h0[0]=(_Float16)v0.x; h0[1]=(_Float16)v0.y; h0[2]=(_Float16)v0.z; h0[3]=(_Float16)v0.w;
            h0[4]=(_Float16)v1.x; h0[5]=(_Float16)v1.y; h0[6]=(_Float16)v1.z; h0[7]=(_Float16)v1.w;
            *(half8*)&Wh[e * 136 + s * 8] = h0;
        }
        __syncthreads();
        half8 af[4];
        #pragma unroll
        for (int ks = 0; ks < 4; ++ks)
            af[ks] = *(const half8*)&Ah[(wave * 16 + lm) * 136 + ks * 32 + quad * 8];
        #pragma unroll
        for (int ks = 0; ks < 4; ++ks) {
            #pragma unroll
            for (int nt = 0; nt < 6; ++nt) {
                half8 bf = *(const half8*)&Wh[(nt * 16 + lm) * 136 + ks * 32 + quad * 8];
                acc[nt] = __builtin_amdgcn_mfma_f32_16x16x32_f16(af[ks], bf, acc[nt], 0, 0, 0);
            }
        }
    }

    #pragma unroll
    for (int nt = 0; nt < 6; ++nt) {
        #pragma unroll
        for (int r = 0; r < 4; ++r) {
            int e = nt * 16 + lm;
            int lp = wave * 16 + quad * 4 + r;
            int patch = p0 + lp;
            int n = patch % NPATCH;
            int ny = n / 14, nx = n % 14;
            float yx = (float)(ny + nx);
            float v = acc[nt][r] + bp[e];
            float other = __shfl_xor(v, 1);
            float fi = (float)(e >> 1);
            float theta = expf(fi * (-2.f / 96.f) * 9.210340371976184f);
            float ang = theta * yx;
            float c = cosf(ang), s = sinf(ang);
            float outv = (lm & 1) ? (other * s + v * c) : (v * c - other * s);
            out[(size_t)patch * 96 + e] = outv;
        }
    }
}

// ---------------------------------------------------------------------------
// row LayerNorm over 96, wave per row
// ---------------------------------------------------------------------------
__global__ void __launch_bounds__(256) k_ln_row(const float* __restrict__ x,
                                                const float* __restrict__ g,
                                                const float* __restrict__ bv,
                                                float* __restrict__ out, int M)
{
    int lane = threadIdx.x & 63;
    int gw = (blockIdx.x * 256 + threadIdx.x) >> 6;
    int nw = (gridDim.x * 256) >> 6;
    float g0 = g[lane], b0 = bv[lane];
    float g1 = 0.f, b1 = 0.f;
    if (lane < 32) { g1 = g[64 + lane]; b1 = bv[64 + lane]; }
    for (int r = gw; r < M; r += nw) {
        const float* xr = x + (size_t)r * 96;
        float a = xr[lane];
        float c = (lane < 32) ? xr[64 + lane] : 0.f;
        float s = a + c, q = a * a + c * c;
        #pragma unroll
        for (int off = 32; off; off >>= 1) {
            s += __shfl_xor(s, off);
            q += __shfl_xor(q, off);
        }
        float mu = s * (1.f / 96.f);
        float rstd = rsqrtf(q * (1.f / 96.f) - mu * mu + 1e-5f);
        float* orow = out + (size_t)r * 96;
        orow[lane] = (a - mu) * rstd * g0 + b0;
        if (lane < 32) orow[64 + lane] = (c - mu) * rstd * g1 + b1;
    }
}

// ---------------------------------------------------------------------------
// MFMA row GEMM (r6, verified). OUTH: write f16 NHWC padded xinh instead.
// ---------------------------------------------------------------------------
template<int NCHUNKS, bool SILU, bool RES, bool ADDTIME, bool OUTH>
__global__ void __launch_bounds__(256) k_gemm_mfma(const float* __restrict__ A,
                                                   const _Float16* __restrict__ Wt,
                                                   const float* __restrict__ bias,
                                                   const float* __restrict__ res,
                                                   const float* __restrict__ timev,
                                                   float* __restrict__ out,
                                                   _Float16* __restrict__ outh)
{
    __shared__ __align__(16) _Float16 Ah[64 * 96];
    __shared__ __align__(16) _Float16 Wh[96 * 96];
    constexpr int NTOT = NCHUNKS * 96;
    int t = threadIdx.x;
    size_t row0 = (size_t)blockIdx.x * 64;

    const float4* a4 = (const float4*)(A + row0 * 96);
    for (int i = t; i < 1536; i += 256) {
        float4 v = a4[i];
        half4v hv;
        hv[0] = (_Float16)v.x; hv[1] = (_Float16)v.y;
        hv[2] = (_Float16)v.z; hv[3] = (_Float16)v.w;
        *(half4v*)&Ah[i * 4] = hv;
    }

    int wave = t >> 6, lane = t & 63;
    int lm = lane & 15, quad = lane >> 4;
    const f32x4 vzero = {0.f, 0.f, 0.f, 0.f};

    for (int ch = 0; ch < NCHUNKS; ++ch) {
        __syncthreads();
        {
            const uint4* src = (const uint4*)(Wt + (size_t)ch * 9216);
            uint4* dst = (uint4*)Wh;
            for (int i = t; i < 1152; i += 256) dst[i] = src[i];
        }
        __syncthreads();

        half8 af[3];
        #pragma unroll
        for (int ks = 0; ks < 3; ++ks)
            af[ks] = *(const half8*)&Ah[(wave * 16 + lm) * 96 + ks * 32 + quad * 8];

        f32x4 acc[6];
        #pragma unroll
        for (int ct = 0; ct < 6; ++ct) acc[ct] = vzero;

        #pragma unroll
        for (int ct = 0; ct < 6; ++ct) {
            #pragma unroll
            for (int ks = 0; ks < 3; ++ks) {
                half8 bf = *(const half8*)&Wh[(ct * 16 + lm) * 96 + ks * 32 + quad * 8];
                acc[ct] = __builtin_amdgcn_mfma_f32_16x16x32_f16(af[ks], bf, acc[ct], 0, 0, 0);
            }
        }

        #pragma unroll
        for (int ct = 0; ct < 6; ++ct) {
            #pragma unroll
            for (int r = 0; r < 4; ++r) {
                int lr = wave * 16 + quad * 4 + r;
                size_t row = row0 + lr;
                int lc = ct * 16 + lm;
                int col = ch * 96 + lc;
                float v = acc[ct][r] + bias[col];
                if constexpr (RES)     v += res[row * 96 + lc];
                if constexpr (ADDTIME) v += timev[lc];
                if constexpr (SILU)    v = v / (1.f + __expf(-v));
                if constexpr (OUTH) {
                    size_t b = row / NPATCH; int n = (int)(row % NPATCH);
                    int ny = n / 14, nx = n % 14;
                    outh[((b * 256) + (1 + ny) * 16 + (1 + nx)) * 96 + col] = (_Float16)v;
                } else {
                    out[row * NTOT + col] = v;
                }
            }
        }
    }
}

// ---------------------------------------------------------------------------
// MFMA attention (r11, verified): one block per (b,h), 4 waves.
// ---------------------------------------------------------------------------
__global__ void __launch_bounds__(256) k_attn_mfma(const float* __restrict__ qkv,
                                                   float* __restrict__ o)
{
    __shared__ __align__(16) _Float16 Qs[208 * 40];
    __shared__ __align__(16) _Float16 Ks[208 * 40];
    __shared__ __align__(16) _Float16 Vt[32 * 232];
    __shared__ __align__(16) _Float16 Pw[4][16 * 232];

    int t = threadIdx.x;
    int bh = blockIdx.x;
    int b = bh >> 2, h = bh & 3;
    const float* base = qkv + (size_t)b * NPATCH * 288 + h * 24;

    // zero all LDS (pads must be 0)
    {
        const int4 z = {0, 0, 0, 0};
        int4* q4 = (int4*)Qs; int4* k4 = (int4*)Ks;
        for (int i = t; i < 1040; i += 256) { q4[i] = z; k4[i] = z; }
        int4* v4 = (int4*)Vt;
        for (int i = t; i < 928; i += 256) v4[i] = z;
        int4* p4 = (int4*)&Pw[0][0];
        for (int i = t; i < 1856; i += 256) p4[i] = z;
    }
    __syncthreads();

    // stage Q,K (row-major, stride 40) and V transposed (Vt[d][key], stride 232)
    for (int i = t; i < NPATCH * 24; i += 256) {
        int r = i / 24, d = i % 24;
        const float* row = base + (size_t)r * 288;
        Qs[r * 40 + d]   = (_Float16)row[d];
        Ks[r * 40 + d]   = (_Float16)row[96 + d];
        Vt[d * 232 + r]  = (_Float16)row[192 + d];
    }
    __syncthreads();

    int wave = t >> 6, lane = t & 63;
    int lm = lane & 15, quad = lane >> 4;
    const float scale = 0.2041241452319315f;

    // hoist K B-fragments (shared across this wave's row-tiles)
    half8 bk[13];
    #pragma unroll
    for (int ct = 0; ct < 13; ++ct)
        bk[ct] = *(const half8*)&Ks[(ct * 16 + lm) * 40 + quad * 8];

    _Float16* pw = &Pw[wave][0];

    for (int rt = wave; rt < 13; rt += 4) {
        half8 aq = *(const half8*)&Qs[(rt * 16 + lm) * 40 + quad * 8];
        float rsum[4] = {0.f, 0.f, 0.f, 0.f};

        #pragma unroll
        for (int ct = 0; ct < 13; ++ct) {
            f32x4 s = (f32x4){0.f, 0.f, 0.f, 0.f};
            s = __builtin_amdgcn_mfma_f32_16x16x32_f16(aq, bk[ct], s, 0, 0, 0);
            #pragma unroll
            for (int r = 0; r < 4; ++r) {
                float p = __expf(fminf(s[r] * scale, 60.f));
                if (ct == 12 && lm >= 4) p = 0.f;   // keys 196..207 invalid
                rsum[r] += p;
                pw[(quad * 4 + r) * 232 + ct * 16 + lm] = (_Float16)p;
            }
        }

        // reduce row sums across the 16 lm-lanes
        #pragma unroll
        for (int r = 0; r < 4; ++r) {
            float s = rsum[r];
            s += __shfl_xor(s, 1);
            s += __shfl_xor(s, 2);
            s += __shfl_xor(s, 4);
            s += __shfl_xor(s, 8);
            rsum[r] = 1.f / s;
        }

        // PV: P[16][208(+pad0)] @ Vt -> O[16][32]
        f32x4 ov0 = (f32x4){0.f, 0.f, 0.f, 0.f};
        f32x4 ov1 = (f32x4){0.f, 0.f, 0.f, 0.f};
        #pragma unroll
        for (int ks = 0; ks < 7; ++ks) {
            half8 ap = *(const half8*)&pw[lm * 232 + ks * 32 + quad * 8];
            half8 bv0 = *(const half8*)&Vt[(lm) * 232 + ks * 32 + quad * 8];
            half8 bv1 = *(const half8*)&Vt[(16 + lm) * 232 + ks * 32 + quad * 8];
            ov0 = __builtin_amdgcn_mfma_f32_16x16x32_f16(ap, bv0, ov0, 0, 0, 0);
            ov1 = __builtin_amdgcn_mfma_f32_16x16x32_f16(ap, bv1, ov1, 0, 0, 0);
        }

        // write O (d = lm for ov0, 16+lm for ov1; valid d < 24)
        #pragma unroll
        for (int r = 0; r < 4; ++r) {
            int row = rt * 16 + quad * 4 + r;
            if (row < NPATCH) {
                float* orow = o + ((size_t)b * NPATCH + row) * 96 + h * 24;
                orow[lm] = ov0[r] * rsum[r];
                if (lm < 8) orow[16 + lm] = ov1[r] * rsum[r];
            }
        }
    }
}

// ---------------------------------------------------------------------------
// conv L1 via MFMA (r7, verified): xinh NHWC f16 padded -> C1 NHWC fp32
// ---------------------------------------------------------------------------
__global__ void __launch_bounds__(256) k_conv1(const _Float16* __restrict__ xinh,
                                               const _Float16* __restrict__ wc,
                                               const float* __restrict__ bias,
                                               float* __restrict__ c1)
{
    __shared__ __align__(16) _Float16 Ah[64 * 392];
    int t = threadIdx.x;
    int blk = blockIdx.x;
    int wave = t >> 6, lane = t & 63;
    int lm = lane & 15, quad = lane >> 4;

    for (int p = 0; p < 4; ++p) {
        int ry = p >> 1, rx = p & 1;
        __syncthreads();
        for (int i = t; i < 64 * 48; i += 256) {
            int lp = i / 48, rem = i % 48;
            int tap = rem / 12;
            int gp = blk * 64 + lp;
            int b = gp / NPATCH, pix = gp % NPATCH;
            int py = pix / 14, px = pix % 14;
            int row = py + ry + (tap >> 1), col = px + rx + (tap & 1);
            const uint4* src = (const uint4*)(xinh +
                ((size_t)(b * 256) + row * 16 + col) * 96 + (rem % 12) * 8);
            *(uint4*)&Ah[lp * 392 + rem * 8] = *src;
        }
        __syncthreads();

        half8 af[12];
        #pragma unroll
        for (int ks = 0; ks < 12; ++ks)
            af[ks] = *(const half8*)&Ah[(wave * 16 + lm) * 392 + ks * 32 + quad * 8];

        f32x4 acc[3];
        #pragma unroll
        for (int nt = 0; nt < 3; ++nt) acc[nt] = (f32x4){0.f, 0.f, 0.f, 0.f};

        #pragma unroll
        for (int ks = 0; ks < 12; ++ks) {
            #pragma unroll
            for (int nt = 0; nt < 3; ++nt) {
                half8 bf = *(const half8*)&wc[((size_t)(p * 48 + nt * 16 + lm)) * 384
                                              + ks * 32 + quad * 8];
                acc[nt] = __builtin_amdgcn_mfma_f32_16x16x32_f16(af[ks], bf, acc[nt], 0, 0, 0);
            }
        }

        #pragma unroll
        for (int nt = 0; nt < 3; ++nt) {
            #pragma unroll
            for (int r = 0; r < 4; ++r) {
                int o = nt * 16 + lm;
                int lp = wave * 16 + quad * 4 + r;
                int gp = blk * 64 + lp;
                int b = gp / NPATCH, pix = gp % NPATCH;
                int py = pix / 14, px = pix % 14;
                int oy = 2 * py + ry, ox = 2 * px + rx;
                c1[((size_t)(b * 28 + oy) * 28 + ox) * 48 + o] = acc[nt][r] + bias[o];
            }
        }
    }
}

// ---------------------------------------------------------------------------
// L1 LN stats: one wave per (b,ch) over NHWC C1 -> stat[b*48+ch] = {mu,rstd}
// ---------------------------------------------------------------------------
__global__ void __launch_bounds__(256) k_ln1_stats(const float* __restrict__ c1,
                                                   float* __restrict__ stat)
{
    int idx = blockIdx.x * 4 + (threadIdx.x >> 6);   // b*48+ch
    int lane = threadIdx.x & 63;
    int b = idx / 48, ch = idx % 48;
    const float* base = c1 + (size_t)b * 784 * 48 + ch;
    float s = 0.f, q = 0.f;
    for (int pix = lane; pix < 784; pix += 64) {
        float v = base[(size_t)pix * 48];
        s += v; q += v * v;
    }
    #pragma unroll
    for (int off = 32; off; off >>= 1) {
        s += __shfl_xor(s, off);
        q += __shfl_xor(q, off);
    }
    if (lane == 0) {
        float mu = s * (1.f / 784.f);
        float rstd = rsqrtf(q * (1.f / 784.f) - mu * mu + 1e-5f);
        stat[idx * 2]     = mu;
        stat[idx * 2 + 1] = rstd;
    }
}

// ---------------------------------------------------------------------------
// L1 LN apply, float4-vectorized: NHWC C1 + stat -> f16 NHWC padded XH2
// [b][30][30][48], silu (__expf). grid 5400.
// ---------------------------------------------------------------------------
__global__ void __launch_bounds__(256) k_ln1_apply(const float* __restrict__ c1,
                                                   const float* __restrict__ stat,
                                                   const float* __restrict__ g,
                                                   const float* __restrict__ bv,
                                                   _Float16* __restrict__ xh)
{
    int i4 = blockIdx.x * 256 + threadIdx.x;
    int idx = i4 * 4;                                // ((b*900)+pos)*48 + ch
    int ch = idx % 48;
    int t2 = idx / 48;
    int pos = t2 % 900;
    int b = t2 / 900;
    int py = pos / 30, px = pos % 30;
    half4v hv = (half4v){(_Float16)0.f, (_Float16)0.f, (_Float16)0.f, (_Float16)0.f};
    if (py >= 1 && py <= 28 && px >= 1 && px <= 28) {
        int j = (py - 1) * 28 + (px - 1);
        float4 v = *(const float4*)&c1[((size_t)b * 784 + j) * 48 + ch];
        const float* st = stat + ((size_t)b * 48 + ch) * 2;
        float gj = g[j], bj = bv[j];
        float u0 = (v.x - st[0]) * st[1] * gj + bj;
        float u1 = (v.y - st[2]) * st[3] * gj + bj;
        float u2 = (v.z - st[4]) * st[5] * gj + bj;
        float u3 = (v.w - st[6]) * st[7] * gj + bj;
        hv[0] = (_Float16)(u0 / (1.f + __expf(-u0)));
        hv[1] = (_Float16)(u1 / (1.f + __expf(-u1)));
        hv[2] = (_Float16)(u2 / (1.f + __expf(-u2)));
        hv[3] = (_Float16)(u3 / (1.f + __expf(-u3)));
    }
    *(half4v*)&xh[idx] = hv;
}

// ---------------------------------------------------------------------------
// conv L2, tile-resident (r12, verified).
// ---------------------------------------------------------------------------
__global__ void __launch_bounds__(256) k_conv2_tile(const _Float16* __restrict__ xh,
                                                    const _Float16* __restrict__ wc,
                                                    const float* __restrict__ bias,
                                                    float* __restrict__ c2)
{
    __shared__ __align__(16) _Float16 Xs[4 * 30 * 56];   // 13.1 KB
    int t = threadIdx.x;
    int blk = blockIdx.x;
    int b = blk / 14, s = blk % 14;      // strip covers pixel rows 2s, 2s+1

    for (int i = t; i < 720; i += 256) {
        int r = i / 180, rem = i % 180;
        int c = rem / 6, ch = (rem % 6) * 8;
        *(uint4*)&Xs[(r * 30 + c) * 56 + ch] =
            *(const uint4*)(xh + ((size_t)(b * 900) + (2 * s + r) * 30 + c) * 48 + ch);
    }

    int wave = t >> 6, lane = t & 63;
    int lm = lane & 15, quad = lane >> 4;
    int ry = wave >> 1, rx = wave & 1;   // parity per wave

    half8 bf0[6], bf1[6];
    #pragma unroll
    for (int ks = 0; ks < 6; ++ks) {
        bf0[ks] = *(const half8*)&wc[((size_t)(wave * 32 + lm)) * 192 + ks * 32 + quad * 8];
        bf1[ks] = *(const half8*)&wc[((size_t)(wave * 32 + 16 + lm)) * 192 + ks * 32 + quad * 8];
    }

    __syncthreads();

    #pragma unroll
    for (int rt = 0; rt < 4; ++rt) {
        int pp = rt * 16 + lm;
        int ppc = pp < 56 ? pp : 55;
        int pyl = ppc / 28, px = ppc % 28;

        half8 af[6];
        #pragma unroll
        for (int ks = 0; ks < 6; ++ks) {
            int k0 = ks * 32 + quad * 8;
            int tap = k0 / 48, off = k0 % 48;
            int dy = tap >> 1, dx = tap & 1;
            af[ks] = *(const half8*)&Xs[((pyl + ry + dy) * 30 + (px + rx + dx)) * 56 + off];
        }

        f32x4 acc0 = (f32x4){0.f, 0.f, 0.f, 0.f};
        f32x4 acc1 = (f32x4){0.f, 0.f, 0.f, 0.f};
        #pragma unroll
        for (int ks = 0; ks < 6; ++ks) {
            acc0 = __builtin_amdgcn_mfma_f32_16x16x32_f16(af[ks], bf0[ks], acc0, 0, 0, 0);
            acc1 = __builtin_amdgcn_mfma_f32_16x16x32_f16(af[ks], bf1[ks], acc1, 0, 0, 0);
        }

        #pragma unroll
        for (int r = 0; r < 4; ++r) {
            int pw = rt * 16 + quad * 4 + r;
            if (pw < 56) {
                int pylw = pw / 28, pxw = pw % 28;
                int oy = 2 * (2 * s + pylw) + ry, ox = 2 * pxw + rx;
                float* orow = c2 + ((size_t)(b * 56 + oy) * 56 + ox) * 24;
                orow[lm] = acc0[r] + bias[lm];
                if (lm < 8) orow[16 + lm] = acc1[r] + bias[16 + lm];
            }
        }
    }
}

// ---------------------------------------------------------------------------
// L2 LN stats, coalesced: block per (image b, half h).
// ---------------------------------------------------------------------------
__global__ void __launch_bounds__(256) k_ln2_stats(const float* __restrict__ c2,
                                                   float* __restrict__ pstat)
{
    __shared__ float bins[48];
    int t = threadIdx.x;
    int b = blockIdx.x >> 1, h = blockIdx.x & 1;
    if (t < 48) bins[t] = 0.f;
    __syncthreads();
    const float* base = c2 + (size_t)b * 75264 + h * 37632;
    float s0 = 0.f, s1 = 0.f, s2 = 0.f, q0 = 0.f, q1 = 0.f, q2 = 0.f;
    for (int k = 0; k < 147; k += 3) {
        float v0 = base[t + 256 * k];
        float v1 = base[t + 256 * (k + 1)];
        float v2 = base[t + 256 * (k + 2)];
        s0 += v0; q0 += v0 * v0;
        s1 += v1; q1 += v1 * v1;
        s2 += v2; q2 += v2 * v2;
    }
    int c0 = t % 24;
    int c1 = (c0 + 16) % 24;
    int c2i = (c0 + 8) % 24;
    atomicAdd(&bins[c0 * 2],      s0); atomicAdd(&bins[c0 * 2 + 1],  q0);
    atomicAdd(&bins[c1 * 2],      s1); atomicAdd(&bins[c1 * 2 + 1],  q1);
    atomicAdd(&bins[c2i * 2],     s2); atomicAdd(&bins[c2i * 2 + 1], q2);
    __syncthreads();
    if (t < 48) pstat[(size_t)blockIdx.x * 48 + t] = bins[t];
}

// ---------------------------------------------------------------------------
// L2 LN apply, float4-vectorized: C2 NHWC + pstat -> f16 NHWC padded XH3
// [b][58][58][24], silu (__expf). grid 10092.
// ---------------------------------------------------------------------------
__global__ void __launch_bounds__(256) k_ln2_apply(const float* __restrict__ c2,
                                                   const float* __restrict__ pstat,
                                                   const float* __restrict__ g,
                                                   const float* __restrict__ bv,
                                                   _Float16* __restrict__ xh)
{
    int i4 = blockIdx.x * 256 + threadIdx.x;
    int idx = i4 * 4;                                // ((b*3364)+pos)*24 + ch
    int ch = idx % 24;
    int t2 = idx / 24;
    int pos = t2 % 3364;
    int b = t2 / 3364;
    int py = pos / 58, px = pos % 58;
    half4v hv = (half4v){(_Float16)0.f, (_Float16)0.f, (_Float16)0.f, (_Float16)0.f};
    if (py >= 1 && py <= 56 && px >= 1 && px <= 56) {
        int j = (py - 1) * 56 + (px - 1);
        float4 v = *(const float4*)&c2[((size_t)b * 3136 + j) * 24 + ch];
        const float* ps = pstat + (size_t)b * 96 + ch * 2;
        float gj = g[j], bj = bv[j];
        #pragma unroll
        for (int k = 0; k < 4; ++k) {
            float s = ps[2 * k] + ps[48 + 2 * k];
            float q = ps[2 * k + 1] + ps[49 + 2 * k];
            float mu = s * (1.f / 3136.f);
            float rstd = rsqrtf(q * (1.f / 3136.f) - mu * mu + 1e-5f);
            float vv = (k == 0) ? v.x : (k == 1) ? v.y : (k == 2) ? v.z : v.w;
            float u = (vv - mu) * rstd * gj + bj;
            hv[k] = (_Float16)(u / (1.f + __expf(-u)));
        }
    }
    *(half4v*)&xh[idx] = hv;
}

// ---------------------------------------------------------------------------
// conv L3, tile-resident (r12, verified).
// ---------------------------------------------------------------------------
__global__ void __launch_bounds__(256) k_conv3_tile(const _Float16* __restrict__ xh,
                                                    const _Float16* __restrict__ wc,
                                                    const float* __restrict__ bias,
                                                    float* __restrict__ c3)
{
    __shared__ __align__(16) _Float16 Xs[3 * 58 * 40];   // 13.6 KB
    int t = threadIdx.x;
    int blk = blockIdx.x;
    int b = blk / 56, s = blk % 56;     // strip covers pixel row s

    for (int i = t; i < 522; i += 256) {
        int r = i / 174, rem = i % 174;
        int c = rem / 3, ch = (rem % 3) * 8;
        *(uint4*)&Xs[(r * 58 + c) * 40 + ch] =
            *(const uint4*)(xh + ((size_t)(b * 3364) + (s + r) * 58 + c) * 24 + ch);
    }

    int wave = t >> 6, lane = t & 63;
    int lm = lane & 15, quad = lane >> 4;
    int ry = wave >> 1, rx = wave & 1;

    half8 bf[3];
    #pragma unroll
    for (int ks = 0; ks < 3; ++ks)
        bf[ks] = *(const half8*)&wc[((size_t)(wave * 16 + lm)) * 96 + ks * 32 + quad * 8];

    __syncthreads();

    #pragma unroll
    for (int rt = 0; rt < 4; ++rt) {
        int px = rt * 16 + lm;
        int pxc = px < 56 ? px : 55;

        half8 af[3];
        #pragma unroll
        for (int ks = 0; ks < 3; ++ks) {
            int k0 = ks * 32 + quad * 8;
            int tap = k0 / 24, off = k0 % 24;
            int dy = tap >> 1, dx = tap & 1;
            af[ks] = *(const half8*)&Xs[((ry + dy) * 58 + (pxc + rx + dx)) * 40 + off];
        }

        f32x4 acc = (f32x4){0.f, 0.f, 0.f, 0.f};
        #pragma unroll
        for (int ks = 0; ks < 3; ++ks)
            acc = __builtin_amdgcn_mfma_f32_16x16x32_f16(af[ks], bf[ks], acc, 0, 0, 0);

        if (lm < 12) {
            #pragma unroll
            for (int r = 0; r < 4; ++r) {
                int pw = rt * 16 + quad * 4 + r;
                if (pw < 56) {
                    int oy = 2 * s + ry, ox = 2 * pw + rx;
                    c3[((size_t)(b * 112 + oy) * 112 + ox) * 12 + lm] = acc[r] + bias[lm];
                }
            }
        }
    }
}

// ---------------------------------------------------------------------------
// L3 LN stats, coalesced: block per (image b, quarter h).
// ---------------------------------------------------------------------------
__global__ void __launch_bounds__(256) k_ln3_stats(const float* __restrict__ c3,
                                                   float* __restrict__ pstat)
{
    __shared__ float bins[24];
    int t = threadIdx.x;
    int b = blockIdx.x >> 2, h = blockIdx.x & 3;
    if (t < 24) bins[t] = 0.f;
    __syncthreads();
    const float* base = c3 + (size_t)b * 150528 + h * 37632;
    float s0 = 0.f, s1 = 0.f, s2 = 0.f, q0 = 0.f, q1 = 0.f, q2 = 0.f;
    for (int k = 0; k < 147; k += 3) {
        float v0 = base[t + 256 * k];
        float v1 = base[t + 256 * (k + 1)];
        float v2 = base[t + 256 * (k + 2)];
        s0 += v0; q0 += v0 * v0;
        s1 += v1; q1 += v1 * v1;
        s2 += v2; q2 += v2 * v2;
    }
    int c0 = t % 12;
    int c1 = (c0 + 4) % 12;
    int c2i = (c0 + 8) % 12;
    atomicAdd(&bins[c0 * 2],      s0); atomicAdd(&bins[c0 * 2 + 1],  q0);
    atomicAdd(&bins[c1 * 2],      s1); atomicAdd(&bins[c1 * 2 + 1],  q1);
    atomicAdd(&bins[c2i * 2],     s2); atomicAdd(&bins[c2i * 2 + 1], q2);
    __syncthreads();
    if (t < 24) pstat[(size_t)blockIdx.x * 24 + t] = bins[t];
}

// ---------------------------------------------------------------------------
// L3 LN apply, float4-vectorized: C3 NHWC + pstat -> f16 NHWC xh4
// [b][112][112][12], silu (__expf). grid 18816.
// ---------------------------------------------------------------------------
__global__ void __launch_bounds__(256) k_ln3_apply(const float* __restrict__ c3,
                                                   const float* __restrict__ pstat,
                                                   const float* __restrict__ g,
                                                   const float* __restrict__ bv,
                                                   _Float16* __restrict__ xh4)
{
    int i4 = blockIdx.x * 256 + threadIdx.x;
    int idx = i4 * 4;
    int ch = idx % 12;                               // 0, 4, 8
    int t2 = idx / 12;
    int pix = t2 % 12544;
    int b = t2 / 12544;
    float4 v = *(const float4*)&c3[idx];
    const float* ps = pstat + (size_t)b * 96 + ch * 2;
    float gp = g[pix], bp = bv[pix];
    half4v hv;
    #pragma unroll
    for (int k = 0; k < 4; ++k) {
        float s = ps[2 * k] + ps[24 + 2 * k] + ps[48 + 2 * k] + ps[72 + 2 * k];
        float q = ps[2 * k + 1] + ps[25 + 2 * k] + ps[49 + 2 * k] + ps[73 + 2 * k];
        float mu = s * (1.f / 12544.f);
        float rstd = rsqrtf(q * (1.f / 12544.f) - mu * mu + 1e-5f);
        float vv = (k == 0) ? v.x : (k == 1) ? v.y : (k == 2) ? v.z : v.w;
        float u = (vv - mu) * rstd * gp + bp;
        hv[k] = (_Float16)(u / (1.f + __expf(-u)));
    }
    *(half4v*)&xh4[idx] = hv;
}

// ---------------------------------------------------------------------------
// final convT 12->1, f16 NHWC input (xh4).
// ---------------------------------------------------------------------------
__global__ void __launch_bounds__(256) k_conv_final_nhwc(const _Float16* __restrict__ x,
                                                         const float* __restrict__ wr,
                                                         const float* __restrict__ bias,
                                                         float* __restrict__ out)
{
    constexpr int HIN = 112, CIN = 12;
    constexpr int NPB = (B_ * HIN * HIN) / 256;   // 6272
    int pb = blockIdx.x % NPB;
    int ry = blockIdx.x / NPB;
    int rem = pb * 256 + threadIdx.x;
    int b   = rem / (HIN * HIN);
    int pix = rem % (HIN * HIN);
    int py = pix / HIN, px = pix % HIN;
    int r0 = py + ry - 1, r1 = r0 + 1;
    const _Float16* xb = x + (size_t)b * (HIN * HIN * CIN);

    int   rows[2] = { r0, r1 };
    bool  rm[2]   = { r0 >= 0, r1 < HIN };
    int   cols[3] = { px - 1, px, px + 1 };
    bool  cm[3]   = { px >= 1, true, px + 1 < HIN };

    float gv[6][12];
    #pragma unroll
    for (int a = 0; a < 2; ++a) {
        #pragma unroll
        for (int cc = 0; cc < 3; ++cc) {
            int gi = a * 3 + cc;
            if (rm[a] && cm[cc]) {
                const _Float16* p = xb + ((size_t)(rows[a] * HIN + cols[cc])) * CIN;
                half4v h0 = *(const half4v*)&p[0];
                half4v h1 = *(const half4v*)&p[4];
                half4v h2 = *(const half4v*)&p[8];
                #pragma unroll
                for (int j = 0; j < 4; ++j) {
                    gv[gi][j]     = (float)h0[j];
                    gv[gi][4 + j] = (float)h1[j];
                    gv[gi][8 + j] = (float)h2[j];
                }
            } else {
                #pragma unroll
                for (int j = 0; j < 12; ++j) gv[gi][j] = 0.f;
            }
        }
    }

    const float4* w4 = (const float4*)wr;
    float acc0 = 0.f, acc1 = 0.f;
    #pragma unroll
    for (int ci = 0; ci < CIN; ++ci) {
        float4 W0 = w4[(2 * ry) * CIN + ci];
        float4 W1 = w4[(2 * ry + 1) * CIN + ci];
        acc0 += gv[0][ci] * W0.x + gv[1][ci] * W0.y + gv[3][ci] * W0.z + gv[4][ci] * W0.w;
        acc1 += gv[1][ci] * W1.x + gv[2][ci] * W1.y + gv[4][ci] * W1.z + gv[5][ci] * W1.w;
    }

    float bb = bias[0];
    float u0 = acc0 + bb, u1 = acc1 + bb;
    u0 = u0 / (1.f + __expf(-u0));
    u1 = u1 / (1.f + __expf(-u1));
    float2 v;
    v.x = fminf(fmaxf(u0, 0.f), 1.f);
    v.y = fminf(fmaxf(u1, 0.f), 1.f);
    int oy = 2 * py + ry;
    *(float2*)(out + (size_t)b * 50176 + oy * 224 + 2 * px) = v;
}

// ---------------------------------------------------------------------------
// launch
// ---------------------------------------------------------------------------
extern "C" void kernel_launch(void* const* d_in, const int* in_sizes, int n_in,
                              void* d_out, int out_size, void* d_ws, size_t ws_size,
                              hipStream_t stream)
{
    const float* x       = (const float*)d_in[0];
    const float* ts      = (const float*)d_in[1];
    const float* Wp      = (const float*)d_in[2];
    const float* bp      = (const float*)d_in[3];
    const float* Wt1     = (const float*)d_in[4];
    const float* bt1     = (const float*)d_in[5];
    const float* Wt2     = (const float*)d_in[6];
    const float* bt2     = (const float*)d_in[7];
    const float* a0_g    = (const float*)d_in[8];
    const float* a0_b    = (const float*)d_in[9];
    const float* a0_Wqkv = (const float*)d_in[10];
    const float* a0_bqkv = (const float*)d_in[11];
    const float* a0_Wo   = (const float*)d_in[12];
    const float* a0_bo   = (const float*)d_in[13];
    const float* a1_g    = (const float*)d_in[14];
    const float* a1_b    = (const float*)d_in[15];
    const float* a1_Wqkv = (const float*)d_in[16];
    const float* a1_bqkv = (const float*)d_in[17];
    const float* a1_Wo   = (const float*)d_in[18];
    const float* a1_bo   = (const float*)d_in[19];
    const float* Wm0     = (const float*)d_in[20];
    const float* bm0     = (const float*)d_in[21];
    const float* Wm1     = (const float*)d_in[22];
    const float* bm1     = (const float*)d_in[23];
    const float* Wm2     = (const float*)d_in[24];
    const float* bm2     = (const float*)d_in[25];
    const float* Wd1     = (const float*)d_in[26];
    const float* bd1     = (const float*)d_in[27];
    const float* l1g     = (const float*)d_in[28];
    const float* l1b     = (const float*)d_in[29];
    const float* Wd2     = (const float*)d_in[30];
    const float* bd2     = (const float*)d_in[31];
    const float* l2g     = (const float*)d_in[32];
    const float* l2b     = (const float*)d_in[33];
    const float* Wd3     = (const float*)d_in[34];
    const float* bd3     = (const float*)d_in[35];
    const float* l3g     = (const float*)d_in[36];
    const float* l3b     = (const float*)d_in[37];
    const float* Wd4     = (const float*)d_in[38];
    const float* bd4     = (const float*)d_in[39];
    float* out = (float*)d_out;

    // arena (floats); R = 25088*96
    const size_t R = 2408448;
    float* ws   = (float*)d_ws;
    float* tvec = ws;                          // 96
    float* p0   = ws + 512;                    // R
    float* h    = ws + 512 + R;                // R
    float* qkvb = ws + 512 + 2 * R;            // 3R
    float* ob   = ws + 512 + 5 * R;            // R
    float* p1   = ws + 512 + 6 * R;            // R
    // decoder aliases:
    _Float16* xinh = (_Float16*)(ws + 512 + 2 * R);   // f16 NHWC (qkv region)
    float* C1   = ws + 512 + 5 * R;            // NHWC fp32 [b][28][28][48] (ob+p1)
    _Float16* xh2 = (_Float16*)(ws + 512 + 7 * R);    // f16 NHWC padded [b][30][30][48]
    float* C2   = ws + 512;                    // NHWC fp32 [b][56][56][24] (p0..qkv)
    _Float16* xh3 = (_Float16*)(ws + 512 + 7 * R + 5529600); // f16 NHWC padded [b][58][58][24]
    float* C3   = ws + 512;                    // NHWC fp32 [b][112][112][12]
    _Float16* xh4 = (_Float16*)(ws + 512 + 7 * R + 5529600); // f16 NHWC [b][112][112][12] (reuses xh3)
    float* Wr   = ws + 512 + 7 * R + 5529600 + 10334208;  // 96,960 floats
    _Float16* WH = (_Float16*)(Wr + 96960);                // 101,376 halves
    _Float16* Wc  = (_Float16*)Wr;              // conv1 f16 B-weights (dead L1 slice)
    _Float16* Wc2 = (_Float16*)(Wr + 36864);    // conv2 f16 B-weights
    _Float16* Wc3 = (_Float16*)(Wr + 49152);    // conv3 f16 B-weights
    float* stat = Wr + 96960 + 50688;          // 12,288 floats (LN stats, reused)
    const size_t NEED = (512 + 7 * R + 5529600 + 10334208 + 96960 + 50688 + 12288 + 16)
                        * sizeof(float);
    if (ws_size < NEED) return;

    _Float16* WHqkv0 = WH;
    _Float16* WHqkv1 = WH + 27648;
    _Float16* WHwo0  = WH + 55296;
    _Float16* WHwo1  = WH + 64512;
    _Float16* WHwm0  = WH + 73728;
    _Float16* WHwm1  = WH + 82944;
    _Float16* WHwm2  = WH + 92160;

    k_time<<<1, 128, 0, stream>>>(ts, Wt1, bt1, Wt2, bt2, tvec);
    k_repack<<<379, 256, 0, stream>>>(Wd1, Wd2, Wd3, Wd4, Wr);
    k_wcvtc<<<288, 256, 0, stream>>>(Wd1, Wc);
    k_wcvt2<<<96, 256, 0, stream>>>(Wd2, Wc2);
    k_wcvt3<<<24, 256, 0, stream>>>(Wd3, Wc3);
    k_wcvt<<<396, 256, 0, stream>>>(a0_Wqkv, a1_Wqkv, a0_Wo, a1_Wo,
                                    Wm0, Wm1, Wm2, WH);
    k_patch_mfma<<<M_ROWS / 64, 256, 0, stream>>>(x, Wp, bp, p0);

    // MHSA block 0
    k_ln_row<<<1024, 256, 0, stream>>>(p0, a0_g, a0_b, h, M_ROWS);
    k_gemm_mfma<3, false, false, false, false><<<M_ROWS / 64, 256, 0, stream>>>(
        h, WHqkv0, a0_bqkv, nullptr, nullptr, qkvb, nullptr);
    k_attn_mfma<<<B_ * 4, 256, 0, stream>>>(qkvb, ob);
    k_gemm_mfma<1, false, true, false, false><<<M_ROWS / 64, 256, 0, stream>>>(
        ob, WHwo0, a0_bo, p0, nullptr, p1, nullptr);

    // MHSA block 1 (+time)
    k_ln_row<<<1024, 256, 0, stream>>>(p1, a1_g, a1_b, h, M_ROWS);
    k_gemm_mfma<3, false, false, false, false><<<M_ROWS / 64, 256, 0, stream>>>(
        h, WHqkv1, a1_bqkv, nullptr, nullptr, qkvb, nullptr);
    k_attn_mfma<<<B_ * 4, 256, 0, stream>>>(qkvb, ob);
    k_gemm_mfma<1, false, true, true, false><<<M_ROWS / 64, 256, 0, stream>>>(
        ob, WHwo1, a1_bo, p1, tvec, p0, nullptr);

    // qkv region free: zero xinh borders before MLP3 writes interior
    k_zb_h<<<2880, 256, 0, stream>>>(xinh);

    // MLP x3 (silu); last writes f16 NHWC padded xinh
    k_gemm_mfma<1, true, false, false, false><<<M_ROWS / 64, 256, 0, stream>>>(
        p0, WHwm0, bm0, nullptr, nullptr, p1, nullptr);
    k_gemm_mfma<1, true, false, false, false><<<M_ROWS / 64, 256, 0, stream>>>(
        p1, WHwm1, bm1, nullptr, nullptr, p0, nullptr);
    k_gemm_mfma<1, true, false, false, true><<<M_ROWS / 64, 256, 0, stream>>>(
        p0, WHwm2, bm2, nullptr, nullptr, nullptr, xinh);

    // decoder: all-NHWC chain, tile-resident convs
    k_conv1<<<M_ROWS / 64, 256, 0, stream>>>(xinh, Wc, bd1, C1);
    k_ln1_stats<<<1536, 256, 0, stream>>>(C1, stat);
    k_ln1_apply<<<5400, 256, 0, stream>>>(C1, stat, l1g, l1b, xh2);
    k_conv2_tile<<<B_ * 14, 256, 0, stream>>>(xh2, Wc2, bd2, C2);
    k_ln2_stats<<<256, 256, 0, stream>>>(C2, stat);
    k_ln2_apply<<<10092, 256, 0, stream>>>(C2, stat, l2g, l2b, xh3);
    k_conv3_tile<<<B_ * 56, 256, 0, stream>>>(xh3, Wc3, bd3, C3);
    k_ln3_stats<<<512, 256, 0, stream>>>(C3, stat);
    k_ln3_apply<<<18816, 256, 0, stream>>>(C3, stat, l3g, l3b, xh4);
    k_conv_final_nhwc<<<2 * 6272, 256, 0, stream>>>(xh4, Wr + 96768, bd4, out);
}

// Round 6
// 513.813 us; speedup vs baseline: 1.5646x; 1.0379x over previous
//
#include <hip/hip_runtime.h>
#include <cmath>

// ---------------------------------------------------------------------------
// TimestepVisionTransformer — Round 14: tile-resident conv1.
//   - k_conv1_tile replaces 4-phase-serial k_conv1 (50us, MfmaUtil 2.5%,
//     occupancy 12.8%, latency-bound): stage strip once, one barrier,
//     parity-per-wave, B-frags hoisted per col-tile, 104-stride LDS
//     (bank-spread), merged stride-2 writes. Grid 896 blocks.
// Everything else = r13 (verified, 533us).
// B=128, IMG=224, P=16, C_IN=1, E=96, H=4, d=24, NAX=14, N=196, M=B*N=25088
// ---------------------------------------------------------------------------

#define B_   128
#define NPATCH 196
#define M_ROWS (B_*NPATCH)     // 25088
#define E_   96

typedef _Float16 half8 __attribute__((ext_vector_type(8)));
typedef _Float16 half4v __attribute__((ext_vector_type(4)));
typedef float f32x4 __attribute__((ext_vector_type(4)));

// ---------------------------------------------------------------------------
// time embedding
// ---------------------------------------------------------------------------
__global__ void k_time(const float* __restrict__ ts,
                       const float* __restrict__ Wt1, const float* __restrict__ bt1,
                       const float* __restrict__ Wt2, const float* __restrict__ bt2,
                       float* __restrict__ timev)
{
    __shared__ float h[128];
    float e = 0.69314718055994530942f * ts[0];
    float sv = sinf(e), cv = cosf(e);
    int t = threadIdx.x;
    float z = sv * Wt1[t] + cv * Wt1[128 + t] + bt1[t];
    h[t] = z / (1.f + expf(-z));
    __syncthreads();
    if (t < 96) {
        float acc = bt2[t];
        for (int j = 0; j < 128; ++j) acc += h[j] * Wt2[j * 96 + t];
        timev[t] = acc;
    }
}

// ---------------------------------------------------------------------------
// weight repack (fp32 per-parity taps). Only the L4 slice [96768,96960) is
// still consumed as fp32 (conv_final); other slices overwritten by f16 packs.
// ---------------------------------------------------------------------------
__global__ void __launch_bounds__(256) k_repack(const float* __restrict__ w1,
                                                const float* __restrict__ w2,
                                                const float* __restrict__ w3,
                                                const float* __restrict__ w4f,
                                                float* __restrict__ wr)
{
    int i = blockIdx.x * 256 + threadIdx.x;
    const float* src; int CIN, COUT, e; float* dst;
    if      (i < 73728) { src = w1;  CIN = 96; COUT = 48; e = i;          dst = wr; }
    else if (i < 92160) { src = w2;  CIN = 48; COUT = 24; e = i - 73728;  dst = wr + 73728; }
    else if (i < 96768) { src = w3;  CIN = 24; COUT = 12; e = i - 92160;  dst = wr + 92160; }
    else if (i < 96960) { src = w4f; CIN = 12; COUT = 1;  e = i - 96768;  dst = wr + 96768; }
    else return;
    int per = CIN * COUT * 4;
    int par = e / per, rem = e % per;
    int ci = rem / (COUT * 4);
    int o  = (rem >> 2) % COUT;
    int j  = rem & 3;
    int ry = par >> 1, rx = par & 1;
    int wy = (j < 2)  ? (3 - ry) : (1 - ry);
    int wx = (j & 1)  ? (1 - rx) : (3 - rx);
    dst[e] = src[(ci * COUT + o) * 16 + wy * 4 + wx];
}

// ---------------------------------------------------------------------------
// conv1 weights -> f16 B-layout Wc[p][o][k=tap*96+ci]
// ---------------------------------------------------------------------------
__global__ void __launch_bounds__(256) k_wcvtc(const float* __restrict__ w1,
                                               _Float16* __restrict__ wc)
{
    int i = blockIdx.x * 256 + threadIdx.x;
    if (i >= 4 * 48 * 384) return;
    int p = i / 18432, rem = i % 18432;
    int o = rem / 384, k = rem % 384;
    int tap = k / 96, ci = k % 96;
    int ry = p >> 1, rx = p & 1;
    int wy = (tap < 2) ? (3 - ry) : (1 - ry);
    int wx = (tap & 1) ? (1 - rx) : (3 - rx);
    wc[i] = (_Float16)w1[(ci * 48 + o) * 16 + wy * 4 + wx];
}

// ---------------------------------------------------------------------------
// conv2 weights -> f16 B-layout Wc2[p][o(32, o>=24 zero)][k=tap*48+ci]
// ---------------------------------------------------------------------------
__global__ void __launch_bounds__(256) k_wcvt2(const float* __restrict__ w2,
                                               _Float16* __restrict__ wc2)
{
    int i = blockIdx.x * 256 + threadIdx.x;
    if (i >= 4 * 32 * 192) return;
    int p = i / 6144, rem = i % 6144;
    int o = rem / 192, k = rem % 192;
    int tap = k / 48, ci = k % 48;
    int ry = p >> 1, rx = p & 1;
    int wy = (tap < 2) ? (3 - ry) : (1 - ry);
    int wx = (tap & 1) ? (1 - rx) : (3 - rx);
    wc2[i] = (o < 24) ? (_Float16)w2[(ci * 24 + o) * 16 + wy * 4 + wx]
                      : (_Float16)0.f;
}

// ---------------------------------------------------------------------------
// conv3 weights -> f16 B-layout Wc3[p][o(16, o>=12 zero)][k=tap*24+ci]
// ---------------------------------------------------------------------------
__global__ void __launch_bounds__(256) k_wcvt3(const float* __restrict__ w3,
                                               _Float16* __restrict__ wc3)
{
    int i = blockIdx.x * 256 + threadIdx.x;
    if (i >= 4 * 16 * 96) return;
    int p = i / 1536, rem = i % 1536;
    int o = rem / 96, k = rem % 96;
    int tap = k / 24, ci = k % 24;
    int ry = p >> 1, rx = p & 1;
    int wy = (tap < 2) ? (3 - ry) : (1 - ry);
    int wx = (tap & 1) ? (1 - rx) : (3 - rx);
    wc3[i] = (o < 12) ? (_Float16)w3[(ci * 12 + o) * 16 + wy * 4 + wx]
                      : (_Float16)0.f;
}

// ---------------------------------------------------------------------------
// transformer weight convert+transpose to half: Wt[n][k] = W[k][n]
// ---------------------------------------------------------------------------
__global__ void __launch_bounds__(256) k_wcvt(const float* __restrict__ qkv0,
                                              const float* __restrict__ qkv1,
                                              const float* __restrict__ wo0,
                                              const float* __restrict__ wo1,
                                              const float* __restrict__ wm0,
                                              const float* __restrict__ wm1,
                                              const float* __restrict__ wm2,
                                              _Float16* __restrict__ wh)
{
    int i = blockIdx.x * 256 + threadIdx.x;
    const float* src; int N; int e;
    if      (i < 27648)  { src = qkv0; N = 288; e = i; }
    else if (i < 55296)  { src = qkv1; N = 288; e = i - 27648; }
    else if (i < 64512)  { src = wo0;  N = 96;  e = i - 55296; }
    else if (i < 73728)  { src = wo1;  N = 96;  e = i - 64512; }
    else if (i < 82944)  { src = wm0;  N = 96;  e = i - 73728; }
    else if (i < 92160)  { src = wm1;  N = 96;  e = i - 82944; }
    else if (i < 101376) { src = wm2;  N = 96;  e = i - 92160; }
    else return;
    int n = e / 96, k = e % 96;
    wh[i] = (_Float16)src[k * N + n];
}

// ---------------------------------------------------------------------------
// zero the borders of xinh NHWC f16 [b][16][16][96]
// ---------------------------------------------------------------------------
__global__ void __launch_bounds__(256) k_zb_h(_Float16* __restrict__ xinh)
{
    int i = blockIdx.x * 256 + threadIdx.x;
    if (i >= 128 * 60 * 96) return;
    int b = i / 5760, r = i % 5760;
    int pos = r / 96, ch = r % 96;
    int py, px;
    if      (pos < 16) { py = 0;        px = pos; }
    else if (pos < 32) { py = 15;       px = pos - 16; }
    else if (pos < 46) { py = pos - 31; px = 0; }
    else               { py = pos - 45; px = 15; }
    xinh[((size_t)(b * 256) + py * 16 + px) * 96 + ch] = (_Float16)0.f;
}

// ---------------------------------------------------------------------------
// patch embed GEMM via f16 MFMA (r7, verified)
// ---------------------------------------------------------------------------
__global__ void __launch_bounds__(256) k_patch_mfma(const float* __restrict__ x,
                                                    const float* __restrict__ Wp,
                                                    const float* __restrict__ bp,
                                                    float* __restrict__ out)
{
    __shared__ __align__(16) _Float16 Ah[64 * 136];
    __shared__ __align__(16) _Float16 Wh[96 * 136];
    int t = threadIdx.x;
    int p0 = blockIdx.x * 64;
    int wave = t >> 6, lane = t & 63;
    int lm = lane & 15, quad = lane >> 4;
    f32x4 acc[6];
    #pragma unroll
    for (int nt = 0; nt < 6; ++nt) acc[nt] = (f32x4){0.f, 0.f, 0.f, 0.f};

    for (int kc = 0; kc < 2; ++kc) {
        __syncthreads();
        for (int i = t; i < 512; i += 256) {
            int lp = i >> 3, pyl = i & 7;
            int patch = p0 + lp;
            int b = patch / NPATCH, n = patch % NPATCH;
            int ny = n / 14, nx = n % 14;
            const float4* s4 = (const float4*)(x +
                ((size_t)(b * 224) + ny * 16 + kc * 8 + pyl) * 224 + nx * 16);
            float4 v0 = s4[0], v1 = s4[1], v2 = s4[2], v3 = s4[3];
            half8 h0, h1;
            h0[0]=(_Float16)v0.x; h0[1]=(_Float16)v0.y; h0[2]=(_Float16)v0.z; h0[3]=(_Float16)v0.w;
            h0[4]=(_Float16)v1.x; h0[5]=(_Float16)v1.y; h0[6]=(_Float16)v1.z; h0[7]=(_Float16)v1.w;
            h1[0]=(_Float16)v2.x; h1[1]=(_Float16)v2.y; h1[2]=(_Float16)v2.z; h1[3]=(_Float16)v2.w;
            h1[4]=(_Float16)v3.x; h1[5]=(_Float16)v3.y; h1[6]=(_Float16)v3.z; h1[7]=(_Float16)v3.w;
            *(half8*)&Ah[lp * 136 + pyl * 16]     = h0;
            *(half8*)&Ah[lp * 136 + pyl * 16 + 8] = h1;
        }
        for (int i = t; i < 1536; i += 256) {
            int e = i >> 4, s = i & 15;
            const float4* s4 = (const float4*)(Wp + e * 256 + kc * 128 + s * 8);
            float4 v0 = s4[0], v1 = s4[1];
            half8 h0;
            h0[0]=(_Float16)v0.x; h0[1]=(_Float16)v0.y; h0[2]=(_Float16)v0.z; h0[3]=(_Float16)v0.w;
            h0[4]=(_Float16)v1.x; h0[5]=(_Float16)v1.y; h0[6]=(_Float16)v1.z; h0[7]=(_Float16)v1.w;
            *(half8*)&Wh[e * 136 + s * 8] = h0;
        }
        __syncthreads();
        half8 af[4];
        #pragma unroll
        for (int ks = 0; ks < 4; ++ks)
            af[ks] = *(const half8*)&Ah[(wave * 16 + lm) * 136 + ks * 32 + quad * 8];
        #pragma unroll
        for (int ks = 0; ks < 4; ++ks) {
            #pragma unroll
            for (int nt = 0; nt < 6; ++nt) {
                half8 bf = *(const half8*)&Wh[(nt * 16 + lm) * 136 + ks * 32 + quad * 8];
                acc[nt] = __builtin_amdgcn_mfma_f32_16x16x32_f16(af[ks], bf, acc[nt], 0, 0, 0);
            }
        }
    }

    #pragma unroll
    for (int nt = 0; nt < 6; ++nt) {
        #pragma unroll
        for (int r = 0; r < 4; ++r) {
            int e = nt * 16 + lm;
            int lp = wave * 16 + quad * 4 + r;
            int patch = p0 + lp;
            int n = patch % NPATCH;
            int ny = n / 14, nx = n % 14;
            float yx = (float)(ny + nx);
            float v = acc[nt][r] + bp[e];
            float other = __shfl_xor(v, 1);
            float fi = (float)(e >> 1);
            float theta = expf(fi * (-2.f / 96.f) * 9.210340371976184f);
            float ang = theta * yx;
            float c = cosf(ang), s = sinf(ang);
            float outv = (lm & 1) ? (other * s + v * c) : (v * c - other * s);
            out[(size_t)patch * 96 + e] = outv;
        }
    }
}

// ---------------------------------------------------------------------------
// row LayerNorm over 96, wave per row
// ---------------------------------------------------------------------------
__global__ void __launch_bounds__(256) k_ln_row(const float* __restrict__ x,
                                                const float* __restrict__ g,
                                                const float* __restrict__ bv,
                                                float* __restrict__ out, int M)
{
    int lane = threadIdx.x & 63;
    int gw = (blockIdx.x * 256 + threadIdx.x) >> 6;
    int nw = (gridDim.x * 256) >> 6;
    float g0 = g[lane], b0 = bv[lane];
    float g1 = 0.f, b1 = 0.f;
    if (lane < 32) { g1 = g[64 + lane]; b1 = bv[64 + lane]; }
    for (int r = gw; r < M; r += nw) {
        const float* xr = x + (size_t)r * 96;
        float a = xr[lane];
        float c = (lane < 32) ? xr[64 + lane] : 0.f;
        float s = a + c, q = a * a + c * c;
        #pragma unroll
        for (int off = 32; off; off >>= 1) {
            s += __shfl_xor(s, off);
            q += __shfl_xor(q, off);
        }
        float mu = s * (1.f / 96.f);
        float rstd = rsqrtf(q * (1.f / 96.f) - mu * mu + 1e-5f);
        float* orow = out + (size_t)r * 96;
        orow[lane] = (a - mu) * rstd * g0 + b0;
        if (lane < 32) orow[64 + lane] = (c - mu) * rstd * g1 + b1;
    }
}

// ---------------------------------------------------------------------------
// MFMA row GEMM (r6, verified). OUTH: write f16 NHWC padded xinh instead.
// ---------------------------------------------------------------------------
template<int NCHUNKS, bool SILU, bool RES, bool ADDTIME, bool OUTH>
__global__ void __launch_bounds__(256) k_gemm_mfma(const float* __restrict__ A,
                                                   const _Float16* __restrict__ Wt,
                                                   const float* __restrict__ bias,
                                                   const float* __restrict__ res,
                                                   const float* __restrict__ timev,
                                                   float* __restrict__ out,
                                                   _Float16* __restrict__ outh)
{
    __shared__ __align__(16) _Float16 Ah[64 * 96];
    __shared__ __align__(16) _Float16 Wh[96 * 96];
    constexpr int NTOT = NCHUNKS * 96;
    int t = threadIdx.x;
    size_t row0 = (size_t)blockIdx.x * 64;

    const float4* a4 = (const float4*)(A + row0 * 96);
    for (int i = t; i < 1536; i += 256) {
        float4 v = a4[i];
        half4v hv;
        hv[0] = (_Float16)v.x; hv[1] = (_Float16)v.y;
        hv[2] = (_Float16)v.z; hv[3] = (_Float16)v.w;
        *(half4v*)&Ah[i * 4] = hv;
    }

    int wave = t >> 6, lane = t & 63;
    int lm = lane & 15, quad = lane >> 4;
    const f32x4 vzero = {0.f, 0.f, 0.f, 0.f};

    for (int ch = 0; ch < NCHUNKS; ++ch) {
        __syncthreads();
        {
            const uint4* src = (const uint4*)(Wt + (size_t)ch * 9216);
            uint4* dst = (uint4*)Wh;
            for (int i = t; i < 1152; i += 256) dst[i] = src[i];
        }
        __syncthreads();

        half8 af[3];
        #pragma unroll
        for (int ks = 0; ks < 3; ++ks)
            af[ks] = *(const half8*)&Ah[(wave * 16 + lm) * 96 + ks * 32 + quad * 8];

        f32x4 acc[6];
        #pragma unroll
        for (int ct = 0; ct < 6; ++ct) acc[ct] = vzero;

        #pragma unroll
        for (int ct = 0; ct < 6; ++ct) {
            #pragma unroll
            for (int ks = 0; ks < 3; ++ks) {
                half8 bf = *(const half8*)&Wh[(ct * 16 + lm) * 96 + ks * 32 + quad * 8];
                acc[ct] = __builtin_amdgcn_mfma_f32_16x16x32_f16(af[ks], bf, acc[ct], 0, 0, 0);
            }
        }

        #pragma unroll
        for (int ct = 0; ct < 6; ++ct) {
            #pragma unroll
            for (int r = 0; r < 4; ++r) {
                int lr = wave * 16 + quad * 4 + r;
                size_t row = row0 + lr;
                int lc = ct * 16 + lm;
                int col = ch * 96 + lc;
                float v = acc[ct][r] + bias[col];
                if constexpr (RES)     v += res[row * 96 + lc];
                if constexpr (ADDTIME) v += timev[lc];
                if constexpr (SILU)    v = v / (1.f + __expf(-v));
                if constexpr (OUTH) {
                    size_t b = row / NPATCH; int n = (int)(row % NPATCH);
                    int ny = n / 14, nx = n % 14;
                    outh[((b * 256) + (1 + ny) * 16 + (1 + nx)) * 96 + col] = (_Float16)v;
                } else {
                    out[row * NTOT + col] = v;
                }
            }
        }
    }
}

// ---------------------------------------------------------------------------
// MFMA attention (r11, verified): one block per (b,h), 4 waves.
// ---------------------------------------------------------------------------
__global__ void __launch_bounds__(256) k_attn_mfma(const float* __restrict__ qkv,
                                                   float* __restrict__ o)
{
    __shared__ __align__(16) _Float16 Qs[208 * 40];
    __shared__ __align__(16) _Float16 Ks[208 * 40];
    __shared__ __align__(16) _Float16 Vt[32 * 232];
    __shared__ __align__(16) _Float16 Pw[4][16 * 232];

    int t = threadIdx.x;
    int bh = blockIdx.x;
    int b = bh >> 2, h = bh & 3;
    const float* base = qkv + (size_t)b * NPATCH * 288 + h * 24;

    // zero all LDS (pads must be 0)
    {
        const int4 z = {0, 0, 0, 0};
        int4* q4 = (int4*)Qs; int4* k4 = (int4*)Ks;
        for (int i = t; i < 1040; i += 256) { q4[i] = z; k4[i] = z; }
        int4* v4 = (int4*)Vt;
        for (int i = t; i < 928; i += 256) v4[i] = z;
        int4* p4 = (int4*)&Pw[0][0];
        for (int i = t; i < 1856; i += 256) p4[i] = z;
    }
    __syncthreads();

    // stage Q,K (row-major, stride 40) and V transposed (Vt[d][key], stride 232)
    for (int i = t; i < NPATCH * 24; i += 256) {
        int r = i / 24, d = i % 24;
        const float* row = base + (size_t)r * 288;
        Qs[r * 40 + d]   = (_Float16)row[d];
        Ks[r * 40 + d]   = (_Float16)row[96 + d];
        Vt[d * 232 + r]  = (_Float16)row[192 + d];
    }
    __syncthreads();

    int wave = t >> 6, lane = t & 63;
    int lm = lane & 15, quad = lane >> 4;
    const float scale = 0.2041241452319315f;

    // hoist K B-fragments (shared across this wave's row-tiles)
    half8 bk[13];
    #pragma unroll
    for (int ct = 0; ct < 13; ++ct)
        bk[ct] = *(const half8*)&Ks[(ct * 16 + lm) * 40 + quad * 8];

    _Float16* pw = &Pw[wave][0];

    for (int rt = wave; rt < 13; rt += 4) {
        half8 aq = *(const half8*)&Qs[(rt * 16 + lm) * 40 + quad * 8];
        float rsum[4] = {0.f, 0.f, 0.f, 0.f};

        #pragma unroll
        for (int ct = 0; ct < 13; ++ct) {
            f32x4 s = (f32x4){0.f, 0.f, 0.f, 0.f};
            s = __builtin_amdgcn_mfma_f32_16x16x32_f16(aq, bk[ct], s, 0, 0, 0);
            #pragma unroll
            for (int r = 0; r < 4; ++r) {
                float p = __expf(fminf(s[r] * scale, 60.f));
                if (ct == 12 && lm >= 4) p = 0.f;   // keys 196..207 invalid
                rsum[r] += p;
                pw[(quad * 4 + r) * 232 + ct * 16 + lm] = (_Float16)p;
            }
        }

        // reduce row sums across the 16 lm-lanes
        #pragma unroll
        for (int r = 0; r < 4; ++r) {
            float s = rsum[r];
            s += __shfl_xor(s, 1);
            s += __shfl_xor(s, 2);
            s += __shfl_xor(s, 4);
            s += __shfl_xor(s, 8);
            rsum[r] = 1.f / s;
        }

        // PV: P[16][208(+pad0)] @ Vt -> O[16][32]
        f32x4 ov0 = (f32x4){0.f, 0.f, 0.f, 0.f};
        f32x4 ov1 = (f32x4){0.f, 0.f, 0.f, 0.f};
        #pragma unroll
        for (int ks = 0; ks < 7; ++ks) {
            half8 ap = *(const half8*)&pw[lm * 232 + ks * 32 + quad * 8];
            half8 bv0 = *(const half8*)&Vt[(lm) * 232 + ks * 32 + quad * 8];
            half8 bv1 = *(const half8*)&Vt[(16 + lm) * 232 + ks * 32 + quad * 8];
            ov0 = __builtin_amdgcn_mfma_f32_16x16x32_f16(ap, bv0, ov0, 0, 0, 0);
            ov1 = __builtin_amdgcn_mfma_f32_16x16x32_f16(ap, bv1, ov1, 0, 0, 0);
        }

        // write O (d = lm for ov0, 16+lm for ov1; valid d < 24)
        #pragma unroll
        for (int r = 0; r < 4; ++r) {
            int row = rt * 16 + quad * 4 + r;
            if (row < NPATCH) {
                float* orow = o + ((size_t)b * NPATCH + row) * 96 + h * 24;
                orow[lm] = ov0[r] * rsum[r];
                if (lm < 8) orow[16 + lm] = ov1[r] * rsum[r];
            }
        }
    }
}

// ---------------------------------------------------------------------------
// conv L1, tile-resident: xinh NHWC f16 padded [b][16][16][96] -> C1 NHWC
// fp32 [b][28][28][48]. Block = 2-pixel-row strip (28 px) of one image:
// stage input rows 2s..2s+3 once (pixel stride 104 halves, bank-spread),
// one barrier, parity-per-wave, B-frags hoisted per col-tile (L2-resident).
// ---------------------------------------------------------------------------
__global__ void __launch_bounds__(256) k_conv1_tile(const _Float16* __restrict__ xinh,
                                                    const _Float16* __restrict__ wc,
                                                    const float* __restrict__ bias,
                                                    float* __restrict__ c1)
{
    __shared__ __align__(16) _Float16 Xs[4 * 16 * 104];   // 13.3 KB
    int t = threadIdx.x;
    int blk = blockIdx.x;
    int b = blk / 7, s = blk % 7;        // output pixel rows 2s, 2s+1

    // stage padded rows 2s..2s+3, 16 cols, 96 ch (12 chunks of 8 halves)
    for (int i = t; i < 768; i += 256) {
        int r = i / 192, rem = i % 192;
        int c = rem / 12, ch = (rem % 12) * 8;
        *(uint4*)&Xs[(r * 16 + c) * 104 + ch] =
            *(const uint4*)(xinh + ((size_t)(b * 256) + (2 * s + r) * 16 + c) * 96 + ch);
    }

    int wave = t >> 6, lane = t & 63;
    int lm = lane & 15, quad = lane >> 4;
    int ry = wave >> 1, rx = wave & 1;   // parity per wave

    __syncthreads();

    for (int nt = 0; nt < 3; ++nt) {
        // hoist B fragments for this col-tile (L2-resident weights)
        half8 bf[12];
        #pragma unroll
        for (int ks = 0; ks < 12; ++ks)
            bf[ks] = *(const half8*)&wc[((size_t)(wave * 48 + nt * 16 + lm)) * 384
                                        + ks * 32 + quad * 8];

        #pragma unroll
        for (int rt = 0; rt < 2; ++rt) {
            int pp = rt * 16 + lm;
            int ppc = pp < 28 ? pp : 27;
            int pyl = ppc / 14, px = ppc % 14;

            half8 af[12];
            #pragma unroll
            for (int ks = 0; ks < 12; ++ks) {
                int k0 = ks * 32 + quad * 8;
                int tap = k0 / 96, off = k0 % 96;
                int dy = tap >> 1, dx = tap & 1;
                af[ks] = *(const half8*)&Xs[((pyl + ry + dy) * 16 + (px + rx + dx)) * 104 + off];
            }

            f32x4 acc = (f32x4){0.f, 0.f, 0.f, 0.f};
            #pragma unroll
            for (int ks = 0; ks < 12; ++ks)
                acc = __builtin_amdgcn_mfma_f32_16x16x32_f16(af[ks], bf[ks], acc, 0, 0, 0);

            #pragma unroll
            for (int r = 0; r < 4; ++r) {
                int pw = rt * 16 + quad * 4 + r;
                if (pw < 28) {
                    int pylw = pw / 14, pxw = pw % 14;
                    int oy = 2 * (2 * s + pylw) + ry, ox = 2 * pxw + rx;
                    c1[((size_t)(b * 28 + oy) * 28 + ox) * 48 + nt * 16 + lm]
                        = acc[r] + bias[nt * 16 + lm];
                }
            }
        }
    }
}

// ---------------------------------------------------------------------------
// L1 LN stats: one wave per (b,ch) over NHWC C1 -> stat[b*48+ch] = {mu,rstd}
// ---------------------------------------------------------------------------
__global__ void __launch_bounds__(256) k_ln1_stats(const float* __restrict__ c1,
                                                   float* __restrict__ stat)
{
    int idx = blockIdx.x * 4 + (threadIdx.x >> 6);   // b*48+ch
    int lane = threadIdx.x & 63;
    int b = idx / 48, ch = idx % 48;
    const float* base = c1 + (size_t)b * 784 * 48 + ch;
    float s = 0.f, q = 0.f;
    for (int pix = lane; pix < 784; pix += 64) {
        float v = base[(size_t)pix * 48];
        s += v; q += v * v;
    }
    #pragma unroll
    for (int off = 32; off; off >>= 1) {
        s += __shfl_xor(s, off);
        q += __shfl_xor(q, off);
    }
    if (lane == 0) {
        float mu = s * (1.f / 784.f);
        float rstd = rsqrtf(q * (1.f / 784.f) - mu * mu + 1e-5f);
        stat[idx * 2]     = mu;
        stat[idx * 2 + 1] = rstd;
    }
}

// ---------------------------------------------------------------------------
// L1 LN apply, float4-vectorized: NHWC C1 + stat -> f16 NHWC padded XH2
// [b][30][30][48], silu (__expf). grid 5400.
// ---------------------------------------------------------------------------
__global__ void __launch_bounds__(256) k_ln1_apply(const float* __restrict__ c1,
                                                   const float* __restrict__ stat,
                                                   const float* __restrict__ g,
                                                   const float* __restrict__ bv,
                                                   _Float16* __restrict__ xh)
{
    int i4 = blockIdx.x * 256 + threadIdx.x;
    int idx = i4 * 4;                                // ((b*900)+pos)*48 + ch
    int ch = idx % 48;
    int t2 = idx / 48;
    int pos = t2 % 900;
    int b = t2 / 900;
    int py = pos / 30, px = pos % 30;
    half4v hv = (half4v){(_Float16)0.f, (_Float16)0.f, (_Float16)0.f, (_Float16)0.f};
    if (py >= 1 && py <= 28 && px >= 1 && px <= 28) {
        int j = (py - 1) * 28 + (px - 1);
        float4 v = *(const float4*)&c1[((size_t)b * 784 + j) * 48 + ch];
        const float* st = stat + ((size_t)b * 48 + ch) * 2;
        float gj = g[j], bj = bv[j];
        float u0 = (v.x - st[0]) * st[1] * gj + bj;
        float u1 = (v.y - st[2]) * st[3] * gj + bj;
        float u2 = (v.z - st[4]) * st[5] * gj + bj;
        float u3 = (v.w - st[6]) * st[7] * gj + bj;
        hv[0] = (_Float16)(u0 / (1.f + __expf(-u0)));
        hv[1] = (_Float16)(u1 / (1.f + __expf(-u1)));
        hv[2] = (_Float16)(u2 / (1.f + __expf(-u2)));
        hv[3] = (_Float16)(u3 / (1.f + __expf(-u3)));
    }
    *(half4v*)&xh[idx] = hv;
}

// ---------------------------------------------------------------------------
// conv L2, tile-resident (r12, verified).
// ---------------------------------------------------------------------------
__global__ void __launch_bounds__(256) k_conv2_tile(const _Float16* __restrict__ xh,
                                                    const _Float16* __restrict__ wc,
                                                    const float* __restrict__ bias,
                                                    float* __restrict__ c2)
{
    __shared__ __align__(16) _Float16 Xs[4 * 30 * 56];   // 13.1 KB
    int t = threadIdx.x;
    int blk = blockIdx.x;
    int b = blk / 14, s = blk % 14;      // strip covers pixel rows 2s, 2s+1

    for (int i = t; i < 720; i += 256) {
        int r = i / 180, rem = i % 180;
        int c = rem / 6, ch = (rem % 6) * 8;
        *(uint4*)&Xs[(r * 30 + c) * 56 + ch] =
            *(const uint4*)(xh + ((size_t)(b * 900) + (2 * s + r) * 30 + c) * 48 + ch);
    }

    int wave = t >> 6, lane = t & 63;
    int lm = lane & 15, quad = lane >> 4;
    int ry = wave >> 1, rx = wave & 1;   // parity per wave

    half8 bf0[6], bf1[6];
    #pragma unroll
    for (int ks = 0; ks < 6; ++ks) {
        bf0[ks] = *(const half8*)&wc[((size_t)(wave * 32 + lm)) * 192 + ks * 32 + quad * 8];
        bf1[ks] = *(const half8*)&wc[((size_t)(wave * 32 + 16 + lm)) * 192 + ks * 32 + quad * 8];
    }

    __syncthreads();

    #pragma unroll
    for (int rt = 0; rt < 4; ++rt) {
        int pp = rt * 16 + lm;
        int ppc = pp < 56 ? pp : 55;
        int pyl = ppc / 28, px = ppc % 28;

        half8 af[6];
        #pragma unroll
        for (int ks = 0; ks < 6; ++ks) {
            int k0 = ks * 32 + quad * 8;
            int tap = k0 / 48, off = k0 % 48;
            int dy = tap >> 1, dx = tap & 1;
            af[ks] = *(const half8*)&Xs[((pyl + ry + dy) * 30 + (px + rx + dx)) * 56 + off];
        }

        f32x4 acc0 = (f32x4){0.f, 0.f, 0.f, 0.f};
        f32x4 acc1 = (f32x4){0.f, 0.f, 0.f, 0.f};
        #pragma unroll
        for (int ks = 0; ks < 6; ++ks) {
            acc0 = __builtin_amdgcn_mfma_f32_16x16x32_f16(af[ks], bf0[ks], acc0, 0, 0, 0);
            acc1 = __builtin_amdgcn_mfma_f32_16x16x32_f16(af[ks], bf1[ks], acc1, 0, 0, 0);
        }

        #pragma unroll
        for (int r = 0; r < 4; ++r) {
            int pw = rt * 16 + quad * 4 + r;
            if (pw < 56) {
                int pylw = pw / 28, pxw = pw % 28;
                int oy = 2 * (2 * s + pylw) + ry, ox = 2 * pxw + rx;
                float* orow = c2 + ((size_t)(b * 56 + oy) * 56 + ox) * 24;
                orow[lm] = acc0[r] + bias[lm];
                if (lm < 8) orow[16 + lm] = acc1[r] + bias[16 + lm];
            }
        }
    }
}

// ---------------------------------------------------------------------------
// L2 LN stats, coalesced: block per (image b, half h).
// ---------------------------------------------------------------------------
__global__ void __launch_bounds__(256) k_ln2_stats(const float* __restrict__ c2,
                                                   float* __restrict__ pstat)
{
    __shared__ float bins[48];
    int t = threadIdx.x;
    int b = blockIdx.x >> 1, h = blockIdx.x & 1;
    if (t < 48) bins[t] = 0.f;
    __syncthreads();
    const float* base = c2 + (size_t)b * 75264 + h * 37632;
    float s0 = 0.f, s1 = 0.f, s2 = 0.f, q0 = 0.f, q1 = 0.f, q2 = 0.f;
    for (int k = 0; k < 147; k += 3) {
        float v0 = base[t + 256 * k];
        float v1 = base[t + 256 * (k + 1)];
        float v2 = base[t + 256 * (k + 2)];
        s0 += v0; q0 += v0 * v0;
        s1 += v1; q1 += v1 * v1;
        s2 += v2; q2 += v2 * v2;
    }
    int c0 = t % 24;
    int c1 = (c0 + 16) % 24;
    int c2i = (c0 + 8) % 24;
    atomicAdd(&bins[c0 * 2],      s0); atomicAdd(&bins[c0 * 2 + 1],  q0);
    atomicAdd(&bins[c1 * 2],      s1); atomicAdd(&bins[c1 * 2 + 1],  q1);
    atomicAdd(&bins[c2i * 2],     s2); atomicAdd(&bins[c2i * 2 + 1], q2);
    __syncthreads();
    if (t < 48) pstat[(size_t)blockIdx.x * 48 + t] = bins[t];
}

// ---------------------------------------------------------------------------
// L2 LN apply, float4-vectorized: C2 NHWC + pstat -> f16 NHWC padded XH3
// [b][58][58][24], silu (__expf). grid 10092.
// ---------------------------------------------------------------------------
__global__ void __launch_bounds__(256) k_ln2_apply(const float* __restrict__ c2,
                                                   const float* __restrict__ pstat,
                                                   const float* __restrict__ g,
                                                   const float* __restrict__ bv,
                                                   _Float16* __restrict__ xh)
{
    int i4 = blockIdx.x * 256 + threadIdx.x;
    int idx = i4 * 4;                                // ((b*3364)+pos)*24 + ch
    int ch = idx % 24;
    int t2 = idx / 24;
    int pos = t2 % 3364;
    int b = t2 / 3364;
    int py = pos / 58, px = pos % 58;
    half4v hv = (half4v){(_Float16)0.f, (_Float16)0.f, (_Float16)0.f, (_Float16)0.f};
    if (py >= 1 && py <= 56 && px >= 1 && px <= 56) {
        int j = (py - 1) * 56 + (px - 1);
        float4 v = *(const float4*)&c2[((size_t)b * 3136 + j) * 24 + ch];
        const float* ps = pstat + (size_t)b * 96 + ch * 2;
        float gj = g[j], bj = bv[j];
        #pragma unroll
        for (int k = 0; k < 4; ++k) {
            float s = ps[2 * k] + ps[48 + 2 * k];
            float q = ps[2 * k + 1] + ps[49 + 2 * k];
            float mu = s * (1.f / 3136.f);
            float rstd = rsqrtf(q * (1.f / 3136.f) - mu * mu + 1e-5f);
            float vv = (k == 0) ? v.x : (k == 1) ? v.y : (k == 2) ? v.z : v.w;
            float u = (vv - mu) * rstd * gj + bj;
            hv[k] = (_Float16)(u / (1.f + __expf(-u)));
        }
    }
    *(half4v*)&xh[idx] = hv;
}

// ---------------------------------------------------------------------------
// conv L3, tile-resident (r12, verified).
// ---------------------------------------------------------------------------
__global__ void __launch_bounds__(256) k_conv3_tile(const _Float16* __restrict__ xh,
                                                    const _Float16* __restrict__ wc,
                                                    const float* __restrict__ bias,
                                                    float* __restrict__ c3)
{
    __shared__ __align__(16) _Float16 Xs[3 * 58 * 40];   // 13.6 KB
    int t = threadIdx.x;
    int blk = blockIdx.x;
    int b = blk / 56, s = blk % 56;     // strip covers pixel row s

    for (int i = t; i < 522; i += 256) {
        int r = i / 174, rem = i % 174;
        int c = rem / 3, ch = (rem % 3) * 8;
        *(uint4*)&Xs[(r * 58 + c) * 40 + ch] =
            *(const uint4*)(xh + ((size_t)(b * 3364) + (s + r) * 58 + c) * 24 + ch);
    }

    int wave = t >> 6, lane = t & 63;
    int lm = lane & 15, quad = lane >> 4;
    int ry = wave >> 1, rx = wave & 1;

    half8 bf[3];
    #pragma unroll
    for (int ks = 0; ks < 3; ++ks)
        bf[ks] = *(const half8*)&wc[((size_t)(wave * 16 + lm)) * 96 + ks * 32 + quad * 8];

    __syncthreads();

    #pragma unroll
    for (int rt = 0; rt < 4; ++rt) {
        int px = rt * 16 + lm;
        int pxc = px < 56 ? px : 55;

        half8 af[3];
        #pragma unroll
        for (int ks = 0; ks < 3; ++ks) {
            int k0 = ks * 32 + quad * 8;
            int tap = k0 / 24, off = k0 % 24;
            int dy = tap >> 1, dx = tap & 1;
            af[ks] = *(const half8*)&Xs[((ry + dy) * 58 + (pxc + rx + dx)) * 40 + off];
        }

        f32x4 acc = (f32x4){0.f, 0.f, 0.f, 0.f};
        #pragma unroll
        for (int ks = 0; ks < 3; ++ks)
            acc = __builtin_amdgcn_mfma_f32_16x16x32_f16(af[ks], bf[ks], acc, 0, 0, 0);

        if (lm < 12) {
            #pragma unroll
            for (int r = 0; r < 4; ++r) {
                int pw = rt * 16 + quad * 4 + r;
                if (pw < 56) {
                    int oy = 2 * s + ry, ox = 2 * pw + rx;
                    c3[((size_t)(b * 112 + oy) * 112 + ox) * 12 + lm] = acc[r] + bias[lm];
                }
            }
        }
    }
}

// ---------------------------------------------------------------------------
// L3 LN stats, coalesced: block per (image b, quarter h).
// ---------------------------------------------------------------------------
__global__ void __launch_bounds__(256) k_ln3_stats(const float* __restrict__ c3,
                                                   float* __restrict__ pstat)
{
    __shared__ float bins[24];
    int t = threadIdx.x;
    int b = blockIdx.x >> 2, h = blockIdx.x & 3;
    if (t < 24) bins[t] = 0.f;
    __syncthreads();
    const float* base = c3 + (size_t)b * 150528 + h * 37632;
    float s0 = 0.f, s1 = 0.f, s2 = 0.f, q0 = 0.f, q1 = 0.f, q2 = 0.f;
    for (int k = 0; k < 147; k += 3) {
        float v0 = base[t + 256 * k];
        float v1 = base[t + 256 * (k + 1)];
        float v2 = base[t + 256 * (k + 2)];
        s0 += v0; q0 += v0 * v0;
        s1 += v1; q1 += v1 * v1;
        s2 += v2; q2 += v2 * v2;
    }
    int c0 = t % 12;
    int c1 = (c0 + 4) % 12;
    int c2i = (c0 + 8) % 12;
    atomicAdd(&bins[c0 * 2],      s0); atomicAdd(&bins[c0 * 2 + 1],  q0);
    atomicAdd(&bins[c1 * 2],      s1); atomicAdd(&bins[c1 * 2 + 1],  q1);
    atomicAdd(&bins[c2i * 2],     s2); atomicAdd(&bins[c2i * 2 + 1], q2);
    __syncthreads();
    if (t < 24) pstat[(size_t)blockIdx.x * 24 + t] = bins[t];
}

// ---------------------------------------------------------------------------
// L3 LN apply, float4-vectorized: C3 NHWC + pstat -> f16 NHWC xh4
// [b][112][112][12], silu (__expf). grid 18816.
// ---------------------------------------------------------------------------
__global__ void __launch_bounds__(256) k_ln3_apply(const float* __restrict__ c3,
                                                   const float* __restrict__ pstat,
                                                   const float* __restrict__ g,
                                                   const float* __restrict__ bv,
                                                   _Float16* __restrict__ xh4)
{
    int i4 = blockIdx.x * 256 + threadIdx.x;
    int idx = i4 * 4;
    int ch = idx % 12;                               // 0, 4, 8
    int t2 = idx / 12;
    int pix = t2 % 12544;
    int b = t2 / 12544;
    float4 v = *(const float4*)&c3[idx];
    const float* ps = pstat + (size_t)b * 96 + ch * 2;
    float gp = g[pix], bp = bv[pix];
    half4v hv;
    #pragma unroll
    for (int k = 0; k < 4; ++k) {
        float s = ps[2 * k] + ps[24 + 2 * k] + ps[48 + 2 * k] + ps[72 + 2 * k];
        float q = ps[2 * k + 1] + ps[25 + 2 * k] + ps[49 + 2 * k] + ps[73 + 2 * k];
        float mu = s * (1.f / 12544.f);
        float rstd = rsqrtf(q * (1.f / 12544.f) - mu * mu + 1e-5f);
        float vv = (k == 0) ? v.x : (k == 1) ? v.y : (k == 2) ? v.z : v.w;
        float u = (vv - mu) * rstd * gp + bp;
        hv[k] = (_Float16)(u / (1.f + __expf(-u)));
    }
    *(half4v*)&xh4[idx] = hv;
}

// ---------------------------------------------------------------------------
// final convT 12->1, f16 NHWC input (xh4).
// ---------------------------------------------------------------------------
__global__ void __launch_bounds__(256) k_conv_final_nhwc(const _Float16* __restrict__ x,
                                                         const float* __restrict__ wr,
                                                         const float* __restrict__ bias,
                                                         float* __restrict__ out)
{
    constexpr int HIN = 112, CIN = 12;
    constexpr int NPB = (B_ * HIN * HIN) / 256;   // 6272
    int pb = blockIdx.x % NPB;
    int ry = blockIdx.x / NPB;
    int rem = pb * 256 + threadIdx.x;
    int b   = rem / (HIN * HIN);
    int pix = rem % (HIN * HIN);
    int py = pix / HIN, px = pix % HIN;
    int r0 = py + ry - 1, r1 = r0 + 1;
    const _Float16* xb = x + (size_t)b * (HIN * HIN * CIN);

    int   rows[2] = { r0, r1 };
    bool  rm[2]   = { r0 >= 0, r1 < HIN };
    int   cols[3] = { px - 1, px, px + 1 };
    bool  cm[3]   = { px >= 1, true, px + 1 < HIN };

    float gv[6][12];
    #pragma unroll
    for (int a = 0; a < 2; ++a) {
        #pragma unroll
        for (int cc = 0; cc < 3; ++cc) {
            int gi = a * 3 + cc;
            if (rm[a] && cm[cc]) {
                const _Float16* p = xb + ((size_t)(rows[a] * HIN + cols[cc])) * CIN;
                half4v h0 = *(const half4v*)&p[0];
                half4v h1 = *(const half4v*)&p[4];
                half4v h2 = *(const half4v*)&p[8];
                #pragma unroll
                for (int j = 0; j < 4; ++j) {
                    gv[gi][j]     = (float)h0[j];
                    gv[gi][4 + j] = (float)h1[j];
                    gv[gi][8 + j] = (float)h2[j];
                }
            } else {
                #pragma unroll
                for (int j = 0; j < 12; ++j) gv[gi][j] = 0.f;
            }
        }
    }

    const float4* w4 = (const float4*)wr;
    float acc0 = 0.f, acc1 = 0.f;
    #pragma unroll
    for (int ci = 0; ci < CIN; ++ci) {
        float4 W0 = w4[(2 * ry) * CIN + ci];
        float4 W1 = w4[(2 * ry + 1) * CIN + ci];
        acc0 += gv[0][ci] * W0.x + gv[1][ci] * W0.y + gv[3][ci] * W0.z + gv[4][ci] * W0.w;
        acc1 += gv[1][ci] * W1.x + gv[2][ci] * W1.y + gv[4][ci] * W1.z + gv[5][ci] * W1.w;
    }

    float bb = bias[0];
    float u0 = acc0 + bb, u1 = acc1 + bb;
    u0 = u0 / (1.f + __expf(-u0));
    u1 = u1 / (1.f + __expf(-u1));
    float2 v;
    v.x = fminf(fmaxf(u0, 0.f), 1.f);
    v.y = fminf(fmaxf(u1, 0.f), 1.f);
    int oy = 2 * py + ry;
    *(float2*)(out + (size_t)b * 50176 + oy * 224 + 2 * px) = v;
}

// ---------------------------------------------------------------------------
// launch
// ---------------------------------------------------------------------------
extern "C" void kernel_launch(void* const* d_in, const int* in_sizes, int n_in,
                              void* d_out, int out_size, void* d_ws, size_t ws_size,
                              hipStream_t stream)
{
    const float* x       = (const float*)d_in[0];
    const float* ts      = (const float*)d_in[1];
    const float* Wp      = (const float*)d_in[2];
    const float* bp      = (const float*)d_in[3];
    const float* Wt1     = (const float*)d_in[4];
    const float* bt1     = (const float*)d_in[5];
    const float* Wt2     = (const float*)d_in[6];
    const float* bt2     = (const float*)d_in[7];
    const float* a0_g    = (const float*)d_in[8];
    const float* a0_b    = (const float*)d_in[9];
    const float* a0_Wqkv = (const float*)d_in[10];
    const float* a0_bqkv = (const float*)d_in[11];
    const float* a0_Wo   = (const float*)d_in[12];
    const float* a0_bo   = (const float*)d_in[13];
    const float* a1_g    = (const float*)d_in[14];
    const float* a1_b    = (const float*)d_in[15];
    const float* a1_Wqkv = (const float*)d_in[16];
    const float* a1_bqkv = (const float*)d_in[17];
    const float* a1_Wo   = (const float*)d_in[18];
    const float* a1_bo   = (const float*)d_in[19];
    const float* Wm0     = (const float*)d_in[20];
    const float* bm0     = (const float*)d_in[21];
    const float* Wm1     = (const float*)d_in[22];
    const float* bm1     = (const float*)d_in[23];
    const float* Wm2     = (const float*)d_in[24];
    const float* bm2     = (const float*)d_in[25];
    const float* Wd1     = (const float*)d_in[26];
    const float* bd1     = (const float*)d_in[27];
    const float* l1g     = (const float*)d_in[28];
    const float* l1b     = (const float*)d_in[29];
    const float* Wd2     = (const float*)d_in[30];
    const float* bd2     = (const float*)d_in[31];
    const float* l2g     = (const float*)d_in[32];
    const float* l2b     = (const float*)d_in[33];
    const float* Wd3     = (const float*)d_in[34];
    const float* bd3     = (const float*)d_in[35];
    const float* l3g     = (const float*)d_in[36];
    const float* l3b     = (const float*)d_in[37];
    const float* Wd4     = (const float*)d_in[38];
    const float* bd4     = (const float*)d_in[39];
    float* out = (float*)d_out;

    // arena (floats); R = 25088*96
    const size_t R = 2408448;
    float* ws   = (float*)d_ws;
    float* tvec = ws;                          // 96
    float* p0   = ws + 512;                    // R
    float* h    = ws + 512 + R;                // R
    float* qkvb = ws + 512 + 2 * R;            // 3R
    float* ob   = ws + 512 + 5 * R;            // R
    float* p1   = ws + 512 + 6 * R;            // R
    // decoder aliases:
    _Float16* xinh = (_Float16*)(ws + 512 + 2 * R);   // f16 NHWC (qkv region)
    float* C1   = ws + 512 + 5 * R;            // NHWC fp32 [b][28][28][48] (ob+p1)
    _Float16* xh2 = (_Float16*)(ws + 512 + 7 * R);    // f16 NHWC padded [b][30][30][48]
    float* C2   = ws + 512;                    // NHWC fp32 [b][56][56][24] (p0..qkv)
    _Float16* xh3 = (_Float16*)(ws + 512 + 7 * R + 5529600); // f16 NHWC padded [b][58][58][24]
    float* C3   = ws + 512;                    // NHWC fp32 [b][112][112][12]
    _Float16* xh4 = (_Float16*)(ws + 512 + 7 * R + 5529600); // f16 NHWC [b][112][112][12] (reuses xh3)
    float* Wr   = ws + 512 + 7 * R + 5529600 + 10334208;  // 96,960 floats
    _Float16* WH = (_Float16*)(Wr + 96960);                // 101,376 halves
    _Float16* Wc  = (_Float16*)Wr;              // conv1 f16 B-weights (dead L1 slice)
    _Float16* Wc2 = (_Float16*)(Wr + 36864);    // conv2 f16 B-weights
    _Float16* Wc3 = (_Float16*)(Wr + 49152);    // conv3 f16 B-weights
    float* stat = Wr + 96960 + 50688;          // 12,288 floats (LN stats, reused)
    const size_t NEED = (512 + 7 * R + 5529600 + 10334208 + 96960 + 50688 + 12288 + 16)
                        * sizeof(float);
    if (ws_size < NEED) return;

    _Float16* WHqkv0 = WH;
    _Float16* WHqkv1 = WH + 27648;
    _Float16* WHwo0  = WH + 55296;
    _Float16* WHwo1  = WH + 64512;
    _Float16* WHwm0  = WH + 73728;
    _Float16* WHwm1  = WH + 82944;
    _Float16* WHwm2  = WH + 92160;

    k_time<<<1, 128, 0, stream>>>(ts, Wt1, bt1, Wt2, bt2, tvec);
    k_repack<<<379, 256, 0, stream>>>(Wd1, Wd2, Wd3, Wd4, Wr);
    k_wcvtc<<<288, 256, 0, stream>>>(Wd1, Wc);
    k_wcvt2<<<96, 256, 0, stream>>>(Wd2, Wc2);
    k_wcvt3<<<24, 256, 0, stream>>>(Wd3, Wc3);
    k_wcvt<<<396, 256, 0, stream>>>(a0_Wqkv, a1_Wqkv, a0_Wo, a1_Wo,
                                    Wm0, Wm1, Wm2, WH);
    k_patch_mfma<<<M_ROWS / 64, 256, 0, stream>>>(x, Wp, bp, p0);

    // MHSA block 0
    k_ln_row<<<1024, 256, 0, stream>>>(p0, a0_g, a0_b, h, M_ROWS);
    k_gemm_mfma<3, false, false, false, false><<<M_ROWS / 64, 256, 0, stream>>>(
        h, WHqkv0, a0_bqkv, nullptr, nullptr, qkvb, nullptr);
    k_attn_mfma<<<B_ * 4, 256, 0, stream>>>(qkvb, ob);
    k_gemm_mfma<1, false, true, false, false><<<M_ROWS / 64, 256, 0, stream>>>(
        ob, WHwo0, a0_bo, p0, nullptr, p1, nullptr);

    // MHSA block 1 (+time)
    k_ln_row<<<1024, 256, 0, stream>>>(p1, a1_g, a1_b, h, M_ROWS);
    k_gemm_mfma<3, false, false, false, false><<<M_ROWS / 64, 256, 0, stream>>>(
        h, WHqkv1, a1_bqkv, nullptr, nullptr, qkvb, nullptr);
    k_attn_mfma<<<B_ * 4, 256, 0, stream>>>(qkvb, ob);
    k_gemm_mfma<1, false, true, true, false><<<M_ROWS / 64, 256, 0, stream>>>(
        ob, WHwo1, a1_bo, p1, tvec, p0, nullptr);

    // qkv region free: zero xinh borders before MLP3 writes interior
    k_zb_h<<<2880, 256, 0, stream>>>(xinh);

    // MLP x3 (silu); last writes f16 NHWC padded xinh
    k_gemm_mfma<1, true, false, false, false><<<M_ROWS / 64, 256, 0, stream>>>(
        p0, WHwm0, bm0, nullptr, nullptr, p1, nullptr);
    k_gemm_mfma<1, true, false, false, false><<<M_ROWS / 64, 256, 0, stream>>>(
        p1, WHwm1, bm1, nullptr, nullptr, p0, nullptr);
    k_gemm_mfma<1, true, false, false, true><<<M_ROWS / 64, 256, 0, stream>>>(
        p0, WHwm2, bm2, nullptr, nullptr, nullptr, xinh);

    // decoder: all-NHWC chain, tile-resident convs
    k_conv1_tile<<<B_ * 7, 256, 0, stream>>>(xinh, Wc, bd1, C1);
    k_ln1_stats<<<1536, 256, 0, stream>>>(C1, stat);
    k_ln1_apply<<<5400, 256, 0, stream>>>(C1, stat, l1g, l1b, xh2);
    k_conv2_tile<<<B_ * 14, 256, 0, stream>>>(xh2, Wc2, bd2, C2);
    k_ln2_stats<<<256, 256, 0, stream>>>(C2, stat);
    k_ln2_apply<<<10092, 256, 0, stream>>>(C2, stat, l2g, l2b, xh3);
    k_conv3_tile<<<B_ * 56, 256, 0, stream>>>(xh3, Wc3, bd3, C3);
    k_ln3_stats<<<512, 256, 0, stream>>>(C3, stat);
    k_ln3_apply<<<18816, 256, 0, stream>>>(C3, stat, l3g, l3b, xh4);
    k_conv_final_nhwc<<<2 * 6272, 256, 0, stream>>>(xh4, Wr + 96768, bd4, out);
}

// Round 7
// 494.537 us; speedup vs baseline: 1.6256x; 1.0390x over previous
//
#include <hip/hip_runtime.h>
#include <cmath>

// ---------------------------------------------------------------------------
// TimestepVisionTransformer — Round 15: transformer de-latency + f16 links.
//   - qkv GEMM chunks split over blockIdx.y (grid 392x3, no serial loop)
//   - h / ob / qkvb stored f16 at producer (identical rounding points as
//     before — consumers converted to f16 anyway): ~58MB traffic removed
//   - k_mlp_fused: 3 MLP GEMMs in ONE kernel (3x 96x96 f16 weights in LDS,
//     double-buffered act tile, silu chain, final writes padded NHWC xinh)
// Everything else = r14 (verified, 513.8us).
// B=128, IMG=224, P=16, C_IN=1, E=96, H=4, d=24, NAX=14, N=196, M=B*N=25088
// ---------------------------------------------------------------------------

#define B_   128
#define NPATCH 196
#define M_ROWS (B_*NPATCH)     // 25088
#define E_   96

typedef _Float16 half8 __attribute__((ext_vector_type(8)));
typedef _Float16 half4v __attribute__((ext_vector_type(4)));
typedef float f32x4 __attribute__((ext_vector_type(4)));

// ---------------------------------------------------------------------------
// time embedding
// ---------------------------------------------------------------------------
__global__ void k_time(const float* __restrict__ ts,
                       const float* __restrict__ Wt1, const float* __restrict__ bt1,
                       const float* __restrict__ Wt2, const float* __restrict__ bt2,
                       float* __restrict__ timev)
{
    __shared__ float h[128];
    float e = 0.69314718055994530942f * ts[0];
    float sv = sinf(e), cv = cosf(e);
    int t = threadIdx.x;
    float z = sv * Wt1[t] + cv * Wt1[128 + t] + bt1[t];
    h[t] = z / (1.f + expf(-z));
    __syncthreads();
    if (t < 96) {
        float acc = bt2[t];
        for (int j = 0; j < 128; ++j) acc += h[j] * Wt2[j * 96 + t];
        timev[t] = acc;
    }
}

// ---------------------------------------------------------------------------
// weight repack (fp32 per-parity taps). Only the L4 slice [96768,96960) is
// still consumed as fp32 (conv_final); other slices overwritten by f16 packs.
// ---------------------------------------------------------------------------
__global__ void __launch_bounds__(256) k_repack(const float* __restrict__ w1,
                                                const float* __restrict__ w2,
                                                const float* __restrict__ w3,
                                                const float* __restrict__ w4f,
                                                float* __restrict__ wr)
{
    int i = blockIdx.x * 256 + threadIdx.x;
    const float* src; int CIN, COUT, e; float* dst;
    if      (i < 73728) { src = w1;  CIN = 96; COUT = 48; e = i;          dst = wr; }
    else if (i < 92160) { src = w2;  CIN = 48; COUT = 24; e = i - 73728;  dst = wr + 73728; }
    else if (i < 96768) { src = w3;  CIN = 24; COUT = 12; e = i - 92160;  dst = wr + 92160; }
    else if (i < 96960) { src = w4f; CIN = 12; COUT = 1;  e = i - 96768;  dst = wr + 96768; }
    else return;
    int per = CIN * COUT * 4;
    int par = e / per, rem = e % per;
    int ci = rem / (COUT * 4);
    int o  = (rem >> 2) % COUT;
    int j  = rem & 3;
    int ry = par >> 1, rx = par & 1;
    int wy = (j < 2)  ? (3 - ry) : (1 - ry);
    int wx = (j & 1)  ? (1 - rx) : (3 - rx);
    dst[e] = src[(ci * COUT + o) * 16 + wy * 4 + wx];
}

// ---------------------------------------------------------------------------
// conv1 weights -> f16 B-layout Wc[p][o][k=tap*96+ci]
// ---------------------------------------------------------------------------
__global__ void __launch_bounds__(256) k_wcvtc(const float* __restrict__ w1,
                                               _Float16* __restrict__ wc)
{
    int i = blockIdx.x * 256 + threadIdx.x;
    if (i >= 4 * 48 * 384) return;
    int p = i / 18432, rem = i % 18432;
    int o = rem / 384, k = rem % 384;
    int tap = k / 96, ci = k % 96;
    int ry = p >> 1, rx = p & 1;
    int wy = (tap < 2) ? (3 - ry) : (1 - ry);
    int wx = (tap & 1) ? (1 - rx) : (3 - rx);
    wc[i] = (_Float16)w1[(ci * 48 + o) * 16 + wy * 4 + wx];
}

// ---------------------------------------------------------------------------
// conv2 weights -> f16 B-layout Wc2[p][o(32, o>=24 zero)][k=tap*48+ci]
// ---------------------------------------------------------------------------
__global__ void __launch_bounds__(256) k_wcvt2(const float* __restrict__ w2,
                                               _Float16* __restrict__ wc2)
{
    int i = blockIdx.x * 256 + threadIdx.x;
    if (i >= 4 * 32 * 192) return;
    int p = i / 6144, rem = i % 6144;
    int o = rem / 192, k = rem % 192;
    int tap = k / 48, ci = k % 48;
    int ry = p >> 1, rx = p & 1;
    int wy = (tap < 2) ? (3 - ry) : (1 - ry);
    int wx = (tap & 1) ? (1 - rx) : (3 - rx);
    wc2[i] = (o < 24) ? (_Float16)w2[(ci * 24 + o) * 16 + wy * 4 + wx]
                      : (_Float16)0.f;
}

// ---------------------------------------------------------------------------
// conv3 weights -> f16 B-layout Wc3[p][o(16, o>=12 zero)][k=tap*24+ci]
// ---------------------------------------------------------------------------
__global__ void __launch_bounds__(256) k_wcvt3(const float* __restrict__ w3,
                                               _Float16* __restrict__ wc3)
{
    int i = blockIdx.x * 256 + threadIdx.x;
    if (i >= 4 * 16 * 96) return;
    int p = i / 1536, rem = i % 1536;
    int o = rem / 96, k = rem % 96;
    int tap = k / 24, ci = k % 24;
    int ry = p >> 1, rx = p & 1;
    int wy = (tap < 2) ? (3 - ry) : (1 - ry);
    int wx = (tap & 1) ? (1 - rx) : (3 - rx);
    wc3[i] = (o < 12) ? (_Float16)w3[(ci * 12 + o) * 16 + wy * 4 + wx]
                      : (_Float16)0.f;
}

// ---------------------------------------------------------------------------
// transformer weight convert+transpose to half: Wt[n][k] = W[k][n]
// ---------------------------------------------------------------------------
__global__ void __launch_bounds__(256) k_wcvt(const float* __restrict__ qkv0,
                                              const float* __restrict__ qkv1,
                                              const float* __restrict__ wo0,
                                              const float* __restrict__ wo1,
                                              const float* __restrict__ wm0,
                                              const float* __restrict__ wm1,
                                              const float* __restrict__ wm2,
                                              _Float16* __restrict__ wh)
{
    int i = blockIdx.x * 256 + threadIdx.x;
    const float* src; int N; int e;
    if      (i < 27648)  { src = qkv0; N = 288; e = i; }
    else if (i < 55296)  { src = qkv1; N = 288; e = i - 27648; }
    else if (i < 64512)  { src = wo0;  N = 96;  e = i - 55296; }
    else if (i < 73728)  { src = wo1;  N = 96;  e = i - 64512; }
    else if (i < 82944)  { src = wm0;  N = 96;  e = i - 73728; }
    else if (i < 92160)  { src = wm1;  N = 96;  e = i - 82944; }
    else if (i < 101376) { src = wm2;  N = 96;  e = i - 92160; }
    else return;
    int n = e / 96, k = e % 96;
    wh[i] = (_Float16)src[k * N + n];
}

// ---------------------------------------------------------------------------
// zero the borders of xinh NHWC f16 [b][16][16][96]
// ---------------------------------------------------------------------------
__global__ void __launch_bounds__(256) k_zb_h(_Float16* __restrict__ xinh)
{
    int i = blockIdx.x * 256 + threadIdx.x;
    if (i >= 128 * 60 * 96) return;
    int b = i / 5760, r = i % 5760;
    int pos = r / 96, ch = r % 96;
    int py, px;
    if      (pos < 16) { py = 0;        px = pos; }
    else if (pos < 32) { py = 15;       px = pos - 16; }
    else if (pos < 46) { py = pos - 31; px = 0; }
    else               { py = pos - 45; px = 15; }
    xinh[((size_t)(b * 256) + py * 16 + px) * 96 + ch] = (_Float16)0.f;
}

// ---------------------------------------------------------------------------
// patch embed GEMM via f16 MFMA (r7, verified)
// ---------------------------------------------------------------------------
__global__ void __launch_bounds__(256) k_patch_mfma(const float* __restrict__ x,
                                                    const float* __restrict__ Wp,
                                                    const float* __restrict__ bp,
                                                    float* __restrict__ out)
{
    __shared__ __align__(16) _Float16 Ah[64 * 136];
    __shared__ __align__(16) _Float16 Wh[96 * 136];
    int t = threadIdx.x;
    int p0 = blockIdx.x * 64;
    int wave = t >> 6, lane = t & 63;
    int lm = lane & 15, quad = lane >> 4;
    f32x4 acc[6];
    #pragma unroll
    for (int nt = 0; nt < 6; ++nt) acc[nt] = (f32x4){0.f, 0.f, 0.f, 0.f};

    for (int kc = 0; kc < 2; ++kc) {
        __syncthreads();
        for (int i = t; i < 512; i += 256) {
            int lp = i >> 3, pyl = i & 7;
            int patch = p0 + lp;
            int b = patch / NPATCH, n = patch % NPATCH;
            int ny = n / 14, nx = n % 14;
            const float4* s4 = (const float4*)(x +
                ((size_t)(b * 224) + ny * 16 + kc * 8 + pyl) * 224 + nx * 16);
            float4 v0 = s4[0], v1 = s4[1], v2 = s4[2], v3 = s4[3];
            half8 h0, h1;
            h0[0]=(_Float16)v0.x; h0[1]=(_Float16)v0.y; h0[2]=(_Float16)v0.z; h0[3]=(_Float16)v0.w;
            h0[4]=(_Float16)v1.x; h0[5]=(_Float16)v1.y; h0[6]=(_Float16)v1.z; h0[7]=(_Float16)v1.w;
            h1[0]=(_Float16)v2.x; h1[1]=(_Float16)v2.y; h1[2]=(_Float16)v2.z; h1[3]=(_Float16)v2.w;
            h1[4]=(_Float16)v3.x; h1[5]=(_Float16)v3.y; h1[6]=(_Float16)v3.z; h1[7]=(_Float16)v3.w;
            *(half8*)&Ah[lp * 136 + pyl * 16]     = h0;
            *(half8*)&Ah[lp * 136 + pyl * 16 + 8] = h1;
        }
        for (int i = t; i < 1536; i += 256) {
            int e = i >> 4, s = i & 15;
            const float4* s4 = (const float4*)(Wp + e * 256 + kc * 128 + s * 8);
            float4 v0 = s4[0], v1 = s4[1];
            half8 h0;
            h0[0]=(_Float16)v0.x; h0[1]=(_Float16)v0.y; h0[2]=(_Float16)v0.z; h0[3]=(_Float16)v0.w;
            h0[4]=(_Float16)v1.x; h0[5]=(_Float16)v1.y; h0[6]=(_Float16)v1.z; h0[7]=(_Float16)v1.w;
            *(half8*)&Wh[e * 136 + s * 8] = h0;
        }
        __syncthreads();
        half8 af[4];
        #pragma unroll
        for (int ks = 0; ks < 4; ++ks)
            af[ks] = *(const half8*)&Ah[(wave * 16 + lm) * 136 + ks * 32 + quad * 8];
        #pragma unroll
        for (int ks = 0; ks < 4; ++ks) {
            #pragma unroll
            for (int nt = 0; nt < 6; ++nt) {
                half8 bf = *(const half8*)&Wh[(nt * 16 + lm) * 136 + ks * 32 + quad * 8];
                acc[nt] = __builtin_amdgcn_mfma_f32_16x16x32_f16(af[ks], bf, acc[nt], 0, 0, 0);
            }
        }
    }

    #pragma unroll
    for (int nt = 0; nt < 6; ++nt) {
        #pragma unroll
        for (int r = 0; r < 4; ++r) {
            int e = nt * 16 + lm;
            int lp = wave * 16 + quad * 4 + r;
            int patch = p0 + lp;
            int n = patch % NPATCH;
            int ny = n / 14, nx = n % 14;
            float yx = (float)(ny + nx);
            float v = acc[nt][r] + bp[e];
            float other = __shfl_xor(v, 1);
            float fi = (float)(e >> 1);
            float theta = expf(fi * (-2.f / 96.f) * 9.210340371976184f);
            float ang = theta * yx;
            float c = cosf(ang), s = sinf(ang);
            float outv = (lm & 1) ? (other * s + v * c) : (v * c - other * s);
            out[(size_t)patch * 96 + e] = outv;
        }
    }
}

// ---------------------------------------------------------------------------
// row LayerNorm over 96, wave per row — writes f16 (same rounding the
// consumer GEMM applied at staging before).
// ---------------------------------------------------------------------------
__global__ void __launch_bounds__(256) k_ln_row(const float* __restrict__ x,
                                                const float* __restrict__ g,
                                                const float* __restrict__ bv,
                                                _Float16* __restrict__ out, int M)
{
    int lane = threadIdx.x & 63;
    int gw = (blockIdx.x * 256 + threadIdx.x) >> 6;
    int nw = (gridDim.x * 256) >> 6;
    float g0 = g[lane], b0 = bv[lane];
    float g1 = 0.f, b1 = 0.f;
    if (lane < 32) { g1 = g[64 + lane]; b1 = bv[64 + lane]; }
    for (int r = gw; r < M; r += nw) {
        const float* xr = x + (size_t)r * 96;
        float a = xr[lane];
        float c = (lane < 32) ? xr[64 + lane] : 0.f;
        float s = a + c, q = a * a + c * c;
        #pragma unroll
        for (int off = 32; off; off >>= 1) {
            s += __shfl_xor(s, off);
            q += __shfl_xor(q, off);
        }
        float mu = s * (1.f / 96.f);
        float rstd = rsqrtf(q * (1.f / 96.f) - mu * mu + 1e-5f);
        _Float16* orow = out + (size_t)r * 96;
        orow[lane] = (_Float16)((a - mu) * rstd * g0 + b0);
        if (lane < 32) orow[64 + lane] = (_Float16)((c - mu) * rstd * g1 + b1);
    }
}

// ---------------------------------------------------------------------------
// MFMA row GEMM. AHALF: A is f16 (straight copy). OUTMODE: 0=fp32 linear,
// 1=f16 linear. Chunks run over blockIdx.y (launch gridDim.y=NCHUNKS).
// ---------------------------------------------------------------------------
template<int NCHUNKS, int OUTMODE, bool SILU, bool RES, bool ADDTIME, bool AHALF>
__global__ void __launch_bounds__(256) k_gemm_mfma(const void* __restrict__ A,
                                                   const _Float16* __restrict__ Wt,
                                                   const float* __restrict__ bias,
                                                   const float* __restrict__ res,
                                                   const float* __restrict__ timev,
                                                   void* __restrict__ outp)
{
    __shared__ __align__(16) _Float16 Ah[64 * 96];
    __shared__ __align__(16) _Float16 Wh[96 * 96];
    constexpr int NTOT = NCHUNKS * 96;
    int t = threadIdx.x;
    size_t row0 = (size_t)blockIdx.x * 64;

    if constexpr (AHALF) {
        const uint4* a4 = (const uint4*)((const _Float16*)A + row0 * 96);
        uint4* dst = (uint4*)Ah;
        for (int i = t; i < 768; i += 256) dst[i] = a4[i];
    } else {
        const float4* a4 = (const float4*)((const float*)A + row0 * 96);
        for (int i = t; i < 1536; i += 256) {
            float4 v = a4[i];
            half4v hv;
            hv[0] = (_Float16)v.x; hv[1] = (_Float16)v.y;
            hv[2] = (_Float16)v.z; hv[3] = (_Float16)v.w;
            *(half4v*)&Ah[i * 4] = hv;
        }
    }

    int wave = t >> 6, lane = t & 63;
    int lm = lane & 15, quad = lane >> 4;
    const f32x4 vzero = {0.f, 0.f, 0.f, 0.f};

    for (int ch = blockIdx.y; ch < NCHUNKS; ch += gridDim.y) {
        __syncthreads();
        {
            const uint4* src = (const uint4*)(Wt + (size_t)ch * 9216);
            uint4* dst = (uint4*)Wh;
            for (int i = t; i < 1152; i += 256) dst[i] = src[i];
        }
        __syncthreads();

        half8 af[3];
        #pragma unroll
        for (int ks = 0; ks < 3; ++ks)
            af[ks] = *(const half8*)&Ah[(wave * 16 + lm) * 96 + ks * 32 + quad * 8];

        f32x4 acc[6];
        #pragma unroll
        for (int ct = 0; ct < 6; ++ct) acc[ct] = vzero;

        #pragma unroll
        for (int ct = 0; ct < 6; ++ct) {
            #pragma unroll
            for (int ks = 0; ks < 3; ++ks) {
                half8 bf = *(const half8*)&Wh[(ct * 16 + lm) * 96 + ks * 32 + quad * 8];
                acc[ct] = __builtin_amdgcn_mfma_f32_16x16x32_f16(af[ks], bf, acc[ct], 0, 0, 0);
            }
        }

        #pragma unroll
        for (int ct = 0; ct < 6; ++ct) {
            #pragma unroll
            for (int r = 0; r < 4; ++r) {
                int lr = wave * 16 + quad * 4 + r;
                size_t row = row0 + lr;
                int lc = ct * 16 + lm;
                int col = ch * 96 + lc;
                float v = acc[ct][r] + bias[col];
                if constexpr (RES)     v += res[row * 96 + lc];
                if constexpr (ADDTIME) v += timev[lc];
                if constexpr (SILU)    v = v / (1.f + __expf(-v));
                if constexpr (OUTMODE == 0) {
                    ((float*)outp)[row * NTOT + col] = v;
                } else {
                    ((_Float16*)outp)[row * NTOT + col] = (_Float16)v;
                }
            }
        }
    }
}

// ---------------------------------------------------------------------------
// fused MLP: 3 chained 96x96 GEMMs + silu, one kernel. Weights (wm0,wm1,wm2
// consecutive f16) all in LDS; double-buffered activation tile; final stage
// writes f16 NHWC padded xinh.
// ---------------------------------------------------------------------------
__global__ void __launch_bounds__(256) k_mlp_fused(const float* __restrict__ A,
                                                   const _Float16* __restrict__ W,
                                                   const float* __restrict__ b0,
                                                   const float* __restrict__ b1,
                                                   const float* __restrict__ b2,
                                                   _Float16* __restrict__ outh)
{
    __shared__ __align__(16) _Float16 Ah[2][64 * 96];
    __shared__ __align__(16) _Float16 Wh[3][96 * 96];
    int t = threadIdx.x;
    size_t row0 = (size_t)blockIdx.x * 64;

    const float4* a4 = (const float4*)(A + row0 * 96);
    for (int i = t; i < 1536; i += 256) {
        float4 v = a4[i];
        half4v hv;
        hv[0] = (_Float16)v.x; hv[1] = (_Float16)v.y;
        hv[2] = (_Float16)v.z; hv[3] = (_Float16)v.w;
        *(half4v*)&Ah[0][i * 4] = hv;
    }
    {
        const uint4* src = (const uint4*)W;
        uint4* dst = (uint4*)&Wh[0][0];
        for (int i = t; i < 3456; i += 256) dst[i] = src[i];
    }

    int wave = t >> 6, lane = t & 63;
    int lm = lane & 15, quad = lane >> 4;
    const float* biases[3] = { b0, b1, b2 };
    int cur = 0;

    #pragma unroll
    for (int s = 0; s < 3; ++s) {
        __syncthreads();
        half8 af[3];
        #pragma unroll
        for (int ks = 0; ks < 3; ++ks)
            af[ks] = *(const half8*)&Ah[cur][(wave * 16 + lm) * 96 + ks * 32 + quad * 8];

        f32x4 acc[6];
        #pragma unroll
        for (int ct = 0; ct < 6; ++ct) acc[ct] = (f32x4){0.f, 0.f, 0.f, 0.f};

        #pragma unroll
        for (int ct = 0; ct < 6; ++ct) {
            #pragma unroll
            for (int ks = 0; ks < 3; ++ks) {
                half8 bf = *(const half8*)&Wh[s][(ct * 16 + lm) * 96 + ks * 32 + quad * 8];
                acc[ct] = __builtin_amdgcn_mfma_f32_16x16x32_f16(af[ks], bf, acc[ct], 0, 0, 0);
            }
        }

        const float* bias = biases[s];
        if (s < 2) {
            #pragma unroll
            for (int ct = 0; ct < 6; ++ct) {
                #pragma unroll
                for (int r = 0; r < 4; ++r) {
                    int lr = wave * 16 + quad * 4 + r;
                    int lc = ct * 16 + lm;
                    float v = acc[ct][r] + bias[lc];
                    v = v / (1.f + __expf(-v));
                    Ah[cur ^ 1][lr * 96 + lc] = (_Float16)v;
                }
            }
            cur ^= 1;
        } else {
            #pragma unroll
            for (int ct = 0; ct < 6; ++ct) {
                #pragma unroll
                for (int r = 0; r < 4; ++r) {
                    int lr = wave * 16 + quad * 4 + r;
                    size_t row = row0 + lr;
                    int lc = ct * 16 + lm;
                    float v = acc[ct][r] + bias[lc];
                    v = v / (1.f + __expf(-v));
                    size_t b = row / NPATCH; int n = (int)(row % NPATCH);
                    int ny = n / 14, nx = n % 14;
                    outh[((b * 256) + (1 + ny) * 16 + (1 + nx)) * 96 + lc] = (_Float16)v;
                }
            }
        }
    }
}

// ---------------------------------------------------------------------------
// MFMA attention (r11 structure): qkv input f16, output f16.
// ---------------------------------------------------------------------------
__global__ void __launch_bounds__(256) k_attn_mfma(const _Float16* __restrict__ qkv,
                                                   _Float16* __restrict__ o)
{
    __shared__ __align__(16) _Float16 Qs[208 * 40];
    __shared__ __align__(16) _Float16 Ks[208 * 40];
    __shared__ __align__(16) _Float16 Vt[32 * 232];
    __shared__ __align__(16) _Float16 Pw[4][16 * 232];

    int t = threadIdx.x;
    int bh = blockIdx.x;
    int b = bh >> 2, h = bh & 3;
    const _Float16* base = qkv + (size_t)b * NPATCH * 288 + h * 24;

    // zero all LDS (pads must be 0)
    {
        const int4 z = {0, 0, 0, 0};
        int4* q4 = (int4*)Qs; int4* k4 = (int4*)Ks;
        for (int i = t; i < 1040; i += 256) { q4[i] = z; k4[i] = z; }
        int4* v4 = (int4*)Vt;
        for (int i = t; i < 928; i += 256) v4[i] = z;
        int4* p4 = (int4*)&Pw[0][0];
        for (int i = t; i < 1856; i += 256) p4[i] = z;
    }
    __syncthreads();

    // stage Q,K (row-major, stride 40) and V transposed (Vt[d][key])
    for (int i = t; i < NPATCH * 24; i += 256) {
        int r = i / 24, d = i % 24;
        const _Float16* row = base + (size_t)r * 288;
        Qs[r * 40 + d]   = row[d];
        Ks[r * 40 + d]   = row[96 + d];
        Vt[d * 232 + r]  = row[192 + d];
    }
    __syncthreads();

    int wave = t >> 6, lane = t & 63;
    int lm = lane & 15, quad = lane >> 4;
    const float scale = 0.2041241452319315f;

    half8 bk[13];
    #pragma unroll
    for (int ct = 0; ct < 13; ++ct)
        bk[ct] = *(const half8*)&Ks[(ct * 16 + lm) * 40 + quad * 8];

    _Float16* pw = &Pw[wave][0];

    for (int rt = wave; rt < 13; rt += 4) {
        half8 aq = *(const half8*)&Qs[(rt * 16 + lm) * 40 + quad * 8];
        float rsum[4] = {0.f, 0.f, 0.f, 0.f};

        #pragma unroll
        for (int ct = 0; ct < 13; ++ct) {
            f32x4 s = (f32x4){0.f, 0.f, 0.f, 0.f};
            s = __builtin_amdgcn_mfma_f32_16x16x32_f16(aq, bk[ct], s, 0, 0, 0);
            #pragma unroll
            for (int r = 0; r < 4; ++r) {
                float p = __expf(fminf(s[r] * scale, 60.f));
                if (ct == 12 && lm >= 4) p = 0.f;   // keys 196..207 invalid
                rsum[r] += p;
                pw[(quad * 4 + r) * 232 + ct * 16 + lm] = (_Float16)p;
            }
        }

        #pragma unroll
        for (int r = 0; r < 4; ++r) {
            float s = rsum[r];
            s += __shfl_xor(s, 1);
            s += __shfl_xor(s, 2);
            s += __shfl_xor(s, 4);
            s += __shfl_xor(s, 8);
            rsum[r] = 1.f / s;
        }

        f32x4 ov0 = (f32x4){0.f, 0.f, 0.f, 0.f};
        f32x4 ov1 = (f32x4){0.f, 0.f, 0.f, 0.f};
        #pragma unroll
        for (int ks = 0; ks < 7; ++ks) {
            half8 ap = *(const half8*)&pw[lm * 232 + ks * 32 + quad * 8];
            half8 bv0 = *(const half8*)&Vt[(lm) * 232 + ks * 32 + quad * 8];
            half8 bv1 = *(const half8*)&Vt[(16 + lm) * 232 + ks * 32 + quad * 8];
            ov0 = __builtin_amdgcn_mfma_f32_16x16x32_f16(ap, bv0, ov0, 0, 0, 0);
            ov1 = __builtin_amdgcn_mfma_f32_16x16x32_f16(ap, bv1, ov1, 0, 0, 0);
        }

        #pragma unroll
        for (int r = 0; r < 4; ++r) {
            int row = rt * 16 + quad * 4 + r;
            if (row < NPATCH) {
                _Float16* orow = o + ((size_t)b * NPATCH + row) * 96 + h * 24;
                orow[lm] = (_Float16)(ov0[r] * rsum[r]);
                if (lm < 8) orow[16 + lm] = (_Float16)(ov1[r] * rsum[r]);
            }
        }
    }
}

// ---------------------------------------------------------------------------
// conv L1, tile-resident (r14, verified).
// ---------------------------------------------------------------------------
__global__ void __launch_bounds__(256) k_conv1_tile(const _Float16* __restrict__ xinh,
                                                    const _Float16* __restrict__ wc,
                                                    const float* __restrict__ bias,
                                                    float* __restrict__ c1)
{
    __shared__ __align__(16) _Float16 Xs[4 * 16 * 104];   // 13.3 KB
    int t = threadIdx.x;
    int blk = blockIdx.x;
    int b = blk / 7, s = blk % 7;        // output pixel rows 2s, 2s+1

    for (int i = t; i < 768; i += 256) {
        int r = i / 192, rem = i % 192;
        int c = rem / 12, ch = (rem % 12) * 8;
        *(uint4*)&Xs[(r * 16 + c) * 104 + ch] =
            *(const uint4*)(xinh + ((size_t)(b * 256) + (2 * s + r) * 16 + c) * 96 + ch);
    }

    int wave = t >> 6, lane = t & 63;
    int lm = lane & 15, quad = lane >> 4;
    int ry = wave >> 1, rx = wave & 1;   // parity per wave

    __syncthreads();

    for (int nt = 0; nt < 3; ++nt) {
        half8 bf[12];
        #pragma unroll
        for (int ks = 0; ks < 12; ++ks)
            bf[ks] = *(const half8*)&wc[((size_t)(wave * 48 + nt * 16 + lm)) * 384
                                        + ks * 32 + quad * 8];

        #pragma unroll
        for (int rt = 0; rt < 2; ++rt) {
            int pp = rt * 16 + lm;
            int ppc = pp < 28 ? pp : 27;
            int pyl = ppc / 14, px = ppc % 14;

            half8 af[12];
            #pragma unroll
            for (int ks = 0; ks < 12; ++ks) {
                int k0 = ks * 32 + quad * 8;
                int tap = k0 / 96, off = k0 % 96;
                int dy = tap >> 1, dx = tap & 1;
                af[ks] = *(const half8*)&Xs[((pyl + ry + dy) * 16 + (px + rx + dx)) * 104 + off];
            }

            f32x4 acc = (f32x4){0.f, 0.f, 0.f, 0.f};
            #pragma unroll
            for (int ks = 0; ks < 12; ++ks)
                acc = __builtin_amdgcn_mfma_f32_16x16x32_f16(af[ks], bf[ks], acc, 0, 0, 0);

            #pragma unroll
            for (int r = 0; r < 4; ++r) {
                int pw = rt * 16 + quad * 4 + r;
                if (pw < 28) {
                    int pylw = pw / 14, pxw = pw % 14;
                    int oy = 2 * (2 * s + pylw) + ry, ox = 2 * pxw + rx;
                    c1[((size_t)(b * 28 + oy) * 28 + ox) * 48 + nt * 16 + lm]
                        = acc[r] + bias[nt * 16 + lm];
                }
            }
        }
    }
}

// ---------------------------------------------------------------------------
// L1 LN stats: one wave per (b,ch) over NHWC C1 -> stat[b*48+ch] = {mu,rstd}
// ---------------------------------------------------------------------------
__global__ void __launch_bounds__(256) k_ln1_stats(const float* __restrict__ c1,
                                                   float* __restrict__ stat)
{
    int idx = blockIdx.x * 4 + (threadIdx.x >> 6);   // b*48+ch
    int lane = threadIdx.x & 63;
    int b = idx / 48, ch = idx % 48;
    const float* base = c1 + (size_t)b * 784 * 48 + ch;
    float s = 0.f, q = 0.f;
    for (int pix = lane; pix < 784; pix += 64) {
        float v = base[(size_t)pix * 48];
        s += v; q += v * v;
    }
    #pragma unroll
    for (int off = 32; off; off >>= 1) {
        s += __shfl_xor(s, off);
        q += __shfl_xor(q, off);
    }
    if (lane == 0) {
        float mu = s * (1.f / 784.f);
        float rstd = rsqrtf(q * (1.f / 784.f) - mu * mu + 1e-5f);
        stat[idx * 2]     = mu;
        stat[idx * 2 + 1] = rstd;
    }
}

// ---------------------------------------------------------------------------
// L1 LN apply, float4-vectorized: NHWC C1 + stat -> f16 NHWC padded XH2
// [b][30][30][48], silu (__expf). grid 5400.
// ---------------------------------------------------------------------------
__global__ void __launch_bounds__(256) k_ln1_apply(const float* __restrict__ c1,
                                                   const float* __restrict__ stat,
                                                   const float* __restrict__ g,
                                                   const float* __restrict__ bv,
                                                   _Float16* __restrict__ xh)
{
    int i4 = blockIdx.x * 256 + threadIdx.x;
    int idx = i4 * 4;                                // ((b*900)+pos)*48 + ch
    int ch = idx % 48;
    int t2 = idx / 48;
    int pos = t2 % 900;
    int b = t2 / 900;
    int py = pos / 30, px = pos % 30;
    half4v hv = (half4v){(_Float16)0.f, (_Float16)0.f, (_Float16)0.f, (_Float16)0.f};
    if (py >= 1 && py <= 28 && px >= 1 && px <= 28) {
        int j = (py - 1) * 28 + (px - 1);
        float4 v = *(const float4*)&c1[((size_t)b * 784 + j) * 48 + ch];
        const float* st = stat + ((size_t)b * 48 + ch) * 2;
        float gj = g[j], bj = bv[j];
        float u0 = (v.x - st[0]) * st[1] * gj + bj;
        float u1 = (v.y - st[2]) * st[3] * gj + bj;
        float u2 = (v.z - st[4]) * st[5] * gj + bj;
        float u3 = (v.w - st[6]) * st[7] * gj + bj;
        hv[0] = (_Float16)(u0 / (1.f + __expf(-u0)));
        hv[1] = (_Float16)(u1 / (1.f + __expf(-u1)));
        hv[2] = (_Float16)(u2 / (1.f + __expf(-u2)));
        hv[3] = (_Float16)(u3 / (1.f + __expf(-u3)));
    }
    *(half4v*)&xh[idx] = hv;
}

// ---------------------------------------------------------------------------
// conv L2, tile-resident (r12, verified).
// ---------------------------------------------------------------------------
__global__ void __launch_bounds__(256) k_conv2_tile(const _Float16* __restrict__ xh,
                                                    const _Float16* __restrict__ wc,
                                                    const float* __restrict__ bias,
                                                    float* __restrict__ c2)
{
    __shared__ __align__(16) _Float16 Xs[4 * 30 * 56];   // 13.1 KB
    int t = threadIdx.x;
    int blk = blockIdx.x;
    int b = blk / 14, s = blk % 14;      // strip covers pixel rows 2s, 2s+1

    for (int i = t; i < 720; i += 256) {
        int r = i / 180, rem = i % 180;
        int c = rem / 6, ch = (rem % 6) * 8;
        *(uint4*)&Xs[(r * 30 + c) * 56 + ch] =
            *(const uint4*)(xh + ((size_t)(b * 900) + (2 * s + r) * 30 + c) * 48 + ch);
    }

    int wave = t >> 6, lane = t & 63;
    int lm = lane & 15, quad = lane >> 4;
    int ry = wave >> 1, rx = wave & 1;   // parity per wave

    half8 bf0[6], bf1[6];
    #pragma unroll
    for (int ks = 0; ks < 6; ++ks) {
        bf0[ks] = *(const half8*)&wc[((size_t)(wave * 32 + lm)) * 192 + ks * 32 + quad * 8];
        bf1[ks] = *(const half8*)&wc[((size_t)(wave * 32 + 16 + lm)) * 192 + ks * 32 + quad * 8];
    }

    __syncthreads();

    #pragma unroll
    for (int rt = 0; rt < 4; ++rt) {
        int pp = rt * 16 + lm;
        int ppc = pp < 56 ? pp : 55;
        int pyl = ppc / 28, px = ppc % 28;

        half8 af[6];
        #pragma unroll
        for (int ks = 0; ks < 6; ++ks) {
            int k0 = ks * 32 + quad * 8;
            int tap = k0 / 48, off = k0 % 48;
            int dy = tap >> 1, dx = tap & 1;
            af[ks] = *(const half8*)&Xs[((pyl + ry + dy) * 30 + (px + rx + dx)) * 56 + off];
        }

        f32x4 acc0 = (f32x4){0.f, 0.f, 0.f, 0.f};
        f32x4 acc1 = (f32x4){0.f, 0.f, 0.f, 0.f};
        #pragma unroll
        for (int ks = 0; ks < 6; ++ks) {
            acc0 = __builtin_amdgcn_mfma_f32_16x16x32_f16(af[ks], bf0[ks], acc0, 0, 0, 0);
            acc1 = __builtin_amdgcn_mfma_f32_16x16x32_f16(af[ks], bf1[ks], acc1, 0, 0, 0);
        }

        #pragma unroll
        for (int r = 0; r < 4; ++r) {
            int pw = rt * 16 + quad * 4 + r;
            if (pw < 56) {
                int pylw = pw / 28, pxw = pw % 28;
                int oy = 2 * (2 * s + pylw) + ry, ox = 2 * pxw + rx;
                float* orow = c2 + ((size_t)(b * 56 + oy) * 56 + ox) * 24;
                orow[lm] = acc0[r] + bias[lm];
                if (lm < 8) orow[16 + lm] = acc1[r] + bias[16 + lm];
            }
        }
    }
}

// ---------------------------------------------------------------------------
// L2 LN stats, coalesced: block per (image b, half h).
// ---------------------------------------------------------------------------
__global__ void __launch_bounds__(256) k_ln2_stats(const float* __restrict__ c2,
                                                   float* __restrict__ pstat)
{
    __shared__ float bins[48];
    int t = threadIdx.x;
    int b = blockIdx.x >> 1, h = blockIdx.x & 1;
    if (t < 48) bins[t] = 0.f;
    __syncthreads();
    const float* base = c2 + (size_t)b * 75264 + h * 37632;
    float s0 = 0.f, s1 = 0.f, s2 = 0.f, q0 = 0.f, q1 = 0.f, q2 = 0.f;
    for (int k = 0; k < 147; k += 3) {
        float v0 = base[t + 256 * k];
        float v1 = base[t + 256 * (k + 1)];
        float v2 = base[t + 256 * (k + 2)];
        s0 += v0; q0 += v0 * v0;
        s1 += v1; q1 += v1 * v1;
        s2 += v2; q2 += v2 * v2;
    }
    int c0 = t % 24;
    int c1 = (c0 + 16) % 24;
    int c2i = (c0 + 8) % 24;
    atomicAdd(&bins[c0 * 2],      s0); atomicAdd(&bins[c0 * 2 + 1],  q0);
    atomicAdd(&bins[c1 * 2],      s1); atomicAdd(&bins[c1 * 2 + 1],  q1);
    atomicAdd(&bins[c2i * 2],     s2); atomicAdd(&bins[c2i * 2 + 1], q2);
    __syncthreads();
    if (t < 48) pstat[(size_t)blockIdx.x * 48 + t] = bins[t];
}

// ---------------------------------------------------------------------------
// L2 LN apply, float4-vectorized: C2 NHWC + pstat -> f16 NHWC padded XH3
// [b][58][58][24], silu (__expf). grid 10092.
// ---------------------------------------------------------------------------
__global__ void __launch_bounds__(256) k_ln2_apply(const float* __restrict__ c2,
                                                   const float* __restrict__ pstat,
                                                   const float* __restrict__ g,
                                                   const float* __restrict__ bv,
                                                   _Float16* __restrict__ xh)
{
    int i4 = blockIdx.x * 256 + threadIdx.x;
    int idx = i4 * 4;                                // ((b*3364)+pos)*24 + ch
    int ch = idx % 24;
    int t2 = idx / 24;
    int pos = t2 % 3364;
    int b = t2 / 3364;
    int py = pos / 58, px = pos % 58;
    half4v hv = (half4v){(_Float16)0.f, (_Float16)0.f, (_Float16)0.f, (_Float16)0.f};
    if (py >= 1 && py <= 56 && px >= 1 && px <= 56) {
        int j = (py - 1) * 56 + (px - 1);
        float4 v = *(const float4*)&c2[((size_t)b * 3136 + j) * 24 + ch];
        const float* ps = pstat + (size_t)b * 96 + ch * 2;
        float gj = g[j], bj = bv[j];
        #pragma unroll
        for (int k = 0; k < 4; ++k) {
            float s = ps[2 * k] + ps[48 + 2 * k];
            float q = ps[2 * k + 1] + ps[49 + 2 * k];
            float mu = s * (1.f / 3136.f);
            float rstd = rsqrtf(q * (1.f / 3136.f) - mu * mu + 1e-5f);
            float vv = (k == 0) ? v.x : (k == 1) ? v.y : (k == 2) ? v.z : v.w;
            float u = (vv - mu) * rstd * gj + bj;
            hv[k] = (_Float16)(u / (1.f + __expf(-u)));
        }
    }
    *(half4v*)&xh[idx] = hv;
}

// ---------------------------------------------------------------------------
// conv L3, tile-resident (r12, verified).
// ---------------------------------------------------------------------------
__global__ void __launch_bounds__(256) k_conv3_tile(const _Float16* __restrict__ xh,
                                                    const _Float16* __restrict__ wc,
                                                    const float* __restrict__ bias,
                                                    float* __restrict__ c3)
{
    __shared__ __align__(16) _Float16 Xs[3 * 58 * 40];   // 13.6 KB
    int t = threadIdx.x;
    int blk = blockIdx.x;
    int b = blk / 56, s = blk % 56;     // strip covers pixel row s

    for (int i = t; i < 522; i += 256) {
        int r = i / 174, rem = i % 174;
        int c = rem / 3, ch = (rem % 3) * 8;
        *(uint4*)&Xs[(r * 58 + c) * 40 + ch] =
            *(const uint4*)(xh + ((size_t)(b * 3364) + (s + r) * 58 + c) * 24 + ch);
    }

    int wave = t >> 6, lane = t & 63;
    int lm = lane & 15, quad = lane >> 4;
    int ry = wave >> 1, rx = wave & 1;

    half8 bf[3];
    #pragma unroll
    for (int ks = 0; ks < 3; ++ks)
        bf[ks] = *(const half8*)&wc[((size_t)(wave * 16 + lm)) * 96 + ks * 32 + quad * 8];

    __syncthreads();

    #pragma unroll
    for (int rt = 0; rt < 4; ++rt) {
        int px = rt * 16 + lm;
        int pxc = px < 56 ? px : 55;

        half8 af[3];
        #pragma unroll
        for (int ks = 0; ks < 3; ++ks) {
            int k0 = ks * 32 + quad * 8;
            int tap = k0 / 24, off = k0 % 24;
            int dy = tap >> 1, dx = tap & 1;
            af[ks] = *(const half8*)&Xs[((ry + dy) * 58 + (pxc + rx + dx)) * 40 + off];
        }

        f32x4 acc = (f32x4){0.f, 0.f, 0.f, 0.f};
        #pragma unroll
        for (int ks = 0; ks < 3; ++ks)
            acc = __builtin_amdgcn_mfma_f32_16x16x32_f16(af[ks], bf[ks], acc, 0, 0, 0);

        if (lm < 12) {
            #pragma unroll
            for (int r = 0; r < 4; ++r) {
                int pw = rt * 16 + quad * 4 + r;
                if (pw < 56) {
                    int oy = 2 * s + ry, ox = 2 * pw + rx;
                    c3[((size_t)(b * 112 + oy) * 112 + ox) * 12 + lm] = acc[r] + bias[lm];
                }
            }
        }
    }
}

// ---------------------------------------------------------------------------
// L3 LN stats, coalesced: block per (image b, quarter h).
// ---------------------------------------------------------------------------
__global__ void __launch_bounds__(256) k_ln3_stats(const float* __restrict__ c3,
                                                   float* __restrict__ pstat)
{
    __shared__ float bins[24];
    int t = threadIdx.x;
    int b = blockIdx.x >> 2, h = blockIdx.x & 3;
    if (t < 24) bins[t] = 0.f;
    __syncthreads();
    const float* base = c3 + (size_t)b * 150528 + h * 37632;
    float s0 = 0.f, s1 = 0.f, s2 = 0.f, q0 = 0.f, q1 = 0.f, q2 = 0.f;
    for (int k = 0; k < 147; k += 3) {
        float v0 = base[t + 256 * k];
        float v1 = base[t + 256 * (k + 1)];
        float v2 = base[t + 256 * (k + 2)];
        s0 += v0; q0 += v0 * v0;
        s1 += v1; q1 += v1 * v1;
        s2 += v2; q2 += v2 * v2;
    }
    int c0 = t % 12;
    int c1 = (c0 + 4) % 12;
    int c2i = (c0 + 8) % 12;
    atomicAdd(&bins[c0 * 2],      s0); atomicAdd(&bins[c0 * 2 + 1],  q0);
    atomicAdd(&bins[c1 * 2],      s1); atomicAdd(&bins[c1 * 2 + 1],  q1);
    atomicAdd(&bins[c2i * 2],     s2); atomicAdd(&bins[c2i * 2 + 1], q2);
    __syncthreads();
    if (t < 24) pstat[(size_t)blockIdx.x * 24 + t] = bins[t];
}

// ---------------------------------------------------------------------------
// L3 LN apply, float4-vectorized: C3 NHWC + pstat -> f16 NHWC xh4
// [b][112][112][12], silu (__expf). grid 18816.
// ---------------------------------------------------------------------------
__global__ void __launch_bounds__(256) k_ln3_apply(const float* __restrict__ c3,
                                                   const float* __restrict__ pstat,
                                                   const float* __restrict__ g,
                                                   const float* __restrict__ bv,
                                                   _Float16* __restrict__ xh4)
{
    int i4 = blockIdx.x * 256 + threadIdx.x;
    int idx = i4 * 4;
    int ch = idx % 12;                               // 0, 4, 8
    int t2 = idx / 12;
    int pix = t2 % 12544;
    int b = t2 / 12544;
    float4 v = *(const float4*)&c3[idx];
    const float* ps = pstat + (size_t)b * 96 + ch * 2;
    float gp = g[pix], bp = bv[pix];
    half4v hv;
    #pragma unroll
    for (int k = 0; k < 4; ++k) {
        float s = ps[2 * k] + ps[24 + 2 * k] + ps[48 + 2 * k] + ps[72 + 2 * k];
        float q = ps[2 * k + 1] + ps[25 + 2 * k] + ps[49 + 2 * k] + ps[73 + 2 * k];
        float mu = s * (1.f / 12544.f);
        float rstd = rsqrtf(q * (1.f / 12544.f) - mu * mu + 1e-5f);
        float vv = (k == 0) ? v.x : (k == 1) ? v.y : (k == 2) ? v.z : v.w;
        float u = (vv - mu) * rstd * gp + bp;
        hv[k] = (_Float16)(u / (1.f + __expf(-u)));
    }
    *(half4v*)&xh4[idx] = hv;
}

// ---------------------------------------------------------------------------
// final convT 12->1, f16 NHWC input (xh4).
// ---------------------------------------------------------------------------
__global__ void __launch_bounds__(256) k_conv_final_nhwc(const _Float16* __restrict__ x,
                                                         const float* __restrict__ wr,
                                                         const float* __restrict__ bias,
                                                         float* __restrict__ out)
{
    constexpr int HIN = 112, CIN = 12;
    constexpr int NPB = (B_ * HIN * HIN) / 256;   // 6272
    int pb = blockIdx.x % NPB;
    int ry = blockIdx.x / NPB;
    int rem = pb * 256 + threadIdx.x;
    int b   = rem / (HIN * HIN);
    int pix = rem % (HIN * HIN);
    int py = pix / HIN, px = pix % HIN;
    int r0 = py + ry - 1, r1 = r0 + 1;
    const _Float16* xb = x + (size_t)b * (HIN * HIN * CIN);

    int   rows[2] = { r0, r1 };
    bool  rm[2]   = { r0 >= 0, r1 < HIN };
    int   cols[3] = { px - 1, px, px + 1 };
    bool  cm[3]   = { px >= 1, true, px + 1 < HIN };

    float gv[6][12];
    #pragma unroll
    for (int a = 0; a < 2; ++a) {
        #pragma unroll
        for (int cc = 0; cc < 3; ++cc) {
            int gi = a * 3 + cc;
            if (rm[a] && cm[cc]) {
                const _Float16* p = xb + ((size_t)(rows[a] * HIN + cols[cc])) * CIN;
                half4v h0 = *(const half4v*)&p[0];
                half4v h1 = *(const half4v*)&p[4];
                half4v h2 = *(const half4v*)&p[8];
                #pragma unroll
                for (int j = 0; j < 4; ++j) {
                    gv[gi][j]     = (float)h0[j];
                    gv[gi][4 + j] = (float)h1[j];
                    gv[gi][8 + j] = (float)h2[j];
                }
            } else {
                #pragma unroll
                for (int j = 0; j < 12; ++j) gv[gi][j] = 0.f;
            }
        }
    }

    const float4* w4 = (const float4*)wr;
    float acc0 = 0.f, acc1 = 0.f;
    #pragma unroll
    for (int ci = 0; ci < CIN; ++ci) {
        float4 W0 = w4[(2 * ry) * CIN + ci];
        float4 W1 = w4[(2 * ry + 1) * CIN + ci];
        acc0 += gv[0][ci] * W0.x + gv[1][ci] * W0.y + gv[3][ci] * W0.z + gv[4][ci] * W0.w;
        acc1 += gv[1][ci] * W1.x + gv[2][ci] * W1.y + gv[4][ci] * W1.z + gv[5][ci] * W1.w;
    }

    float bb = bias[0];
    float u0 = acc0 + bb, u1 = acc1 + bb;
    u0 = u0 / (1.f + __expf(-u0));
    u1 = u1 / (1.f + __expf(-u1));
    float2 v;
    v.x = fminf(fmaxf(u0, 0.f), 1.f);
    v.y = fminf(fmaxf(u1, 0.f), 1.f);
    int oy = 2 * py + ry;
    *(float2*)(out + (size_t)b * 50176 + oy * 224 + 2 * px) = v;
}

// ---------------------------------------------------------------------------
// launch
// ---------------------------------------------------------------------------
extern "C" void kernel_launch(void* const* d_in, const int* in_sizes, int n_in,
                              void* d_out, int out_size, void* d_ws, size_t ws_size,
                              hipStream_t stream)
{
    const float* x       = (const float*)d_in[0];
    const float* ts      = (const float*)d_in[1];
    const float* Wp      = (const float*)d_in[2];
    const float* bp      = (const float*)d_in[3];
    const float* Wt1     = (const float*)d_in[4];
    const float* bt1     = (const float*)d_in[5];
    const float* Wt2     = (const float*)d_in[6];
    const float* bt2     = (const float*)d_in[7];
    const float* a0_g    = (const float*)d_in[8];
    const float* a0_b    = (const float*)d_in[9];
    const float* a0_Wqkv = (const float*)d_in[10];
    const float* a0_bqkv = (const float*)d_in[11];
    const float* a0_Wo   = (const float*)d_in[12];
    const float* a0_bo   = (const float*)d_in[13];
    const float* a1_g    = (const float*)d_in[14];
    const float* a1_b    = (const float*)d_in[15];
    const float* a1_Wqkv = (const float*)d_in[16];
    const float* a1_bqkv = (const float*)d_in[17];
    const float* a1_Wo   = (const float*)d_in[18];
    const float* a1_bo   = (const float*)d_in[19];
    const float* Wm0     = (const float*)d_in[20];
    const float* bm0     = (const float*)d_in[21];
    const float* Wm1     = (const float*)d_in[22];
    const float* bm1     = (const float*)d_in[23];
    const float* Wm2     = (const float*)d_in[24];
    const float* bm2     = (const float*)d_in[25];
    const float* Wd1     = (const float*)d_in[26];
    const float* bd1     = (const float*)d_in[27];
    const float* l1g     = (const float*)d_in[28];
    const float* l1b     = (const float*)d_in[29];
    const float* Wd2     = (const float*)d_in[30];
    const float* bd2     = (const float*)d_in[31];
    const float* l2g     = (const float*)d_in[32];
    const float* l2b     = (const float*)d_in[33];
    const float* Wd3     = (const float*)d_in[34];
    const float* bd3     = (const float*)d_in[35];
    const float* l3g     = (const float*)d_in[36];
    const float* l3b     = (const float*)d_in[37];
    const float* Wd4     = (const float*)d_in[38];
    const float* bd4     = (const float*)d_in[39];
    float* out = (float*)d_out;

    // arena (floats); R = 25088*96
    const size_t R = 2408448;
    float* ws   = (float*)d_ws;
    float* tvec = ws;                          // 96
    float* p0   = ws + 512;                    // R
    _Float16* hh   = (_Float16*)(ws + 512 + R);       // f16 LN out (h region)
    _Float16* qkvh = (_Float16*)(ws + 512 + 2 * R);   // f16 qkv [M][288] (qkv region)
    _Float16* obh  = (_Float16*)(ws + 512 + 5 * R);   // f16 attn out (ob region)
    float* p1   = ws + 512 + 6 * R;            // R
    // decoder aliases:
    _Float16* xinh = (_Float16*)(ws + 512 + 2 * R);   // f16 NHWC (qkv region)
    float* C1   = ws + 512 + 5 * R;            // NHWC fp32 [b][28][28][48] (ob+p1)
    _Float16* xh2 = (_Float16*)(ws + 512 + 7 * R);    // f16 NHWC padded [b][30][30][48]
    float* C2   = ws + 512;                    // NHWC fp32 [b][56][56][24] (p0..qkv)
    _Float16* xh3 = (_Float16*)(ws + 512 + 7 * R + 5529600); // f16 NHWC padded [b][58][58][24]
    float* C3   = ws + 512;                    // NHWC fp32 [b][112][112][12]
    _Float16* xh4 = (_Float16*)(ws + 512 + 7 * R + 5529600); // f16 NHWC [b][112][112][12] (reuses xh3)
    float* Wr   = ws + 512 + 7 * R + 5529600 + 10334208;  // 96,960 floats
    _Float16* WH = (_Float16*)(Wr + 96960);                // 101,376 halves
    _Float16* Wc  = (_Float16*)Wr;              // conv1 f16 B-weights (dead L1 slice)
    _Float16* Wc2 = (_Float16*)(Wr + 36864);    // conv2 f16 B-weights
    _Float16* Wc3 = (_Float16*)(Wr + 49152);    // conv3 f16 B-weights
    float* stat = Wr + 96960 + 50688;          // 12,288 floats (LN stats, reused)
    const size_t NEED = (512 + 7 * R + 5529600 + 10334208 + 96960 + 50688 + 12288 + 16)
                        * sizeof(float);
    if (ws_size < NEED) return;

    _Float16* WHqkv0 = WH;
    _Float16* WHqkv1 = WH + 27648;
    _Float16* WHwo0  = WH + 55296;
    _Float16* WHwo1  = WH + 64512;
    _Float16* WHwm0  = WH + 73728;   // wm0,wm1,wm2 consecutive (27648 halves)

    k_time<<<1, 128, 0, stream>>>(ts, Wt1, bt1, Wt2, bt2, tvec);
    k_repack<<<379, 256, 0, stream>>>(Wd1, Wd2, Wd3, Wd4, Wr);
    k_wcvtc<<<288, 256, 0, stream>>>(Wd1, Wc);
    k_wcvt2<<<96, 256, 0, stream>>>(Wd2, Wc2);
    k_wcvt3<<<24, 256, 0, stream>>>(Wd3, Wc3);
    k_wcvt<<<396, 256, 0, stream>>>(a0_Wqkv, a1_Wqkv, a0_Wo, a1_Wo,
                                    Wm0, Wm1, Wm2, WH);
    k_patch_mfma<<<M_ROWS / 64, 256, 0, stream>>>(x, Wp, bp, p0);

    // MHSA block 0
    k_ln_row<<<1024, 256, 0, stream>>>(p0, a0_g, a0_b, hh, M_ROWS);
    k_gemm_mfma<3, 1, false, false, false, true><<<dim3(M_ROWS / 64, 3), 256, 0, stream>>>(
        hh, WHqkv0, a0_bqkv, nullptr, nullptr, qkvh);
    k_attn_mfma<<<B_ * 4, 256, 0, stream>>>(qkvh, obh);
    k_gemm_mfma<1, 0, false, true, false, true><<<dim3(M_ROWS / 64, 1), 256, 0, stream>>>(
        obh, WHwo0, a0_bo, p0, nullptr, p1);

    // MHSA block 1 (+time)
    k_ln_row<<<1024, 256, 0, stream>>>(p1, a1_g, a1_b, hh, M_ROWS);
    k_gemm_mfma<3, 1, false, false, false, true><<<dim3(M_ROWS / 64, 3), 256, 0, stream>>>(
        hh, WHqkv1, a1_bqkv, nullptr, nullptr, qkvh);
    k_attn_mfma<<<B_ * 4, 256, 0, stream>>>(qkvh, obh);
    k_gemm_mfma<1, 0, false, true, true, true><<<dim3(M_ROWS / 64, 1), 256, 0, stream>>>(
        obh, WHwo1, a1_bo, p1, tvec, p0);

    // qkv region free: zero xinh borders before MLP writes interior
    k_zb_h<<<2880, 256, 0, stream>>>(xinh);

    // fused MLP x3 (silu); writes f16 NHWC padded xinh
    k_mlp_fused<<<M_ROWS / 64, 256, 0, stream>>>(p0, WHwm0, bm0, bm1, bm2, xinh);

    // decoder: all-NHWC chain, tile-resident convs
    k_conv1_tile<<<B_ * 7, 256, 0, stream>>>(xinh, Wc, bd1, C1);
    k_ln1_stats<<<1536, 256, 0, stream>>>(C1, stat);
    k_ln1_apply<<<5400, 256, 0, stream>>>(C1, stat, l1g, l1b, xh2);
    k_conv2_tile<<<B_ * 14, 256, 0, stream>>>(xh2, Wc2, bd2, C2);
    k_ln2_stats<<<256, 256, 0, stream>>>(C2, stat);
    k_ln2_apply<<<10092, 256, 0, stream>>>(C2, stat, l2g, l2b, xh3);
    k_conv3_tile<<<B_ * 56, 256, 0, stream>>>(xh3, Wc3, bd3, C3);
    k_ln3_stats<<<512, 256, 0, stream>>>(C3, stat);
    k_ln3_apply<<<18816, 256, 0, stream>>>(C3, stat, l3g, l3b, xh4);
    k_conv_final_nhwc<<<2 * 6272, 256, 0, stream>>>(xh4, Wr + 96768, bd4, out);
}

// Round 8
// 457.655 us; speedup vs baseline: 1.7566x; 1.0806x over previous
//
#include <hip/hip_runtime.h>
#include <cmath>

// ---------------------------------------------------------------------------
// TimestepVisionTransformer — Round 16: fused LN stats + f16 conv outputs.
//   - conv1/2/3_tile accumulate per-channel sum/sumsq in LDS and atomicAdd
//     to global pstat (per image,channel) -> k_ln{1,2,3}_stats DELETED.
//   - C1/C2/C3 stored f16 (apply reads f16; stats from fp32 accs — same
//     values as before, only summation order differs).
//   - k_zstat zeroes the stat table (workspace persists across replays).
// Everything else = r15 (verified, 494.5us).
// B=128, IMG=224, P=16, C_IN=1, E=96, H=4, d=24, NAX=14, N=196, M=B*N=25088
// ---------------------------------------------------------------------------

#define B_   128
#define NPATCH 196
#define M_ROWS (B_*NPATCH)     // 25088
#define E_   96

typedef _Float16 half8 __attribute__((ext_vector_type(8)));
typedef _Float16 half4v __attribute__((ext_vector_type(4)));
typedef float f32x4 __attribute__((ext_vector_type(4)));

// ---------------------------------------------------------------------------
// time embedding
// ---------------------------------------------------------------------------
__global__ void k_time(const float* __restrict__ ts,
                       const float* __restrict__ Wt1, const float* __restrict__ bt1,
                       const float* __restrict__ Wt2, const float* __restrict__ bt2,
                       float* __restrict__ timev)
{
    __shared__ float h[128];
    float e = 0.69314718055994530942f * ts[0];
    float sv = sinf(e), cv = cosf(e);
    int t = threadIdx.x;
    float z = sv * Wt1[t] + cv * Wt1[128 + t] + bt1[t];
    h[t] = z / (1.f + expf(-z));
    __syncthreads();
    if (t < 96) {
        float acc = bt2[t];
        for (int j = 0; j < 128; ++j) acc += h[j] * Wt2[j * 96 + t];
        timev[t] = acc;
    }
}

// ---------------------------------------------------------------------------
// zero LN partial-stat table (21504 floats)
// ---------------------------------------------------------------------------
__global__ void __launch_bounds__(256) k_zstat(float* __restrict__ stat)
{
    int i = blockIdx.x * 256 + threadIdx.x;
    if (i < 21504) stat[i] = 0.f;
}

// ---------------------------------------------------------------------------
// weight repack (fp32 per-parity taps). Only the L4 slice [96768,96960) is
// still consumed as fp32 (conv_final); other slices overwritten by f16 packs.
// ---------------------------------------------------------------------------
__global__ void __launch_bounds__(256) k_repack(const float* __restrict__ w1,
                                                const float* __restrict__ w2,
                                                const float* __restrict__ w3,
                                                const float* __restrict__ w4f,
                                                float* __restrict__ wr)
{
    int i = blockIdx.x * 256 + threadIdx.x;
    const float* src; int CIN, COUT, e; float* dst;
    if      (i < 73728) { src = w1;  CIN = 96; COUT = 48; e = i;          dst = wr; }
    else if (i < 92160) { src = w2;  CIN = 48; COUT = 24; e = i - 73728;  dst = wr + 73728; }
    else if (i < 96768) { src = w3;  CIN = 24; COUT = 12; e = i - 92160;  dst = wr + 92160; }
    else if (i < 96960) { src = w4f; CIN = 12; COUT = 1;  e = i - 96768;  dst = wr + 96768; }
    else return;
    int per = CIN * COUT * 4;
    int par = e / per, rem = e % per;
    int ci = rem / (COUT * 4);
    int o  = (rem >> 2) % COUT;
    int j  = rem & 3;
    int ry = par >> 1, rx = par & 1;
    int wy = (j < 2)  ? (3 - ry) : (1 - ry);
    int wx = (j & 1)  ? (1 - rx) : (3 - rx);
    dst[e] = src[(ci * COUT + o) * 16 + wy * 4 + wx];
}

// ---------------------------------------------------------------------------
// conv1 weights -> f16 B-layout Wc[p][o][k=tap*96+ci]
// ---------------------------------------------------------------------------
__global__ void __launch_bounds__(256) k_wcvtc(const float* __restrict__ w1,
                                               _Float16* __restrict__ wc)
{
    int i = blockIdx.x * 256 + threadIdx.x;
    if (i >= 4 * 48 * 384) return;
    int p = i / 18432, rem = i % 18432;
    int o = rem / 384, k = rem % 384;
    int tap = k / 96, ci = k % 96;
    int ry = p >> 1, rx = p & 1;
    int wy = (tap < 2) ? (3 - ry) : (1 - ry);
    int wx = (tap & 1) ? (1 - rx) : (3 - rx);
    wc[i] = (_Float16)w1[(ci * 48 + o) * 16 + wy * 4 + wx];
}

// ---------------------------------------------------------------------------
// conv2 weights -> f16 B-layout Wc2[p][o(32, o>=24 zero)][k=tap*48+ci]
// ---------------------------------------------------------------------------
__global__ void __launch_bounds__(256) k_wcvt2(const float* __restrict__ w2,
                                               _Float16* __restrict__ wc2)
{
    int i = blockIdx.x * 256 + threadIdx.x;
    if (i >= 4 * 32 * 192) return;
    int p = i / 6144, rem = i % 6144;
    int o = rem / 192, k = rem % 192;
    int tap = k / 48, ci = k % 48;
    int ry = p >> 1, rx = p & 1;
    int wy = (tap < 2) ? (3 - ry) : (1 - ry);
    int wx = (tap & 1) ? (1 - rx) : (3 - rx);
    wc2[i] = (o < 24) ? (_Float16)w2[(ci * 24 + o) * 16 + wy * 4 + wx]
                      : (_Float16)0.f;
}

// ---------------------------------------------------------------------------
// conv3 weights -> f16 B-layout Wc3[p][o(16, o>=12 zero)][k=tap*24+ci]
// ---------------------------------------------------------------------------
__global__ void __launch_bounds__(256) k_wcvt3(const float* __restrict__ w3,
                                               _Float16* __restrict__ wc3)
{
    int i = blockIdx.x * 256 + threadIdx.x;
    if (i >= 4 * 16 * 96) return;
    int p = i / 1536, rem = i % 1536;
    int o = rem / 96, k = rem % 96;
    int tap = k / 24, ci = k % 24;
    int ry = p >> 1, rx = p & 1;
    int wy = (tap < 2) ? (3 - ry) : (1 - ry);
    int wx = (tap & 1) ? (1 - rx) : (3 - rx);
    wc3[i] = (o < 12) ? (_Float16)w3[(ci * 12 + o) * 16 + wy * 4 + wx]
                      : (_Float16)0.f;
}

// ---------------------------------------------------------------------------
// transformer weight convert+transpose to half: Wt[n][k] = W[k][n]
// ---------------------------------------------------------------------------
__global__ void __launch_bounds__(256) k_wcvt(const float* __restrict__ qkv0,
                                              const float* __restrict__ qkv1,
                                              const float* __restrict__ wo0,
                                              const float* __restrict__ wo1,
                                              const float* __restrict__ wm0,
                                              const float* __restrict__ wm1,
                                              const float* __restrict__ wm2,
                                              _Float16* __restrict__ wh)
{
    int i = blockIdx.x * 256 + threadIdx.x;
    const float* src; int N; int e;
    if      (i < 27648)  { src = qkv0; N = 288; e = i; }
    else if (i < 55296)  { src = qkv1; N = 288; e = i - 27648; }
    else if (i < 64512)  { src = wo0;  N = 96;  e = i - 55296; }
    else if (i < 73728)  { src = wo1;  N = 96;  e = i - 64512; }
    else if (i < 82944)  { src = wm0;  N = 96;  e = i - 73728; }
    else if (i < 92160)  { src = wm1;  N = 96;  e = i - 82944; }
    else if (i < 101376) { src = wm2;  N = 96;  e = i - 92160; }
    else return;
    int n = e / 96, k = e % 96;
    wh[i] = (_Float16)src[k * N + n];
}

// ---------------------------------------------------------------------------
// zero the borders of xinh NHWC f16 [b][16][16][96]
// ---------------------------------------------------------------------------
__global__ void __launch_bounds__(256) k_zb_h(_Float16* __restrict__ xinh)
{
    int i = blockIdx.x * 256 + threadIdx.x;
    if (i >= 128 * 60 * 96) return;
    int b = i / 5760, r = i % 5760;
    int pos = r / 96, ch = r % 96;
    int py, px;
    if      (pos < 16) { py = 0;        px = pos; }
    else if (pos < 32) { py = 15;       px = pos - 16; }
    else if (pos < 46) { py = pos - 31; px = 0; }
    else               { py = pos - 45; px = 15; }
    xinh[((size_t)(b * 256) + py * 16 + px) * 96 + ch] = (_Float16)0.f;
}

// ---------------------------------------------------------------------------
// patch embed GEMM via f16 MFMA (r7, verified)
// ---------------------------------------------------------------------------
__global__ void __launch_bounds__(256) k_patch_mfma(const float* __restrict__ x,
                                                    const float* __restrict__ Wp,
                                                    const float* __restrict__ bp,
                                                    float* __restrict__ out)
{
    __shared__ __align__(16) _Float16 Ah[64 * 136];
    __shared__ __align__(16) _Float16 Wh[96 * 136];
    int t = threadIdx.x;
    int p0 = blockIdx.x * 64;
    int wave = t >> 6, lane = t & 63;
    int lm = lane & 15, quad = lane >> 4;
    f32x4 acc[6];
    #pragma unroll
    for (int nt = 0; nt < 6; ++nt) acc[nt] = (f32x4){0.f, 0.f, 0.f, 0.f};

    for (int kc = 0; kc < 2; ++kc) {
        __syncthreads();
        for (int i = t; i < 512; i += 256) {
            int lp = i >> 3, pyl = i & 7;
            int patch = p0 + lp;
            int b = patch / NPATCH, n = patch % NPATCH;
            int ny = n / 14, nx = n % 14;
            const float4* s4 = (const float4*)(x +
                ((size_t)(b * 224) + ny * 16 + kc * 8 + pyl) * 224 + nx * 16);
            float4 v0 = s4[0], v1 = s4[1], v2 = s4[2], v3 = s4[3];
            half8 h0, h1;
            h0[0]=(_Float16)v0.x; h0[1]=(_Float16)v0.y; h0[2]=(_Float16)v0.z; h0[3]=(_Float16)v0.w;
            h0[4]=(_Float16)v1.x; h0[5]=(_Float16)v1.y; h0[6]=(_Float16)v1.z; h0[7]=(_Float16)v1.w;
            h1[0]=(_Float16)v2.x; h1[1]=(_Float16)v2.y; h1[2]=(_Float16)v2.z; h1[3]=(_Float16)v2.w;
            h1[4]=(_Float16)v3.x; h1[5]=(_Float16)v3.y; h1[6]=(_Float16)v3.z; h1[7]=(_Float16)v3.w;
            *(half8*)&Ah[lp * 136 + pyl * 16]     = h0;
            *(half8*)&Ah[lp * 136 + pyl * 16 + 8] = h1;
        }
        for (int i = t; i < 1536; i += 256) {
            int e = i >> 4, s = i & 15;
            const float4* s4 = (const float4*)(Wp + e * 256 + kc * 128 + s * 8);
            float4 v0 = s4[0], v1 = s4[1];
            half8 h0;
            h0[0]=(_Float16)v0.x; h0[1]=(_Float16)v0.y; h0[2]=(_Float16)v0.z; h0[3]=(_Float16)v0.w;
            h0[4]=(_Float16)v1.x; h0[5]=(_Float16)v1.y; h0[6]=(_Float16)v1.z; h0[7]=(_Float16)v1.w;
            *(half8*)&Wh[e * 136 + s * 8] = h0;
        }
        __syncthreads();
        half8 af[4];
        #pragma unroll
        for (int ks = 0; ks < 4; ++ks)
            af[ks] = *(const half8*)&Ah[(wave * 16 + lm) * 136 + ks * 32 + quad * 8];
        #pragma unroll
        for (int ks = 0; ks < 4; ++ks) {
            #pragma unroll
            for (int nt = 0; nt < 6; ++nt) {
                half8 bf = *(const half8*)&Wh[(nt * 16 + lm) * 136 + ks * 32 + quad * 8];
                acc[nt] = __builtin_amdgcn_mfma_f32_16x16x32_f16(af[ks], bf, acc[nt], 0, 0, 0);
            }
        }
    }

    #pragma unroll
    for (int nt = 0; nt < 6; ++nt) {
        #pragma unroll
        for (int r = 0; r < 4; ++r) {
            int e = nt * 16 + lm;
            int lp = wave * 16 + quad * 4 + r;
            int patch = p0 + lp;
            int n = patch % NPATCH;
            int ny = n / 14, nx = n % 14;
            float yx = (float)(ny + nx);
            float v = acc[nt][r] + bp[e];
            float other = __shfl_xor(v, 1);
            float fi = (float)(e >> 1);
            float theta = expf(fi * (-2.f / 96.f) * 9.210340371976184f);
            float ang = theta * yx;
            float c = cosf(ang), s = sinf(ang);
            float outv = (lm & 1) ? (other * s + v * c) : (v * c - other * s);
            out[(size_t)patch * 96 + e] = outv;
        }
    }
}

// ---------------------------------------------------------------------------
// row LayerNorm over 96, wave per row — writes f16.
// ---------------------------------------------------------------------------
__global__ void __launch_bounds__(256) k_ln_row(const float* __restrict__ x,
                                                const float* __restrict__ g,
                                                const float* __restrict__ bv,
                                                _Float16* __restrict__ out, int M)
{
    int lane = threadIdx.x & 63;
    int gw = (blockIdx.x * 256 + threadIdx.x) >> 6;
    int nw = (gridDim.x * 256) >> 6;
    float g0 = g[lane], b0 = bv[lane];
    float g1 = 0.f, b1 = 0.f;
    if (lane < 32) { g1 = g[64 + lane]; b1 = bv[64 + lane]; }
    for (int r = gw; r < M; r += nw) {
        const float* xr = x + (size_t)r * 96;
        float a = xr[lane];
        float c = (lane < 32) ? xr[64 + lane] : 0.f;
        float s = a + c, q = a * a + c * c;
        #pragma unroll
        for (int off = 32; off; off >>= 1) {
            s += __shfl_xor(s, off);
            q += __shfl_xor(q, off);
        }
        float mu = s * (1.f / 96.f);
        float rstd = rsqrtf(q * (1.f / 96.f) - mu * mu + 1e-5f);
        _Float16* orow = out + (size_t)r * 96;
        orow[lane] = (_Float16)((a - mu) * rstd * g0 + b0);
        if (lane < 32) orow[64 + lane] = (_Float16)((c - mu) * rstd * g1 + b1);
    }
}

// ---------------------------------------------------------------------------
// MFMA row GEMM (r15, verified). AHALF: A f16. OUTMODE: 0=fp32, 1=f16.
// Chunks over blockIdx.y.
// ---------------------------------------------------------------------------
template<int NCHUNKS, int OUTMODE, bool SILU, bool RES, bool ADDTIME, bool AHALF>
__global__ void __launch_bounds__(256) k_gemm_mfma(const void* __restrict__ A,
                                                   const _Float16* __restrict__ Wt,
                                                   const float* __restrict__ bias,
                                                   const float* __restrict__ res,
                                                   const float* __restrict__ timev,
                                                   void* __restrict__ outp)
{
    __shared__ __align__(16) _Float16 Ah[64 * 96];
    __shared__ __align__(16) _Float16 Wh[96 * 96];
    constexpr int NTOT = NCHUNKS * 96;
    int t = threadIdx.x;
    size_t row0 = (size_t)blockIdx.x * 64;

    if constexpr (AHALF) {
        const uint4* a4 = (const uint4*)((const _Float16*)A + row0 * 96);
        uint4* dst = (uint4*)Ah;
        for (int i = t; i < 768; i += 256) dst[i] = a4[i];
    } else {
        const float4* a4 = (const float4*)((const float*)A + row0 * 96);
        for (int i = t; i < 1536; i += 256) {
            float4 v = a4[i];
            half4v hv;
            hv[0] = (_Float16)v.x; hv[1] = (_Float16)v.y;
            hv[2] = (_Float16)v.z; hv[3] = (_Float16)v.w;
            *(half4v*)&Ah[i * 4] = hv;
        }
    }

    int wave = t >> 6, lane = t & 63;
    int lm = lane & 15, quad = lane >> 4;
    const f32x4 vzero = {0.f, 0.f, 0.f, 0.f};

    for (int ch = blockIdx.y; ch < NCHUNKS; ch += gridDim.y) {
        __syncthreads();
        {
            const uint4* src = (const uint4*)(Wt + (size_t)ch * 9216);
            uint4* dst = (uint4*)Wh;
            for (int i = t; i < 1152; i += 256) dst[i] = src[i];
        }
        __syncthreads();

        half8 af[3];
        #pragma unroll
        for (int ks = 0; ks < 3; ++ks)
            af[ks] = *(const half8*)&Ah[(wave * 16 + lm) * 96 + ks * 32 + quad * 8];

        f32x4 acc[6];
        #pragma unroll
        for (int ct = 0; ct < 6; ++ct) acc[ct] = vzero;

        #pragma unroll
        for (int ct = 0; ct < 6; ++ct) {
            #pragma unroll
            for (int ks = 0; ks < 3; ++ks) {
                half8 bf = *(const half8*)&Wh[(ct * 16 + lm) * 96 + ks * 32 + quad * 8];
                acc[ct] = __builtin_amdgcn_mfma_f32_16x16x32_f16(af[ks], bf, acc[ct], 0, 0, 0);
            }
        }

        #pragma unroll
        for (int ct = 0; ct < 6; ++ct) {
            #pragma unroll
            for (int r = 0; r < 4; ++r) {
                int lr = wave * 16 + quad * 4 + r;
                size_t row = row0 + lr;
                int lc = ct * 16 + lm;
                int col = ch * 96 + lc;
                float v = acc[ct][r] + bias[col];
                if constexpr (RES)     v += res[row * 96 + lc];
                if constexpr (ADDTIME) v += timev[lc];
                if constexpr (SILU)    v = v / (1.f + __expf(-v));
                if constexpr (OUTMODE == 0) {
                    ((float*)outp)[row * NTOT + col] = v;
                } else {
                    ((_Float16*)outp)[row * NTOT + col] = (_Float16)v;
                }
            }
        }
    }
}

// ---------------------------------------------------------------------------
// fused MLP (r15, verified): 3 chained 96x96 GEMMs + silu, one kernel.
// ---------------------------------------------------------------------------
__global__ void __launch_bounds__(256) k_mlp_fused(const float* __restrict__ A,
                                                   const _Float16* __restrict__ W,
                                                   const float* __restrict__ b0,
                                                   const float* __restrict__ b1,
                                                   const float* __restrict__ b2,
                                                   _Float16* __restrict__ outh)
{
    __shared__ __align__(16) _Float16 Ah[2][64 * 96];
    __shared__ __align__(16) _Float16 Wh[3][96 * 96];
    int t = threadIdx.x;
    size_t row0 = (size_t)blockIdx.x * 64;

    const float4* a4 = (const float4*)(A + row0 * 96);
    for (int i = t; i < 1536; i += 256) {
        float4 v = a4[i];
        half4v hv;
        hv[0] = (_Float16)v.x; hv[1] = (_Float16)v.y;
        hv[2] = (_Float16)v.z; hv[3] = (_Float16)v.w;
        *(half4v*)&Ah[0][i * 4] = hv;
    }
    {
        const uint4* src = (const uint4*)W;
        uint4* dst = (uint4*)&Wh[0][0];
        for (int i = t; i < 3456; i += 256) dst[i] = src[i];
    }

    int wave = t >> 6, lane = t & 63;
    int lm = lane & 15, quad = lane >> 4;
    const float* biases[3] = { b0, b1, b2 };
    int cur = 0;

    #pragma unroll
    for (int s = 0; s < 3; ++s) {
        __syncthreads();
        half8 af[3];
        #pragma unroll
        for (int ks = 0; ks < 3; ++ks)
            af[ks] = *(const half8*)&Ah[cur][(wave * 16 + lm) * 96 + ks * 32 + quad * 8];

        f32x4 acc[6];
        #pragma unroll
        for (int ct = 0; ct < 6; ++ct) acc[ct] = (f32x4){0.f, 0.f, 0.f, 0.f};

        #pragma unroll
        for (int ct = 0; ct < 6; ++ct) {
            #pragma unroll
            for (int ks = 0; ks < 3; ++ks) {
                half8 bf = *(const half8*)&Wh[s][(ct * 16 + lm) * 96 + ks * 32 + quad * 8];
                acc[ct] = __builtin_amdgcn_mfma_f32_16x16x32_f16(af[ks], bf, acc[ct], 0, 0, 0);
            }
        }

        const float* bias = biases[s];
        if (s < 2) {
            #pragma unroll
            for (int ct = 0; ct < 6; ++ct) {
                #pragma unroll
                for (int r = 0; r < 4; ++r) {
                    int lr = wave * 16 + quad * 4 + r;
                    int lc = ct * 16 + lm;
                    float v = acc[ct][r] + bias[lc];
                    v = v / (1.f + __expf(-v));
                    Ah[cur ^ 1][lr * 96 + lc] = (_Float16)v;
                }
            }
            cur ^= 1;
        } else {
            #pragma unroll
            for (int ct = 0; ct < 6; ++ct) {
                #pragma unroll
                for (int r = 0; r < 4; ++r) {
                    int lr = wave * 16 + quad * 4 + r;
                    size_t row = row0 + lr;
                    int lc = ct * 16 + lm;
                    float v = acc[ct][r] + bias[lc];
                    v = v / (1.f + __expf(-v));
                    size_t b = row / NPATCH; int n = (int)(row % NPATCH);
                    int ny = n / 14, nx = n % 14;
                    outh[((b * 256) + (1 + ny) * 16 + (1 + nx)) * 96 + lc] = (_Float16)v;
                }
            }
        }
    }
}

// ---------------------------------------------------------------------------
// MFMA attention (r11 structure): qkv input f16, output f16.
// ---------------------------------------------------------------------------
__global__ void __launch_bounds__(256) k_attn_mfma(const _Float16* __restrict__ qkv,
                                                   _Float16* __restrict__ o)
{
    __shared__ __align__(16) _Float16 Qs[208 * 40];
    __shared__ __align__(16) _Float16 Ks[208 * 40];
    __shared__ __align__(16) _Float16 Vt[32 * 232];
    __shared__ __align__(16) _Float16 Pw[4][16 * 232];

    int t = threadIdx.x;
    int bh = blockIdx.x;
    int b = bh >> 2, h = bh & 3;
    const _Float16* base = qkv + (size_t)b * NPATCH * 288 + h * 24;

    {
        const int4 z = {0, 0, 0, 0};
        int4* q4 = (int4*)Qs; int4* k4 = (int4*)Ks;
        for (int i = t; i < 1040; i += 256) { q4[i] = z; k4[i] = z; }
        int4* v4 = (int4*)Vt;
        for (int i = t; i < 928; i += 256) v4[i] = z;
        int4* p4 = (int4*)&Pw[0][0];
        for (int i = t; i < 1856; i += 256) p4[i] = z;
    }
    __syncthreads();

    for (int i = t; i < NPATCH * 24; i += 256) {
        int r = i / 24, d = i % 24;
        const _Float16* row = base + (size_t)r * 288;
        Qs[r * 40 + d]   = row[d];
        Ks[r * 40 + d]   = row[96 + d];
        Vt[d * 232 + r]  = row[192 + d];
    }
    __syncthreads();

    int wave = t >> 6, lane = t & 63;
    int lm = lane & 15, quad = lane >> 4;
    const float scale = 0.2041241452319315f;

    half8 bk[13];
    #pragma unroll
    for (int ct = 0; ct < 13; ++ct)
        bk[ct] = *(const half8*)&Ks[(ct * 16 + lm) * 40 + quad * 8];

    _Float16* pw = &Pw[wave][0];

    for (int rt = wave; rt < 13; rt += 4) {
        half8 aq = *(const half8*)&Qs[(rt * 16 + lm) * 40 + quad * 8];
        float rsum[4] = {0.f, 0.f, 0.f, 0.f};

        #pragma unroll
        for (int ct = 0; ct < 13; ++ct) {
            f32x4 s = (f32x4){0.f, 0.f, 0.f, 0.f};
            s = __builtin_amdgcn_mfma_f32_16x16x32_f16(aq, bk[ct], s, 0, 0, 0);
            #pragma unroll
            for (int r = 0; r < 4; ++r) {
                float p = __expf(fminf(s[r] * scale, 60.f));
                if (ct == 12 && lm >= 4) p = 0.f;   // keys 196..207 invalid
                rsum[r] += p;
                pw[(quad * 4 + r) * 232 + ct * 16 + lm] = (_Float16)p;
            }
        }

        #pragma unroll
        for (int r = 0; r < 4; ++r) {
            float s = rsum[r];
            s += __shfl_xor(s, 1);
            s += __shfl_xor(s, 2);
            s += __shfl_xor(s, 4);
            s += __shfl_xor(s, 8);
            rsum[r] = 1.f / s;
        }

        f32x4 ov0 = (f32x4){0.f, 0.f, 0.f, 0.f};
        f32x4 ov1 = (f32x4){0.f, 0.f, 0.f, 0.f};
        #pragma unroll
        for (int ks = 0; ks < 7; ++ks) {
            half8 ap = *(const half8*)&pw[lm * 232 + ks * 32 + quad * 8];
            half8 bv0 = *(const half8*)&Vt[(lm) * 232 + ks * 32 + quad * 8];
            half8 bv1 = *(const half8*)&Vt[(16 + lm) * 232 + ks * 32 + quad * 8];
            ov0 = __builtin_amdgcn_mfma_f32_16x16x32_f16(ap, bv0, ov0, 0, 0, 0);
            ov1 = __builtin_amdgcn_mfma_f32_16x16x32_f16(ap, bv1, ov1, 0, 0, 0);
        }

        #pragma unroll
        for (int r = 0; r < 4; ++r) {
            int row = rt * 16 + quad * 4 + r;
            if (row < NPATCH) {
                _Float16* orow = o + ((size_t)b * NPATCH + row) * 96 + h * 24;
                orow[lm] = (_Float16)(ov0[r] * rsum[r]);
                if (lm < 8) orow[16 + lm] = (_Float16)(ov1[r] * rsum[r]);
            }
        }
    }
}

// ---------------------------------------------------------------------------
// conv L1, tile-resident + fused LN partial stats. C1 f16 NHWC out.
// pstat1[b*96 + ch*2 + {0,1}] accumulated via LDS bins + global atomics.
// ---------------------------------------------------------------------------
__global__ void __launch_bounds__(256) k_conv1_tile(const _Float16* __restrict__ xinh,
                                                    const _Float16* __restrict__ wc,
                                                    const float* __restrict__ bias,
                                                    _Float16* __restrict__ c1,
                                                    float* __restrict__ pstat1)
{
    __shared__ __align__(16) _Float16 Xs[4 * 16 * 104];   // 13.3 KB
    __shared__ float bins[96];
    int t = threadIdx.x;
    int blk = blockIdx.x;
    int b = blk / 7, s = blk % 7;        // output pixel rows 4s..4s+3

    if (t < 96) bins[t] = 0.f;

    for (int i = t; i < 768; i += 256) {
        int r = i / 192, rem = i % 192;
        int c = rem / 12, ch = (rem % 12) * 8;
        *(uint4*)&Xs[(r * 16 + c) * 104 + ch] =
            *(const uint4*)(xinh + ((size_t)(b * 256) + (2 * s + r) * 16 + c) * 96 + ch);
    }

    int wave = t >> 6, lane = t & 63;
    int lm = lane & 15, quad = lane >> 4;
    int ry = wave >> 1, rx = wave & 1;   // parity per wave

    __syncthreads();

    for (int nt = 0; nt < 3; ++nt) {
        half8 bf[12];
        #pragma unroll
        for (int ks = 0; ks < 12; ++ks)
            bf[ks] = *(const half8*)&wc[((size_t)(wave * 48 + nt * 16 + lm)) * 384
                                        + ks * 32 + quad * 8];

        float sl = 0.f, ql = 0.f;
        #pragma unroll
        for (int rt = 0; rt < 2; ++rt) {
            int pp = rt * 16 + lm;
            int ppc = pp < 28 ? pp : 27;
            int pyl = ppc / 14, px = ppc % 14;

            half8 af[12];
            #pragma unroll
            for (int ks = 0; ks < 12; ++ks) {
                int k0 = ks * 32 + quad * 8;
                int tap = k0 / 96, off = k0 % 96;
                int dy = tap >> 1, dx = tap & 1;
                af[ks] = *(const half8*)&Xs[((pyl + ry + dy) * 16 + (px + rx + dx)) * 104 + off];
            }

            f32x4 acc = (f32x4){0.f, 0.f, 0.f, 0.f};
            #pragma unroll
            for (int ks = 0; ks < 12; ++ks)
                acc = __builtin_amdgcn_mfma_f32_16x16x32_f16(af[ks], bf[ks], acc, 0, 0, 0);

            #pragma unroll
            for (int r = 0; r < 4; ++r) {
                int pw = rt * 16 + quad * 4 + r;
                if (pw < 28) {
                    int pylw = pw / 14, pxw = pw % 14;
                    int oy = 2 * (2 * s + pylw) + ry, ox = 2 * pxw + rx;
                    float v = acc[r] + bias[nt * 16 + lm];
                    sl += v; ql += v * v;
                    c1[((size_t)(b * 28 + oy) * 28 + ox) * 48 + nt * 16 + lm] = (_Float16)v;
                }
            }
        }
        atomicAdd(&bins[(nt * 16 + lm) * 2],     sl);
        atomicAdd(&bins[(nt * 16 + lm) * 2 + 1], ql);
    }
    __syncthreads();
    if (t < 96) atomicAdd(&pstat1[(size_t)b * 96 + t], bins[t]);
}

// ---------------------------------------------------------------------------
// L1 LN apply, float4-vectorized: f16 NHWC C1 + raw sums -> f16 NHWC padded
// XH2 [b][30][30][48], silu (__expf). grid 5400.
// ---------------------------------------------------------------------------
__global__ void __launch_bounds__(256) k_ln1_apply(const _Float16* __restrict__ c1,
                                                   const float* __restrict__ pstat1,
                                                   const float* __restrict__ g,
                                                   const float* __restrict__ bv,
                                                   _Float16* __restrict__ xh)
{
    int i4 = blockIdx.x * 256 + threadIdx.x;
    int idx = i4 * 4;                                // ((b*900)+pos)*48 + ch
    int ch = idx % 48;
    int t2 = idx / 48;
    int pos = t2 % 900;
    int b = t2 / 900;
    int py = pos / 30, px = pos % 30;
    half4v hv = (half4v){(_Float16)0.f, (_Float16)0.f, (_Float16)0.f, (_Float16)0.f};
    if (py >= 1 && py <= 28 && px >= 1 && px <= 28) {
        int j = (py - 1) * 28 + (px - 1);
        half4v v = *(const half4v*)&c1[((size_t)b * 784 + j) * 48 + ch];
        const float* ps = pstat1 + (size_t)b * 96 + ch * 2;
        float gj = g[j], bj = bv[j];
        #pragma unroll
        for (int k = 0; k < 4; ++k) {
            float mu = ps[2 * k] * (1.f / 784.f);
            float rstd = rsqrtf(ps[2 * k + 1] * (1.f / 784.f) - mu * mu + 1e-5f);
            float u = ((float)v[k] - mu) * rstd * gj + bj;
            hv[k] = (_Float16)(u / (1.f + __expf(-u)));
        }
    }
    *(half4v*)&xh[idx] = hv;
}

// ---------------------------------------------------------------------------
// conv L2, tile-resident + fused LN partial stats. C2 f16 NHWC out.
// ---------------------------------------------------------------------------
__global__ void __launch_bounds__(256) k_conv2_tile(const _Float16* __restrict__ xh,
                                                    const _Float16* __restrict__ wc,
                                                    const float* __restrict__ bias,
                                                    _Float16* __restrict__ c2,
                                                    float* __restrict__ pstat2)
{
    __shared__ __align__(16) _Float16 Xs[4 * 30 * 56];   // 13.1 KB
    __shared__ float bins[48];
    int t = threadIdx.x;
    int blk = blockIdx.x;
    int b = blk / 14, s = blk % 14;      // output rows 4s..4s+3

    if (t < 48) bins[t] = 0.f;

    for (int i = t; i < 720; i += 256) {
        int r = i / 180, rem = i % 180;
        int c = rem / 6, ch = (rem % 6) * 8;
        *(uint4*)&Xs[(r * 30 + c) * 56 + ch] =
            *(const uint4*)(xh + ((size_t)(b * 900) + (2 * s + r) * 30 + c) * 48 + ch);
    }

    int wave = t >> 6, lane = t & 63;
    int lm = lane & 15, quad = lane >> 4;
    int ry = wave >> 1, rx = wave & 1;   // parity per wave

    half8 bf0[6], bf1[6];
    #pragma unroll
    for (int ks = 0; ks < 6; ++ks) {
        bf0[ks] = *(const half8*)&wc[((size_t)(wave * 32 + lm)) * 192 + ks * 32 + quad * 8];
        bf1[ks] = *(const half8*)&wc[((size_t)(wave * 32 + 16 + lm)) * 192 + ks * 32 + quad * 8];
    }

    __syncthreads();

    float s0l = 0.f, q0l = 0.f, s1l = 0.f, q1l = 0.f;
    #pragma unroll
    for (int rt = 0; rt < 4; ++rt) {
        int pp = rt * 16 + lm;
        int ppc = pp < 56 ? pp : 55;
        int pyl = ppc / 28, px = ppc % 28;

        half8 af[6];
        #pragma unroll
        for (int ks = 0; ks < 6; ++ks) {
            int k0 = ks * 32 + quad * 8;
            int tap = k0 / 48, off = k0 % 48;
            int dy = tap >> 1, dx = tap & 1;
            af[ks] = *(const half8*)&Xs[((pyl + ry + dy) * 30 + (px + rx + dx)) * 56 + off];
        }

        f32x4 acc0 = (f32x4){0.f, 0.f, 0.f, 0.f};
        f32x4 acc1 = (f32x4){0.f, 0.f, 0.f, 0.f};
        #pragma unroll
        for (int ks = 0; ks < 6; ++ks) {
            acc0 = __builtin_amdgcn_mfma_f32_16x16x32_f16(af[ks], bf0[ks], acc0, 0, 0, 0);
            acc1 = __builtin_amdgcn_mfma_f32_16x16x32_f16(af[ks], bf1[ks], acc1, 0, 0, 0);
        }

        #pragma unroll
        for (int r = 0; r < 4; ++r) {
            int pw = rt * 16 + quad * 4 + r;
            if (pw < 56) {
                int pylw = pw / 28, pxw = pw % 28;
                int oy = 2 * (2 * s + pylw) + ry, ox = 2 * pxw + rx;
                _Float16* orow = c2 + ((size_t)(b * 56 + oy) * 56 + ox) * 24;
                float v0 = acc0[r] + bias[lm];
                orow[lm] = (_Float16)v0;
                s0l += v0; q0l += v0 * v0;
                if (lm < 8) {
                    float v1 = acc1[r] + bias[16 + lm];
                    orow[16 + lm] = (_Float16)v1;
                    s1l += v1; q1l += v1 * v1;
                }
            }
        }
    }
    atomicAdd(&bins[lm * 2],     s0l);
    atomicAdd(&bins[lm * 2 + 1], q0l);
    if (lm < 8) {
        atomicAdd(&bins[(16 + lm) * 2],     s1l);
        atomicAdd(&bins[(16 + lm) * 2 + 1], q1l);
    }
    __syncthreads();
    if (t < 48) atomicAdd(&pstat2[(size_t)b * 48 + t], bins[t]);
}

// ---------------------------------------------------------------------------
// L2 LN apply, float4-vectorized: f16 C2 + raw sums -> f16 NHWC padded XH3
// [b][58][58][24], silu (__expf). grid 10092.
// ---------------------------------------------------------------------------
__global__ void __launch_bounds__(256) k_ln2_apply(const _Float16* __restrict__ c2,
                                                   const float* __restrict__ pstat2,
                                                   const float* __restrict__ g,
                                                   const float* __restrict__ bv,
                                                   _Float16* __restrict__ xh)
{
    int i4 = blockIdx.x * 256 + threadIdx.x;
    int idx = i4 * 4;                                // ((b*3364)+pos)*24 + ch
    int ch = idx % 24;
    int t2 = idx / 24;
    int pos = t2 % 3364;
    int b = t2 / 3364;
    int py = pos / 58, px = pos % 58;
    half4v hv = (half4v){(_Float16)0.f, (_Float16)0.f, (_Float16)0.f, (_Float16)0.f};
    if (py >= 1 && py <= 56 && px >= 1 && px <= 56) {
        int j = (py - 1) * 56 + (px - 1);
        half4v v = *(const half4v*)&c2[((size_t)b * 3136 + j) * 24 + ch];
        const float* ps = pstat2 + (size_t)b * 48 + ch * 2;
        float gj = g[j], bj = bv[j];
        #pragma unroll
        for (int k = 0; k < 4; ++k) {
            float mu = ps[2 * k] * (1.f / 3136.f);
            float rstd = rsqrtf(ps[2 * k + 1] * (1.f / 3136.f) - mu * mu + 1e-5f);
            float u = ((float)v[k] - mu) * rstd * gj + bj;
            hv[k] = (_Float16)(u / (1.f + __expf(-u)));
        }
    }
    *(half4v*)&xh[idx] = hv;
}

// ---------------------------------------------------------------------------
// conv L3, tile-resident + fused LN partial stats. C3 f16 NHWC out.
// ---------------------------------------------------------------------------
__global__ void __launch_bounds__(256) k_conv3_tile(const _Float16* __restrict__ xh,
                                                    const _Float16* __restrict__ wc,
                                                    const float* __restrict__ bias,
                                                    _Float16* __restrict__ c3,
                                                    float* __restrict__ pstat3)
{
    __shared__ __align__(16) _Float16 Xs[3 * 58 * 40];   // 13.6 KB
    __shared__ float bins[24];
    int t = threadIdx.x;
    int blk = blockIdx.x;
    int b = blk / 56, s = blk % 56;     // output rows 2s, 2s+1

    if (t < 24) bins[t] = 0.f;

    for (int i = t; i < 522; i += 256) {
        int r = i / 174, rem = i % 174;
        int c = rem / 3, ch = (rem % 3) * 8;
        *(uint4*)&Xs[(r * 58 + c) * 40 + ch] =
            *(const uint4*)(xh + ((size_t)(b * 3364) + (s + r) * 58 + c) * 24 + ch);
    }

    int wave = t >> 6, lane = t & 63;
    int lm = lane & 15, quad = lane >> 4;
    int ry = wave >> 1, rx = wave & 1;

    half8 bf[3];
    #pragma unroll
    for (int ks = 0; ks < 3; ++ks)
        bf[ks] = *(const half8*)&wc[((size_t)(wave * 16 + lm)) * 96 + ks * 32 + quad * 8];

    __syncthreads();

    float sl = 0.f, ql = 0.f;
    #pragma unroll
    for (int rt = 0; rt < 4; ++rt) {
        int px = rt * 16 + lm;
        int pxc = px < 56 ? px : 55;

        half8 af[3];
        #pragma unroll
        for (int ks = 0; ks < 3; ++ks) {
            int k0 = ks * 32 + quad * 8;
            int tap = k0 / 24, off = k0 % 24;
            int dy = tap >> 1, dx = tap & 1;
            af[ks] = *(const half8*)&Xs[((ry + dy) * 58 + (pxc + rx + dx)) * 40 + off];
        }

        f32x4 acc = (f32x4){0.f, 0.f, 0.f, 0.f};
        #pragma unroll
        for (int ks = 0; ks < 3; ++ks)
            acc = __builtin_amdgcn_mfma_f32_16x16x32_f16(af[ks], bf[ks], acc, 0, 0, 0);

        if (lm < 12) {
            #pragma unroll
            for (int r = 0; r < 4; ++r) {
                int pw = rt * 16 + quad * 4 + r;
                if (pw < 56) {
                    int oy = 2 * s + ry, ox = 2 * pw + rx;
                    float v = acc[r] + bias[lm];
                    sl += v; ql += v * v;
                    c3[((size_t)(b * 112 + oy) * 112 + ox) * 12 + lm] = (_Float16)v;
                }
            }
        }
    }
    if (lm < 12) {
        atomicAdd(&bins[lm * 2],     sl);
        atomicAdd(&bins[lm * 2 + 1], ql);
    }
    __syncthreads();
    if (t < 24) atomicAdd(&pstat3[(size_t)b * 24 + t], bins[t]);
}

// ---------------------------------------------------------------------------
// L3 LN apply, float4-vectorized: f16 C3 + raw sums -> f16 NHWC xh4
// [b][112][112][12], silu (__expf). grid 18816.
// ---------------------------------------------------------------------------
__global__ void __launch_bounds__(256) k_ln3_apply(const _Float16* __restrict__ c3,
                                                   const float* __restrict__ pstat3,
                                                   const float* __restrict__ g,
                                                   const float* __restrict__ bv,
                                                   _Float16* __restrict__ xh4)
{
    int i4 = blockIdx.x * 256 + threadIdx.x;
    int idx = i4 * 4;
    int ch = idx % 12;                               // 0, 4, 8
    int t2 = idx / 12;
    int pix = t2 % 12544;
    int b = t2 / 12544;
    half4v v = *(const half4v*)&c3[idx];
    const float* ps = pstat3 + (size_t)b * 24 + ch * 2;
    float gp = g[pix], bp = bv[pix];
    half4v hv;
    #pragma unroll
    for (int k = 0; k < 4; ++k) {
        float mu = ps[2 * k] * (1.f / 12544.f);
        float rstd = rsqrtf(ps[2 * k + 1] * (1.f / 12544.f) - mu * mu + 1e-5f);
        float u = ((float)v[k] - mu) * rstd * gp + bp;
        hv[k] = (_Float16)(u / (1.f + __expf(-u)));
    }
    *(half4v*)&xh4[idx] = hv;
}

// ---------------------------------------------------------------------------
// final convT 12->1, f16 NHWC input (xh4).
// ---------------------------------------------------------------------------
__global__ void __launch_bounds__(256) k_conv_final_nhwc(const _Float16* __restrict__ x,
                                                         const float* __restrict__ wr,
                                                         const float* __restrict__ bias,
                                                         float* __restrict__ out)
{
    constexpr int HIN = 112, CIN = 12;
    constexpr int NPB = (B_ * HIN * HIN) / 256;   // 6272
    int pb = blockIdx.x % NPB;
    int ry = blockIdx.x / NPB;
    int rem = pb * 256 + threadIdx.x;
    int b   = rem / (HIN * HIN);
    int pix = rem % (HIN * HIN);
    int py = pix / HIN, px = pix % HIN;
    int r0 = py + ry - 1, r1 = r0 + 1;
    const _Float16* xb = x + (size_t)b * (HIN * HIN * CIN);

    int   rows[2] = { r0, r1 };
    bool  rm[2]   = { r0 >= 0, r1 < HIN };
    int   cols[3] = { px - 1, px, px + 1 };
    bool  cm[3]   = { px >= 1, true, px + 1 < HIN };

    float gv[6][12];
    #pragma unroll
    for (int a = 0; a < 2; ++a) {
        #pragma unroll
        for (int cc = 0; cc < 3; ++cc) {
            int gi = a * 3 + cc;
            if (rm[a] && cm[cc]) {
                const _Float16* p = xb + ((size_t)(rows[a] * HIN + cols[cc])) * CIN;
                half4v h0 = *(const half4v*)&p[0];
                half4v h1 = *(const half4v*)&p[4];
                half4v h2 = *(const half4v*)&p[8];
                #pragma unroll
                for (int j = 0; j < 4; ++j) {
                    gv[gi][j]     = (float)h0[j];
                    gv[gi][4 + j] = (float)h1[j];
                    gv[gi][8 + j] = (float)h2[j];
                }
            } else {
                #pragma unroll
                for (int j = 0; j < 12; ++j) gv[gi][j] = 0.f;
            }
        }
    }

    const float4* w4 = (const float4*)wr;
    float acc0 = 0.f, acc1 = 0.f;
    #pragma unroll
    for (int ci = 0; ci < CIN; ++ci) {
        float4 W0 = w4[(2 * ry) * CIN + ci];
        float4 W1 = w4[(2 * ry + 1) * CIN + ci];
        acc0 += gv[0][ci] * W0.x + gv[1][ci] * W0.y + gv[3][ci] * W0.z + gv[4][ci] * W0.w;
        acc1 += gv[1][ci] * W1.x + gv[2][ci] * W1.y + gv[4][ci] * W1.z + gv[5][ci] * W1.w;
    }

    float bb = bias[0];
    float u0 = acc0 + bb, u1 = acc1 + bb;
    u0 = u0 / (1.f + __expf(-u0));
    u1 = u1 / (1.f + __expf(-u1));
    float2 v;
    v.x = fminf(fmaxf(u0, 0.f), 1.f);
    v.y = fminf(fmaxf(u1, 0.f), 1.f);
    int oy = 2 * py + ry;
    *(float2*)(out + (size_t)b * 50176 + oy * 224 + 2 * px) = v;
}

// ---------------------------------------------------------------------------
// launch
// ---------------------------------------------------------------------------
extern "C" void kernel_launch(void* const* d_in, const int* in_sizes, int n_in,
                              void* d_out, int out_size, void* d_ws, size_t ws_size,
                              hipStream_t stream)
{
    const float* x       = (const float*)d_in[0];
    const float* ts      = (const float*)d_in[1];
    const float* Wp      = (const float*)d_in[2];
    const float* bp      = (const float*)d_in[3];
    const float* Wt1     = (const float*)d_in[4];
    const float* bt1     = (const float*)d_in[5];
    const float* Wt2     = (const float*)d_in[6];
    const float* bt2     = (const float*)d_in[7];
    const float* a0_g    = (const float*)d_in[8];
    const float* a0_b    = (const float*)d_in[9];
    const float* a0_Wqkv = (const float*)d_in[10];
    const float* a0_bqkv = (const float*)d_in[11];
    const float* a0_Wo   = (const float*)d_in[12];
    const float* a0_bo   = (const float*)d_in[13];
    const float* a1_g    = (const float*)d_in[14];
    const float* a1_b    = (const float*)d_in[15];
    const float* a1_Wqkv = (const float*)d_in[16];
    const float* a1_bqkv = (const float*)d_in[17];
    const float* a1_Wo   = (const float*)d_in[18];
    const float* a1_bo   = (const float*)d_in[19];
    const float* Wm0     = (const float*)d_in[20];
    const float* bm0     = (const float*)d_in[21];
    const float* Wm1     = (const float*)d_in[22];
    const float* bm1     = (const float*)d_in[23];
    const float* Wm2     = (const float*)d_in[24];
    const float* bm2     = (const float*)d_in[25];
    const float* Wd1     = (const float*)d_in[26];
    const float* bd1     = (const float*)d_in[27];
    const float* l1g     = (const float*)d_in[28];
    const float* l1b     = (const float*)d_in[29];
    const float* Wd2     = (const float*)d_in[30];
    const float* bd2     = (const float*)d_in[31];
    const float* l2g     = (const float*)d_in[32];
    const float* l2b     = (const float*)d_in[33];
    const float* Wd3     = (const float*)d_in[34];
    const float* bd3     = (const float*)d_in[35];
    const float* l3g     = (const float*)d_in[36];
    const float* l3b     = (const float*)d_in[37];
    const float* Wd4     = (const float*)d_in[38];
    const float* bd4     = (const float*)d_in[39];
    float* out = (float*)d_out;

    // arena (floats); R = 25088*96
    const size_t R = 2408448;
    float* ws   = (float*)d_ws;
    float* tvec = ws;                          // 96
    float* p0   = ws + 512;                    // R
    _Float16* hh   = (_Float16*)(ws + 512 + R);       // f16 LN out (h region)
    _Float16* qkvh = (_Float16*)(ws + 512 + 2 * R);   // f16 qkv [M][288] (qkv region)
    _Float16* obh  = (_Float16*)(ws + 512 + 5 * R);   // f16 attn out (ob region)
    float* p1   = ws + 512 + 6 * R;            // R
    // decoder aliases:
    _Float16* xinh = (_Float16*)(ws + 512 + 2 * R);   // f16 NHWC (qkv region)
    _Float16* C1h  = (_Float16*)(ws + 512 + 5 * R);   // f16 NHWC [b][28][28][48] (ob region)
    _Float16* xh2  = (_Float16*)(ws + 512 + 7 * R);   // f16 NHWC padded [b][30][30][48]
    _Float16* C2h  = (_Float16*)(ws + 512);           // f16 NHWC [b][56][56][24] (p0+h regions)
    _Float16* xh3  = (_Float16*)(ws + 512 + 7 * R + 5529600); // f16 NHWC padded [b][58][58][24]
    _Float16* C3h  = (_Float16*)(ws + 512);           // f16 NHWC [b][112][112][12] (p0..qkv)
    _Float16* xh4  = (_Float16*)(ws + 512 + 7 * R + 5529600); // f16 NHWC [b][112][112][12] (reuses xh3)
    float* Wr   = ws + 512 + 7 * R + 5529600 + 10334208;  // 96,960 floats
    _Float16* WH = (_Float16*)(Wr + 96960);                // 101,376 halves
    _Float16* Wc  = (_Float16*)Wr;              // conv1 f16 B-weights (dead L1 slice)
    _Float16* Wc2 = (_Float16*)(Wr + 36864);    // conv2 f16 B-weights
    _Float16* Wc3 = (_Float16*)(Wr + 49152);    // conv3 f16 B-weights
    float* stat = Wr + 96960 + 50688;          // 21,504 floats (raw LN sums)
    float* stat1 = stat;                       // 128*96
    float* stat2 = stat + 12288;               // 128*48
    float* stat3 = stat + 18432;               // 128*24
    const size_t NEED = (512 + 7 * R + 5529600 + 10334208 + 96960 + 50688 + 21504 + 16)
                        * sizeof(float);
    if (ws_size < NEED) return;

    _Float16* WHqkv0 = WH;
    _Float16* WHqkv1 = WH + 27648;
    _Float16* WHwo0  = WH + 55296;
    _Float16* WHwo1  = WH + 64512;
    _Float16* WHwm0  = WH + 73728;   // wm0,wm1,wm2 consecutive (27648 halves)

    k_time<<<1, 128, 0, stream>>>(ts, Wt1, bt1, Wt2, bt2, tvec);
    k_zstat<<<84, 256, 0, stream>>>(stat);
    k_repack<<<379, 256, 0, stream>>>(Wd1, Wd2, Wd3, Wd4, Wr);
    k_wcvtc<<<288, 256, 0, stream>>>(Wd1, Wc);
    k_wcvt2<<<96, 256, 0, stream>>>(Wd2, Wc2);
    k_wcvt3<<<24, 256, 0, stream>>>(Wd3, Wc3);
    k_wcvt<<<396, 256, 0, stream>>>(a0_Wqkv, a1_Wqkv, a0_Wo, a1_Wo,
                                    Wm0, Wm1, Wm2, WH);
    k_patch_mfma<<<M_ROWS / 64, 256, 0, stream>>>(x, Wp, bp, p0);

    // MHSA block 0
    k_ln_row<<<1024, 256, 0, stream>>>(p0, a0_g, a0_b, hh, M_ROWS);
    k_gemm_mfma<3, 1, false, false, false, true><<<dim3(M_ROWS / 64, 3), 256, 0, stream>>>(
        hh, WHqkv0, a0_bqkv, nullptr, nullptr, qkvh);
    k_attn_mfma<<<B_ * 4, 256, 0, stream>>>(qkvh, obh);
    k_gemm_mfma<1, 0, false, true, false, true><<<dim3(M_ROWS / 64, 1), 256, 0, stream>>>(
        obh, WHwo0, a0_bo, p0, nullptr, p1);

    // MHSA block 1 (+time)
    k_ln_row<<<1024, 256, 0, stream>>>(p1, a1_g, a1_b, hh, M_ROWS);
    k_gemm_mfma<3, 1, false, false, false, true><<<dim3(M_ROWS / 64, 3), 256, 0, stream>>>(
        hh, WHqkv1, a1_bqkv, nullptr, nullptr, qkvh);
    k_attn_mfma<<<B_ * 4, 256, 0, stream>>>(qkvh, obh);
    k_gemm_mfma<1, 0, false, true, true, true><<<dim3(M_ROWS / 64, 1), 256, 0, stream>>>(
        obh, WHwo1, a1_bo, p1, tvec, p0);

    // qkv region free: zero xinh borders before MLP writes interior
    k_zb_h<<<2880, 256, 0, stream>>>(xinh);

    // fused MLP x3 (silu); writes f16 NHWC padded xinh
    k_mlp_fused<<<M_ROWS / 64, 256, 0, stream>>>(p0, WHwm0, bm0, bm1, bm2, xinh);

    // decoder: all-NHWC f16 chain, tile-resident convs with fused LN stats
    k_conv1_tile<<<B_ * 7, 256, 0, stream>>>(xinh, Wc, bd1, C1h, stat1);
    k_ln1_apply<<<5400, 256, 0, stream>>>(C1h, stat1, l1g, l1b, xh2);
    k_conv2_tile<<<B_ * 14, 256, 0, stream>>>(xh2, Wc2, bd2, C2h, stat2);
    k_ln2_apply<<<10092, 256, 0, stream>>>(C2h, stat2, l2g, l2b, xh3);
    k_conv3_tile<<<B_ * 56, 256, 0, stream>>>(xh3, Wc3, bd3, C3h, stat3);
    k_ln3_apply<<<18816, 256, 0, stream>>>(C3h, stat3, l3g, l3b, xh4);
    k_conv_final_nhwc<<<2 * 6272, 256, 0, stream>>>(xh4, Wr + 96768, bd4, out);
}